// Round 2
// baseline (3241.912 us; speedup 1.0000x reference)
//
#include <hip/hip_runtime.h>
#include <cmath>
#include <cstdint>

#define D_MODEL 512
#define NH 8
#define DH 64

static inline int ceil_div(int a, int b) { return (a + b - 1) / b; }

// ---------------- threefry2x32 (JAX-exact) ----------------
#define TF_ROTL(x, r) (((x) << (r)) | ((x) >> (32 - (r))))

__host__ __device__ inline void threefry2x32(uint32_t k0, uint32_t k1,
                                             uint32_t x0, uint32_t x1,
                                             uint32_t* o0, uint32_t* o1) {
  uint32_t ks2 = k0 ^ k1 ^ 0x1BD11BDAu;
  x0 += k0; x1 += k1;
#define TF_R4(a, b, c, d)                                    \
  x0 += x1; x1 = TF_ROTL(x1, a); x1 ^= x0;                   \
  x0 += x1; x1 = TF_ROTL(x1, b); x1 ^= x0;                   \
  x0 += x1; x1 = TF_ROTL(x1, c); x1 ^= x0;                   \
  x0 += x1; x1 = TF_ROTL(x1, d); x1 ^= x0;
  TF_R4(13, 15, 26, 6);  x0 += k1;  x1 += ks2 + 1u;
  TF_R4(17, 29, 16, 24); x0 += ks2; x1 += k0 + 2u;
  TF_R4(13, 15, 26, 6);  x0 += k0;  x1 += k1 + 3u;
  TF_R4(17, 29, 16, 24); x0 += k1;  x1 += ks2 + 4u;
  TF_R4(13, 15, 26, 6);  x0 += ks2; x1 += k0 + 5u;
#undef TF_R4
  *o0 = x0; *o1 = x1;
}

__global__ void idx_kernel(int* __restrict__ idx, int L, int U,
                           uint32_t k0, uint32_t k1) {
  int n = blockIdx.x * 256 + threadIdx.x;
  if (n >= L * U) return;
  uint32_t o0, o1;
  threefry2x32(k0, k1, 0u, (uint32_t)n, &o0, &o1);
  idx[n] = (int)((o0 ^ o1) & (uint32_t)(L - 1));
}

// ---------------- embedding: circular conv (C=2,K=3) + pos encoding -------
__global__ __launch_bounds__(256) void embed_kernel(
    const float* __restrict__ x_enc, const float* __restrict__ emb_w,
    float* __restrict__ x, int B, int L) {
  int i = blockIdx.x * 256 + threadIdx.x;
  int total = B * L * D_MODEL;
  if (i >= total) return;
  int d = i % D_MODEL;
  int l = (i / D_MODEL) % L;
  int b = i / (D_MODEL * L);
  int lm = (l == 0) ? (L - 1) : (l - 1);
  int lp = (l == L - 1) ? 0 : (l + 1);
  const float* w = emb_w + d * 6;
  const float* xb = x_enc + (size_t)b * L * 2;
  float acc = 0.f;
  acc += xb[lm * 2 + 0] * w[0] + xb[l * 2 + 0] * w[1] + xb[lp * 2 + 0] * w[2];
  acc += xb[lm * 2 + 1] * w[3] + xb[l * 2 + 1] * w[4] + xb[lp * 2 + 1] * w[5];
  int j = d >> 1;
  const float coef = -0.017988946039015985f;  // -ln(10000)/512
  float div = expf((float)(2 * j) * coef);
  float ang = (float)l * div;
  float pe = (d & 1) ? cosf(ang) : sinf(ang);
  x[i] = acc + pe;
}

// ---------------- layer norm over D=512 ----------------
__global__ __launch_bounds__(256) void ln_kernel(
    const float* __restrict__ in, const float* __restrict__ g,
    const float* __restrict__ b, float* __restrict__ out) {
  int row = blockIdx.x;
  int t = threadIdx.x;
  const float* xr = in + (size_t)row * D_MODEL;
  float v0 = xr[t], v1 = xr[t + 256];
  __shared__ float red[256];
  red[t] = v0 + v1;
  __syncthreads();
  for (int s = 128; s > 0; s >>= 1) { if (t < s) red[t] += red[t + s]; __syncthreads(); }
  float mean = red[0] * (1.0f / 512.0f);
  __syncthreads();
  float d0 = v0 - mean, d1 = v1 - mean;
  red[t] = d0 * d0 + d1 * d1;
  __syncthreads();
  for (int s = 128; s > 0; s >>= 1) { if (t < s) red[t] += red[t + s]; __syncthreads(); }
  float var = red[0] * (1.0f / 512.0f);
  float rstd = 1.0f / sqrtf(var + 1e-5f);
  float* outr = out + (size_t)row * D_MODEL;
  outr[t]       = d0 * rstd * g[t]       + b[t];
  outr[t + 256] = d1 * rstd * g[t + 256] + b[t + 256];
}

// MODE 0: +bias   1: gelu(+bias)   2: +bias +R   3: elu((+bias)*scl*g + bb)
__device__ __forceinline__ float epilogue_apply(int MODE, float v, float r,
                                                float g, float bb, float scl) {
  if (MODE == 1) {
    v = 0.5f * v * (1.0f + erff(v * 0.7071067811865475f));
  } else if (MODE == 2) {
    v += r;
  } else if (MODE == 3) {
    v = v * scl * g + bb;
    v = (v > 0.f) ? v : expm1f(v);
  }
  return v;
}

// ---------------- fp32 tiled GEMM 64x64, 4x4/thread (small-M fallback) ----
#define BM 64
#define BN 64
#define BK 16
#define PADR 4

template <int MODE>
__global__ __launch_bounds__(256) void gemm_kernel(
    const float* __restrict__ A, const float* __restrict__ Bt,
    const float* __restrict__ bias, const float* __restrict__ R,
    const float* __restrict__ gvec, const float* __restrict__ bvec,
    float* __restrict__ C, int M, int N, int K, float scl) {
  __shared__ float As[BK][BM + PADR];
  __shared__ float Bs[BK][BN + PADR];
  const int bm = blockIdx.y * BM;
  const int bn = blockIdx.x * BN;
  const int tid = threadIdx.x;
  const int tx = tid & 15, ty = tid >> 4;
  const int lr = tid >> 2;
  const int lc = (tid & 3) << 2;
  const float* Aptr = A + (size_t)(bm + lr) * K + lc;
  const float* Bptr = Bt + (size_t)(bn + lr) * K + lc;
  float acc[4][4] = {};
  for (int k0 = 0; k0 < K; k0 += BK) {
    float4 av = *(const float4*)(Aptr + k0);
    float4 bv = *(const float4*)(Bptr + k0);
    As[lc + 0][lr] = av.x; As[lc + 1][lr] = av.y;
    As[lc + 2][lr] = av.z; As[lc + 3][lr] = av.w;
    Bs[lc + 0][lr] = bv.x; Bs[lc + 1][lr] = bv.y;
    Bs[lc + 2][lr] = bv.z; Bs[lc + 3][lr] = bv.w;
    __syncthreads();
#pragma unroll
    for (int kk = 0; kk < BK; ++kk) {
      float4 a4 = *(const float4*)&As[kk][ty << 2];
      float4 b4 = *(const float4*)&Bs[kk][tx << 2];
      float ar[4] = {a4.x, a4.y, a4.z, a4.w};
      float br[4] = {b4.x, b4.y, b4.z, b4.w};
#pragma unroll
      for (int i = 0; i < 4; ++i)
#pragma unroll
        for (int j = 0; j < 4; ++j) acc[i][j] += ar[i] * br[j];
    }
    __syncthreads();
  }
#pragma unroll
  for (int i = 0; i < 4; ++i) {
    int row = bm + (ty << 2) + i;
    float* Cr = C + (size_t)row * N;
    const float* Rr = (MODE == 2) ? (R + (size_t)row * N) : nullptr;
#pragma unroll
    for (int j = 0; j < 4; ++j) {
      int col = bn + (tx << 2) + j;
      float v = acc[i][j] + bias[col];
      v = epilogue_apply(MODE, v, (MODE == 2) ? Rr[col] : 0.f,
                         (MODE == 3) ? gvec[col] : 0.f,
                         (MODE == 3) ? bvec[col] : 0.f, scl);
      Cr[col] = v;
    }
  }
}

// ---------------- fp32 tiled GEMM 128x128, 8x8/thread (VALU-bound) --------
// Per kk: 64 FMA vs 4 ds_read_b128 -> FMA-issue dominated (~128 cyc VALU vs
// ~50 cyc LDS per wave), targets >2x the 64-tile version.
template <int MODE>
__global__ __launch_bounds__(256) void gemm128_kernel(
    const float* __restrict__ A, const float* __restrict__ Bt,
    const float* __restrict__ bias, const float* __restrict__ R,
    const float* __restrict__ gvec, const float* __restrict__ bvec,
    float* __restrict__ C, int M, int N, int K, float scl) {
  __shared__ float As[8][132];
  __shared__ float Bs[8][132];
  const int bm = blockIdx.y * 128;
  const int bn = blockIdx.x * 128;
  const int tid = threadIdx.x;
  const int tx = tid & 15, ty = tid >> 4;
  const int lr = tid >> 1;         // 0..127
  const int lc = (tid & 1) << 2;   // 0 or 4
  const float* Aptr = A + (size_t)(bm + lr) * K + lc;
  const float* Bptr = Bt + (size_t)(bn + lr) * K + lc;
  float acc[8][8] = {};
  for (int k0 = 0; k0 < K; k0 += 8) {
    float4 av = *(const float4*)(Aptr + k0);
    float4 bv = *(const float4*)(Bptr + k0);
    As[lc + 0][lr] = av.x; As[lc + 1][lr] = av.y;
    As[lc + 2][lr] = av.z; As[lc + 3][lr] = av.w;
    Bs[lc + 0][lr] = bv.x; Bs[lc + 1][lr] = bv.y;
    Bs[lc + 2][lr] = bv.z; Bs[lc + 3][lr] = bv.w;
    __syncthreads();
#pragma unroll
    for (int kk = 0; kk < 8; ++kk) {
      float4 a0 = *(const float4*)&As[kk][ty << 3];
      float4 a1 = *(const float4*)&As[kk][(ty << 3) + 4];
      float4 b0 = *(const float4*)&Bs[kk][tx << 3];
      float4 b1 = *(const float4*)&Bs[kk][(tx << 3) + 4];
      float ar[8] = {a0.x, a0.y, a0.z, a0.w, a1.x, a1.y, a1.z, a1.w};
      float br[8] = {b0.x, b0.y, b0.z, b0.w, b1.x, b1.y, b1.z, b1.w};
#pragma unroll
      for (int i = 0; i < 8; ++i)
#pragma unroll
        for (int j = 0; j < 8; ++j) acc[i][j] += ar[i] * br[j];
    }
    __syncthreads();
  }
#pragma unroll
  for (int i = 0; i < 8; ++i) {
    int row = bm + (ty << 3) + i;
    float* Cr = C + (size_t)row * N;
    const float* Rr = (MODE == 2) ? (R + (size_t)row * N) : nullptr;
#pragma unroll
    for (int j = 0; j < 8; ++j) {
      int col = bn + (tx << 3) + j;
      float v = acc[i][j] + bias[col];
      v = epilogue_apply(MODE, v, (MODE == 2) ? Rr[col] : 0.f,
                         (MODE == 3) ? gvec[col] : 0.f,
                         (MODE == 3) ? bvec[col] : 0.f, scl);
      Cr[col] = v;
    }
  }
}

template <int MODE>
static void run_gemm(const float* A, const float* Bt, const float* bias,
                     const float* R, const float* g, const float* bb, float* C,
                     int M, int N, int K, float scl, hipStream_t stream) {
  if (M >= 4096) {
    dim3 gg(N / 128, M / 128);
    gemm128_kernel<MODE><<<gg, 256, 0, stream>>>(A, Bt, bias, R, g, bb, C, M, N, K, scl);
  } else {
    dim3 gg(N / BN, M / BM);
    gemm_kernel<MODE><<<gg, 256, 0, stream>>>(A, Bt, bias, R, g, bb, C, M, N, K, scl);
  }
}

// ---------------- sparse measurement M = max_u(QK) - sum_u(QK)/L ----------
__global__ __launch_bounds__(256) void sparse_m_kernel(
    const float* __restrict__ Q, const float* __restrict__ Km,
    const int* __restrict__ idx, float* __restrict__ Mout, int B, int L,
    int U) {
  int wid = (blockIdx.x * 256 + threadIdx.x) >> 6;
  int lane = threadIdx.x & 63;
  int total = B * NH * L;
  if (wid >= total) return;
  int l = wid % L;
  int bh = wid / L;
  int b = bh / NH, h = bh % NH;
  float qv = Q[((size_t)(b * L + l)) * D_MODEL + h * DH + lane];
  const float* Kbase = Km + (size_t)b * L * D_MODEL + h * DH;
  float maxv = -INFINITY, sumv = 0.f;
  for (int u = 0; u < U; ++u) {
    int ki = idx[l * U + u];
    float p = qv * Kbase[(size_t)ki * D_MODEL + lane];
#pragma unroll
    for (int m = 32; m; m >>= 1) p += __shfl_xor(p, m);
    maxv = fmaxf(maxv, p);
    sumv += p;
  }
  if (lane == 0) Mout[wid] = maxv - sumv / (float)L;
}

// ---------------- top-k (stable: ties -> lower index), u <= 40 ------------
__global__ __launch_bounds__(256) void topk_kernel(
    const float* __restrict__ Mv, int* __restrict__ Mtop, int L, int u) {
  __shared__ float sv[2048];
  __shared__ float rv[256];
  __shared__ int ri[256];
  int bh = blockIdx.x;
  int t = threadIdx.x;
  for (int l = t; l < L; l += 256) sv[l] = Mv[(size_t)bh * L + l];
  __syncthreads();
  for (int it = 0; it < u; ++it) {
    float bv = -INFINITY;
    int bi = 0x7fffffff;
    for (int l = t; l < L; l += 256) {
      float v = sv[l];
      if (v > bv || (v == bv && l < bi)) { bv = v; bi = l; }
    }
    rv[t] = bv; ri[t] = bi;
    __syncthreads();
    for (int s = 128; s > 0; s >>= 1) {
      if (t < s) {
        float v2 = rv[t + s]; int i2 = ri[t + s];
        if (v2 > rv[t] || (v2 == rv[t] && i2 < ri[t])) { rv[t] = v2; ri[t] = i2; }
      }
      __syncthreads();
    }
    if (t == 0) { Mtop[bh * u + it] = ri[0]; sv[ri[0]] = -INFINITY; }
    __syncthreads();
  }
}

// ---------------- mean of V over L per (b,h) ----------------
__global__ __launch_bounds__(256) void vmean_kernel(
    const float* __restrict__ V, float* __restrict__ vmean, int B, int L) {
  int bh = blockIdx.x;
  int b = bh / NH, h = bh % NH;
  int t = threadIdx.x;
  int e = t & 63, part = t >> 6;
  const float* base = V + (size_t)b * L * D_MODEL + h * DH + e;
  float s = 0.f;
  for (int l = part; l < L; l += 4) s += base[(size_t)l * D_MODEL];
  __shared__ float red[4][64];
  red[part][e] = s;
  __syncthreads();
  if (part == 0) {
    float tot = red[0][e] + red[1][e] + red[2][e] + red[3][e];
    vmean[bh * DH + e] = tot / (float)L;
  }
}

__global__ void fill_ctx_kernel(const float* __restrict__ vmean,
                                float* __restrict__ O, int B, int L) {
  int i = blockIdx.x * 256 + threadIdx.x;
  int total = B * L * D_MODEL;
  if (i >= total) return;
  int dcol = i % D_MODEL;
  int b = i / (D_MODEL * L);
  O[i] = vmean[(b * NH + (dcol >> 6)) * DH + (dcol & 63)];
}

// ---------------- full attention for the u selected query rows ------------
// Wave-per-K-row: lane = e -> coalesced 256B/wave K reads; dot via 64-lane
// butterfly. Replaces the uncoalesced per-thread row walk (132MB fetch).
__global__ __launch_bounds__(256) void attn_kernel(
    const float* __restrict__ Q, const float* __restrict__ Km,
    const float* __restrict__ V, const int* __restrict__ Mtop,
    float* __restrict__ O, int B, int L, int u) {
  __shared__ float p[2048];
  __shared__ float qs[DH];
  __shared__ float wred[4];
  __shared__ float red[256];
  __shared__ float pv[4][DH];
  int j = blockIdx.x;
  int bh = blockIdx.y;
  int b = bh / NH, h = bh % NH;
  int l = Mtop[bh * u + j];
  int t = threadIdx.x;
  int wave = t >> 6, lane = t & 63;
  if (t < DH) qs[t] = Q[((size_t)(b * L + l)) * D_MODEL + h * DH + t];
  __syncthreads();
  float q = qs[lane];
  const float* Kb = Km + (size_t)b * L * D_MODEL + h * DH;
  float lmax = -INFINITY;
  for (int lp = wave; lp < L; lp += 4) {
    float s = q * Kb[(size_t)lp * D_MODEL + lane];
#pragma unroll
    for (int m = 32; m; m >>= 1) s += __shfl_xor(s, m);
    s *= 0.125f;  // 1/sqrt(64)
    if (lane == 0) p[lp] = s;
    lmax = fmaxf(lmax, s);
  }
  if (lane == 0) wred[wave] = lmax;
  __syncthreads();
  float gmax = fmaxf(fmaxf(wred[0], wred[1]), fmaxf(wred[2], wred[3]));
  float lsum = 0.f;
  for (int lp = t; lp < L; lp += 256) {
    float e = expf(p[lp] - gmax);
    p[lp] = e;
    lsum += e;
  }
  red[t] = lsum;
  __syncthreads();
  for (int s = 128; s > 0; s >>= 1) { if (t < s) red[t] += red[t + s]; __syncthreads(); }
  float inv = 1.0f / red[0];
  __syncthreads();
  int e = lane, part = wave;
  const float* Vb = V + (size_t)b * L * D_MODEL + h * DH + e;
  float acc = 0.f;
  for (int lp = part; lp < L; lp += 4) acc += p[lp] * Vb[(size_t)lp * D_MODEL];
  pv[part][e] = acc;
  __syncthreads();
  if (part == 0) {
    float tot = (pv[0][e] + pv[1][e] + pv[2][e] + pv[3][e]) * inv;
    O[((size_t)(b * L + l)) * D_MODEL + h * DH + e] = tot;
  }
}

// ---------------- im2col for circular conv (K=3) over D=512 channels ------
__global__ void im2col_kernel(const float* __restrict__ X,
                              float* __restrict__ Y, int B, int L) {
  int i = blockIdx.x * 256 + threadIdx.x;
  int total = B * L * 1536;
  if (i >= total) return;
  int ck = i % 1536;
  int l = (i / 1536) % L;
  int b = i / (1536 * L);
  int c = ck / 3, k = ck % 3;
  int lm = l + k - 1;
  if (lm < 0) lm += L;
  else if (lm >= L) lm -= L;
  Y[i] = X[((size_t)(b * L + lm)) * D_MODEL + c];
}

// ---------------- maxpool k=3 s=2, one -inf pad each side -----------------
__global__ void maxpool_kernel(const float* __restrict__ Y,
                               float* __restrict__ X, int B, int L) {
  int Lo = L / 2;
  int i = blockIdx.x * 256 + threadIdx.x;
  int total = B * Lo * D_MODEL;
  if (i >= total) return;
  int d = i % D_MODEL;
  int lp = (i / D_MODEL) % Lo;
  int b = i / (D_MODEL * Lo);
  int l0 = 2 * lp - 1;
  float m = -INFINITY;
#pragma unroll
  for (int k = 0; k < 3; ++k) {
    int l = l0 + k;
    if (l >= 0 && l < L) m = fmaxf(m, Y[((size_t)(b * L + l)) * D_MODEL + d]);
  }
  X[i] = m;
}

// ==========================================================================
extern "C" void kernel_launch(void* const* d_in, const int* in_sizes, int n_in,
                              void* d_out, int out_size, void* d_ws,
                              size_t ws_size, hipStream_t stream) {
  const float* x_enc  = (const float*)d_in[0];
  const float* emb_w  = (const float*)d_in[1];
  const float* Wq     = (const float*)d_in[2];
  const float* bq     = (const float*)d_in[3];
  const float* Wk     = (const float*)d_in[4];
  const float* bk     = (const float*)d_in[5];
  const float* Wv     = (const float*)d_in[6];
  const float* bv     = (const float*)d_in[7];
  const float* Wo     = (const float*)d_in[8];
  const float* bo     = (const float*)d_in[9];
  const float* ln1_g  = (const float*)d_in[10];
  const float* ln1_b  = (const float*)d_in[11];
  const float* ff_w1  = (const float*)d_in[12];
  const float* ff_b1  = (const float*)d_in[13];
  const float* ff_w2  = (const float*)d_in[14];
  const float* ff_b2  = (const float*)d_in[15];
  const float* ln2_g  = (const float*)d_in[16];
  const float* ln2_b  = (const float*)d_in[17];
  const float* cv_w   = (const float*)d_in[18];
  const float* cv_b   = (const float*)d_in[19];
  const float* bn_g   = (const float*)d_in[20];
  const float* bn_b   = (const float*)d_in[21];
  const float* norm_g = (const float*)d_in[22];
  const float* norm_b = (const float*)d_in[23];

  const int B = 4, L0 = 2048, EL = 3;
  const size_t SZ = (size_t)B * 2048 * 512;
  float* ws   = (float*)d_ws;
  float* xbuf = ws;
  float* ebuf = ws + SZ;
  float* qbuf = ws + 2 * SZ;
  float* kbuf = ws + 3 * SZ;
  float* vbuf = ws + 4 * SZ;
  float* obuf = ws + 5 * SZ;
  float* im2c = qbuf;  // aliases q..v (48MB); q/k/v dead at conv time
  float* sm   = ws + 6 * SZ;
  int*   d_idx   = (int*)sm;
  float* d_M     = sm + 81920;
  int*   d_Mtop  = (int*)(sm + 81920 + 65536);
  float* d_vmean = sm + 81920 + 65536 + 1280;

  const float inv_s = 1.0f / sqrtf(1.0f + 1e-5f);

  embed_kernel<<<ceil_div(B * L0 * D_MODEL, 256), 256, 0, stream>>>(
      x_enc, emb_w, xbuf, B, L0);

  int L = L0;
  for (int i = 0; i < EL; ++i) {
    const int M_ = B * L;
    int c = 5 * (int)ceil(log((double)L));
    int U = c < L ? c : L;
    const float* Wq_i = Wq + (size_t)i * 512 * 512;
    const float* Wk_i = Wk + (size_t)i * 512 * 512;
    const float* Wv_i = Wv + (size_t)i * 512 * 512;
    const float* Wo_i = Wo + (size_t)i * 512 * 512;
    const float* w1_i = ff_w1 + (size_t)i * 512 * 512;
    const float* w2_i = ff_w2 + (size_t)i * 512 * 512;

    run_gemm<0>(xbuf, Wq_i, bq + i * 512, nullptr, nullptr, nullptr, qbuf,
                M_, 512, 512, 0.f, stream);
    run_gemm<0>(xbuf, Wk_i, bk + i * 512, nullptr, nullptr, nullptr, kbuf,
                M_, 512, 512, 0.f, stream);
    run_gemm<0>(xbuf, Wv_i, bv + i * 512, nullptr, nullptr, nullptr, vbuf,
                M_, 512, 512, 0.f, stream);

    uint32_t lk0, lk1, k20, k21;
    threefry2x32(0u, 42u, 0u, (uint32_t)i, &lk0, &lk1);
    threefry2x32(lk0, lk1, 0u, 1u, &k20, &k21);
    idx_kernel<<<ceil_div(L * U, 256), 256, 0, stream>>>(d_idx, L, U, k20, k21);

    sparse_m_kernel<<<ceil_div(B * NH * L * 64, 256), 256, 0, stream>>>(
        qbuf, kbuf, d_idx, d_M, B, L, U);
    topk_kernel<<<B * NH, 256, 0, stream>>>(d_M, d_Mtop, L, U);
    vmean_kernel<<<B * NH, 256, 0, stream>>>(vbuf, d_vmean, B, L);
    fill_ctx_kernel<<<ceil_div(B * L * D_MODEL, 256), 256, 0, stream>>>(
        d_vmean, obuf, B, L);
    attn_kernel<<<dim3(U, B * NH), 256, 0, stream>>>(qbuf, kbuf, vbuf, d_Mtop,
                                                     obuf, B, L, U);

    run_gemm<2>(obuf, Wo_i, bo + i * 512, xbuf, nullptr, nullptr, ebuf,
                M_, 512, 512, 0.f, stream);
    ln_kernel<<<M_, 256, 0, stream>>>(ebuf, ln1_g + i * 512, ln1_b + i * 512, xbuf);

    run_gemm<1>(xbuf, w1_i, ff_b1 + i * 512, nullptr, nullptr, nullptr, obuf,
                M_, 512, 512, 0.f, stream);
    run_gemm<2>(obuf, w2_i, ff_b2 + i * 512, xbuf, nullptr, nullptr, ebuf,
                M_, 512, 512, 0.f, stream);
    ln_kernel<<<M_, 256, 0, stream>>>(ebuf, ln2_g + i * 512, ln2_b + i * 512, xbuf);

    if (i < EL - 1) {
      im2col_kernel<<<ceil_div(B * L * 1536, 256), 256, 0, stream>>>(xbuf, im2c, B, L);
      run_gemm<3>(im2c, cv_w + (size_t)i * 512 * 1536, cv_b + i * 512, nullptr,
                  bn_g + i * 512, bn_b + i * 512, ebuf, M_, 512, 1536, inv_s,
                  stream);
      maxpool_kernel<<<ceil_div(B * (L / 2) * D_MODEL, 256), 256, 0, stream>>>(
          ebuf, xbuf, B, L);
      L /= 2;
    }
  }

  ln_kernel<<<B * L, 256, 0, stream>>>(xbuf, norm_g, norm_b, (float*)d_out);
}

// Round 3
// 3115.835 us; speedup vs baseline: 1.0405x; 1.0405x over previous
//
#include <hip/hip_runtime.h>
#include <cmath>
#include <cstdint>

#define D_MODEL 512
#define NH 8
#define DH 64

static inline int ceil_div(int a, int b) { return (a + b - 1) / b; }

// ---------------- threefry2x32 (JAX-exact) ----------------
#define TF_ROTL(x, r) (((x) << (r)) | ((x) >> (32 - (r))))

__host__ __device__ inline void threefry2x32(uint32_t k0, uint32_t k1,
                                             uint32_t x0, uint32_t x1,
                                             uint32_t* o0, uint32_t* o1) {
  uint32_t ks2 = k0 ^ k1 ^ 0x1BD11BDAu;
  x0 += k0; x1 += k1;
#define TF_R4(a, b, c, d)                                    \
  x0 += x1; x1 = TF_ROTL(x1, a); x1 ^= x0;                   \
  x0 += x1; x1 = TF_ROTL(x1, b); x1 ^= x0;                   \
  x0 += x1; x1 = TF_ROTL(x1, c); x1 ^= x0;                   \
  x0 += x1; x1 = TF_ROTL(x1, d); x1 ^= x0;
  TF_R4(13, 15, 26, 6);  x0 += k1;  x1 += ks2 + 1u;
  TF_R4(17, 29, 16, 24); x0 += ks2; x1 += k0 + 2u;
  TF_R4(13, 15, 26, 6);  x0 += k0;  x1 += k1 + 3u;
  TF_R4(17, 29, 16, 24); x0 += k1;  x1 += ks2 + 4u;
  TF_R4(13, 15, 26, 6);  x0 += ks2; x1 += k0 + 5u;
#undef TF_R4
  *o0 = x0; *o1 = x1;
}

__global__ void idx_kernel(int* __restrict__ idx, int L, int U,
                           uint32_t k0, uint32_t k1) {
  int n = blockIdx.x * 256 + threadIdx.x;
  if (n >= L * U) return;
  uint32_t o0, o1;
  threefry2x32(k0, k1, 0u, (uint32_t)n, &o0, &o1);
  idx[n] = (int)((o0 ^ o1) & (uint32_t)(L - 1));
}

// ---------------- embedding: circular conv (C=2,K=3) + pos encoding -------
__global__ __launch_bounds__(256) void embed_kernel(
    const float* __restrict__ x_enc, const float* __restrict__ emb_w,
    float* __restrict__ x, int B, int L) {
  int i = blockIdx.x * 256 + threadIdx.x;
  int total = B * L * D_MODEL;
  if (i >= total) return;
  int d = i % D_MODEL;
  int l = (i / D_MODEL) % L;
  int b = i / (D_MODEL * L);
  int lm = (l == 0) ? (L - 1) : (l - 1);
  int lp = (l == L - 1) ? 0 : (l + 1);
  const float* w = emb_w + d * 6;
  const float* xb = x_enc + (size_t)b * L * 2;
  float acc = 0.f;
  acc += xb[lm * 2 + 0] * w[0] + xb[l * 2 + 0] * w[1] + xb[lp * 2 + 0] * w[2];
  acc += xb[lm * 2 + 1] * w[3] + xb[l * 2 + 1] * w[4] + xb[lp * 2 + 1] * w[5];
  int j = d >> 1;
  const float coef = -0.017988946039015985f;  // -ln(10000)/512
  float div = expf((float)(2 * j) * coef);
  float ang = (float)l * div;
  float pe = (d & 1) ? cosf(ang) : sinf(ang);
  x[i] = acc + pe;
}

// ---------------- layer norm over D=512 ----------------
__global__ __launch_bounds__(256) void ln_kernel(
    const float* __restrict__ in, const float* __restrict__ g,
    const float* __restrict__ b, float* __restrict__ out) {
  int row = blockIdx.x;
  int t = threadIdx.x;
  const float* xr = in + (size_t)row * D_MODEL;
  float v0 = xr[t], v1 = xr[t + 256];
  __shared__ float red[256];
  red[t] = v0 + v1;
  __syncthreads();
  for (int s = 128; s > 0; s >>= 1) { if (t < s) red[t] += red[t + s]; __syncthreads(); }
  float mean = red[0] * (1.0f / 512.0f);
  __syncthreads();
  float d0 = v0 - mean, d1 = v1 - mean;
  red[t] = d0 * d0 + d1 * d1;
  __syncthreads();
  for (int s = 128; s > 0; s >>= 1) { if (t < s) red[t] += red[t + s]; __syncthreads(); }
  float var = red[0] * (1.0f / 512.0f);
  float rstd = 1.0f / sqrtf(var + 1e-5f);
  float* outr = out + (size_t)row * D_MODEL;
  outr[t]       = d0 * rstd * g[t]       + b[t];
  outr[t + 256] = d1 * rstd * g[t + 256] + b[t + 256];
}

// MODE 0: +bias   1: gelu(+bias)   2: +bias +R   3: elu((+bias)*scl*g + bb)
__device__ __forceinline__ float epilogue_apply(int MODE, float v, float r,
                                                float g, float bb, float scl) {
  if (MODE == 1) {
    v = 0.5f * v * (1.0f + erff(v * 0.7071067811865475f));
  } else if (MODE == 2) {
    v += r;
  } else if (MODE == 3) {
    v = v * scl * g + bb;
    v = (v > 0.f) ? v : expm1f(v);
  }
  return v;
}

// ---------------- fp32 tiled GEMM 64x64, 4x4/thread ----------
// 1024+ blocks at M>=4096 -> 4 blocks/CU; known-good R1 config.
#define BM 64
#define BN 64
#define BK 16
#define PADR 4

template <int MODE>
__global__ __launch_bounds__(256) void gemm_kernel(
    const float* __restrict__ A, const float* __restrict__ Bt,
    const float* __restrict__ bias, const float* __restrict__ R,
    const float* __restrict__ gvec, const float* __restrict__ bvec,
    float* __restrict__ C, int M, int N, int K, float scl) {
  __shared__ float As[BK][BM + PADR];
  __shared__ float Bs[BK][BN + PADR];
  const int bm = blockIdx.y * BM;
  const int bn = blockIdx.x * BN;
  const int tid = threadIdx.x;
  const int tx = tid & 15, ty = tid >> 4;
  const int lr = tid >> 2;
  const int lc = (tid & 3) << 2;
  const float* Aptr = A + (size_t)(bm + lr) * K + lc;
  const float* Bptr = Bt + (size_t)(bn + lr) * K + lc;
  float acc[4][4] = {};
  for (int k0 = 0; k0 < K; k0 += BK) {
    float4 av = *(const float4*)(Aptr + k0);
    float4 bv = *(const float4*)(Bptr + k0);
    As[lc + 0][lr] = av.x; As[lc + 1][lr] = av.y;
    As[lc + 2][lr] = av.z; As[lc + 3][lr] = av.w;
    Bs[lc + 0][lr] = bv.x; Bs[lc + 1][lr] = bv.y;
    Bs[lc + 2][lr] = bv.z; Bs[lc + 3][lr] = bv.w;
    __syncthreads();
#pragma unroll
    for (int kk = 0; kk < BK; ++kk) {
      float4 a4 = *(const float4*)&As[kk][ty << 2];
      float4 b4 = *(const float4*)&Bs[kk][tx << 2];
      float ar[4] = {a4.x, a4.y, a4.z, a4.w};
      float br[4] = {b4.x, b4.y, b4.z, b4.w};
#pragma unroll
      for (int i = 0; i < 4; ++i)
#pragma unroll
        for (int j = 0; j < 4; ++j) acc[i][j] += ar[i] * br[j];
    }
    __syncthreads();
  }
#pragma unroll
  for (int i = 0; i < 4; ++i) {
    int row = bm + (ty << 2) + i;
    float* Cr = C + (size_t)row * N;
    const float* Rr = (MODE == 2) ? (R + (size_t)row * N) : nullptr;
#pragma unroll
    for (int j = 0; j < 4; ++j) {
      int col = bn + (tx << 2) + j;
      float v = acc[i][j] + bias[col];
      v = epilogue_apply(MODE, v, (MODE == 2) ? Rr[col] : 0.f,
                         (MODE == 3) ? gvec[col] : 0.f,
                         (MODE == 3) ? bvec[col] : 0.f, scl);
      Cr[col] = v;
    }
  }
}

template <int MODE>
static void run_gemm(const float* A, const float* Bt, const float* bias,
                     const float* R, const float* g, const float* bb, float* C,
                     int M, int N, int K, float scl, hipStream_t stream) {
  dim3 gg(N / BN, M / BM);
  gemm_kernel<MODE><<<gg, 256, 0, stream>>>(A, Bt, bias, R, g, bb, C, M, N, K, scl);
}

// ---------------- sparse measurement M = max_u(QK) - sum_u(QK)/L ----------
__global__ __launch_bounds__(256) void sparse_m_kernel(
    const float* __restrict__ Q, const float* __restrict__ Km,
    const int* __restrict__ idx, float* __restrict__ Mout, int B, int L,
    int U) {
  int wid = (blockIdx.x * 256 + threadIdx.x) >> 6;
  int lane = threadIdx.x & 63;
  int total = B * NH * L;
  if (wid >= total) return;
  int l = wid % L;
  int bh = wid / L;
  int b = bh / NH, h = bh % NH;
  float qv = Q[((size_t)(b * L + l)) * D_MODEL + h * DH + lane];
  const float* Kbase = Km + (size_t)b * L * D_MODEL + h * DH;
  float maxv = -INFINITY, sumv = 0.f;
  for (int u = 0; u < U; ++u) {
    int ki = idx[l * U + u];
    float p = qv * Kbase[(size_t)ki * D_MODEL + lane];
#pragma unroll
    for (int m = 32; m; m >>= 1) p += __shfl_xor(p, m);
    maxv = fmaxf(maxv, p);
    sumv += p;
  }
  if (lane == 0) Mout[wid] = maxv - sumv / (float)L;
}

// ---------------- top-k (stable: ties -> lower index), u <= 40 ------------
__global__ __launch_bounds__(256) void topk_kernel(
    const float* __restrict__ Mv, int* __restrict__ Mtop, int L, int u) {
  __shared__ float sv[2048];
  __shared__ float rv[256];
  __shared__ int ri[256];
  int bh = blockIdx.x;
  int t = threadIdx.x;
  for (int l = t; l < L; l += 256) sv[l] = Mv[(size_t)bh * L + l];
  __syncthreads();
  for (int it = 0; it < u; ++it) {
    float bv = -INFINITY;
    int bi = 0x7fffffff;
    for (int l = t; l < L; l += 256) {
      float v = sv[l];
      if (v > bv || (v == bv && l < bi)) { bv = v; bi = l; }
    }
    rv[t] = bv; ri[t] = bi;
    __syncthreads();
    for (int s = 128; s > 0; s >>= 1) {
      if (t < s) {
        float v2 = rv[t + s]; int i2 = ri[t + s];
        if (v2 > rv[t] || (v2 == rv[t] && i2 < ri[t])) { rv[t] = v2; ri[t] = i2; }
      }
      __syncthreads();
    }
    if (t == 0) { Mtop[bh * u + it] = ri[0]; sv[ri[0]] = -INFINITY; }
    __syncthreads();
  }
}

// ---------------- mean of V over L per (b,h) ----------------
__global__ __launch_bounds__(256) void vmean_kernel(
    const float* __restrict__ V, float* __restrict__ vmean, int B, int L) {
  int bh = blockIdx.x;
  int b = bh / NH, h = bh % NH;
  int t = threadIdx.x;
  int e = t & 63, part = t >> 6;
  const float* base = V + (size_t)b * L * D_MODEL + h * DH + e;
  float s = 0.f;
  for (int l = part; l < L; l += 4) s += base[(size_t)l * D_MODEL];
  __shared__ float red[4][64];
  red[part][e] = s;
  __syncthreads();
  if (part == 0) {
    float tot = red[0][e] + red[1][e] + red[2][e] + red[3][e];
    vmean[bh * DH + e] = tot / (float)L;
  }
}

__global__ void fill_ctx_kernel(const float* __restrict__ vmean,
                                float* __restrict__ O, int B, int L) {
  int i = blockIdx.x * 256 + threadIdx.x;
  int total = B * L * D_MODEL;
  if (i >= total) return;
  int dcol = i % D_MODEL;
  int b = i / (D_MODEL * L);
  O[i] = vmean[(b * NH + (dcol >> 6)) * DH + (dcol & 63)];
}

// ============== attention as batched GEMM pipeline ==============
// pack Qred[z][r][d], padded to 64 rows with zeros
__global__ void pack_qred_kernel(const float* __restrict__ Q,
                                 const int* __restrict__ Mtop,
                                 float* __restrict__ qred, int L, int U) {
  int z = blockIdx.x;  // bh
  int b = z / NH, h = z % NH;
  int t = threadIdx.x;
  int d = t & 63;
  for (int r = t >> 6; r < 64; r += 4) {
    float v = 0.f;
    if (r < U) {
      int l = Mtop[z * U + r];
      v = Q[((size_t)(b * L + l)) * D_MODEL + h * DH + d];
    }
    qred[((size_t)z * 64 + r) * 64 + d] = v;
  }
}

// S[z][64][L] = 0.125 * Qred[z](64x64) @ K_z^T ; K_z rows stride 512
__global__ __launch_bounds__(256) void scores_gemm_kernel(
    const float* __restrict__ qred, const float* __restrict__ Km,
    float* __restrict__ S, int L) {
  __shared__ float As[BK][64 + PADR];
  __shared__ float Bs[BK][64 + PADR];
  const int z = blockIdx.y;
  const int b = z / NH, h = z % NH;
  const float* A = qred + (size_t)z * 64 * 64;
  const float* Bt = Km + (size_t)b * L * D_MODEL + h * DH;  // ldb = 512
  float* Sz = S + (size_t)z * 64 * L;
  const int bn = blockIdx.x * 64;
  const int tid = threadIdx.x;
  const int tx = tid & 15, ty = tid >> 4;
  const int lr = tid >> 2;
  const int lc = (tid & 3) << 2;
  float acc[4][4] = {};
  for (int k0 = 0; k0 < 64; k0 += BK) {
    float4 av = *(const float4*)(A + (size_t)lr * 64 + k0 + lc);
    float4 bv = *(const float4*)(Bt + (size_t)(bn + lr) * D_MODEL + k0 + lc);
    As[lc + 0][lr] = av.x; As[lc + 1][lr] = av.y;
    As[lc + 2][lr] = av.z; As[lc + 3][lr] = av.w;
    Bs[lc + 0][lr] = bv.x; Bs[lc + 1][lr] = bv.y;
    Bs[lc + 2][lr] = bv.z; Bs[lc + 3][lr] = bv.w;
    __syncthreads();
#pragma unroll
    for (int kk = 0; kk < BK; ++kk) {
      float4 a4 = *(const float4*)&As[kk][ty << 2];
      float4 b4 = *(const float4*)&Bs[kk][tx << 2];
      float ar[4] = {a4.x, a4.y, a4.z, a4.w};
      float br[4] = {b4.x, b4.y, b4.z, b4.w};
#pragma unroll
      for (int i = 0; i < 4; ++i)
#pragma unroll
        for (int j = 0; j < 4; ++j) acc[i][j] += ar[i] * br[j];
    }
    __syncthreads();
  }
#pragma unroll
  for (int i = 0; i < 4; ++i) {
    float* Sr = Sz + (size_t)((ty << 2) + i) * L + bn;
#pragma unroll
    for (int j = 0; j < 4; ++j) Sr[(tx << 2) + j] = 0.125f * acc[i][j];
  }
}

// per-row softmax over L (rows r < U only); wave per row
__global__ __launch_bounds__(256) void softmax_kernel(float* __restrict__ S,
                                                      int L, int U) {
  int z = blockIdx.x;
  int wave = threadIdx.x >> 6, lane = threadIdx.x & 63;
  for (int r = wave; r < U; r += 4) {
    float* row = S + (size_t)z * 64 * L + (size_t)r * L;
    float m = -INFINITY;
    for (int i = lane; i < L; i += 64) m = fmaxf(m, row[i]);
#pragma unroll
    for (int k = 32; k; k >>= 1) m = fmaxf(m, __shfl_xor(m, k));
    float s = 0.f;
    for (int i = lane; i < L; i += 64) {
      float e = expf(row[i] - m);
      row[i] = e;
      s += e;
    }
#pragma unroll
    for (int k = 32; k; k >>= 1) s += __shfl_xor(s, k);
    float inv = 1.0f / s;
    for (int i = lane; i < L; i += 64) row[i] *= inv;
  }
}

// zero the selected ctx rows before split-K PV atomics
__global__ void zero_sel_kernel(const int* __restrict__ Mtop,
                                float* __restrict__ O, int L, int U) {
  int z = blockIdx.x;
  int b = z / NH, h = z % NH;
  int t = threadIdx.x;
  int d = t & 63;
  for (int r = t >> 6; r < U; r += 4) {
    int l = Mtop[z * U + r];
    O[((size_t)(b * L + l)) * D_MODEL + h * DH + d] = 0.f;
  }
}

// O[sel rows] += P(40xL) @ V(Lx64), split-K over 256-chunks of L
__global__ __launch_bounds__(256) void pv_kernel(
    const float* __restrict__ P, const float* __restrict__ V,
    const int* __restrict__ Mtop, float* __restrict__ O, int L, int U) {
  int z = blockIdx.y;
  int b = z / NH, h = z % NH;
  int c0 = blockIdx.x * 256;
  int wave = threadIdx.x >> 6, lane = threadIdx.x & 63;
  const float* Vb = V + (size_t)b * L * D_MODEL + h * DH + lane;
  const float* Pz = P + (size_t)z * 64 * L + c0;
  float acc[10] = {};
  for (int l = 0; l < 256; ++l) {
    float vv = Vb[(size_t)(c0 + l) * D_MODEL];
    int j = 0;
    for (int r = wave; r < U; r += 4, ++j)
      acc[j] += Pz[(size_t)r * L + l] * vv;
  }
  int j = 0;
  for (int r = wave; r < U; r += 4, ++j) {
    int ml = Mtop[z * U + r];
    atomicAdd(&O[((size_t)(b * L + ml)) * D_MODEL + h * DH + lane], acc[j]);
  }
}

// ---------------- im2col for circular conv (K=3) over D=512 channels ------
__global__ void im2col_kernel(const float* __restrict__ X,
                              float* __restrict__ Y, int B, int L) {
  int i = blockIdx.x * 256 + threadIdx.x;
  int total = B * L * 1536;
  if (i >= total) return;
  int ck = i % 1536;
  int l = (i / 1536) % L;
  int b = i / (1536 * L);
  int c = ck / 3, k = ck % 3;
  int lm = l + k - 1;
  if (lm < 0) lm += L;
  else if (lm >= L) lm -= L;
  Y[i] = X[((size_t)(b * L + lm)) * D_MODEL + c];
}

// ---------------- maxpool k=3 s=2, one -inf pad each side -----------------
__global__ void maxpool_kernel(const float* __restrict__ Y,
                               float* __restrict__ X, int B, int L) {
  int Lo = L / 2;
  int i = blockIdx.x * 256 + threadIdx.x;
  int total = B * Lo * D_MODEL;
  if (i >= total) return;
  int d = i % D_MODEL;
  int lp = (i / D_MODEL) % Lo;
  int b = i / (D_MODEL * Lo);
  int l0 = 2 * lp - 1;
  float m = -INFINITY;
#pragma unroll
  for (int k = 0; k < 3; ++k) {
    int l = l0 + k;
    if (l >= 0 && l < L) m = fmaxf(m, Y[((size_t)(b * L + l)) * D_MODEL + d]);
  }
  X[i] = m;
}

// ==========================================================================
extern "C" void kernel_launch(void* const* d_in, const int* in_sizes, int n_in,
                              void* d_out, int out_size, void* d_ws,
                              size_t ws_size, hipStream_t stream) {
  const float* x_enc  = (const float*)d_in[0];
  const float* emb_w  = (const float*)d_in[1];
  const float* Wq     = (const float*)d_in[2];
  const float* bq     = (const float*)d_in[3];
  const float* Wk     = (const float*)d_in[4];
  const float* bk     = (const float*)d_in[5];
  const float* Wv     = (const float*)d_in[6];
  const float* bv     = (const float*)d_in[7];
  const float* Wo     = (const float*)d_in[8];
  const float* bo     = (const float*)d_in[9];
  const float* ln1_g  = (const float*)d_in[10];
  const float* ln1_b  = (const float*)d_in[11];
  const float* ff_w1  = (const float*)d_in[12];
  const float* ff_b1  = (const float*)d_in[13];
  const float* ff_w2  = (const float*)d_in[14];
  const float* ff_b2  = (const float*)d_in[15];
  const float* ln2_g  = (const float*)d_in[16];
  const float* ln2_b  = (const float*)d_in[17];
  const float* cv_w   = (const float*)d_in[18];
  const float* cv_b   = (const float*)d_in[19];
  const float* bn_g   = (const float*)d_in[20];
  const float* bn_b   = (const float*)d_in[21];
  const float* norm_g = (const float*)d_in[22];
  const float* norm_b = (const float*)d_in[23];

  const int B = 4, L0 = 2048, EL = 3;
  const size_t SZ = (size_t)B * 2048 * 512;
  float* ws   = (float*)d_ws;
  float* xbuf = ws;
  float* ebuf = ws + SZ;       // temp / pre-LN; doubles as S/P during attn
  float* qbuf = ws + 2 * SZ;
  float* kbuf = ws + 3 * SZ;
  float* vbuf = ws + 4 * SZ;
  float* obuf = ws + 5 * SZ;
  float* im2c = qbuf;  // aliases q..v (48MB); q/k/v dead at conv time
  float* sm   = ws + 6 * SZ;
  int*   d_idx   = (int*)sm;                       // <=81920, dead after sparse_m
  float* d_M     = sm + 81920;                     // <=65536, dead after topk
  int*   d_Mtop  = (int*)(sm + 81920 + 65536);     // <=1280, live through attn
  float* d_vmean = sm + 81920 + 65536 + 1280;      // 2048
  float* qred    = sm;  // 131072 floats, reuses idx+M region (dead post-topk)
  float* Sbuf    = ebuf;  // 32*64*L <= 4.19M floats <= SZ

  const float inv_s = 1.0f / sqrtf(1.0f + 1e-5f);

  embed_kernel<<<ceil_div(B * L0 * D_MODEL, 256), 256, 0, stream>>>(
      x_enc, emb_w, xbuf, B, L0);

  int L = L0;
  for (int i = 0; i < EL; ++i) {
    const int M_ = B * L;
    int c = 5 * (int)ceil(log((double)L));
    int U = c < L ? c : L;
    const float* Wq_i = Wq + (size_t)i * 512 * 512;
    const float* Wk_i = Wk + (size_t)i * 512 * 512;
    const float* Wv_i = Wv + (size_t)i * 512 * 512;
    const float* Wo_i = Wo + (size_t)i * 512 * 512;
    const float* w1_i = ff_w1 + (size_t)i * 512 * 512;
    const float* w2_i = ff_w2 + (size_t)i * 512 * 512;

    run_gemm<0>(xbuf, Wq_i, bq + i * 512, nullptr, nullptr, nullptr, qbuf,
                M_, 512, 512, 0.f, stream);
    run_gemm<0>(xbuf, Wk_i, bk + i * 512, nullptr, nullptr, nullptr, kbuf,
                M_, 512, 512, 0.f, stream);
    run_gemm<0>(xbuf, Wv_i, bv + i * 512, nullptr, nullptr, nullptr, vbuf,
                M_, 512, 512, 0.f, stream);

    uint32_t lk0, lk1, k20, k21;
    threefry2x32(0u, 42u, 0u, (uint32_t)i, &lk0, &lk1);
    threefry2x32(lk0, lk1, 0u, 1u, &k20, &k21);
    idx_kernel<<<ceil_div(L * U, 256), 256, 0, stream>>>(d_idx, L, U, k20, k21);

    sparse_m_kernel<<<ceil_div(B * NH * L * 64, 256), 256, 0, stream>>>(
        qbuf, kbuf, d_idx, d_M, B, L, U);
    topk_kernel<<<B * NH, 256, 0, stream>>>(d_M, d_Mtop, L, U);
    vmean_kernel<<<B * NH, 256, 0, stream>>>(vbuf, d_vmean, B, L);
    fill_ctx_kernel<<<ceil_div(B * L * D_MODEL, 256), 256, 0, stream>>>(
        d_vmean, obuf, B, L);

    // attention as batched GEMMs (qred aliases idx/M which are now dead)
    pack_qred_kernel<<<B * NH, 256, 0, stream>>>(qbuf, d_Mtop, qred, L, U);
    scores_gemm_kernel<<<dim3(L / 64, B * NH), 256, 0, stream>>>(qred, kbuf,
                                                                 Sbuf, L);
    softmax_kernel<<<B * NH, 256, 0, stream>>>(Sbuf, L, U);
    zero_sel_kernel<<<B * NH, 256, 0, stream>>>(d_Mtop, obuf, L, U);
    pv_kernel<<<dim3(L / 256, B * NH), 256, 0, stream>>>(Sbuf, vbuf, d_Mtop,
                                                         obuf, L, U);

    run_gemm<2>(obuf, Wo_i, bo + i * 512, xbuf, nullptr, nullptr, ebuf,
                M_, 512, 512, 0.f, stream);
    ln_kernel<<<M_, 256, 0, stream>>>(ebuf, ln1_g + i * 512, ln1_b + i * 512, xbuf);

    run_gemm<1>(xbuf, w1_i, ff_b1 + i * 512, nullptr, nullptr, nullptr, obuf,
                M_, 512, 512, 0.f, stream);
    run_gemm<2>(obuf, w2_i, ff_b2 + i * 512, xbuf, nullptr, nullptr, ebuf,
                M_, 512, 512, 0.f, stream);
    ln_kernel<<<M_, 256, 0, stream>>>(ebuf, ln2_g + i * 512, ln2_b + i * 512, xbuf);

    if (i < EL - 1) {
      im2col_kernel<<<ceil_div(B * L * 1536, 256), 256, 0, stream>>>(xbuf, im2c, B, L);
      run_gemm<3>(im2c, cv_w + (size_t)i * 512 * 1536, cv_b + i * 512, nullptr,
                  bn_g + i * 512, bn_b + i * 512, ebuf, M_, 512, 1536, inv_s,
                  stream);
      maxpool_kernel<<<ceil_div(B * (L / 2) * D_MODEL, 256), 256, 0, stream>>>(
          ebuf, xbuf, B, L);
      L /= 2;
    }
  }

  ln_kernel<<<B * L, 256, 0, stream>>>(xbuf, norm_g, norm_b, (float*)d_out);
}

// Round 4
// 2490.391 us; speedup vs baseline: 1.3018x; 1.2511x over previous
//
#include <hip/hip_runtime.h>
#include <cmath>
#include <cstdint>

#define D_MODEL 512
#define NH 8
#define DH 64

static inline int ceil_div(int a, int b) { return (a + b - 1) / b; }

// ---------------- threefry2x32 (JAX-exact) ----------------
#define TF_ROTL(x, r) (((x) << (r)) | ((x) >> (32 - (r))))

__host__ __device__ inline void threefry2x32(uint32_t k0, uint32_t k1,
                                             uint32_t x0, uint32_t x1,
                                             uint32_t* o0, uint32_t* o1) {
  uint32_t ks2 = k0 ^ k1 ^ 0x1BD11BDAu;
  x0 += k0; x1 += k1;
#define TF_R4(a, b, c, d)                                    \
  x0 += x1; x1 = TF_ROTL(x1, a); x1 ^= x0;                   \
  x0 += x1; x1 = TF_ROTL(x1, b); x1 ^= x0;                   \
  x0 += x1; x1 = TF_ROTL(x1, c); x1 ^= x0;                   \
  x0 += x1; x1 = TF_ROTL(x1, d); x1 ^= x0;
  TF_R4(13, 15, 26, 6);  x0 += k1;  x1 += ks2 + 1u;
  TF_R4(17, 29, 16, 24); x0 += ks2; x1 += k0 + 2u;
  TF_R4(13, 15, 26, 6);  x0 += k0;  x1 += k1 + 3u;
  TF_R4(17, 29, 16, 24); x0 += k1;  x1 += ks2 + 4u;
  TF_R4(13, 15, 26, 6);  x0 += ks2; x1 += k0 + 5u;
#undef TF_R4
  *o0 = x0; *o1 = x1;
}

__global__ void idx_kernel(int* __restrict__ idx, int L, int U,
                           uint32_t k0, uint32_t k1) {
  int n = blockIdx.x * 256 + threadIdx.x;
  if (n >= L * U) return;
  uint32_t o0, o1;
  threefry2x32(k0, k1, 0u, (uint32_t)n, &o0, &o1);
  idx[n] = (int)((o0 ^ o1) & (uint32_t)(L - 1));
}

// ---------------- embedding: circular conv (C=2,K=3) + pos encoding -------
__global__ __launch_bounds__(256) void embed_kernel(
    const float* __restrict__ x_enc, const float* __restrict__ emb_w,
    float* __restrict__ x, int B, int L) {
  int i = blockIdx.x * 256 + threadIdx.x;
  int total = B * L * D_MODEL;
  if (i >= total) return;
  int d = i % D_MODEL;
  int l = (i / D_MODEL) % L;
  int b = i / (D_MODEL * L);
  int lm = (l == 0) ? (L - 1) : (l - 1);
  int lp = (l == L - 1) ? 0 : (l + 1);
  const float* w = emb_w + d * 6;
  const float* xb = x_enc + (size_t)b * L * 2;
  float acc = 0.f;
  acc += xb[lm * 2 + 0] * w[0] + xb[l * 2 + 0] * w[1] + xb[lp * 2 + 0] * w[2];
  acc += xb[lm * 2 + 1] * w[3] + xb[l * 2 + 1] * w[4] + xb[lp * 2 + 1] * w[5];
  int j = d >> 1;
  const float coef = -0.017988946039015985f;  // -ln(10000)/512
  float div = expf((float)(2 * j) * coef);
  float ang = (float)l * div;
  float pe = (d & 1) ? cosf(ang) : sinf(ang);
  x[i] = acc + pe;
}

// ---------------- layer norm over D=512 ----------------
__global__ __launch_bounds__(256) void ln_kernel(
    const float* __restrict__ in, const float* __restrict__ g,
    const float* __restrict__ b, float* __restrict__ out) {
  int row = blockIdx.x;
  int t = threadIdx.x;
  const float* xr = in + (size_t)row * D_MODEL;
  float v0 = xr[t], v1 = xr[t + 256];
  __shared__ float red[256];
  red[t] = v0 + v1;
  __syncthreads();
  for (int s = 128; s > 0; s >>= 1) { if (t < s) red[t] += red[t + s]; __syncthreads(); }
  float mean = red[0] * (1.0f / 512.0f);
  __syncthreads();
  float d0 = v0 - mean, d1 = v1 - mean;
  red[t] = d0 * d0 + d1 * d1;
  __syncthreads();
  for (int s = 128; s > 0; s >>= 1) { if (t < s) red[t] += red[t + s]; __syncthreads(); }
  float var = red[0] * (1.0f / 512.0f);
  float rstd = 1.0f / sqrtf(var + 1e-5f);
  float* outr = out + (size_t)row * D_MODEL;
  outr[t]       = d0 * rstd * g[t]       + b[t];
  outr[t + 256] = d1 * rstd * g[t + 256] + b[t + 256];
}

// MODE 0: +bias   1: gelu(+bias)   2: +bias +R   3: elu((+bias)*scl*g + bb)
__device__ __forceinline__ float epilogue_apply(int MODE, float v, float r,
                                                float g, float bb, float scl) {
  if (MODE == 1) {
    v = 0.5f * v * (1.0f + erff(v * 0.7071067811865475f));
  } else if (MODE == 2) {
    v += r;
  } else if (MODE == 3) {
    v = v * scl * g + bb;
    v = (v > 0.f) ? v : expm1f(v);
  }
  return v;
}

// ---------------- fp32 tiled GEMM 64x64, 4x4/thread ----------
#define BM 64
#define BN 64
#define BK 16
#define PADR 4

template <int MODE>
__global__ __launch_bounds__(256) void gemm_kernel(
    const float* __restrict__ A, const float* __restrict__ Bt,
    const float* __restrict__ bias, const float* __restrict__ R,
    const float* __restrict__ gvec, const float* __restrict__ bvec,
    float* __restrict__ C, int M, int N, int K, float scl) {
  __shared__ float As[BK][BM + PADR];
  __shared__ float Bs[BK][BN + PADR];
  const int bm = blockIdx.y * BM;
  const int bn = blockIdx.x * BN;
  const int tid = threadIdx.x;
  const int tx = tid & 15, ty = tid >> 4;
  const int lr = tid >> 2;
  const int lc = (tid & 3) << 2;
  const float* Aptr = A + (size_t)(bm + lr) * K + lc;
  const float* Bptr = Bt + (size_t)(bn + lr) * K + lc;
  float acc[4][4] = {};
  for (int k0 = 0; k0 < K; k0 += BK) {
    float4 av = *(const float4*)(Aptr + k0);
    float4 bv = *(const float4*)(Bptr + k0);
    As[lc + 0][lr] = av.x; As[lc + 1][lr] = av.y;
    As[lc + 2][lr] = av.z; As[lc + 3][lr] = av.w;
    Bs[lc + 0][lr] = bv.x; Bs[lc + 1][lr] = bv.y;
    Bs[lc + 2][lr] = bv.z; Bs[lc + 3][lr] = bv.w;
    __syncthreads();
#pragma unroll
    for (int kk = 0; kk < BK; ++kk) {
      float4 a4 = *(const float4*)&As[kk][ty << 2];
      float4 b4 = *(const float4*)&Bs[kk][tx << 2];
      float ar[4] = {a4.x, a4.y, a4.z, a4.w};
      float br[4] = {b4.x, b4.y, b4.z, b4.w};
#pragma unroll
      for (int i = 0; i < 4; ++i)
#pragma unroll
        for (int j = 0; j < 4; ++j) acc[i][j] += ar[i] * br[j];
    }
    __syncthreads();
  }
#pragma unroll
  for (int i = 0; i < 4; ++i) {
    int row = bm + (ty << 2) + i;
    float* Cr = C + (size_t)row * N;
    const float* Rr = (MODE == 2) ? (R + (size_t)row * N) : nullptr;
#pragma unroll
    for (int j = 0; j < 4; ++j) {
      int col = bn + (tx << 2) + j;
      float v = acc[i][j] + bias[col];
      v = epilogue_apply(MODE, v, (MODE == 2) ? Rr[col] : 0.f,
                         (MODE == 3) ? gvec[col] : 0.f,
                         (MODE == 3) ? bvec[col] : 0.f, scl);
      Cr[col] = v;
    }
  }
}

template <int MODE>
static void run_gemm(const float* A, const float* Bt, const float* bias,
                     const float* R, const float* g, const float* bb, float* C,
                     int M, int N, int K, float scl, hipStream_t stream) {
  dim3 gg(N / BN, M / BM);
  gemm_kernel<MODE><<<gg, 256, 0, stream>>>(A, Bt, bias, R, g, bb, C, M, N, K, scl);
}

// ---------------- sparse measurement M = max_u(QK) - sum_u(QK)/L ----------
__global__ __launch_bounds__(256) void sparse_m_kernel(
    const float* __restrict__ Q, const float* __restrict__ Km,
    const int* __restrict__ idx, float* __restrict__ Mout, int B, int L,
    int U) {
  int wid = (blockIdx.x * 256 + threadIdx.x) >> 6;
  int lane = threadIdx.x & 63;
  int total = B * NH * L;
  if (wid >= total) return;
  int l = wid % L;
  int bh = wid / L;
  int b = bh / NH, h = bh % NH;
  float qv = Q[((size_t)(b * L + l)) * D_MODEL + h * DH + lane];
  const float* Kbase = Km + (size_t)b * L * D_MODEL + h * DH;
  float maxv = -INFINITY, sumv = 0.f;
  for (int u = 0; u < U; ++u) {
    int ki = idx[l * U + u];
    float p = qv * Kbase[(size_t)ki * D_MODEL + lane];
#pragma unroll
    for (int m = 32; m; m >>= 1) p += __shfl_xor(p, m);
    maxv = fmaxf(maxv, p);
    sumv += p;
  }
  if (lane == 0) Mout[wid] = maxv - sumv / (float)L;
}

// ---------------- top-k (stable: ties -> lower index), u <= 40 ------------
__global__ __launch_bounds__(256) void topk_kernel(
    const float* __restrict__ Mv, int* __restrict__ Mtop, int L, int u) {
  __shared__ float sv[2048];
  __shared__ float rv[256];
  __shared__ int ri[256];
  int bh = blockIdx.x;
  int t = threadIdx.x;
  for (int l = t; l < L; l += 256) sv[l] = Mv[(size_t)bh * L + l];
  __syncthreads();
  for (int it = 0; it < u; ++it) {
    float bv = -INFINITY;
    int bi = 0x7fffffff;
    for (int l = t; l < L; l += 256) {
      float v = sv[l];
      if (v > bv || (v == bv && l < bi)) { bv = v; bi = l; }
    }
    rv[t] = bv; ri[t] = bi;
    __syncthreads();
    for (int s = 128; s > 0; s >>= 1) {
      if (t < s) {
        float v2 = rv[t + s]; int i2 = ri[t + s];
        if (v2 > rv[t] || (v2 == rv[t] && i2 < ri[t])) { rv[t] = v2; ri[t] = i2; }
      }
      __syncthreads();
    }
    if (t == 0) { Mtop[bh * u + it] = ri[0]; sv[ri[0]] = -INFINITY; }
    __syncthreads();
  }
}

// ---------------- mean of V over L per (b,h) ----------------
__global__ __launch_bounds__(256) void vmean_kernel(
    const float* __restrict__ V, float* __restrict__ vmean, int B, int L) {
  int bh = blockIdx.x;
  int b = bh / NH, h = bh % NH;
  int t = threadIdx.x;
  int e = t & 63, part = t >> 6;
  const float* base = V + (size_t)b * L * D_MODEL + h * DH + e;
  float s = 0.f;
  for (int l = part; l < L; l += 4) s += base[(size_t)l * D_MODEL];
  __shared__ float red[4][64];
  red[part][e] = s;
  __syncthreads();
  if (part == 0) {
    float tot = red[0][e] + red[1][e] + red[2][e] + red[3][e];
    vmean[bh * DH + e] = tot / (float)L;
  }
}

__global__ void fill_ctx_kernel(const float* __restrict__ vmean,
                                float* __restrict__ O, int B, int L) {
  int i = blockIdx.x * 256 + threadIdx.x;
  int total = B * L * D_MODEL;
  if (i >= total) return;
  int dcol = i % D_MODEL;
  int b = i / (D_MODEL * L);
  O[i] = vmean[(b * NH + (dcol >> 6)) * DH + (dcol & 63)];
}

// ============== attention as batched GEMM pipeline ==============
__global__ void pack_qred_kernel(const float* __restrict__ Q,
                                 const int* __restrict__ Mtop,
                                 float* __restrict__ qred, int L, int U) {
  int z = blockIdx.x;  // bh
  int b = z / NH, h = z % NH;
  int t = threadIdx.x;
  int d = t & 63;
  for (int r = t >> 6; r < 64; r += 4) {
    float v = 0.f;
    if (r < U) {
      int l = Mtop[z * U + r];
      v = Q[((size_t)(b * L + l)) * D_MODEL + h * DH + d];
    }
    qred[((size_t)z * 64 + r) * 64 + d] = v;
  }
}

// S[z][64][L] = 0.125 * Qred[z](64x64) @ K_z^T ; K_z rows stride 512
__global__ __launch_bounds__(256) void scores_gemm_kernel(
    const float* __restrict__ qred, const float* __restrict__ Km,
    float* __restrict__ S, int L) {
  __shared__ float As[BK][64 + PADR];
  __shared__ float Bs[BK][64 + PADR];
  const int z = blockIdx.y;
  const int b = z / NH, h = z % NH;
  const float* A = qred + (size_t)z * 64 * 64;
  const float* Bt = Km + (size_t)b * L * D_MODEL + h * DH;  // ldb = 512
  float* Sz = S + (size_t)z * 64 * L;
  const int bn = blockIdx.x * 64;
  const int tid = threadIdx.x;
  const int tx = tid & 15, ty = tid >> 4;
  const int lr = tid >> 2;
  const int lc = (tid & 3) << 2;
  float acc[4][4] = {};
  for (int k0 = 0; k0 < 64; k0 += BK) {
    float4 av = *(const float4*)(A + (size_t)lr * 64 + k0 + lc);
    float4 bv = *(const float4*)(Bt + (size_t)(bn + lr) * D_MODEL + k0 + lc);
    As[lc + 0][lr] = av.x; As[lc + 1][lr] = av.y;
    As[lc + 2][lr] = av.z; As[lc + 3][lr] = av.w;
    Bs[lc + 0][lr] = bv.x; Bs[lc + 1][lr] = bv.y;
    Bs[lc + 2][lr] = bv.z; Bs[lc + 3][lr] = bv.w;
    __syncthreads();
#pragma unroll
    for (int kk = 0; kk < BK; ++kk) {
      float4 a4 = *(const float4*)&As[kk][ty << 2];
      float4 b4 = *(const float4*)&Bs[kk][tx << 2];
      float ar[4] = {a4.x, a4.y, a4.z, a4.w};
      float br[4] = {b4.x, b4.y, b4.z, b4.w};
#pragma unroll
      for (int i = 0; i < 4; ++i)
#pragma unroll
        for (int j = 0; j < 4; ++j) acc[i][j] += ar[i] * br[j];
    }
    __syncthreads();
  }
#pragma unroll
  for (int i = 0; i < 4; ++i) {
    float* Sr = Sz + (size_t)((ty << 2) + i) * L + bn;
#pragma unroll
    for (int j = 0; j < 4; ++j) Sr[(tx << 2) + j] = 0.125f * acc[i][j];
  }
}

// per-row softmax over L (rows r < U only); wave per row
__global__ __launch_bounds__(256) void softmax_kernel(float* __restrict__ S,
                                                      int L, int U) {
  int z = blockIdx.x;
  int wave = threadIdx.x >> 6, lane = threadIdx.x & 63;
  for (int r = wave; r < U; r += 4) {
    float* row = S + (size_t)z * 64 * L + (size_t)r * L;
    float m = -INFINITY;
    for (int i = lane; i < L; i += 64) m = fmaxf(m, row[i]);
#pragma unroll
    for (int k = 32; k; k >>= 1) m = fmaxf(m, __shfl_xor(m, k));
    float s = 0.f;
    for (int i = lane; i < L; i += 64) {
      float e = expf(row[i] - m);
      row[i] = e;
      s += e;
    }
#pragma unroll
    for (int k = 32; k; k >>= 1) s += __shfl_xor(s, k);
    float inv = 1.0f / s;
    for (int i = lane; i < L; i += 64) row[i] *= inv;
  }
}

// zero the selected ctx rows before split-K PV atomics
__global__ void zero_sel_kernel(const int* __restrict__ Mtop,
                                float* __restrict__ O, int L, int U) {
  int z = blockIdx.x;
  int b = z / NH, h = z % NH;
  int t = threadIdx.x;
  int d = t & 63;
  for (int r = t >> 6; r < U; r += 4) {
    int l = Mtop[z * U + r];
    O[((size_t)(b * L + l)) * D_MODEL + h * DH + d] = 0.f;
  }
}

// O[sel rows] += P(UxL) @ V(Lx64), split-K over 128-chunks of L.
// LDS-tiled; U is COMPILE-TIME so acc[] stays in registers (R3's runtime-U
// version spilled acc to scratch: VGPR_Count=12, 264us).
#define PV_LC 128

template <int U>
__global__ __launch_bounds__(256) void pv_kernel(
    const float* __restrict__ P, const float* __restrict__ V,
    const int* __restrict__ Mtop, float* __restrict__ O, int L) {
  __shared__ float Pl[U][PV_LC];        // <= 40*128*4 = 20.5 KB
  __shared__ float Vl[PV_LC][DH + 4];   // 128*68*4 = 34.8 KB
  const int z = blockIdx.y;
  const int b = z / NH, h = z % NH;
  const int c0 = blockIdx.x * PV_LC;
  const int tid = threadIdx.x;
  // stage P chunk (U x 128) via float4, coalesced along l
  const float* Pz = P + (size_t)z * 64 * L + c0;
  for (int i4 = tid; i4 < U * (PV_LC / 4); i4 += 256) {
    int r = i4 / (PV_LC / 4);
    int lq = (i4 % (PV_LC / 4)) * 4;
    float4 p4 = *(const float4*)(Pz + (size_t)r * L + lq);
    Pl[r][lq + 0] = p4.x; Pl[r][lq + 1] = p4.y;
    Pl[r][lq + 2] = p4.z; Pl[r][lq + 3] = p4.w;
  }
  // stage V chunk (128 x 64) via float4, coalesced along d
  const float* Vb = V + ((size_t)b * L + c0) * D_MODEL + h * DH;
  for (int i4 = tid; i4 < PV_LC * (DH / 4); i4 += 256) {
    int l = i4 >> 4;
    int d4 = (i4 & 15) * 4;
    float4 v4 = *(const float4*)(Vb + (size_t)l * D_MODEL + d4);
    Vl[l][d4 + 0] = v4.x; Vl[l][d4 + 1] = v4.y;
    Vl[l][d4 + 2] = v4.z; Vl[l][d4 + 3] = v4.w;
  }
  __syncthreads();
  const int wave = tid >> 6, lane = tid & 63;
  constexpr int NJ = (U + 3) / 4;
  float acc[NJ] = {};
  for (int l = 0; l < PV_LC; ++l) {
    float vv = Vl[l][lane];  // stride-1 across lanes: 2-way, free
#pragma unroll
    for (int j = 0; j < NJ; ++j) {
      int r = wave + 4 * j;
      if (r < U) acc[j] += Pl[r][l] * vv;  // broadcast read, free
    }
  }
#pragma unroll
  for (int j = 0; j < NJ; ++j) {
    int r = wave + 4 * j;
    if (r < U) {
      int ml = Mtop[z * U + r];
      atomicAdd(&O[((size_t)(b * L + ml)) * D_MODEL + h * DH + lane], acc[j]);
    }
  }
}

static void run_pv(const float* P, const float* V, const int* Mtop, float* O,
                   int L, int U, hipStream_t stream) {
  dim3 gg(L / PV_LC, 32);
  if (U == 40)      pv_kernel<40><<<gg, 256, 0, stream>>>(P, V, Mtop, O, L);
  else if (U == 35) pv_kernel<35><<<gg, 256, 0, stream>>>(P, V, Mtop, O, L);
  else              pv_kernel<64><<<gg, 256, 0, stream>>>(P, V, Mtop, O, L);
}

// ---------------- im2col for circular conv (K=3) over D=512 channels ------
__global__ void im2col_kernel(const float* __restrict__ X,
                              float* __restrict__ Y, int B, int L) {
  int i = blockIdx.x * 256 + threadIdx.x;
  int total = B * L * 1536;
  if (i >= total) return;
  int ck = i % 1536;
  int l = (i / 1536) % L;
  int b = i / (1536 * L);
  int c = ck / 3, k = ck % 3;
  int lm = l + k - 1;
  if (lm < 0) lm += L;
  else if (lm >= L) lm -= L;
  Y[i] = X[((size_t)(b * L + lm)) * D_MODEL + c];
}

// ---------------- maxpool k=3 s=2, one -inf pad each side -----------------
__global__ void maxpool_kernel(const float* __restrict__ Y,
                               float* __restrict__ X, int B, int L) {
  int Lo = L / 2;
  int i = blockIdx.x * 256 + threadIdx.x;
  int total = B * Lo * D_MODEL;
  if (i >= total) return;
  int d = i % D_MODEL;
  int lp = (i / D_MODEL) % Lo;
  int b = i / (D_MODEL * Lo);
  int l0 = 2 * lp - 1;
  float m = -INFINITY;
#pragma unroll
  for (int k = 0; k < 3; ++k) {
    int l = l0 + k;
    if (l >= 0 && l < L) m = fmaxf(m, Y[((size_t)(b * L + l)) * D_MODEL + d]);
  }
  X[i] = m;
}

// ==========================================================================
extern "C" void kernel_launch(void* const* d_in, const int* in_sizes, int n_in,
                              void* d_out, int out_size, void* d_ws,
                              size_t ws_size, hipStream_t stream) {
  const float* x_enc  = (const float*)d_in[0];
  const float* emb_w  = (const float*)d_in[1];
  const float* Wq     = (const float*)d_in[2];
  const float* bq     = (const float*)d_in[3];
  const float* Wk     = (const float*)d_in[4];
  const float* bk     = (const float*)d_in[5];
  const float* Wv     = (const float*)d_in[6];
  const float* bv     = (const float*)d_in[7];
  const float* Wo     = (const float*)d_in[8];
  const float* bo     = (const float*)d_in[9];
  const float* ln1_g  = (const float*)d_in[10];
  const float* ln1_b  = (const float*)d_in[11];
  const float* ff_w1  = (const float*)d_in[12];
  const float* ff_b1  = (const float*)d_in[13];
  const float* ff_w2  = (const float*)d_in[14];
  const float* ff_b2  = (const float*)d_in[15];
  const float* ln2_g  = (const float*)d_in[16];
  const float* ln2_b  = (const float*)d_in[17];
  const float* cv_w   = (const float*)d_in[18];
  const float* cv_b   = (const float*)d_in[19];
  const float* bn_g   = (const float*)d_in[20];
  const float* bn_b   = (const float*)d_in[21];
  const float* norm_g = (const float*)d_in[22];
  const float* norm_b = (const float*)d_in[23];

  const int B = 4, L0 = 2048, EL = 3;
  const size_t SZ = (size_t)B * 2048 * 512;
  float* ws   = (float*)d_ws;
  float* xbuf = ws;
  float* ebuf = ws + SZ;       // temp / pre-LN; doubles as S/P during attn
  float* qbuf = ws + 2 * SZ;
  float* kbuf = ws + 3 * SZ;
  float* vbuf = ws + 4 * SZ;
  float* obuf = ws + 5 * SZ;
  float* im2c = qbuf;  // aliases q..v (48MB); q/k/v dead at conv time
  float* sm   = ws + 6 * SZ;
  int*   d_idx   = (int*)sm;                       // <=81920, dead after sparse_m
  float* d_M     = sm + 81920;                     // <=65536, dead after topk
  int*   d_Mtop  = (int*)(sm + 81920 + 65536);     // <=1280, live through attn
  float* d_vmean = sm + 81920 + 65536 + 1280;      // 2048
  float* qred    = sm;  // 131072 floats, reuses idx+M region (dead post-topk)
  float* Sbuf    = ebuf;  // 32*64*L <= 4.19M floats <= SZ

  const float inv_s = 1.0f / sqrtf(1.0f + 1e-5f);

  embed_kernel<<<ceil_div(B * L0 * D_MODEL, 256), 256, 0, stream>>>(
      x_enc, emb_w, xbuf, B, L0);

  int L = L0;
  for (int i = 0; i < EL; ++i) {
    const int M_ = B * L;
    int c = 5 * (int)ceil(log((double)L));
    int U = c < L ? c : L;
    const float* Wq_i = Wq + (size_t)i * 512 * 512;
    const float* Wk_i = Wk + (size_t)i * 512 * 512;
    const float* Wv_i = Wv + (size_t)i * 512 * 512;
    const float* Wo_i = Wo + (size_t)i * 512 * 512;
    const float* w1_i = ff_w1 + (size_t)i * 512 * 512;
    const float* w2_i = ff_w2 + (size_t)i * 512 * 512;

    run_gemm<0>(xbuf, Wq_i, bq + i * 512, nullptr, nullptr, nullptr, qbuf,
                M_, 512, 512, 0.f, stream);
    run_gemm<0>(xbuf, Wk_i, bk + i * 512, nullptr, nullptr, nullptr, kbuf,
                M_, 512, 512, 0.f, stream);
    run_gemm<0>(xbuf, Wv_i, bv + i * 512, nullptr, nullptr, nullptr, vbuf,
                M_, 512, 512, 0.f, stream);

    uint32_t lk0, lk1, k20, k21;
    threefry2x32(0u, 42u, 0u, (uint32_t)i, &lk0, &lk1);
    threefry2x32(lk0, lk1, 0u, 1u, &k20, &k21);
    idx_kernel<<<ceil_div(L * U, 256), 256, 0, stream>>>(d_idx, L, U, k20, k21);

    sparse_m_kernel<<<ceil_div(B * NH * L * 64, 256), 256, 0, stream>>>(
        qbuf, kbuf, d_idx, d_M, B, L, U);
    topk_kernel<<<B * NH, 256, 0, stream>>>(d_M, d_Mtop, L, U);
    vmean_kernel<<<B * NH, 256, 0, stream>>>(vbuf, d_vmean, B, L);
    fill_ctx_kernel<<<ceil_div(B * L * D_MODEL, 256), 256, 0, stream>>>(
        d_vmean, obuf, B, L);

    pack_qred_kernel<<<B * NH, 256, 0, stream>>>(qbuf, d_Mtop, qred, L, U);
    scores_gemm_kernel<<<dim3(L / 64, B * NH), 256, 0, stream>>>(qred, kbuf,
                                                                 Sbuf, L);
    softmax_kernel<<<B * NH, 256, 0, stream>>>(Sbuf, L, U);
    zero_sel_kernel<<<B * NH, 256, 0, stream>>>(d_Mtop, obuf, L, U);
    run_pv(Sbuf, vbuf, d_Mtop, obuf, L, U, stream);

    run_gemm<2>(obuf, Wo_i, bo + i * 512, xbuf, nullptr, nullptr, ebuf,
                M_, 512, 512, 0.f, stream);
    ln_kernel<<<M_, 256, 0, stream>>>(ebuf, ln1_g + i * 512, ln1_b + i * 512, xbuf);

    run_gemm<1>(xbuf, w1_i, ff_b1 + i * 512, nullptr, nullptr, nullptr, obuf,
                M_, 512, 512, 0.f, stream);
    run_gemm<2>(obuf, w2_i, ff_b2 + i * 512, xbuf, nullptr, nullptr, ebuf,
                M_, 512, 512, 0.f, stream);
    ln_kernel<<<M_, 256, 0, stream>>>(ebuf, ln2_g + i * 512, ln2_b + i * 512, xbuf);

    if (i < EL - 1) {
      im2col_kernel<<<ceil_div(B * L * 1536, 256), 256, 0, stream>>>(xbuf, im2c, B, L);
      run_gemm<3>(im2c, cv_w + (size_t)i * 512 * 1536, cv_b + i * 512, nullptr,
                  bn_g + i * 512, bn_b + i * 512, ebuf, M_, 512, 1536, inv_s,
                  stream);
      maxpool_kernel<<<ceil_div(B * (L / 2) * D_MODEL, 256), 256, 0, stream>>>(
          ebuf, xbuf, B, L);
      L /= 2;
    }
  }

  ln_kernel<<<B * L, 256, 0, stream>>>(xbuf, norm_g, norm_b, (float*)d_out);
}

// Round 5
// 2388.647 us; speedup vs baseline: 1.3572x; 1.0426x over previous
//
#include <hip/hip_runtime.h>
#include <cmath>
#include <cstdint>

#define D_MODEL 512
#define NH 8
#define DH 64

static inline int ceil_div(int a, int b) { return (a + b - 1) / b; }

// ---------------- threefry2x32 (JAX-exact) ----------------
#define TF_ROTL(x, r) (((x) << (r)) | ((x) >> (32 - (r))))

__host__ __device__ inline void threefry2x32(uint32_t k0, uint32_t k1,
                                             uint32_t x0, uint32_t x1,
                                             uint32_t* o0, uint32_t* o1) {
  uint32_t ks2 = k0 ^ k1 ^ 0x1BD11BDAu;
  x0 += k0; x1 += k1;
#define TF_R4(a, b, c, d)                                    \
  x0 += x1; x1 = TF_ROTL(x1, a); x1 ^= x0;                   \
  x0 += x1; x1 = TF_ROTL(x1, b); x1 ^= x0;                   \
  x0 += x1; x1 = TF_ROTL(x1, c); x1 ^= x0;                   \
  x0 += x1; x1 = TF_ROTL(x1, d); x1 ^= x0;
  TF_R4(13, 15, 26, 6);  x0 += k1;  x1 += ks2 + 1u;
  TF_R4(17, 29, 16, 24); x0 += ks2; x1 += k0 + 2u;
  TF_R4(13, 15, 26, 6);  x0 += k0;  x1 += k1 + 3u;
  TF_R4(17, 29, 16, 24); x0 += k1;  x1 += ks2 + 4u;
  TF_R4(13, 15, 26, 6);  x0 += ks2; x1 += k0 + 5u;
#undef TF_R4
  *o0 = x0; *o1 = x1;
}

__global__ void idx_kernel(int* __restrict__ idx, int L, int U,
                           uint32_t k0, uint32_t k1) {
  int n = blockIdx.x * 256 + threadIdx.x;
  if (n >= L * U) return;
  uint32_t o0, o1;
  threefry2x32(k0, k1, 0u, (uint32_t)n, &o0, &o1);
  idx[n] = (int)((o0 ^ o1) & (uint32_t)(L - 1));
}

// ---------------- embedding: circular conv (C=2,K=3) + pos encoding -------
__global__ __launch_bounds__(256) void embed_kernel(
    const float* __restrict__ x_enc, const float* __restrict__ emb_w,
    float* __restrict__ x, int B, int L) {
  int i = blockIdx.x * 256 + threadIdx.x;
  int total = B * L * D_MODEL;
  if (i >= total) return;
  int d = i % D_MODEL;
  int l = (i / D_MODEL) % L;
  int b = i / (D_MODEL * L);
  int lm = (l == 0) ? (L - 1) : (l - 1);
  int lp = (l == L - 1) ? 0 : (l + 1);
  const float* w = emb_w + d * 6;
  const float* xb = x_enc + (size_t)b * L * 2;
  float acc = 0.f;
  acc += xb[lm * 2 + 0] * w[0] + xb[l * 2 + 0] * w[1] + xb[lp * 2 + 0] * w[2];
  acc += xb[lm * 2 + 1] * w[3] + xb[l * 2 + 1] * w[4] + xb[lp * 2 + 1] * w[5];
  int j = d >> 1;
  const float coef = -0.017988946039015985f;  // -ln(10000)/512
  float div = expf((float)(2 * j) * coef);
  float ang = (float)l * div;
  float pe = (d & 1) ? cosf(ang) : sinf(ang);
  x[i] = acc + pe;
}

// ---------------- layer norm over D=512 ----------------
__global__ __launch_bounds__(256) void ln_kernel(
    const float* __restrict__ in, const float* __restrict__ g,
    const float* __restrict__ b, float* __restrict__ out) {
  int row = blockIdx.x;
  int t = threadIdx.x;
  const float* xr = in + (size_t)row * D_MODEL;
  float v0 = xr[t], v1 = xr[t + 256];
  __shared__ float red[256];
  red[t] = v0 + v1;
  __syncthreads();
  for (int s = 128; s > 0; s >>= 1) { if (t < s) red[t] += red[t + s]; __syncthreads(); }
  float mean = red[0] * (1.0f / 512.0f);
  __syncthreads();
  float d0 = v0 - mean, d1 = v1 - mean;
  red[t] = d0 * d0 + d1 * d1;
  __syncthreads();
  for (int s = 128; s > 0; s >>= 1) { if (t < s) red[t] += red[t + s]; __syncthreads(); }
  float var = red[0] * (1.0f / 512.0f);
  float rstd = 1.0f / sqrtf(var + 1e-5f);
  float* outr = out + (size_t)row * D_MODEL;
  outr[t]       = d0 * rstd * g[t]       + b[t];
  outr[t + 256] = d1 * rstd * g[t + 256] + b[t + 256];
}

// MODE 0: +bias   1: gelu(+bias)   2: +bias +R   3: elu((+bias)*scl*g + bb)
__device__ __forceinline__ float epilogue_apply(int MODE, float v, float r,
                                                float g, float bb, float scl) {
  if (MODE == 1) {
    v = 0.5f * v * (1.0f + erff(v * 0.7071067811865475f));
  } else if (MODE == 2) {
    v += r;
  } else if (MODE == 3) {
    v = v * scl * g + bb;
    v = (v > 0.f) ? v : expm1f(v);
  }
  return v;
}

// ---------------- fp32 tiled GEMM 64x64, 4x4/thread ----------
#define BM 64
#define BN 64
#define BK 16
#define PADR 4

template <int MODE>
__global__ __launch_bounds__(256) void gemm_kernel(
    const float* __restrict__ A, const float* __restrict__ Bt,
    const float* __restrict__ bias, const float* __restrict__ R,
    const float* __restrict__ gvec, const float* __restrict__ bvec,
    float* __restrict__ C, int M, int N, int K, float scl) {
  __shared__ float As[BK][BM + PADR];
  __shared__ float Bs[BK][BN + PADR];
  const int bm = blockIdx.y * BM;
  const int bn = blockIdx.x * BN;
  const int tid = threadIdx.x;
  const int tx = tid & 15, ty = tid >> 4;
  const int lr = tid >> 2;
  const int lc = (tid & 3) << 2;
  const float* Aptr = A + (size_t)(bm + lr) * K + lc;
  const float* Bptr = Bt + (size_t)(bn + lr) * K + lc;
  float acc[4][4] = {};
  for (int k0 = 0; k0 < K; k0 += BK) {
    float4 av = *(const float4*)(Aptr + k0);
    float4 bv = *(const float4*)(Bptr + k0);
    As[lc + 0][lr] = av.x; As[lc + 1][lr] = av.y;
    As[lc + 2][lr] = av.z; As[lc + 3][lr] = av.w;
    Bs[lc + 0][lr] = bv.x; Bs[lc + 1][lr] = bv.y;
    Bs[lc + 2][lr] = bv.z; Bs[lc + 3][lr] = bv.w;
    __syncthreads();
#pragma unroll
    for (int kk = 0; kk < BK; ++kk) {
      float4 a4 = *(const float4*)&As[kk][ty << 2];
      float4 b4 = *(const float4*)&Bs[kk][tx << 2];
      float ar[4] = {a4.x, a4.y, a4.z, a4.w};
      float br[4] = {b4.x, b4.y, b4.z, b4.w};
#pragma unroll
      for (int i = 0; i < 4; ++i)
#pragma unroll
        for (int j = 0; j < 4; ++j) acc[i][j] += ar[i] * br[j];
    }
    __syncthreads();
  }
#pragma unroll
  for (int i = 0; i < 4; ++i) {
    int row = bm + (ty << 2) + i;
    float* Cr = C + (size_t)row * N;
    const float* Rr = (MODE == 2) ? (R + (size_t)row * N) : nullptr;
#pragma unroll
    for (int j = 0; j < 4; ++j) {
      int col = bn + (tx << 2) + j;
      float v = acc[i][j] + bias[col];
      v = epilogue_apply(MODE, v, (MODE == 2) ? Rr[col] : 0.f,
                         (MODE == 3) ? gvec[col] : 0.f,
                         (MODE == 3) ? bvec[col] : 0.f, scl);
      Cr[col] = v;
    }
  }
}

template <int MODE>
static void run_gemm(const float* A, const float* Bt, const float* bias,
                     const float* R, const float* g, const float* bb, float* C,
                     int M, int N, int K, float scl, hipStream_t stream) {
  dim3 gg(N / BN, M / BM);
  gemm_kernel<MODE><<<gg, 256, 0, stream>>>(A, Bt, bias, R, g, bb, C, M, N, K, scl);
}

// ---------------- sparse QK samples: one THREAD per (b,h,l,u) -------------
// No cross-lane ops; 16 independent float4 gathers per thread; write
// coalesced. Replaces the wave-per-query 40x6 dependent-shfl chain (218us).
__global__ __launch_bounds__(256) void sparse_qk_kernel(
    const float* __restrict__ Q, const float* __restrict__ Km,
    const int* __restrict__ idx, float* __restrict__ QKs, int B, int L,
    int U) {
  int n = blockIdx.x * 256 + threadIdx.x;
  int total = B * NH * L * U;
  if (n >= total) return;
  int u = n % U;
  int l = (n / U) % L;
  int bh = n / (U * L);
  int b = bh / NH, h = bh % NH;
  int ki = idx[l * U + u];
  const float4* qr = (const float4*)(Q + ((size_t)(b * L + l)) * D_MODEL + h * DH);
  const float4* kr = (const float4*)(Km + ((size_t)(b * L + ki)) * D_MODEL + h * DH);
  float s = 0.f;
#pragma unroll
  for (int e = 0; e < 16; ++e) {
    float4 q4 = qr[e];
    float4 k4 = kr[e];
    s += q4.x * k4.x + q4.y * k4.y + q4.z * k4.z + q4.w * k4.w;
  }
  QKs[n] = s;
}

// M[bh*L+l] = max_u(QKs) - sum_u(QKs)/L ; one wave per query, ONE butterfly
__global__ __launch_bounds__(256) void sparse_reduce_kernel(
    const float* __restrict__ QKs, float* __restrict__ Mout, int total,
    int L, int U) {
  int wid = (blockIdx.x * 256 + threadIdx.x) >> 6;
  int lane = threadIdx.x & 63;
  if (wid >= total) return;
  float v = (lane < U) ? QKs[(size_t)wid * U + lane] : -INFINITY;
  float m = v;
#pragma unroll
  for (int k = 32; k; k >>= 1) m = fmaxf(m, __shfl_xor(m, k));
  float sv = (lane < U) ? v : 0.f;
#pragma unroll
  for (int k = 32; k; k >>= 1) sv += __shfl_xor(sv, k);
  if (lane == 0) Mout[wid] = m - sv / (float)L;
}

// ---------------- top-k (stable: ties -> lower index), u <= 40 ------------
__global__ __launch_bounds__(256) void topk_kernel(
    const float* __restrict__ Mv, int* __restrict__ Mtop, int L, int u) {
  __shared__ float sv[2048];
  __shared__ float rv[256];
  __shared__ int ri[256];
  int bh = blockIdx.x;
  int t = threadIdx.x;
  for (int l = t; l < L; l += 256) sv[l] = Mv[(size_t)bh * L + l];
  __syncthreads();
  for (int it = 0; it < u; ++it) {
    float bv = -INFINITY;
    int bi = 0x7fffffff;
    for (int l = t; l < L; l += 256) {
      float v = sv[l];
      if (v > bv || (v == bv && l < bi)) { bv = v; bi = l; }
    }
    rv[t] = bv; ri[t] = bi;
    __syncthreads();
    for (int s = 128; s > 0; s >>= 1) {
      if (t < s) {
        float v2 = rv[t + s]; int i2 = ri[t + s];
        if (v2 > rv[t] || (v2 == rv[t] && i2 < ri[t])) { rv[t] = v2; ri[t] = i2; }
      }
      __syncthreads();
    }
    if (t == 0) { Mtop[bh * u + it] = ri[0]; sv[ri[0]] = -INFINITY; }
    __syncthreads();
  }
}

// ---------------- mean of V over L per (b,h) ----------------
__global__ __launch_bounds__(256) void vmean_kernel(
    const float* __restrict__ V, float* __restrict__ vmean, int B, int L) {
  int bh = blockIdx.x;
  int b = bh / NH, h = bh % NH;
  int t = threadIdx.x;
  int e = t & 63, part = t >> 6;
  const float* base = V + (size_t)b * L * D_MODEL + h * DH + e;
  float s = 0.f;
  for (int l = part; l < L; l += 4) s += base[(size_t)l * D_MODEL];
  __shared__ float red[4][64];
  red[part][e] = s;
  __syncthreads();
  if (part == 0) {
    float tot = red[0][e] + red[1][e] + red[2][e] + red[3][e];
    vmean[bh * DH + e] = tot / (float)L;
  }
}

__global__ void fill_ctx_kernel(const float* __restrict__ vmean,
                                float* __restrict__ O, int B, int L) {
  int i = blockIdx.x * 256 + threadIdx.x;
  int total = B * L * D_MODEL;
  if (i >= total) return;
  int dcol = i % D_MODEL;
  int b = i / (D_MODEL * L);
  O[i] = vmean[(b * NH + (dcol >> 6)) * DH + (dcol & 63)];
}

// ============== attention as batched GEMM pipeline ==============
__global__ void pack_qred_kernel(const float* __restrict__ Q,
                                 const int* __restrict__ Mtop,
                                 float* __restrict__ qred, int L, int U) {
  int z = blockIdx.x;  // bh
  int b = z / NH, h = z % NH;
  int t = threadIdx.x;
  int d = t & 63;
  for (int r = t >> 6; r < 64; r += 4) {
    float v = 0.f;
    if (r < U) {
      int l = Mtop[z * U + r];
      v = Q[((size_t)(b * L + l)) * D_MODEL + h * DH + d];
    }
    qred[((size_t)z * 64 + r) * 64 + d] = v;
  }
}

// S[z][64][L] = 0.125 * Qred[z](64x64) @ K_z^T ; K_z rows stride 512
__global__ __launch_bounds__(256) void scores_gemm_kernel(
    const float* __restrict__ qred, const float* __restrict__ Km,
    float* __restrict__ S, int L) {
  __shared__ float As[BK][64 + PADR];
  __shared__ float Bs[BK][64 + PADR];
  const int z = blockIdx.y;
  const int b = z / NH, h = z % NH;
  const float* A = qred + (size_t)z * 64 * 64;
  const float* Bt = Km + (size_t)b * L * D_MODEL + h * DH;  // ldb = 512
  float* Sz = S + (size_t)z * 64 * L;
  const int bn = blockIdx.x * 64;
  const int tid = threadIdx.x;
  const int tx = tid & 15, ty = tid >> 4;
  const int lr = tid >> 2;
  const int lc = (tid & 3) << 2;
  float acc[4][4] = {};
  for (int k0 = 0; k0 < 64; k0 += BK) {
    float4 av = *(const float4*)(A + (size_t)lr * 64 + k0 + lc);
    float4 bv = *(const float4*)(Bt + (size_t)(bn + lr) * D_MODEL + k0 + lc);
    As[lc + 0][lr] = av.x; As[lc + 1][lr] = av.y;
    As[lc + 2][lr] = av.z; As[lc + 3][lr] = av.w;
    Bs[lc + 0][lr] = bv.x; Bs[lc + 1][lr] = bv.y;
    Bs[lc + 2][lr] = bv.z; Bs[lc + 3][lr] = bv.w;
    __syncthreads();
#pragma unroll
    for (int kk = 0; kk < BK; ++kk) {
      float4 a4 = *(const float4*)&As[kk][ty << 2];
      float4 b4 = *(const float4*)&Bs[kk][tx << 2];
      float ar[4] = {a4.x, a4.y, a4.z, a4.w};
      float br[4] = {b4.x, b4.y, b4.z, b4.w};
#pragma unroll
      for (int i = 0; i < 4; ++i)
#pragma unroll
        for (int j = 0; j < 4; ++j) acc[i][j] += ar[i] * br[j];
    }
    __syncthreads();
  }
#pragma unroll
  for (int i = 0; i < 4; ++i) {
    float* Sr = Sz + (size_t)((ty << 2) + i) * L + bn;
#pragma unroll
    for (int j = 0; j < 4; ++j) Sr[(tx << 2) + j] = 0.125f * acc[i][j];
  }
}

// per-row softmax over L (rows r < U only); wave per row
__global__ __launch_bounds__(256) void softmax_kernel(float* __restrict__ S,
                                                      int L, int U) {
  int z = blockIdx.x;
  int wave = threadIdx.x >> 6, lane = threadIdx.x & 63;
  for (int r = wave; r < U; r += 4) {
    float* row = S + (size_t)z * 64 * L + (size_t)r * L;
    float m = -INFINITY;
    for (int i = lane; i < L; i += 64) m = fmaxf(m, row[i]);
#pragma unroll
    for (int k = 32; k; k >>= 1) m = fmaxf(m, __shfl_xor(m, k));
    float s = 0.f;
    for (int i = lane; i < L; i += 64) {
      float e = expf(row[i] - m);
      row[i] = e;
      s += e;
    }
#pragma unroll
    for (int k = 32; k; k >>= 1) s += __shfl_xor(s, k);
    float inv = 1.0f / s;
    for (int i = lane; i < L; i += 64) row[i] *= inv;
  }
}

// zero the selected ctx rows before split-K PV atomics
__global__ void zero_sel_kernel(const int* __restrict__ Mtop,
                                float* __restrict__ O, int L, int U) {
  int z = blockIdx.x;
  int b = z / NH, h = z % NH;
  int t = threadIdx.x;
  int d = t & 63;
  for (int r = t >> 6; r < U; r += 4) {
    int l = Mtop[z * U + r];
    O[((size_t)(b * L + l)) * D_MODEL + h * DH + d] = 0.f;
  }
}

// O[sel rows] += P(UxL) @ V(Lx64), split-K over 128-chunks of L.
#define PV_LC 128

template <int U>
__global__ __launch_bounds__(256) void pv_kernel(
    const float* __restrict__ P, const float* __restrict__ V,
    const int* __restrict__ Mtop, float* __restrict__ O, int L) {
  __shared__ float Pl[U][PV_LC];
  __shared__ float Vl[PV_LC][DH + 4];
  const int z = blockIdx.y;
  const int b = z / NH, h = z % NH;
  const int c0 = blockIdx.x * PV_LC;
  const int tid = threadIdx.x;
  const float* Pz = P + (size_t)z * 64 * L + c0;
  for (int i4 = tid; i4 < U * (PV_LC / 4); i4 += 256) {
    int r = i4 / (PV_LC / 4);
    int lq = (i4 % (PV_LC / 4)) * 4;
    float4 p4 = *(const float4*)(Pz + (size_t)r * L + lq);
    Pl[r][lq + 0] = p4.x; Pl[r][lq + 1] = p4.y;
    Pl[r][lq + 2] = p4.z; Pl[r][lq + 3] = p4.w;
  }
  const float* Vb = V + ((size_t)b * L + c0) * D_MODEL + h * DH;
  for (int i4 = tid; i4 < PV_LC * (DH / 4); i4 += 256) {
    int l = i4 >> 4;
    int d4 = (i4 & 15) * 4;
    float4 v4 = *(const float4*)(Vb + (size_t)l * D_MODEL + d4);
    Vl[l][d4 + 0] = v4.x; Vl[l][d4 + 1] = v4.y;
    Vl[l][d4 + 2] = v4.z; Vl[l][d4 + 3] = v4.w;
  }
  __syncthreads();
  const int wave = tid >> 6, lane = tid & 63;
  constexpr int NJ = (U + 3) / 4;
  float acc[NJ] = {};
  for (int l = 0; l < PV_LC; ++l) {
    float vv = Vl[l][lane];
#pragma unroll
    for (int j = 0; j < NJ; ++j) {
      int r = wave + 4 * j;
      if (r < U) acc[j] += Pl[r][l] * vv;
    }
  }
#pragma unroll
  for (int j = 0; j < NJ; ++j) {
    int r = wave + 4 * j;
    if (r < U) {
      int ml = Mtop[z * U + r];
      atomicAdd(&O[((size_t)(b * L + ml)) * D_MODEL + h * DH + lane], acc[j]);
    }
  }
}

static void run_pv(const float* P, const float* V, const int* Mtop, float* O,
                   int L, int U, hipStream_t stream) {
  dim3 gg(L / PV_LC, 32);
  if (U == 40)      pv_kernel<40><<<gg, 256, 0, stream>>>(P, V, Mtop, O, L);
  else if (U == 35) pv_kernel<35><<<gg, 256, 0, stream>>>(P, V, Mtop, O, L);
  else              pv_kernel<64><<<gg, 256, 0, stream>>>(P, V, Mtop, O, L);
}

// ---------------- im2col for circular conv (K=3) over D=512 channels ------
__global__ void im2col_kernel(const float* __restrict__ X,
                              float* __restrict__ Y, int B, int L) {
  int i = blockIdx.x * 256 + threadIdx.x;
  int total = B * L * 1536;
  if (i >= total) return;
  int ck = i % 1536;
  int l = (i / 1536) % L;
  int b = i / (1536 * L);
  int c = ck / 3, k = ck % 3;
  int lm = l + k - 1;
  if (lm < 0) lm += L;
  else if (lm >= L) lm -= L;
  Y[i] = X[((size_t)(b * L + lm)) * D_MODEL + c];
}

// ---------------- maxpool k=3 s=2, one -inf pad each side -----------------
__global__ void maxpool_kernel(const float* __restrict__ Y,
                               float* __restrict__ X, int B, int L) {
  int Lo = L / 2;
  int i = blockIdx.x * 256 + threadIdx.x;
  int total = B * Lo * D_MODEL;
  if (i >= total) return;
  int d = i % D_MODEL;
  int lp = (i / D_MODEL) % Lo;
  int b = i / (D_MODEL * Lo);
  int l0 = 2 * lp - 1;
  float m = -INFINITY;
#pragma unroll
  for (int k = 0; k < 3; ++k) {
    int l = l0 + k;
    if (l >= 0 && l < L) m = fmaxf(m, Y[((size_t)(b * L + l)) * D_MODEL + d]);
  }
  X[i] = m;
}

// ==========================================================================
extern "C" void kernel_launch(void* const* d_in, const int* in_sizes, int n_in,
                              void* d_out, int out_size, void* d_ws,
                              size_t ws_size, hipStream_t stream) {
  const float* x_enc  = (const float*)d_in[0];
  const float* emb_w  = (const float*)d_in[1];
  const float* Wq     = (const float*)d_in[2];
  const float* bq     = (const float*)d_in[3];
  const float* Wk     = (const float*)d_in[4];
  const float* bk     = (const float*)d_in[5];
  const float* Wv     = (const float*)d_in[6];
  const float* bv     = (const float*)d_in[7];
  const float* Wo     = (const float*)d_in[8];
  const float* bo     = (const float*)d_in[9];
  const float* ln1_g  = (const float*)d_in[10];
  const float* ln1_b  = (const float*)d_in[11];
  const float* ff_w1  = (const float*)d_in[12];
  const float* ff_b1  = (const float*)d_in[13];
  const float* ff_w2  = (const float*)d_in[14];
  const float* ff_b2  = (const float*)d_in[15];
  const float* ln2_g  = (const float*)d_in[16];
  const float* ln2_b  = (const float*)d_in[17];
  const float* cv_w   = (const float*)d_in[18];
  const float* cv_b   = (const float*)d_in[19];
  const float* bn_g   = (const float*)d_in[20];
  const float* bn_b   = (const float*)d_in[21];
  const float* norm_g = (const float*)d_in[22];
  const float* norm_b = (const float*)d_in[23];

  const int B = 4, L0 = 2048, EL = 3;
  const size_t SZ = (size_t)B * 2048 * 512;
  float* ws   = (float*)d_ws;
  float* xbuf = ws;
  float* ebuf = ws + SZ;   // pre-LN temp; QKs during sparse phase; Sbuf during attn
  float* qbuf = ws + 2 * SZ;
  float* kbuf = ws + 3 * SZ;
  float* vbuf = ws + 4 * SZ;
  float* obuf = ws + 5 * SZ;
  float* im2c = qbuf;  // aliases q..v (48MB); q/k/v dead at conv time
  float* sm   = ws + 6 * SZ;
  int*   d_idx   = (int*)sm;                       // <=81920, dead after sparse_qk
  float* d_M     = sm + 81920;                     // <=65536, dead after topk
  int*   d_Mtop  = (int*)(sm + 81920 + 65536);     // <=1280, live through attn
  float* d_vmean = sm + 81920 + 65536 + 1280;      // 2048
  float* qred    = sm;    // 131072 floats, reuses idx+M region (dead post-topk)
  float* QKs     = ebuf;  // B*NH*L*U <= 2.62M floats <= SZ; dead before Sbuf
  float* Sbuf    = ebuf;  // 32*64*L <= 4.19M floats <= SZ

  const float inv_s = 1.0f / sqrtf(1.0f + 1e-5f);

  embed_kernel<<<ceil_div(B * L0 * D_MODEL, 256), 256, 0, stream>>>(
      x_enc, emb_w, xbuf, B, L0);

  int L = L0;
  for (int i = 0; i < EL; ++i) {
    const int M_ = B * L;
    int c = 5 * (int)ceil(log((double)L));
    int U = c < L ? c : L;
    const float* Wq_i = Wq + (size_t)i * 512 * 512;
    const float* Wk_i = Wk + (size_t)i * 512 * 512;
    const float* Wv_i = Wv + (size_t)i * 512 * 512;
    const float* Wo_i = Wo + (size_t)i * 512 * 512;
    const float* w1_i = ff_w1 + (size_t)i * 512 * 512;
    const float* w2_i = ff_w2 + (size_t)i * 512 * 512;

    run_gemm<0>(xbuf, Wq_i, bq + i * 512, nullptr, nullptr, nullptr, qbuf,
                M_, 512, 512, 0.f, stream);
    run_gemm<0>(xbuf, Wk_i, bk + i * 512, nullptr, nullptr, nullptr, kbuf,
                M_, 512, 512, 0.f, stream);
    run_gemm<0>(xbuf, Wv_i, bv + i * 512, nullptr, nullptr, nullptr, vbuf,
                M_, 512, 512, 0.f, stream);

    uint32_t lk0, lk1, k20, k21;
    threefry2x32(0u, 42u, 0u, (uint32_t)i, &lk0, &lk1);
    threefry2x32(lk0, lk1, 0u, 1u, &k20, &k21);
    idx_kernel<<<ceil_div(L * U, 256), 256, 0, stream>>>(d_idx, L, U, k20, k21);

    int nqk = B * NH * L * U;
    sparse_qk_kernel<<<ceil_div(nqk, 256), 256, 0, stream>>>(
        qbuf, kbuf, d_idx, QKs, B, L, U);
    sparse_reduce_kernel<<<ceil_div(B * NH * L * 64, 256), 256, 0, stream>>>(
        QKs, d_M, B * NH * L, L, U);
    topk_kernel<<<B * NH, 256, 0, stream>>>(d_M, d_Mtop, L, U);
    vmean_kernel<<<B * NH, 256, 0, stream>>>(vbuf, d_vmean, B, L);
    fill_ctx_kernel<<<ceil_div(B * L * D_MODEL, 256), 256, 0, stream>>>(
        d_vmean, obuf, B, L);

    pack_qred_kernel<<<B * NH, 256, 0, stream>>>(qbuf, d_Mtop, qred, L, U);
    scores_gemm_kernel<<<dim3(L / 64, B * NH), 256, 0, stream>>>(qred, kbuf,
                                                                 Sbuf, L);
    softmax_kernel<<<B * NH, 256, 0, stream>>>(Sbuf, L, U);
    zero_sel_kernel<<<B * NH, 256, 0, stream>>>(d_Mtop, obuf, L, U);
    run_pv(Sbuf, vbuf, d_Mtop, obuf, L, U, stream);

    run_gemm<2>(obuf, Wo_i, bo + i * 512, xbuf, nullptr, nullptr, ebuf,
                M_, 512, 512, 0.f, stream);
    ln_kernel<<<M_, 256, 0, stream>>>(ebuf, ln1_g + i * 512, ln1_b + i * 512, xbuf);

    run_gemm<1>(xbuf, w1_i, ff_b1 + i * 512, nullptr, nullptr, nullptr, obuf,
                M_, 512, 512, 0.f, stream);
    run_gemm<2>(obuf, w2_i, ff_b2 + i * 512, xbuf, nullptr, nullptr, ebuf,
                M_, 512, 512, 0.f, stream);
    ln_kernel<<<M_, 256, 0, stream>>>(ebuf, ln2_g + i * 512, ln2_b + i * 512, xbuf);

    if (i < EL - 1) {
      im2col_kernel<<<ceil_div(B * L * 1536, 256), 256, 0, stream>>>(xbuf, im2c, B, L);
      run_gemm<3>(im2c, cv_w + (size_t)i * 512 * 1536, cv_b + i * 512, nullptr,
                  bn_g + i * 512, bn_b + i * 512, ebuf, M_, 512, 1536, inv_s,
                  stream);
      maxpool_kernel<<<ceil_div(B * (L / 2) * D_MODEL, 256), 256, 0, stream>>>(
          ebuf, xbuf, B, L);
      L /= 2;
    }
  }

  ln_kernel<<<B * L, 256, 0, stream>>>(xbuf, norm_g, norm_b, (float*)d_out);
}

// Round 6
// 1831.089 us; speedup vs baseline: 1.7705x; 1.3045x over previous
//
#include <hip/hip_runtime.h>
#include <cmath>
#include <cstdint>

#define D_MODEL 512
#define NH 8
#define DH 64

static inline int ceil_div(int a, int b) { return (a + b - 1) / b; }

typedef __attribute__((ext_vector_type(8))) short short8;
typedef __attribute__((ext_vector_type(4))) float floatx4;

// fp32 -> bf16 (RNE)
__device__ __forceinline__ unsigned short f2bf(float f) {
  uint32_t u = __float_as_uint(f);
  uint32_t r = (u + 0x7fffu + ((u >> 16) & 1u)) >> 16;
  return (unsigned short)r;
}

// ---------------- threefry2x32 (JAX-exact) ----------------
#define TF_ROTL(x, r) (((x) << (r)) | ((x) >> (32 - (r))))

__host__ __device__ inline void threefry2x32(uint32_t k0, uint32_t k1,
                                             uint32_t x0, uint32_t x1,
                                             uint32_t* o0, uint32_t* o1) {
  uint32_t ks2 = k0 ^ k1 ^ 0x1BD11BDAu;
  x0 += k0; x1 += k1;
#define TF_R4(a, b, c, d)                                    \
  x0 += x1; x1 = TF_ROTL(x1, a); x1 ^= x0;                   \
  x0 += x1; x1 = TF_ROTL(x1, b); x1 ^= x0;                   \
  x0 += x1; x1 = TF_ROTL(x1, c); x1 ^= x0;                   \
  x0 += x1; x1 = TF_ROTL(x1, d); x1 ^= x0;
  TF_R4(13, 15, 26, 6);  x0 += k1;  x1 += ks2 + 1u;
  TF_R4(17, 29, 16, 24); x0 += ks2; x1 += k0 + 2u;
  TF_R4(13, 15, 26, 6);  x0 += k0;  x1 += k1 + 3u;
  TF_R4(17, 29, 16, 24); x0 += k1;  x1 += ks2 + 4u;
  TF_R4(13, 15, 26, 6);  x0 += ks2; x1 += k0 + 5u;
#undef TF_R4
  *o0 = x0; *o1 = x1;
}

__global__ void idx_kernel(int* __restrict__ idx, int L, int U,
                           uint32_t k0, uint32_t k1) {
  int n = blockIdx.x * 256 + threadIdx.x;
  if (n >= L * U) return;
  uint32_t o0, o1;
  threefry2x32(k0, k1, 0u, (uint32_t)n, &o0, &o1);
  idx[n] = (int)((o0 ^ o1) & (uint32_t)(L - 1));
}

// ---------------- fp32 -> bf16 cast, 4 elems/thread ----------------
__global__ __launch_bounds__(256) void cast_bf16_kernel(
    const float* __restrict__ src, unsigned short* __restrict__ dst, int n) {
  int i = (blockIdx.x * 256 + threadIdx.x) * 4;
  if (i >= n) return;
  float4 v = *(const float4*)(src + i);
  ushort4 o;
  o.x = f2bf(v.x); o.y = f2bf(v.y); o.z = f2bf(v.z); o.w = f2bf(v.w);
  *(ushort4*)(dst + i) = o;
}

// ---------------- embedding: circular conv (C=2,K=3) + pos encoding -------
__global__ __launch_bounds__(256) void embed_kernel(
    const float* __restrict__ x_enc, const float* __restrict__ emb_w,
    float* __restrict__ x, int B, int L) {
  int i = blockIdx.x * 256 + threadIdx.x;
  int total = B * L * D_MODEL;
  if (i >= total) return;
  int d = i % D_MODEL;
  int l = (i / D_MODEL) % L;
  int b = i / (D_MODEL * L);
  int lm = (l == 0) ? (L - 1) : (l - 1);
  int lp = (l == L - 1) ? 0 : (l + 1);
  const float* w = emb_w + d * 6;
  const float* xb = x_enc + (size_t)b * L * 2;
  float acc = 0.f;
  acc += xb[lm * 2 + 0] * w[0] + xb[l * 2 + 0] * w[1] + xb[lp * 2 + 0] * w[2];
  acc += xb[lm * 2 + 1] * w[3] + xb[l * 2 + 1] * w[4] + xb[lp * 2 + 1] * w[5];
  int j = d >> 1;
  const float coef = -0.017988946039015985f;  // -ln(10000)/512
  float div = expf((float)(2 * j) * coef);
  float ang = (float)l * div;
  float pe = (d & 1) ? cosf(ang) : sinf(ang);
  x[i] = acc + pe;
}

// ---------------- layer norm over D=512 ----------------
__global__ __launch_bounds__(256) void ln_kernel(
    const float* __restrict__ in, const float* __restrict__ g,
    const float* __restrict__ b, float* __restrict__ out) {
  int row = blockIdx.x;
  int t = threadIdx.x;
  const float* xr = in + (size_t)row * D_MODEL;
  float v0 = xr[t], v1 = xr[t + 256];
  __shared__ float red[256];
  red[t] = v0 + v1;
  __syncthreads();
  for (int s = 128; s > 0; s >>= 1) { if (t < s) red[t] += red[t + s]; __syncthreads(); }
  float mean = red[0] * (1.0f / 512.0f);
  __syncthreads();
  float d0 = v0 - mean, d1 = v1 - mean;
  red[t] = d0 * d0 + d1 * d1;
  __syncthreads();
  for (int s = 128; s > 0; s >>= 1) { if (t < s) red[t] += red[t + s]; __syncthreads(); }
  float var = red[0] * (1.0f / 512.0f);
  float rstd = 1.0f / sqrtf(var + 1e-5f);
  float* outr = out + (size_t)row * D_MODEL;
  outr[t]       = d0 * rstd * g[t]       + b[t];
  outr[t + 256] = d1 * rstd * g[t + 256] + b[t + 256];
}

// MODE 0: +bias   1: gelu(+bias)   2: +bias +R   3: elu((+bias)*scl*g + bb)
__device__ __forceinline__ float epilogue_apply(int MODE, float v, float r,
                                                float g, float bb, float scl) {
  if (MODE == 1) {
    v = 0.5f * v * (1.0f + erff(v * 0.7071067811865475f));
  } else if (MODE == 2) {
    v += r;
  } else if (MODE == 3) {
    v = v * scl * g + bb;
    v = (v > 0.f) ? v : expm1f(v);
  }
  return v;
}

// ---------------- fp32 tiled GEMM 64x64 (Q,K projections only) ------------
#define BM 64
#define BN 64
#define BK 16
#define PADR 4

template <int MODE>
__global__ __launch_bounds__(256) void gemm_kernel(
    const float* __restrict__ A, const float* __restrict__ Bt,
    const float* __restrict__ bias, const float* __restrict__ R,
    const float* __restrict__ gvec, const float* __restrict__ bvec,
    float* __restrict__ C, int M, int N, int K, float scl) {
  __shared__ float As[BK][BM + PADR];
  __shared__ float Bs[BK][BN + PADR];
  const int bm = blockIdx.y * BM;
  const int bn = blockIdx.x * BN;
  const int tid = threadIdx.x;
  const int tx = tid & 15, ty = tid >> 4;
  const int lr = tid >> 2;
  const int lc = (tid & 3) << 2;
  const float* Aptr = A + (size_t)(bm + lr) * K + lc;
  const float* Bptr = Bt + (size_t)(bn + lr) * K + lc;
  float acc[4][4] = {};
  for (int k0 = 0; k0 < K; k0 += BK) {
    float4 av = *(const float4*)(Aptr + k0);
    float4 bv = *(const float4*)(Bptr + k0);
    As[lc + 0][lr] = av.x; As[lc + 1][lr] = av.y;
    As[lc + 2][lr] = av.z; As[lc + 3][lr] = av.w;
    Bs[lc + 0][lr] = bv.x; Bs[lc + 1][lr] = bv.y;
    Bs[lc + 2][lr] = bv.z; Bs[lc + 3][lr] = bv.w;
    __syncthreads();
#pragma unroll
    for (int kk = 0; kk < BK; ++kk) {
      float4 a4 = *(const float4*)&As[kk][ty << 2];
      float4 b4 = *(const float4*)&Bs[kk][tx << 2];
      float ar[4] = {a4.x, a4.y, a4.z, a4.w};
      float br[4] = {b4.x, b4.y, b4.z, b4.w};
#pragma unroll
      for (int i = 0; i < 4; ++i)
#pragma unroll
        for (int j = 0; j < 4; ++j) acc[i][j] += ar[i] * br[j];
    }
    __syncthreads();
  }
#pragma unroll
  for (int i = 0; i < 4; ++i) {
    int row = bm + (ty << 2) + i;
    float* Cr = C + (size_t)row * N;
    const float* Rr = (MODE == 2) ? (R + (size_t)row * N) : nullptr;
#pragma unroll
    for (int j = 0; j < 4; ++j) {
      int col = bn + (tx << 2) + j;
      float v = acc[i][j] + bias[col];
      v = epilogue_apply(MODE, v, (MODE == 2) ? Rr[col] : 0.f,
                         (MODE == 3) ? gvec[col] : 0.f,
                         (MODE == 3) ? bvec[col] : 0.f, scl);
      Cr[col] = v;
    }
  }
}

template <int MODE>
static void run_gemm(const float* A, const float* Bt, const float* bias,
                     const float* R, const float* g, const float* bb, float* C,
                     int M, int N, int K, float scl, hipStream_t stream) {
  dim3 gg(N / BN, M / BM);
  gemm_kernel<MODE><<<gg, 256, 0, stream>>>(A, Bt, bias, R, g, bb, C, M, N, K, scl);
}

// ---------------- bf16 MFMA GEMM 64x64, BK=32, 4 waves (32x32 each) -------
// A: MxK bf16 row-major; Bt: NxK bf16 row-major. C fp32 with fused epilogue.
// Fragment layouts (m91/m120-verified): A/B [m|n=lane&15][k=quad*8+j],
// C/D col=lane&15, row=quad*4+reg. LDS rows padded to 40 shorts (20-word
// stride): frag ds_read_b128 <=2-way bank aliasing (free).
template <int MODE>
__global__ __launch_bounds__(256) void bgemm_kernel(
    const unsigned short* __restrict__ A, const unsigned short* __restrict__ Bt,
    const float* __restrict__ bias, const float* __restrict__ R,
    const float* __restrict__ gvec, const float* __restrict__ bvec,
    float* __restrict__ C, int M, int N, int K, float scl) {
  __shared__ unsigned short Al[64][40];
  __shared__ unsigned short Bl[64][40];
  const int bm = blockIdx.y * 64, bn = blockIdx.x * 64;
  const int tid = threadIdx.x;
  const int wave = tid >> 6, lane = tid & 63;
  const int wm = (wave >> 1) * 32, wn = (wave & 1) * 32;
  const int quad = lane >> 4, l16 = lane & 15;
  const int sr = tid >> 2;         // staging row 0..63
  const int sc = (tid & 3) * 8;    // staging col 0,8,16,24
  const unsigned short* Ag = A + (size_t)(bm + sr) * K + sc;
  const unsigned short* Bg = Bt + (size_t)(bn + sr) * K + sc;
  floatx4 zero = {0.f, 0.f, 0.f, 0.f};
  floatx4 acc00 = zero, acc01 = zero, acc10 = zero, acc11 = zero;
  for (int k0 = 0; k0 < K; k0 += 32) {
    short8 a8 = *(const short8*)(Ag + k0);
    short8 b8 = *(const short8*)(Bg + k0);
    *(short8*)&Al[sr][sc] = a8;
    *(short8*)&Bl[sr][sc] = b8;
    __syncthreads();
    short8 af0 = *(const short8*)&Al[wm + l16][quad * 8];
    short8 af1 = *(const short8*)&Al[wm + 16 + l16][quad * 8];
    short8 bf0 = *(const short8*)&Bl[wn + l16][quad * 8];
    short8 bf1 = *(const short8*)&Bl[wn + 16 + l16][quad * 8];
    acc00 = __builtin_amdgcn_mfma_f32_16x16x32_bf16(af0, bf0, acc00, 0, 0, 0);
    acc01 = __builtin_amdgcn_mfma_f32_16x16x32_bf16(af0, bf1, acc01, 0, 0, 0);
    acc10 = __builtin_amdgcn_mfma_f32_16x16x32_bf16(af1, bf0, acc10, 0, 0, 0);
    acc11 = __builtin_amdgcn_mfma_f32_16x16x32_bf16(af1, bf1, acc11, 0, 0, 0);
    __syncthreads();
  }
  floatx4 accs[2][2] = {{acc00, acc01}, {acc10, acc11}};
#pragma unroll
  for (int i = 0; i < 2; ++i) {
#pragma unroll
    for (int j = 0; j < 2; ++j) {
      int col = bn + wn + j * 16 + l16;
#pragma unroll
      for (int p = 0; p < 4; ++p) {
        int row = bm + wm + i * 16 + quad * 4 + p;
        float v = accs[i][j][p] + bias[col];
        v = epilogue_apply(MODE, v, (MODE == 2) ? R[(size_t)row * N + col] : 0.f,
                           (MODE == 3) ? gvec[col] : 0.f,
                           (MODE == 3) ? bvec[col] : 0.f, scl);
        C[(size_t)row * N + col] = v;
      }
    }
  }
}

template <int MODE>
static void run_bgemm(const unsigned short* A, const unsigned short* Bt,
                      const float* bias, const float* R, const float* g,
                      const float* bb, float* C, int M, int N, int K,
                      float scl, hipStream_t stream) {
  dim3 gg(N / 64, M / 64);
  bgemm_kernel<MODE><<<gg, 256, 0, stream>>>(A, Bt, bias, R, g, bb, C, M, N, K, scl);
}

// ---------------- sparse QK samples: one THREAD per (b,h,l,u) -------------
__global__ __launch_bounds__(256) void sparse_qk_kernel(
    const float* __restrict__ Q, const float* __restrict__ Km,
    const int* __restrict__ idx, float* __restrict__ QKs, int B, int L,
    int U) {
  int n = blockIdx.x * 256 + threadIdx.x;
  int total = B * NH * L * U;
  if (n >= total) return;
  int u = n % U;
  int l = (n / U) % L;
  int bh = n / (U * L);
  int b = bh / NH, h = bh % NH;
  int ki = idx[l * U + u];
  const float4* qr = (const float4*)(Q + ((size_t)(b * L + l)) * D_MODEL + h * DH);
  const float4* kr = (const float4*)(Km + ((size_t)(b * L + ki)) * D_MODEL + h * DH);
  float s = 0.f;
#pragma unroll
  for (int e = 0; e < 16; ++e) {
    float4 q4 = qr[e];
    float4 k4 = kr[e];
    s += q4.x * k4.x + q4.y * k4.y + q4.z * k4.z + q4.w * k4.w;
  }
  QKs[n] = s;
}

// M[bh*L+l] = max_u(QKs) - sum_u(QKs)/L ; one wave per query, ONE butterfly
__global__ __launch_bounds__(256) void sparse_reduce_kernel(
    const float* __restrict__ QKs, float* __restrict__ Mout, int total,
    int L, int U) {
  int wid = (blockIdx.x * 256 + threadIdx.x) >> 6;
  int lane = threadIdx.x & 63;
  if (wid >= total) return;
  float v = (lane < U) ? QKs[(size_t)wid * U + lane] : -INFINITY;
  float m = v;
#pragma unroll
  for (int k = 32; k; k >>= 1) m = fmaxf(m, __shfl_xor(m, k));
  float sv = (lane < U) ? v : 0.f;
#pragma unroll
  for (int k = 32; k; k >>= 1) sv += __shfl_xor(sv, k);
  if (lane == 0) Mout[wid] = m - sv / (float)L;
}

// ---------------- top-k (stable: ties -> lower index), u <= 40 ------------
__global__ __launch_bounds__(256) void topk_kernel(
    const float* __restrict__ Mv, int* __restrict__ Mtop, int L, int u) {
  __shared__ float sv[2048];
  __shared__ float rv[256];
  __shared__ int ri[256];
  int bh = blockIdx.x;
  int t = threadIdx.x;
  for (int l = t; l < L; l += 256) sv[l] = Mv[(size_t)bh * L + l];
  __syncthreads();
  for (int it = 0; it < u; ++it) {
    float bv = -INFINITY;
    int bi = 0x7fffffff;
    for (int l = t; l < L; l += 256) {
      float v = sv[l];
      if (v > bv || (v == bv && l < bi)) { bv = v; bi = l; }
    }
    rv[t] = bv; ri[t] = bi;
    __syncthreads();
    for (int s = 128; s > 0; s >>= 1) {
      if (t < s) {
        float v2 = rv[t + s]; int i2 = ri[t + s];
        if (v2 > rv[t] || (v2 == rv[t] && i2 < ri[t])) { rv[t] = v2; ri[t] = i2; }
      }
      __syncthreads();
    }
    if (t == 0) { Mtop[bh * u + it] = ri[0]; sv[ri[0]] = -INFINITY; }
    __syncthreads();
  }
}

// ---------------- mean of V over L per (b,h) ----------------
__global__ __launch_bounds__(256) void vmean_kernel(
    const float* __restrict__ V, float* __restrict__ vmean, int B, int L) {
  int bh = blockIdx.x;
  int b = bh / NH, h = bh % NH;
  int t = threadIdx.x;
  int e = t & 63, part = t >> 6;
  const float* base = V + (size_t)b * L * D_MODEL + h * DH + e;
  float s = 0.f;
  for (int l = part; l < L; l += 4) s += base[(size_t)l * D_MODEL];
  __shared__ float red[4][64];
  red[part][e] = s;
  __syncthreads();
  if (part == 0) {
    float tot = red[0][e] + red[1][e] + red[2][e] + red[3][e];
    vmean[bh * DH + e] = tot / (float)L;
  }
}

__global__ void fill_ctx_kernel(const float* __restrict__ vmean,
                                float* __restrict__ O, int B, int L) {
  int i = blockIdx.x * 256 + threadIdx.x;
  int total = B * L * D_MODEL;
  if (i >= total) return;
  int dcol = i % D_MODEL;
  int b = i / (D_MODEL * L);
  O[i] = vmean[(b * NH + (dcol >> 6)) * DH + (dcol & 63)];
}

// ============== attention as batched GEMM pipeline ==============
__global__ void pack_qred_kernel(const float* __restrict__ Q,
                                 const int* __restrict__ Mtop,
                                 float* __restrict__ qred, int L, int U) {
  int z = blockIdx.x;  // bh
  int b = z / NH, h = z % NH;
  int t = threadIdx.x;
  int d = t & 63;
  for (int r = t >> 6; r < 64; r += 4) {
    float v = 0.f;
    if (r < U) {
      int l = Mtop[z * U + r];
      v = Q[((size_t)(b * L + l)) * D_MODEL + h * DH + d];
    }
    qred[((size_t)z * 64 + r) * 64 + d] = v;
  }
}

// S[z][64][L] = 0.125 * Qred[z](64x64) @ K_z^T ; K_z rows stride 512
__global__ __launch_bounds__(256) void scores_gemm_kernel(
    const float* __restrict__ qred, const float* __restrict__ Km,
    float* __restrict__ S, int L) {
  __shared__ float As[BK][64 + PADR];
  __shared__ float Bs[BK][64 + PADR];
  const int z = blockIdx.y;
  const int b = z / NH, h = z % NH;
  const float* A = qred + (size_t)z * 64 * 64;
  const float* Bt = Km + (size_t)b * L * D_MODEL + h * DH;  // ldb = 512
  float* Sz = S + (size_t)z * 64 * L;
  const int bn = blockIdx.x * 64;
  const int tid = threadIdx.x;
  const int tx = tid & 15, ty = tid >> 4;
  const int lr = tid >> 2;
  const int lc = (tid & 3) << 2;
  float acc[4][4] = {};
  for (int k0 = 0; k0 < 64; k0 += BK) {
    float4 av = *(const float4*)(A + (size_t)lr * 64 + k0 + lc);
    float4 bv = *(const float4*)(Bt + (size_t)(bn + lr) * D_MODEL + k0 + lc);
    As[lc + 0][lr] = av.x; As[lc + 1][lr] = av.y;
    As[lc + 2][lr] = av.z; As[lc + 3][lr] = av.w;
    Bs[lc + 0][lr] = bv.x; Bs[lc + 1][lr] = bv.y;
    Bs[lc + 2][lr] = bv.z; Bs[lc + 3][lr] = bv.w;
    __syncthreads();
#pragma unroll
    for (int kk = 0; kk < BK; ++kk) {
      float4 a4 = *(const float4*)&As[kk][ty << 2];
      float4 b4 = *(const float4*)&Bs[kk][tx << 2];
      float ar[4] = {a4.x, a4.y, a4.z, a4.w};
      float br[4] = {b4.x, b4.y, b4.z, b4.w};
#pragma unroll
      for (int i = 0; i < 4; ++i)
#pragma unroll
        for (int j = 0; j < 4; ++j) acc[i][j] += ar[i] * br[j];
    }
    __syncthreads();
  }
#pragma unroll
  for (int i = 0; i < 4; ++i) {
    float* Sr = Sz + (size_t)((ty << 2) + i) * L + bn;
#pragma unroll
    for (int j = 0; j < 4; ++j) Sr[(tx << 2) + j] = 0.125f * acc[i][j];
  }
}

// per-row softmax over L (rows r < U only); wave per row
__global__ __launch_bounds__(256) void softmax_kernel(float* __restrict__ S,
                                                      int L, int U) {
  int z = blockIdx.x;
  int wave = threadIdx.x >> 6, lane = threadIdx.x & 63;
  for (int r = wave; r < U; r += 4) {
    float* row = S + (size_t)z * 64 * L + (size_t)r * L;
    float m = -INFINITY;
    for (int i = lane; i < L; i += 64) m = fmaxf(m, row[i]);
#pragma unroll
    for (int k = 32; k; k >>= 1) m = fmaxf(m, __shfl_xor(m, k));
    float s = 0.f;
    for (int i = lane; i < L; i += 64) {
      float e = expf(row[i] - m);
      row[i] = e;
      s += e;
    }
#pragma unroll
    for (int k = 32; k; k >>= 1) s += __shfl_xor(s, k);
    float inv = 1.0f / s;
    for (int i = lane; i < L; i += 64) row[i] *= inv;
  }
}

// zero the selected ctx rows before split-K PV atomics
__global__ void zero_sel_kernel(const int* __restrict__ Mtop,
                                float* __restrict__ O, int L, int U) {
  int z = blockIdx.x;
  int b = z / NH, h = z % NH;
  int t = threadIdx.x;
  int d = t & 63;
  for (int r = t >> 6; r < U; r += 4) {
    int l = Mtop[z * U + r];
    O[((size_t)(b * L + l)) * D_MODEL + h * DH + d] = 0.f;
  }
}

// O[sel rows] += P(UxL) @ V(Lx64), split-K over 128-chunks of L.
#define PV_LC 128

template <int U>
__global__ __launch_bounds__(256) void pv_kernel(
    const float* __restrict__ P, const float* __restrict__ V,
    const int* __restrict__ Mtop, float* __restrict__ O, int L) {
  __shared__ float Pl[U][PV_LC];
  __shared__ float Vl[PV_LC][DH + 4];
  const int z = blockIdx.y;
  const int b = z / NH, h = z % NH;
  const int c0 = blockIdx.x * PV_LC;
  const int tid = threadIdx.x;
  const float* Pz = P + (size_t)z * 64 * L + c0;
  for (int i4 = tid; i4 < U * (PV_LC / 4); i4 += 256) {
    int r = i4 / (PV_LC / 4);
    int lq = (i4 % (PV_LC / 4)) * 4;
    float4 p4 = *(const float4*)(Pz + (size_t)r * L + lq);
    Pl[r][lq + 0] = p4.x; Pl[r][lq + 1] = p4.y;
    Pl[r][lq + 2] = p4.z; Pl[r][lq + 3] = p4.w;
  }
  const float* Vb = V + ((size_t)b * L + c0) * D_MODEL + h * DH;
  for (int i4 = tid; i4 < PV_LC * (DH / 4); i4 += 256) {
    int l = i4 >> 4;
    int d4 = (i4 & 15) * 4;
    float4 v4 = *(const float4*)(Vb + (size_t)l * D_MODEL + d4);
    Vl[l][d4 + 0] = v4.x; Vl[l][d4 + 1] = v4.y;
    Vl[l][d4 + 2] = v4.z; Vl[l][d4 + 3] = v4.w;
  }
  __syncthreads();
  const int wave = tid >> 6, lane = tid & 63;
  constexpr int NJ = (U + 3) / 4;
  float acc[NJ] = {};
  for (int l = 0; l < PV_LC; ++l) {
    float vv = Vl[l][lane];
#pragma unroll
    for (int j = 0; j < NJ; ++j) {
      int r = wave + 4 * j;
      if (r < U) acc[j] += Pl[r][l] * vv;
    }
  }
#pragma unroll
  for (int j = 0; j < NJ; ++j) {
    int r = wave + 4 * j;
    if (r < U) {
      int ml = Mtop[z * U + r];
      atomicAdd(&O[((size_t)(b * L + ml)) * D_MODEL + h * DH + lane], acc[j]);
    }
  }
}

static void run_pv(const float* P, const float* V, const int* Mtop, float* O,
                   int L, int U, hipStream_t stream) {
  dim3 gg(L / PV_LC, 32);
  if (U == 40)      pv_kernel<40><<<gg, 256, 0, stream>>>(P, V, Mtop, O, L);
  else if (U == 35) pv_kernel<35><<<gg, 256, 0, stream>>>(P, V, Mtop, O, L);
  else              pv_kernel<64><<<gg, 256, 0, stream>>>(P, V, Mtop, O, L);
}

// ---------------- im2col (circular, K=3) -> bf16 --------------------------
__global__ void im2col_kernel(const float* __restrict__ X,
                              unsigned short* __restrict__ Y, int B, int L) {
  int i = blockIdx.x * 256 + threadIdx.x;
  int total = B * L * 1536;
  if (i >= total) return;
  int ck = i % 1536;
  int l = (i / 1536) % L;
  int b = i / (1536 * L);
  int c = ck / 3, k = ck % 3;
  int lm = l + k - 1;
  if (lm < 0) lm += L;
  else if (lm >= L) lm -= L;
  Y[i] = f2bf(X[((size_t)(b * L + lm)) * D_MODEL + c]);
}

// ---------------- maxpool k=3 s=2, one -inf pad each side -----------------
__global__ void maxpool_kernel(const float* __restrict__ Y,
                               float* __restrict__ X, int B, int L) {
  int Lo = L / 2;
  int i = blockIdx.x * 256 + threadIdx.x;
  int total = B * Lo * D_MODEL;
  if (i >= total) return;
  int d = i % D_MODEL;
  int lp = (i / D_MODEL) % Lo;
  int b = i / (D_MODEL * Lo);
  int l0 = 2 * lp - 1;
  float m = -INFINITY;
#pragma unroll
  for (int k = 0; k < 3; ++k) {
    int l = l0 + k;
    if (l >= 0 && l < L) m = fmaxf(m, Y[((size_t)(b * L + l)) * D_MODEL + d]);
  }
  X[i] = m;
}

// ==========================================================================
extern "C" void kernel_launch(void* const* d_in, const int* in_sizes, int n_in,
                              void* d_out, int out_size, void* d_ws,
                              size_t ws_size, hipStream_t stream) {
  const float* x_enc  = (const float*)d_in[0];
  const float* emb_w  = (const float*)d_in[1];
  const float* Wq     = (const float*)d_in[2];
  const float* bq     = (const float*)d_in[3];
  const float* Wk     = (const float*)d_in[4];
  const float* bk     = (const float*)d_in[5];
  const float* Wv     = (const float*)d_in[6];
  const float* bv     = (const float*)d_in[7];
  const float* Wo     = (const float*)d_in[8];
  const float* bo     = (const float*)d_in[9];
  const float* ln1_g  = (const float*)d_in[10];
  const float* ln1_b  = (const float*)d_in[11];
  const float* ff_w1  = (const float*)d_in[12];
  const float* ff_b1  = (const float*)d_in[13];
  const float* ff_w2  = (const float*)d_in[14];
  const float* ff_b2  = (const float*)d_in[15];
  const float* ln2_g  = (const float*)d_in[16];
  const float* ln2_b  = (const float*)d_in[17];
  const float* cv_w   = (const float*)d_in[18];
  const float* cv_b   = (const float*)d_in[19];
  const float* bn_g   = (const float*)d_in[20];
  const float* bn_b   = (const float*)d_in[21];
  const float* norm_g = (const float*)d_in[22];
  const float* norm_b = (const float*)d_in[23];

  const int B = 4, L0 = 2048, EL = 3;
  const size_t SZ = (size_t)B * 2048 * 512;
  float* ws   = (float*)d_ws;
  float* xbuf = ws;
  float* ebuf = ws + SZ;   // pre-LN temp; QKs; Sbuf; ab16(V)
  float* qbuf = ws + 2 * SZ;
  float* kbuf = ws + 3 * SZ;
  float* vbuf = ws + 4 * SZ;
  float* obuf = ws + 5 * SZ;
  float* sm   = ws + 6 * SZ;
  int*   d_idx   = (int*)sm;
  float* d_M     = sm + 81920;
  int*   d_Mtop  = (int*)(sm + 81920 + 65536);
  float* d_vmean = sm + 81920 + 65536 + 1280;
  float* qred    = sm;    // reuses idx+M region (dead post-topk)
  float* QKs     = ebuf;
  float* Sbuf    = ebuf;

  const float inv_s = 1.0f / sqrtf(1.0f + 1e-5f);
  auto cast = [&](const float* s, unsigned short* d, int n) {
    cast_bf16_kernel<<<ceil_div(n / 4, 256), 256, 0, stream>>>(s, d, n);
  };

  embed_kernel<<<ceil_div(B * L0 * D_MODEL, 256), 256, 0, stream>>>(
      x_enc, emb_w, xbuf, B, L0);

  int L = L0;
  for (int i = 0; i < EL; ++i) {
    const int M_ = B * L;
    int c = 5 * (int)ceil(log((double)L));
    int U = c < L ? c : L;
    const float* Wq_i = Wq + (size_t)i * 512 * 512;
    const float* Wk_i = Wk + (size_t)i * 512 * 512;
    const float* Wv_i = Wv + (size_t)i * 512 * 512;
    const float* Wo_i = Wo + (size_t)i * 512 * 512;
    const float* w1_i = ff_w1 + (size_t)i * 512 * 512;
    const float* w2_i = ff_w2 + (size_t)i * 512 * 512;

    // Q, K stay fp32 (feed the discontinuous top-k path exactly)
    run_gemm<0>(xbuf, Wq_i, bq + i * 512, nullptr, nullptr, nullptr, qbuf,
                M_, 512, 512, 0.f, stream);
    run_gemm<0>(xbuf, Wk_i, bk + i * 512, nullptr, nullptr, nullptr, kbuf,
                M_, 512, 512, 0.f, stream);

    // V in bf16 MFMA: ab16 @ ebuf (free), wb16 @ obuf (free), C=vbuf
    {
      unsigned short* ab16 = (unsigned short*)ebuf;
      unsigned short* wb16 = (unsigned short*)obuf;
      cast(xbuf, ab16, M_ * 512);
      cast(Wv_i, wb16, 512 * 512);
      run_bgemm<0>(ab16, wb16, bv + i * 512, nullptr, nullptr, nullptr, vbuf,
                   M_, 512, 512, 0.f, stream);
    }

    uint32_t lk0, lk1, k20, k21;
    threefry2x32(0u, 42u, 0u, (uint32_t)i, &lk0, &lk1);
    threefry2x32(lk0, lk1, 0u, 1u, &k20, &k21);
    idx_kernel<<<ceil_div(L * U, 256), 256, 0, stream>>>(d_idx, L, U, k20, k21);

    int nqk = B * NH * L * U;
    sparse_qk_kernel<<<ceil_div(nqk, 256), 256, 0, stream>>>(
        qbuf, kbuf, d_idx, QKs, B, L, U);
    sparse_reduce_kernel<<<ceil_div(B * NH * L * 64, 256), 256, 0, stream>>>(
        QKs, d_M, B * NH * L, L, U);
    topk_kernel<<<B * NH, 256, 0, stream>>>(d_M, d_Mtop, L, U);
    vmean_kernel<<<B * NH, 256, 0, stream>>>(vbuf, d_vmean, B, L);
    fill_ctx_kernel<<<ceil_div(B * L * D_MODEL, 256), 256, 0, stream>>>(
        d_vmean, obuf, B, L);

    pack_qred_kernel<<<B * NH, 256, 0, stream>>>(qbuf, d_Mtop, qred, L, U);
    scores_gemm_kernel<<<dim3(L / 64, B * NH), 256, 0, stream>>>(qred, kbuf,
                                                                 Sbuf, L);
    softmax_kernel<<<B * NH, 256, 0, stream>>>(Sbuf, L, U);
    zero_sel_kernel<<<B * NH, 256, 0, stream>>>(d_Mtop, obuf, L, U);
    run_pv(Sbuf, vbuf, d_Mtop, obuf, L, U, stream);

    // O-proj bf16: ab16 @ qbuf (Q dead), wb16 @ kbuf (K dead), C=ebuf
    unsigned short* ab16 = (unsigned short*)qbuf;
    unsigned short* wb16 = (unsigned short*)kbuf;
    cast(obuf, ab16, M_ * 512);
    cast(Wo_i, wb16, 512 * 512);
    run_bgemm<2>(ab16, wb16, bo + i * 512, xbuf, nullptr, nullptr, ebuf,
                 M_, 512, 512, 0.f, stream);
    ln_kernel<<<M_, 256, 0, stream>>>(ebuf, ln1_g + i * 512, ln1_b + i * 512, xbuf);

    // FF1 bf16 (gelu fused), C=obuf
    cast(xbuf, ab16, M_ * 512);
    cast(w1_i, wb16, 512 * 512);
    run_bgemm<1>(ab16, wb16, ff_b1 + i * 512, nullptr, nullptr, nullptr, obuf,
                 M_, 512, 512, 0.f, stream);
    // FF2 bf16 (+residual), C=ebuf
    cast(obuf, ab16, M_ * 512);
    cast(w2_i, wb16, 512 * 512);
    run_bgemm<2>(ab16, wb16, ff_b2 + i * 512, xbuf, nullptr, nullptr, ebuf,
                 M_, 512, 512, 0.f, stream);
    ln_kernel<<<M_, 256, 0, stream>>>(ebuf, ln2_g + i * 512, ln2_b + i * 512, xbuf);

    if (i < EL - 1) {
      // conv distill bf16: im2col -> imb16 @ qbuf(+kbuf), weights @ vbuf
      unsigned short* imb16 = (unsigned short*)qbuf;  // M_*1536*2B <= 2*SZ*4B
      unsigned short* wb16c = (unsigned short*)vbuf;
      im2col_kernel<<<ceil_div(B * L * 1536, 256), 256, 0, stream>>>(xbuf, imb16, B, L);
      cast(cv_w + (size_t)i * 512 * 1536, wb16c, 512 * 1536);
      run_bgemm<3>(imb16, wb16c, cv_b + i * 512, nullptr, bn_g + i * 512,
                   bn_b + i * 512, ebuf, M_, 512, 1536, inv_s, stream);
      maxpool_kernel<<<ceil_div(B * (L / 2) * D_MODEL, 256), 256, 0, stream>>>(
          ebuf, xbuf, B, L);
      L /= 2;
    }
  }

  ln_kernel<<<B * L, 256, 0, stream>>>(xbuf, norm_g, norm_b, (float*)d_out);
}

// Round 7
// 1593.286 us; speedup vs baseline: 2.0347x; 1.1493x over previous
//
#include <hip/hip_runtime.h>
#include <cmath>
#include <cstdint>

#define D_MODEL 512
#define NH 8
#define DH 64

static inline int ceil_div(int a, int b) { return (a + b - 1) / b; }

typedef __attribute__((ext_vector_type(8))) short short8;
typedef __attribute__((ext_vector_type(4))) float floatx4;

// fp32 -> bf16 (RNE)
__device__ __forceinline__ unsigned short f2bf(float f) {
  uint32_t u = __float_as_uint(f);
  uint32_t r = (u + 0x7fffu + ((u >> 16) & 1u)) >> 16;
  return (unsigned short)r;
}

// ---------------- threefry2x32 (JAX-exact) ----------------
#define TF_ROTL(x, r) (((x) << (r)) | ((x) >> (32 - (r))))

__host__ __device__ inline void threefry2x32(uint32_t k0, uint32_t k1,
                                             uint32_t x0, uint32_t x1,
                                             uint32_t* o0, uint32_t* o1) {
  uint32_t ks2 = k0 ^ k1 ^ 0x1BD11BDAu;
  x0 += k0; x1 += k1;
#define TF_R4(a, b, c, d)                                    \
  x0 += x1; x1 = TF_ROTL(x1, a); x1 ^= x0;                   \
  x0 += x1; x1 = TF_ROTL(x1, b); x1 ^= x0;                   \
  x0 += x1; x1 = TF_ROTL(x1, c); x1 ^= x0;                   \
  x0 += x1; x1 = TF_ROTL(x1, d); x1 ^= x0;
  TF_R4(13, 15, 26, 6);  x0 += k1;  x1 += ks2 + 1u;
  TF_R4(17, 29, 16, 24); x0 += ks2; x1 += k0 + 2u;
  TF_R4(13, 15, 26, 6);  x0 += k0;  x1 += k1 + 3u;
  TF_R4(17, 29, 16, 24); x0 += k1;  x1 += ks2 + 4u;
  TF_R4(13, 15, 26, 6);  x0 += ks2; x1 += k0 + 5u;
#undef TF_R4
  *o0 = x0; *o1 = x1;
}

__global__ void idx_kernel(int* __restrict__ idx, int L, int U,
                           uint32_t k0, uint32_t k1) {
  int n = blockIdx.x * 256 + threadIdx.x;
  if (n >= L * U) return;
  uint32_t o0, o1;
  threefry2x32(k0, k1, 0u, (uint32_t)n, &o0, &o1);
  idx[n] = (int)((o0 ^ o1) & (uint32_t)(L - 1));
}

// ---------------- fp32 -> bf16 cast, 4 elems/thread ----------------
__global__ __launch_bounds__(256) void cast_bf16_kernel(
    const float* __restrict__ src, unsigned short* __restrict__ dst, int n) {
  int i = (blockIdx.x * 256 + threadIdx.x) * 4;
  if (i >= n) return;
  float4 v = *(const float4*)(src + i);
  ushort4 o;
  o.x = f2bf(v.x); o.y = f2bf(v.y); o.z = f2bf(v.z); o.w = f2bf(v.w);
  *(ushort4*)(dst + i) = o;
}

// ---------------- embedding: circular conv (C=2,K=3) + pos encoding -------
__global__ __launch_bounds__(256) void embed_kernel(
    const float* __restrict__ x_enc, const float* __restrict__ emb_w,
    float* __restrict__ x, int B, int L) {
  int i = blockIdx.x * 256 + threadIdx.x;
  int total = B * L * D_MODEL;
  if (i >= total) return;
  int d = i % D_MODEL;
  int l = (i / D_MODEL) % L;
  int b = i / (D_MODEL * L);
  int lm = (l == 0) ? (L - 1) : (l - 1);
  int lp = (l == L - 1) ? 0 : (l + 1);
  const float* w = emb_w + d * 6;
  const float* xb = x_enc + (size_t)b * L * 2;
  float acc = 0.f;
  acc += xb[lm * 2 + 0] * w[0] + xb[l * 2 + 0] * w[1] + xb[lp * 2 + 0] * w[2];
  acc += xb[lm * 2 + 1] * w[3] + xb[l * 2 + 1] * w[4] + xb[lp * 2 + 1] * w[5];
  int j = d >> 1;
  const float coef = -0.017988946039015985f;  // -ln(10000)/512
  float div = expf((float)(2 * j) * coef);
  float ang = (float)l * div;
  float pe = (d & 1) ? cosf(ang) : sinf(ang);
  x[i] = acc + pe;
}

// ---------------- layer norm over D=512 ----------------
__global__ __launch_bounds__(256) void ln_kernel(
    const float* __restrict__ in, const float* __restrict__ g,
    const float* __restrict__ b, float* __restrict__ out) {
  int row = blockIdx.x;
  int t = threadIdx.x;
  const float* xr = in + (size_t)row * D_MODEL;
  float v0 = xr[t], v1 = xr[t + 256];
  __shared__ float red[256];
  red[t] = v0 + v1;
  __syncthreads();
  for (int s = 128; s > 0; s >>= 1) { if (t < s) red[t] += red[t + s]; __syncthreads(); }
  float mean = red[0] * (1.0f / 512.0f);
  __syncthreads();
  float d0 = v0 - mean, d1 = v1 - mean;
  red[t] = d0 * d0 + d1 * d1;
  __syncthreads();
  for (int s = 128; s > 0; s >>= 1) { if (t < s) red[t] += red[t + s]; __syncthreads(); }
  float var = red[0] * (1.0f / 512.0f);
  float rstd = 1.0f / sqrtf(var + 1e-5f);
  float* outr = out + (size_t)row * D_MODEL;
  outr[t]       = d0 * rstd * g[t]       + b[t];
  outr[t + 256] = d1 * rstd * g[t + 256] + b[t + 256];
}

// MODE 0: +bias   1: gelu(+bias)   2: +bias +R   3: elu((+bias)*scl*g + bb)
__device__ __forceinline__ float epilogue_apply(int MODE, float v, float r,
                                                float g, float bb, float scl) {
  if (MODE == 1) {
    v = 0.5f * v * (1.0f + erff(v * 0.7071067811865475f));
  } else if (MODE == 2) {
    v += r;
  } else if (MODE == 3) {
    v = v * scl * g + bb;
    v = (v > 0.f) ? v : expm1f(v);
  }
  return v;
}

// ---------------- fp32 tiled GEMM 64x64 (Q,K projections only) ------------
#define BM 64
#define BN 64
#define BK 16
#define PADR 4

template <int MODE>
__global__ __launch_bounds__(256) void gemm_kernel(
    const float* __restrict__ A, const float* __restrict__ Bt,
    const float* __restrict__ bias, const float* __restrict__ R,
    const float* __restrict__ gvec, const float* __restrict__ bvec,
    float* __restrict__ C, int M, int N, int K, float scl) {
  __shared__ float As[BK][BM + PADR];
  __shared__ float Bs[BK][BN + PADR];
  const int bm = blockIdx.y * BM;
  const int bn = blockIdx.x * BN;
  const int tid = threadIdx.x;
  const int tx = tid & 15, ty = tid >> 4;
  const int lr = tid >> 2;
  const int lc = (tid & 3) << 2;
  const float* Aptr = A + (size_t)(bm + lr) * K + lc;
  const float* Bptr = Bt + (size_t)(bn + lr) * K + lc;
  float acc[4][4] = {};
  for (int k0 = 0; k0 < K; k0 += BK) {
    float4 av = *(const float4*)(Aptr + k0);
    float4 bv = *(const float4*)(Bptr + k0);
    As[lc + 0][lr] = av.x; As[lc + 1][lr] = av.y;
    As[lc + 2][lr] = av.z; As[lc + 3][lr] = av.w;
    Bs[lc + 0][lr] = bv.x; Bs[lc + 1][lr] = bv.y;
    Bs[lc + 2][lr] = bv.z; Bs[lc + 3][lr] = bv.w;
    __syncthreads();
#pragma unroll
    for (int kk = 0; kk < BK; ++kk) {
      float4 a4 = *(const float4*)&As[kk][ty << 2];
      float4 b4 = *(const float4*)&Bs[kk][tx << 2];
      float ar[4] = {a4.x, a4.y, a4.z, a4.w};
      float br[4] = {b4.x, b4.y, b4.z, b4.w};
#pragma unroll
      for (int i = 0; i < 4; ++i)
#pragma unroll
        for (int j = 0; j < 4; ++j) acc[i][j] += ar[i] * br[j];
    }
    __syncthreads();
  }
#pragma unroll
  for (int i = 0; i < 4; ++i) {
    int row = bm + (ty << 2) + i;
    float* Cr = C + (size_t)row * N;
    const float* Rr = (MODE == 2) ? (R + (size_t)row * N) : nullptr;
#pragma unroll
    for (int j = 0; j < 4; ++j) {
      int col = bn + (tx << 2) + j;
      float v = acc[i][j] + bias[col];
      v = epilogue_apply(MODE, v, (MODE == 2) ? Rr[col] : 0.f,
                         (MODE == 3) ? gvec[col] : 0.f,
                         (MODE == 3) ? bvec[col] : 0.f, scl);
      Cr[col] = v;
    }
  }
}

template <int MODE>
static void run_gemm(const float* A, const float* Bt, const float* bias,
                     const float* R, const float* g, const float* bb, float* C,
                     int M, int N, int K, float scl, hipStream_t stream) {
  dim3 gg(N / BN, M / BM);
  gemm_kernel<MODE><<<gg, 256, 0, stream>>>(A, Bt, bias, R, g, bb, C, M, N, K, scl);
}

// ---------------- bf16 MFMA GEMM 64x64, BK=32, 4 waves (32x32 each) -------
template <int MODE>
__global__ __launch_bounds__(256) void bgemm_kernel(
    const unsigned short* __restrict__ A, const unsigned short* __restrict__ Bt,
    const float* __restrict__ bias, const float* __restrict__ R,
    const float* __restrict__ gvec, const float* __restrict__ bvec,
    float* __restrict__ C, int M, int N, int K, float scl) {
  __shared__ unsigned short Al[64][40];
  __shared__ unsigned short Bl[64][40];
  const int bm = blockIdx.y * 64, bn = blockIdx.x * 64;
  const int tid = threadIdx.x;
  const int wave = tid >> 6, lane = tid & 63;
  const int wm = (wave >> 1) * 32, wn = (wave & 1) * 32;
  const int quad = lane >> 4, l16 = lane & 15;
  const int sr = tid >> 2;
  const int sc = (tid & 3) * 8;
  const unsigned short* Ag = A + (size_t)(bm + sr) * K + sc;
  const unsigned short* Bg = Bt + (size_t)(bn + sr) * K + sc;
  floatx4 zero = {0.f, 0.f, 0.f, 0.f};
  floatx4 acc00 = zero, acc01 = zero, acc10 = zero, acc11 = zero;
  for (int k0 = 0; k0 < K; k0 += 32) {
    short8 a8 = *(const short8*)(Ag + k0);
    short8 b8 = *(const short8*)(Bg + k0);
    *(short8*)&Al[sr][sc] = a8;
    *(short8*)&Bl[sr][sc] = b8;
    __syncthreads();
    short8 af0 = *(const short8*)&Al[wm + l16][quad * 8];
    short8 af1 = *(const short8*)&Al[wm + 16 + l16][quad * 8];
    short8 bf0 = *(const short8*)&Bl[wn + l16][quad * 8];
    short8 bf1 = *(const short8*)&Bl[wn + 16 + l16][quad * 8];
    acc00 = __builtin_amdgcn_mfma_f32_16x16x32_bf16(af0, bf0, acc00, 0, 0, 0);
    acc01 = __builtin_amdgcn_mfma_f32_16x16x32_bf16(af0, bf1, acc01, 0, 0, 0);
    acc10 = __builtin_amdgcn_mfma_f32_16x16x32_bf16(af1, bf0, acc10, 0, 0, 0);
    acc11 = __builtin_amdgcn_mfma_f32_16x16x32_bf16(af1, bf1, acc11, 0, 0, 0);
    __syncthreads();
  }
  floatx4 accs[2][2] = {{acc00, acc01}, {acc10, acc11}};
#pragma unroll
  for (int i = 0; i < 2; ++i) {
#pragma unroll
    for (int j = 0; j < 2; ++j) {
      int col = bn + wn + j * 16 + l16;
#pragma unroll
      for (int p = 0; p < 4; ++p) {
        int row = bm + wm + i * 16 + quad * 4 + p;
        float v = accs[i][j][p] + bias[col];
        v = epilogue_apply(MODE, v, (MODE == 2) ? R[(size_t)row * N + col] : 0.f,
                           (MODE == 3) ? gvec[col] : 0.f,
                           (MODE == 3) ? bvec[col] : 0.f, scl);
        C[(size_t)row * N + col] = v;
      }
    }
  }
}

template <int MODE>
static void run_bgemm(const unsigned short* A, const unsigned short* Bt,
                      const float* bias, const float* R, const float* g,
                      const float* bb, float* C, int M, int N, int K,
                      float scl, hipStream_t stream) {
  dim3 gg(N / 64, M / 64);
  bgemm_kernel<MODE><<<gg, 256, 0, stream>>>(A, Bt, bias, R, g, bb, C, M, N, K, scl);
}

// ---------------- sparse QK samples: one THREAD per (b,h,l,u) -------------
__global__ __launch_bounds__(256) void sparse_qk_kernel(
    const float* __restrict__ Q, const float* __restrict__ Km,
    const int* __restrict__ idx, float* __restrict__ QKs, int B, int L,
    int U) {
  int n = blockIdx.x * 256 + threadIdx.x;
  int total = B * NH * L * U;
  if (n >= total) return;
  int u = n % U;
  int l = (n / U) % L;
  int bh = n / (U * L);
  int b = bh / NH, h = bh % NH;
  int ki = idx[l * U + u];
  const float4* qr = (const float4*)(Q + ((size_t)(b * L + l)) * D_MODEL + h * DH);
  const float4* kr = (const float4*)(Km + ((size_t)(b * L + ki)) * D_MODEL + h * DH);
  float s = 0.f;
#pragma unroll
  for (int e = 0; e < 16; ++e) {
    float4 q4 = qr[e];
    float4 k4 = kr[e];
    s += q4.x * k4.x + q4.y * k4.y + q4.z * k4.z + q4.w * k4.w;
  }
  QKs[n] = s;
}

// M[bh*L+l] = max_u(QKs) - sum_u(QKs)/L ; one wave per query, ONE butterfly
__global__ __launch_bounds__(256) void sparse_reduce_kernel(
    const float* __restrict__ QKs, float* __restrict__ Mout, int total,
    int L, int U) {
  int wid = (blockIdx.x * 256 + threadIdx.x) >> 6;
  int lane = threadIdx.x & 63;
  if (wid >= total) return;
  float v = (lane < U) ? QKs[(size_t)wid * U + lane] : -INFINITY;
  float m = v;
#pragma unroll
  for (int k = 32; k; k >>= 1) m = fmaxf(m, __shfl_xor(m, k));
  float sv = (lane < U) ? v : 0.f;
#pragma unroll
  for (int k = 32; k; k >>= 1) sv += __shfl_xor(sv, k);
  if (lane == 0) Mout[wid] = m - sv / (float)L;
}

// ---------------- top-k (stable: ties -> lower index), u <= 40 ------------
__global__ __launch_bounds__(256) void topk_kernel(
    const float* __restrict__ Mv, int* __restrict__ Mtop, int L, int u) {
  __shared__ float sv[2048];
  __shared__ float rv[256];
  __shared__ int ri[256];
  int bh = blockIdx.x;
  int t = threadIdx.x;
  for (int l = t; l < L; l += 256) sv[l] = Mv[(size_t)bh * L + l];
  __syncthreads();
  for (int it = 0; it < u; ++it) {
    float bv = -INFINITY;
    int bi = 0x7fffffff;
    for (int l = t; l < L; l += 256) {
      float v = sv[l];
      if (v > bv || (v == bv && l < bi)) { bv = v; bi = l; }
    }
    rv[t] = bv; ri[t] = bi;
    __syncthreads();
    for (int s = 128; s > 0; s >>= 1) {
      if (t < s) {
        float v2 = rv[t + s]; int i2 = ri[t + s];
        if (v2 > rv[t] || (v2 == rv[t] && i2 < ri[t])) { rv[t] = v2; ri[t] = i2; }
      }
      __syncthreads();
    }
    if (t == 0) { Mtop[bh * u + it] = ri[0]; sv[ri[0]] = -INFINITY; }
    __syncthreads();
  }
}

// ---------------- mean of V over L per (b,h) ----------------
__global__ __launch_bounds__(256) void vmean_kernel(
    const float* __restrict__ V, float* __restrict__ vmean, int B, int L) {
  int bh = blockIdx.x;
  int b = bh / NH, h = bh % NH;
  int t = threadIdx.x;
  int e = t & 63, part = t >> 6;
  const float* base = V + (size_t)b * L * D_MODEL + h * DH + e;
  float s = 0.f;
  for (int l = part; l < L; l += 4) s += base[(size_t)l * D_MODEL];
  __shared__ float red[4][64];
  red[part][e] = s;
  __syncthreads();
  if (part == 0) {
    float tot = red[0][e] + red[1][e] + red[2][e] + red[3][e];
    vmean[bh * DH + e] = tot / (float)L;
  }
}

__global__ void fill_ctx_kernel(const float* __restrict__ vmean,
                                float* __restrict__ O, int B, int L) {
  int i = blockIdx.x * 256 + threadIdx.x;
  int total = B * L * D_MODEL;
  if (i >= total) return;
  int dcol = i % D_MODEL;
  int b = i / (D_MODEL * L);
  O[i] = vmean[(b * NH + (dcol >> 6)) * DH + (dcol & 63)];
}

// ============== attention as batched GEMM pipeline ==============
__global__ void pack_qred_kernel(const float* __restrict__ Q,
                                 const int* __restrict__ Mtop,
                                 float* __restrict__ qred, int L, int U) {
  int z = blockIdx.x;  // bh
  int b = z / NH, h = z % NH;
  int t = threadIdx.x;
  int d = t & 63;
  for (int r = t >> 6; r < 64; r += 4) {
    float v = 0.f;
    if (r < U) {
      int l = Mtop[z * U + r];
      v = Q[((size_t)(b * L + l)) * D_MODEL + h * DH + d];
    }
    qred[((size_t)z * 64 + r) * 64 + d] = v;
  }
}

// S[z][64][L] = 0.125 * Qred[z](64x64) @ K_z^T ; K_z rows stride 512
__global__ __launch_bounds__(256) void scores_gemm_kernel(
    const float* __restrict__ qred, const float* __restrict__ Km,
    float* __restrict__ S, int L) {
  __shared__ float As[BK][64 + PADR];
  __shared__ float Bs[BK][64 + PADR];
  const int z = blockIdx.y;
  const int b = z / NH, h = z % NH;
  const float* A = qred + (size_t)z * 64 * 64;
  const float* Bt = Km + (size_t)b * L * D_MODEL + h * DH;  // ldb = 512
  float* Sz = S + (size_t)z * 64 * L;
  const int bn = blockIdx.x * 64;
  const int tid = threadIdx.x;
  const int tx = tid & 15, ty = tid >> 4;
  const int lr = tid >> 2;
  const int lc = (tid & 3) << 2;
  float acc[4][4] = {};
  for (int k0 = 0; k0 < 64; k0 += BK) {
    float4 av = *(const float4*)(A + (size_t)lr * 64 + k0 + lc);
    float4 bv = *(const float4*)(Bt + (size_t)(bn + lr) * D_MODEL + k0 + lc);
    As[lc + 0][lr] = av.x; As[lc + 1][lr] = av.y;
    As[lc + 2][lr] = av.z; As[lc + 3][lr] = av.w;
    Bs[lc + 0][lr] = bv.x; Bs[lc + 1][lr] = bv.y;
    Bs[lc + 2][lr] = bv.z; Bs[lc + 3][lr] = bv.w;
    __syncthreads();
#pragma unroll
    for (int kk = 0; kk < BK; ++kk) {
      float4 a4 = *(const float4*)&As[kk][ty << 2];
      float4 b4 = *(const float4*)&Bs[kk][tx << 2];
      float ar[4] = {a4.x, a4.y, a4.z, a4.w};
      float br[4] = {b4.x, b4.y, b4.z, b4.w};
#pragma unroll
      for (int i = 0; i < 4; ++i)
#pragma unroll
        for (int j = 0; j < 4; ++j) acc[i][j] += ar[i] * br[j];
    }
    __syncthreads();
  }
#pragma unroll
  for (int i = 0; i < 4; ++i) {
    float* Sr = Sz + (size_t)((ty << 2) + i) * L + bn;
#pragma unroll
    for (int j = 0; j < 4; ++j) Sr[(tx << 2) + j] = 0.125f * acc[i][j];
  }
}

// ---------------- softmax: one block per (z,row) ----------------
// R6's version had grid=32 blocks (1.4% occupancy, 151us). Now 32*U blocks,
// row staged in registers (LC compile-time -> no scratch), 2 LDS reductions,
// one global read + one write.
template <int LC>
__global__ __launch_bounds__(256) void softmax_kernel(float* __restrict__ S,
                                                      int U) {
  constexpr int NE = LC / 256;
  int rid = blockIdx.x;
  int z = rid / U, r = rid % U;
  float* row = S + (size_t)z * 64 * LC + (size_t)r * LC;
  int t = threadIdx.x;
  float vals[NE];
  float m = -INFINITY;
#pragma unroll
  for (int i = 0; i < NE; ++i) {
    vals[i] = row[t + i * 256];
    m = fmaxf(m, vals[i]);
  }
  __shared__ float red[256];
  red[t] = m;
  __syncthreads();
  for (int s = 128; s > 0; s >>= 1) { if (t < s) red[t] = fmaxf(red[t], red[t + s]); __syncthreads(); }
  m = red[0];
  __syncthreads();
  float sum = 0.f;
#pragma unroll
  for (int i = 0; i < NE; ++i) {
    vals[i] = expf(vals[i] - m);
    sum += vals[i];
  }
  red[t] = sum;
  __syncthreads();
  for (int s = 128; s > 0; s >>= 1) { if (t < s) red[t] += red[t + s]; __syncthreads(); }
  float inv = 1.0f / red[0];
#pragma unroll
  for (int i = 0; i < NE; ++i) row[t + i * 256] = vals[i] * inv;
}

static void run_softmax(float* S, int L, int U, hipStream_t stream) {
  int blocks = 32 * U;
  if (L == 2048)      softmax_kernel<2048><<<blocks, 256, 0, stream>>>(S, U);
  else if (L == 1024) softmax_kernel<1024><<<blocks, 256, 0, stream>>>(S, U);
  else                softmax_kernel<512><<<blocks, 256, 0, stream>>>(S, U);
}

// zero the selected ctx rows before split-K PV atomics
__global__ void zero_sel_kernel(const int* __restrict__ Mtop,
                                float* __restrict__ O, int L, int U) {
  int z = blockIdx.x;
  int b = z / NH, h = z % NH;
  int t = threadIdx.x;
  int d = t & 63;
  for (int r = t >> 6; r < U; r += 4) {
    int l = Mtop[z * U + r];
    O[((size_t)(b * L + l)) * D_MODEL + h * DH + d] = 0.f;
  }
}

// O[sel rows] += P(UxL) @ V(Lx64), split-K over 128-chunks of L.
#define PV_LC 128

template <int U>
__global__ __launch_bounds__(256) void pv_kernel(
    const float* __restrict__ P, const float* __restrict__ V,
    const int* __restrict__ Mtop, float* __restrict__ O, int L) {
  __shared__ float Pl[U][PV_LC];
  __shared__ float Vl[PV_LC][DH + 4];
  const int z = blockIdx.y;
  const int b = z / NH, h = z % NH;
  const int c0 = blockIdx.x * PV_LC;
  const int tid = threadIdx.x;
  const float* Pz = P + (size_t)z * 64 * L + c0;
  for (int i4 = tid; i4 < U * (PV_LC / 4); i4 += 256) {
    int r = i4 / (PV_LC / 4);
    int lq = (i4 % (PV_LC / 4)) * 4;
    float4 p4 = *(const float4*)(Pz + (size_t)r * L + lq);
    Pl[r][lq + 0] = p4.x; Pl[r][lq + 1] = p4.y;
    Pl[r][lq + 2] = p4.z; Pl[r][lq + 3] = p4.w;
  }
  const float* Vb = V + ((size_t)b * L + c0) * D_MODEL + h * DH;
  for (int i4 = tid; i4 < PV_LC * (DH / 4); i4 += 256) {
    int l = i4 >> 4;
    int d4 = (i4 & 15) * 4;
    float4 v4 = *(const float4*)(Vb + (size_t)l * D_MODEL + d4);
    Vl[l][d4 + 0] = v4.x; Vl[l][d4 + 1] = v4.y;
    Vl[l][d4 + 2] = v4.z; Vl[l][d4 + 3] = v4.w;
  }
  __syncthreads();
  const int wave = tid >> 6, lane = tid & 63;
  constexpr int NJ = (U + 3) / 4;
  float acc[NJ] = {};
  for (int l = 0; l < PV_LC; ++l) {
    float vv = Vl[l][lane];
#pragma unroll
    for (int j = 0; j < NJ; ++j) {
      int r = wave + 4 * j;
      if (r < U) acc[j] += Pl[r][l] * vv;
    }
  }
#pragma unroll
  for (int j = 0; j < NJ; ++j) {
    int r = wave + 4 * j;
    if (r < U) {
      int ml = Mtop[z * U + r];
      atomicAdd(&O[((size_t)(b * L + ml)) * D_MODEL + h * DH + lane], acc[j]);
    }
  }
}

static void run_pv(const float* P, const float* V, const int* Mtop, float* O,
                   int L, int U, hipStream_t stream) {
  dim3 gg(L / PV_LC, 32);
  if (U == 40)      pv_kernel<40><<<gg, 256, 0, stream>>>(P, V, Mtop, O, L);
  else if (U == 35) pv_kernel<35><<<gg, 256, 0, stream>>>(P, V, Mtop, O, L);
  else              pv_kernel<64><<<gg, 256, 0, stream>>>(P, V, Mtop, O, L);
}

// ---------------- im2col (circular, K=3) -> bf16 --------------------------
__global__ void im2col_kernel(const float* __restrict__ X,
                              unsigned short* __restrict__ Y, int B, int L) {
  int i = blockIdx.x * 256 + threadIdx.x;
  int total = B * L * 1536;
  if (i >= total) return;
  int ck = i % 1536;
  int l = (i / 1536) % L;
  int b = i / (1536 * L);
  int c = ck / 3, k = ck % 3;
  int lm = l + k - 1;
  if (lm < 0) lm += L;
  else if (lm >= L) lm -= L;
  Y[i] = f2bf(X[((size_t)(b * L + lm)) * D_MODEL + c]);
}

// ---------------- maxpool k=3 s=2, one -inf pad each side -----------------
__global__ void maxpool_kernel(const float* __restrict__ Y,
                               float* __restrict__ X, int B, int L) {
  int Lo = L / 2;
  int i = blockIdx.x * 256 + threadIdx.x;
  int total = B * Lo * D_MODEL;
  if (i >= total) return;
  int d = i % D_MODEL;
  int lp = (i / D_MODEL) % Lo;
  int b = i / (D_MODEL * Lo);
  int l0 = 2 * lp - 1;
  float m = -INFINITY;
#pragma unroll
  for (int k = 0; k < 3; ++k) {
    int l = l0 + k;
    if (l >= 0 && l < L) m = fmaxf(m, Y[((size_t)(b * L + l)) * D_MODEL + d]);
  }
  X[i] = m;
}

// ==========================================================================
extern "C" void kernel_launch(void* const* d_in, const int* in_sizes, int n_in,
                              void* d_out, int out_size, void* d_ws,
                              size_t ws_size, hipStream_t stream) {
  const float* x_enc  = (const float*)d_in[0];
  const float* emb_w  = (const float*)d_in[1];
  const float* Wq     = (const float*)d_in[2];
  const float* bq     = (const float*)d_in[3];
  const float* Wk     = (const float*)d_in[4];
  const float* bk     = (const float*)d_in[5];
  const float* Wv     = (const float*)d_in[6];
  const float* bv     = (const float*)d_in[7];
  const float* Wo     = (const float*)d_in[8];
  const float* bo     = (const float*)d_in[9];
  const float* ln1_g  = (const float*)d_in[10];
  const float* ln1_b  = (const float*)d_in[11];
  const float* ff_w1  = (const float*)d_in[12];
  const float* ff_b1  = (const float*)d_in[13];
  const float* ff_w2  = (const float*)d_in[14];
  const float* ff_b2  = (const float*)d_in[15];
  const float* ln2_g  = (const float*)d_in[16];
  const float* ln2_b  = (const float*)d_in[17];
  const float* cv_w   = (const float*)d_in[18];
  const float* cv_b   = (const float*)d_in[19];
  const float* bn_g   = (const float*)d_in[20];
  const float* bn_b   = (const float*)d_in[21];
  const float* norm_g = (const float*)d_in[22];
  const float* norm_b = (const float*)d_in[23];

  const int B = 4, L0 = 2048, EL = 3;
  const size_t SZ = (size_t)B * 2048 * 512;
  float* ws   = (float*)d_ws;
  float* xbuf = ws;
  float* ebuf = ws + SZ;   // pre-LN temp; QKs; Sbuf; ab16(V)
  float* qbuf = ws + 2 * SZ;
  float* kbuf = ws + 3 * SZ;
  float* vbuf = ws + 4 * SZ;
  float* obuf = ws + 5 * SZ;
  float* sm   = ws + 6 * SZ;
  int*   d_idx   = (int*)sm;
  float* d_M     = sm + 81920;
  int*   d_Mtop  = (int*)(sm + 81920 + 65536);
  float* d_vmean = sm + 81920 + 65536 + 1280;
  float* qred    = sm;    // reuses idx+M region (dead post-topk)
  float* QKs     = ebuf;
  float* Sbuf    = ebuf;

  const float inv_s = 1.0f / sqrtf(1.0f + 1e-5f);
  auto cast = [&](const float* s, unsigned short* d, int n) {
    cast_bf16_kernel<<<ceil_div(n / 4, 256), 256, 0, stream>>>(s, d, n);
  };

  embed_kernel<<<ceil_div(B * L0 * D_MODEL, 256), 256, 0, stream>>>(
      x_enc, emb_w, xbuf, B, L0);

  int L = L0;
  for (int i = 0; i < EL; ++i) {
    const int M_ = B * L;
    int c = 5 * (int)ceil(log((double)L));
    int U = c < L ? c : L;
    const float* Wq_i = Wq + (size_t)i * 512 * 512;
    const float* Wk_i = Wk + (size_t)i * 512 * 512;
    const float* Wv_i = Wv + (size_t)i * 512 * 512;
    const float* Wo_i = Wo + (size_t)i * 512 * 512;
    const float* w1_i = ff_w1 + (size_t)i * 512 * 512;
    const float* w2_i = ff_w2 + (size_t)i * 512 * 512;

    // Q, K stay fp32 (feed the discontinuous top-k path exactly)
    run_gemm<0>(xbuf, Wq_i, bq + i * 512, nullptr, nullptr, nullptr, qbuf,
                M_, 512, 512, 0.f, stream);
    run_gemm<0>(xbuf, Wk_i, bk + i * 512, nullptr, nullptr, nullptr, kbuf,
                M_, 512, 512, 0.f, stream);

    // V in bf16 MFMA: ab16 @ ebuf (free), wb16 @ obuf (free), C=vbuf
    {
      unsigned short* ab16 = (unsigned short*)ebuf;
      unsigned short* wb16 = (unsigned short*)obuf;
      cast(xbuf, ab16, M_ * 512);
      cast(Wv_i, wb16, 512 * 512);
      run_bgemm<0>(ab16, wb16, bv + i * 512, nullptr, nullptr, nullptr, vbuf,
                   M_, 512, 512, 0.f, stream);
    }

    uint32_t lk0, lk1, k20, k21;
    threefry2x32(0u, 42u, 0u, (uint32_t)i, &lk0, &lk1);
    threefry2x32(lk0, lk1, 0u, 1u, &k20, &k21);
    idx_kernel<<<ceil_div(L * U, 256), 256, 0, stream>>>(d_idx, L, U, k20, k21);

    int nqk = B * NH * L * U;
    sparse_qk_kernel<<<ceil_div(nqk, 256), 256, 0, stream>>>(
        qbuf, kbuf, d_idx, QKs, B, L, U);
    sparse_reduce_kernel<<<ceil_div(B * NH * L * 64, 256), 256, 0, stream>>>(
        QKs, d_M, B * NH * L, L, U);
    topk_kernel<<<B * NH, 256, 0, stream>>>(d_M, d_Mtop, L, U);
    vmean_kernel<<<B * NH, 256, 0, stream>>>(vbuf, d_vmean, B, L);
    fill_ctx_kernel<<<ceil_div(B * L * D_MODEL, 256), 256, 0, stream>>>(
        d_vmean, obuf, B, L);

    pack_qred_kernel<<<B * NH, 256, 0, stream>>>(qbuf, d_Mtop, qred, L, U);
    scores_gemm_kernel<<<dim3(L / 64, B * NH), 256, 0, stream>>>(qred, kbuf,
                                                                 Sbuf, L);
    run_softmax(Sbuf, L, U, stream);
    zero_sel_kernel<<<B * NH, 256, 0, stream>>>(d_Mtop, obuf, L, U);
    run_pv(Sbuf, vbuf, d_Mtop, obuf, L, U, stream);

    // O-proj bf16: ab16 @ qbuf (Q dead), wb16 @ kbuf (K dead), C=ebuf
    unsigned short* ab16 = (unsigned short*)qbuf;
    unsigned short* wb16 = (unsigned short*)kbuf;
    cast(obuf, ab16, M_ * 512);
    cast(Wo_i, wb16, 512 * 512);
    run_bgemm<2>(ab16, wb16, bo + i * 512, xbuf, nullptr, nullptr, ebuf,
                 M_, 512, 512, 0.f, stream);
    ln_kernel<<<M_, 256, 0, stream>>>(ebuf, ln1_g + i * 512, ln1_b + i * 512, xbuf);

    // FF1 bf16 (gelu fused), C=obuf
    cast(xbuf, ab16, M_ * 512);
    cast(w1_i, wb16, 512 * 512);
    run_bgemm<1>(ab16, wb16, ff_b1 + i * 512, nullptr, nullptr, nullptr, obuf,
                 M_, 512, 512, 0.f, stream);
    // FF2 bf16 (+residual), C=ebuf
    cast(obuf, ab16, M_ * 512);
    cast(w2_i, wb16, 512 * 512);
    run_bgemm<2>(ab16, wb16, ff_b2 + i * 512, xbuf, nullptr, nullptr, ebuf,
                 M_, 512, 512, 0.f, stream);
    ln_kernel<<<M_, 256, 0, stream>>>(ebuf, ln2_g + i * 512, ln2_b + i * 512, xbuf);

    if (i < EL - 1) {
      // conv distill bf16: im2col -> imb16 @ qbuf(+kbuf), weights @ vbuf
      unsigned short* imb16 = (unsigned short*)qbuf;
      unsigned short* wb16c = (unsigned short*)vbuf;
      im2col_kernel<<<ceil_div(B * L * 1536, 256), 256, 0, stream>>>(xbuf, imb16, B, L);
      cast(cv_w + (size_t)i * 512 * 1536, wb16c, 512 * 1536);
      run_bgemm<3>(imb16, wb16c, cv_b + i * 512, nullptr, bn_g + i * 512,
                   bn_b + i * 512, ebuf, M_, 512, 1536, inv_s, stream);
      maxpool_kernel<<<ceil_div(B * (L / 2) * D_MODEL, 256), 256, 0, stream>>>(
          ebuf, xbuf, B, L);
      L /= 2;
    }
  }

  ln_kernel<<<B * L, 256, 0, stream>>>(xbuf, norm_g, norm_b, (float*)d_out);
}

// Round 8
// 1477.813 us; speedup vs baseline: 2.1937x; 1.0781x over previous
//
#include <hip/hip_runtime.h>
#include <cmath>
#include <cstdint>

#define D_MODEL 512
#define NH 8
#define DH 64

static inline int ceil_div(int a, int b) { return (a + b - 1) / b; }

typedef __attribute__((ext_vector_type(8))) short short8;
typedef __attribute__((ext_vector_type(4))) float floatx4;

// fp32 -> bf16 (RNE)
__device__ __forceinline__ unsigned short f2bf(float f) {
  uint32_t u = __float_as_uint(f);
  uint32_t r = (u + 0x7fffu + ((u >> 16) & 1u)) >> 16;
  return (unsigned short)r;
}

// ---------------- threefry2x32 (JAX-exact) ----------------
#define TF_ROTL(x, r) (((x) << (r)) | ((x) >> (32 - (r))))

__host__ __device__ inline void threefry2x32(uint32_t k0, uint32_t k1,
                                             uint32_t x0, uint32_t x1,
                                             uint32_t* o0, uint32_t* o1) {
  uint32_t ks2 = k0 ^ k1 ^ 0x1BD11BDAu;
  x0 += k0; x1 += k1;
#define TF_R4(a, b, c, d)                                    \
  x0 += x1; x1 = TF_ROTL(x1, a); x1 ^= x0;                   \
  x0 += x1; x1 = TF_ROTL(x1, b); x1 ^= x0;                   \
  x0 += x1; x1 = TF_ROTL(x1, c); x1 ^= x0;                   \
  x0 += x1; x1 = TF_ROTL(x1, d); x1 ^= x0;
  TF_R4(13, 15, 26, 6);  x0 += k1;  x1 += ks2 + 1u;
  TF_R4(17, 29, 16, 24); x0 += ks2; x1 += k0 + 2u;
  TF_R4(13, 15, 26, 6);  x0 += k0;  x1 += k1 + 3u;
  TF_R4(17, 29, 16, 24); x0 += k1;  x1 += ks2 + 4u;
  TF_R4(13, 15, 26, 6);  x0 += ks2; x1 += k0 + 5u;
#undef TF_R4
  *o0 = x0; *o1 = x1;
}

__global__ void idx_kernel(int* __restrict__ idx, int L, int U,
                           uint32_t k0, uint32_t k1) {
  int n = blockIdx.x * 256 + threadIdx.x;
  if (n >= L * U) return;
  uint32_t o0, o1;
  threefry2x32(k0, k1, 0u, (uint32_t)n, &o0, &o1);
  idx[n] = (int)((o0 ^ o1) & (uint32_t)(L - 1));
}

// ---------------- fp32 -> bf16 cast, 4 elems/thread ----------------
__global__ __launch_bounds__(256) void cast_bf16_kernel(
    const float* __restrict__ src, unsigned short* __restrict__ dst, int n) {
  int i = (blockIdx.x * 256 + threadIdx.x) * 4;
  if (i >= n) return;
  float4 v = *(const float4*)(src + i);
  ushort4 o;
  o.x = f2bf(v.x); o.y = f2bf(v.y); o.z = f2bf(v.z); o.w = f2bf(v.w);
  *(ushort4*)(dst + i) = o;
}

// ---------------- embedding: circular conv (C=2,K=3) + pos encoding -------
__global__ __launch_bounds__(256) void embed_kernel(
    const float* __restrict__ x_enc, const float* __restrict__ emb_w,
    float* __restrict__ x, int B, int L) {
  int i = blockIdx.x * 256 + threadIdx.x;
  int total = B * L * D_MODEL;
  if (i >= total) return;
  int d = i % D_MODEL;
  int l = (i / D_MODEL) % L;
  int b = i / (D_MODEL * L);
  int lm = (l == 0) ? (L - 1) : (l - 1);
  int lp = (l == L - 1) ? 0 : (l + 1);
  const float* w = emb_w + d * 6;
  const float* xb = x_enc + (size_t)b * L * 2;
  float acc = 0.f;
  acc += xb[lm * 2 + 0] * w[0] + xb[l * 2 + 0] * w[1] + xb[lp * 2 + 0] * w[2];
  acc += xb[lm * 2 + 1] * w[3] + xb[l * 2 + 1] * w[4] + xb[lp * 2 + 1] * w[5];
  int j = d >> 1;
  const float coef = -0.017988946039015985f;  // -ln(10000)/512
  float div = expf((float)(2 * j) * coef);
  float ang = (float)l * div;
  float pe = (d & 1) ? cosf(ang) : sinf(ang);
  x[i] = acc + pe;
}

// ---------------- layer norm over D=512 ----------------
__global__ __launch_bounds__(256) void ln_kernel(
    const float* __restrict__ in, const float* __restrict__ g,
    const float* __restrict__ b, float* __restrict__ out) {
  int row = blockIdx.x;
  int t = threadIdx.x;
  const float* xr = in + (size_t)row * D_MODEL;
  float v0 = xr[t], v1 = xr[t + 256];
  __shared__ float red[256];
  red[t] = v0 + v1;
  __syncthreads();
  for (int s = 128; s > 0; s >>= 1) { if (t < s) red[t] += red[t + s]; __syncthreads(); }
  float mean = red[0] * (1.0f / 512.0f);
  __syncthreads();
  float d0 = v0 - mean, d1 = v1 - mean;
  red[t] = d0 * d0 + d1 * d1;
  __syncthreads();
  for (int s = 128; s > 0; s >>= 1) { if (t < s) red[t] += red[t + s]; __syncthreads(); }
  float var = red[0] * (1.0f / 512.0f);
  float rstd = 1.0f / sqrtf(var + 1e-5f);
  float* outr = out + (size_t)row * D_MODEL;
  outr[t]       = d0 * rstd * g[t]       + b[t];
  outr[t + 256] = d1 * rstd * g[t + 256] + b[t + 256];
}

// MODE 0: +bias   1: gelu(+bias)   2: +bias +R   3: elu((+bias)*scl*g + bb)
__device__ __forceinline__ float epilogue_apply(int MODE, float v, float r,
                                                float g, float bb, float scl) {
  if (MODE == 1) {
    v = 0.5f * v * (1.0f + erff(v * 0.7071067811865475f));
  } else if (MODE == 2) {
    v += r;
  } else if (MODE == 3) {
    v = v * scl * g + bb;
    v = (v > 0.f) ? v : expm1f(v);
  }
  return v;
}

// ---------------- fp32 tiled GEMM 64x64, 4x4/thread ----------
#define BM 64
#define BN 64
#define BK 16
#define PADR 4

template <int MODE>
__global__ __launch_bounds__(256) void gemm_kernel(
    const float* __restrict__ A, const float* __restrict__ Bt,
    const float* __restrict__ bias, const float* __restrict__ R,
    const float* __restrict__ gvec, const float* __restrict__ bvec,
    float* __restrict__ C, int M, int N, int K, float scl) {
  __shared__ float As[BK][BM + PADR];
  __shared__ float Bs[BK][BN + PADR];
  const int bm = blockIdx.y * BM;
  const int bn = blockIdx.x * BN;
  const int tid = threadIdx.x;
  const int tx = tid & 15, ty = tid >> 4;
  const int lr = tid >> 2;
  const int lc = (tid & 3) << 2;
  const float* Aptr = A + (size_t)(bm + lr) * K + lc;
  const float* Bptr = Bt + (size_t)(bn + lr) * K + lc;
  float acc[4][4] = {};
  for (int k0 = 0; k0 < K; k0 += BK) {
    float4 av = *(const float4*)(Aptr + k0);
    float4 bv = *(const float4*)(Bptr + k0);
    As[lc + 0][lr] = av.x; As[lc + 1][lr] = av.y;
    As[lc + 2][lr] = av.z; As[lc + 3][lr] = av.w;
    Bs[lc + 0][lr] = bv.x; Bs[lc + 1][lr] = bv.y;
    Bs[lc + 2][lr] = bv.z; Bs[lc + 3][lr] = bv.w;
    __syncthreads();
#pragma unroll
    for (int kk = 0; kk < BK; ++kk) {
      float4 a4 = *(const float4*)&As[kk][ty << 2];
      float4 b4 = *(const float4*)&Bs[kk][tx << 2];
      float ar[4] = {a4.x, a4.y, a4.z, a4.w};
      float br[4] = {b4.x, b4.y, b4.z, b4.w};
#pragma unroll
      for (int i = 0; i < 4; ++i)
#pragma unroll
        for (int j = 0; j < 4; ++j) acc[i][j] += ar[i] * br[j];
    }
    __syncthreads();
  }
#pragma unroll
  for (int i = 0; i < 4; ++i) {
    int row = bm + (ty << 2) + i;
    float* Cr = C + (size_t)row * N;
    const float* Rr = (MODE == 2) ? (R + (size_t)row * N) : nullptr;
#pragma unroll
    for (int j = 0; j < 4; ++j) {
      int col = bn + (tx << 2) + j;
      float v = acc[i][j] + bias[col];
      v = epilogue_apply(MODE, v, (MODE == 2) ? Rr[col] : 0.f,
                         (MODE == 3) ? gvec[col] : 0.f,
                         (MODE == 3) ? bvec[col] : 0.f, scl);
      Cr[col] = v;
    }
  }
}

// ---------------- fp32 GEMM 128x64 tile, 8x4/thread (M>=8192 only) --------
// 32 FMA : 3 ds_read_b128 per kk -> VALU-bound. Grid 512 blocks at M=8192
// (2 blocks/CU, 8 waves/CU) -- avoids R2's 1-block/CU cliff.
template <int MODE>
__global__ __launch_bounds__(256) void gemm128_kernel(
    const float* __restrict__ A, const float* __restrict__ Bt,
    const float* __restrict__ bias, const float* __restrict__ R,
    const float* __restrict__ gvec, const float* __restrict__ bvec,
    float* __restrict__ C, int M, int N, int K, float scl) {
  __shared__ float As[BK][128 + PADR];
  __shared__ float Bs[BK][64 + PADR];
  const int bm = blockIdx.y * 128;
  const int bn = blockIdx.x * 64;
  const int tid = threadIdx.x;
  const int tx = tid & 15, ty = tid >> 4;   // ty:0..15 -> 8 rows each
  const int arow = tid >> 1;                // 0..127
  const int acol = (tid & 1) * 8;           // 0 or 8
  const int brow = tid >> 2;                // 0..63
  const int bcol = (tid & 3) * 4;           // 0,4,8,12
  const float* Aptr = A + (size_t)(bm + arow) * K + acol;
  const float* Bptr = Bt + (size_t)(bn + brow) * K + bcol;
  float acc[8][4] = {};
  for (int k0 = 0; k0 < K; k0 += BK) {
    float4 av0 = *(const float4*)(Aptr + k0);
    float4 av1 = *(const float4*)(Aptr + k0 + 4);
    float4 bv = *(const float4*)(Bptr + k0);
    As[acol + 0][arow] = av0.x; As[acol + 1][arow] = av0.y;
    As[acol + 2][arow] = av0.z; As[acol + 3][arow] = av0.w;
    As[acol + 4][arow] = av1.x; As[acol + 5][arow] = av1.y;
    As[acol + 6][arow] = av1.z; As[acol + 7][arow] = av1.w;
    Bs[bcol + 0][brow] = bv.x; Bs[bcol + 1][brow] = bv.y;
    Bs[bcol + 2][brow] = bv.z; Bs[bcol + 3][brow] = bv.w;
    __syncthreads();
#pragma unroll
    for (int kk = 0; kk < BK; ++kk) {
      float4 a0 = *(const float4*)&As[kk][ty << 3];
      float4 a1 = *(const float4*)&As[kk][(ty << 3) + 4];
      float4 b4 = *(const float4*)&Bs[kk][tx << 2];
      float ar[8] = {a0.x, a0.y, a0.z, a0.w, a1.x, a1.y, a1.z, a1.w};
      float br[4] = {b4.x, b4.y, b4.z, b4.w};
#pragma unroll
      for (int i = 0; i < 8; ++i)
#pragma unroll
        for (int j = 0; j < 4; ++j) acc[i][j] += ar[i] * br[j];
    }
    __syncthreads();
  }
#pragma unroll
  for (int i = 0; i < 8; ++i) {
    int row = bm + (ty << 3) + i;
    float* Cr = C + (size_t)row * N;
    const float* Rr = (MODE == 2) ? (R + (size_t)row * N) : nullptr;
#pragma unroll
    for (int j = 0; j < 4; ++j) {
      int col = bn + (tx << 2) + j;
      float v = acc[i][j] + bias[col];
      v = epilogue_apply(MODE, v, (MODE == 2) ? Rr[col] : 0.f,
                         (MODE == 3) ? gvec[col] : 0.f,
                         (MODE == 3) ? bvec[col] : 0.f, scl);
      Cr[col] = v;
    }
  }
}

template <int MODE>
static void run_gemm(const float* A, const float* Bt, const float* bias,
                     const float* R, const float* g, const float* bb, float* C,
                     int M, int N, int K, float scl, hipStream_t stream) {
  if (M >= 8192) {
    dim3 gg(N / 64, M / 128);
    gemm128_kernel<MODE><<<gg, 256, 0, stream>>>(A, Bt, bias, R, g, bb, C, M, N, K, scl);
  } else {
    dim3 gg(N / BN, M / BM);
    gemm_kernel<MODE><<<gg, 256, 0, stream>>>(A, Bt, bias, R, g, bb, C, M, N, K, scl);
  }
}

// ---------------- bf16 MFMA GEMM 64x64, BK=32, 4 waves (32x32 each) -------
template <int MODE>
__global__ __launch_bounds__(256) void bgemm_kernel(
    const unsigned short* __restrict__ A, const unsigned short* __restrict__ Bt,
    const float* __restrict__ bias, const float* __restrict__ R,
    const float* __restrict__ gvec, const float* __restrict__ bvec,
    float* __restrict__ C, int M, int N, int K, float scl) {
  __shared__ unsigned short Al[64][40];
  __shared__ unsigned short Bl[64][40];
  const int bm = blockIdx.y * 64, bn = blockIdx.x * 64;
  const int tid = threadIdx.x;
  const int wave = tid >> 6, lane = tid & 63;
  const int wm = (wave >> 1) * 32, wn = (wave & 1) * 32;
  const int quad = lane >> 4, l16 = lane & 15;
  const int sr = tid >> 2;
  const int sc = (tid & 3) * 8;
  const unsigned short* Ag = A + (size_t)(bm + sr) * K + sc;
  const unsigned short* Bg = Bt + (size_t)(bn + sr) * K + sc;
  floatx4 zero = {0.f, 0.f, 0.f, 0.f};
  floatx4 acc00 = zero, acc01 = zero, acc10 = zero, acc11 = zero;
  for (int k0 = 0; k0 < K; k0 += 32) {
    short8 a8 = *(const short8*)(Ag + k0);
    short8 b8 = *(const short8*)(Bg + k0);
    *(short8*)&Al[sr][sc] = a8;
    *(short8*)&Bl[sr][sc] = b8;
    __syncthreads();
    short8 af0 = *(const short8*)&Al[wm + l16][quad * 8];
    short8 af1 = *(const short8*)&Al[wm + 16 + l16][quad * 8];
    short8 bf0 = *(const short8*)&Bl[wn + l16][quad * 8];
    short8 bf1 = *(const short8*)&Bl[wn + 16 + l16][quad * 8];
    acc00 = __builtin_amdgcn_mfma_f32_16x16x32_bf16(af0, bf0, acc00, 0, 0, 0);
    acc01 = __builtin_amdgcn_mfma_f32_16x16x32_bf16(af0, bf1, acc01, 0, 0, 0);
    acc10 = __builtin_amdgcn_mfma_f32_16x16x32_bf16(af1, bf0, acc10, 0, 0, 0);
    acc11 = __builtin_amdgcn_mfma_f32_16x16x32_bf16(af1, bf1, acc11, 0, 0, 0);
    __syncthreads();
  }
  floatx4 accs[2][2] = {{acc00, acc01}, {acc10, acc11}};
#pragma unroll
  for (int i = 0; i < 2; ++i) {
#pragma unroll
    for (int j = 0; j < 2; ++j) {
      int col = bn + wn + j * 16 + l16;
#pragma unroll
      for (int p = 0; p < 4; ++p) {
        int row = bm + wm + i * 16 + quad * 4 + p;
        float v = accs[i][j][p] + bias[col];
        v = epilogue_apply(MODE, v, (MODE == 2) ? R[(size_t)row * N + col] : 0.f,
                           (MODE == 3) ? gvec[col] : 0.f,
                           (MODE == 3) ? bvec[col] : 0.f, scl);
        C[(size_t)row * N + col] = v;
      }
    }
  }
}

template <int MODE>
static void run_bgemm(const unsigned short* A, const unsigned short* Bt,
                      const float* bias, const float* R, const float* g,
                      const float* bb, float* C, int M, int N, int K,
                      float scl, hipStream_t stream) {
  dim3 gg(N / 64, M / 64);
  bgemm_kernel<MODE><<<gg, 256, 0, stream>>>(A, Bt, bias, R, g, bb, C, M, N, K, scl);
}

// ---------------- sparse QK: one BLOCK per (b,l), all heads at once -------
// idx[l][u] is (b,h)-independent and K's 8 heads are contiguous per (b,l):
// a wave reads the whole 2KB K row coalesced (2 dwordx4/lane), computes all
// 8 head-dots via per-lane 8-elem partials + 3 shfl_xor within 8-lane
// groups. Replaces per-(b,h,l,u)-thread gathers (64 txns per wave load).
__global__ __launch_bounds__(256) void sparse_qk_kernel(
    const float* __restrict__ Q, const float* __restrict__ Km,
    const int* __restrict__ idx, float* __restrict__ QKs, int B, int L,
    int U) {
  int bl = blockIdx.x;  // b*L + l
  int b = bl / L, l = bl - b * L;
  int tid = threadIdx.x;
  int wave = tid >> 6, lane = tid & 63;
  int h = lane >> 3;
  const float4* qr = (const float4*)(Q + (size_t)bl * D_MODEL + lane * 8);
  float4 q0 = qr[0], q1 = qr[1];
  const int* idxl = idx + l * U;
  for (int u = wave; u < U; u += 4) {
    int ki = idxl[u];
    const float4* kr =
        (const float4*)(Km + ((size_t)b * L + ki) * D_MODEL + lane * 8);
    float4 k0 = kr[0], k1 = kr[1];
    float p = q0.x * k0.x + q0.y * k0.y + q0.z * k0.z + q0.w * k0.w +
              q1.x * k1.x + q1.y * k1.y + q1.z * k1.z + q1.w * k1.w;
    p += __shfl_xor(p, 1);
    p += __shfl_xor(p, 2);
    p += __shfl_xor(p, 4);
    if ((lane & 7) == 0)
      QKs[(((size_t)(b * NH + h)) * L + l) * U + u] = p;
  }
}

// M[bh*L+l] = max_u(QKs) - sum_u(QKs)/L ; one wave per query, ONE butterfly
__global__ __launch_bounds__(256) void sparse_reduce_kernel(
    const float* __restrict__ QKs, float* __restrict__ Mout, int total,
    int L, int U) {
  int wid = (blockIdx.x * 256 + threadIdx.x) >> 6;
  int lane = threadIdx.x & 63;
  if (wid >= total) return;
  float v = (lane < U) ? QKs[(size_t)wid * U + lane] : -INFINITY;
  float m = v;
#pragma unroll
  for (int k = 32; k; k >>= 1) m = fmaxf(m, __shfl_xor(m, k));
  float sv = (lane < U) ? v : 0.f;
#pragma unroll
  for (int k = 32; k; k >>= 1) sv += __shfl_xor(sv, k);
  if (lane == 0) Mout[wid] = m - sv / (float)L;
}

// ---------------- top-k (stable: ties -> lower index), u <= 40 ------------
__global__ __launch_bounds__(256) void topk_kernel(
    const float* __restrict__ Mv, int* __restrict__ Mtop, int L, int u) {
  __shared__ float sv[2048];
  __shared__ float rv[256];
  __shared__ int ri[256];
  int bh = blockIdx.x;
  int t = threadIdx.x;
  for (int l = t; l < L; l += 256) sv[l] = Mv[(size_t)bh * L + l];
  __syncthreads();
  for (int it = 0; it < u; ++it) {
    float bv = -INFINITY;
    int bi = 0x7fffffff;
    for (int l = t; l < L; l += 256) {
      float v = sv[l];
      if (v > bv || (v == bv && l < bi)) { bv = v; bi = l; }
    }
    rv[t] = bv; ri[t] = bi;
    __syncthreads();
    for (int s = 128; s > 0; s >>= 1) {
      if (t < s) {
        float v2 = rv[t + s]; int i2 = ri[t + s];
        if (v2 > rv[t] || (v2 == rv[t] && i2 < ri[t])) { rv[t] = v2; ri[t] = i2; }
      }
      __syncthreads();
    }
    if (t == 0) { Mtop[bh * u + it] = ri[0]; sv[ri[0]] = -INFINITY; }
    __syncthreads();
  }
}

// ---------------- mean of V over L per (b,h) ----------------
__global__ __launch_bounds__(256) void vmean_kernel(
    const float* __restrict__ V, float* __restrict__ vmean, int B, int L) {
  int bh = blockIdx.x;
  int b = bh / NH, h = bh % NH;
  int t = threadIdx.x;
  int e = t & 63, part = t >> 6;
  const float* base = V + (size_t)b * L * D_MODEL + h * DH + e;
  float s = 0.f;
  for (int l = part; l < L; l += 4) s += base[(size_t)l * D_MODEL];
  __shared__ float red[4][64];
  red[part][e] = s;
  __syncthreads();
  if (part == 0) {
    float tot = red[0][e] + red[1][e] + red[2][e] + red[3][e];
    vmean[bh * DH + e] = tot / (float)L;
  }
}

__global__ void fill_ctx_kernel(const float* __restrict__ vmean,
                                float* __restrict__ O, int B, int L) {
  int i = blockIdx.x * 256 + threadIdx.x;
  int total = B * L * D_MODEL;
  if (i >= total) return;
  int dcol = i % D_MODEL;
  int b = i / (D_MODEL * L);
  O[i] = vmean[(b * NH + (dcol >> 6)) * DH + (dcol & 63)];
}

// ============== attention as batched GEMM pipeline ==============
__global__ void pack_qred_kernel(const float* __restrict__ Q,
                                 const int* __restrict__ Mtop,
                                 float* __restrict__ qred, int L, int U) {
  int z = blockIdx.x;  // bh
  int b = z / NH, h = z % NH;
  int t = threadIdx.x;
  int d = t & 63;
  for (int r = t >> 6; r < 64; r += 4) {
    float v = 0.f;
    if (r < U) {
      int l = Mtop[z * U + r];
      v = Q[((size_t)(b * L + l)) * D_MODEL + h * DH + d];
    }
    qred[((size_t)z * 64 + r) * 64 + d] = v;
  }
}

// S[z][64][L] = 0.125 * Qred[z](64x64) @ K_z^T ; K_z rows stride 512
__global__ __launch_bounds__(256) void scores_gemm_kernel(
    const float* __restrict__ qred, const float* __restrict__ Km,
    float* __restrict__ S, int L) {
  __shared__ float As[BK][64 + PADR];
  __shared__ float Bs[BK][64 + PADR];
  const int z = blockIdx.y;
  const int b = z / NH, h = z % NH;
  const float* A = qred + (size_t)z * 64 * 64;
  const float* Bt = Km + (size_t)b * L * D_MODEL + h * DH;  // ldb = 512
  float* Sz = S + (size_t)z * 64 * L;
  const int bn = blockIdx.x * 64;
  const int tid = threadIdx.x;
  const int tx = tid & 15, ty = tid >> 4;
  const int lr = tid >> 2;
  const int lc = (tid & 3) << 2;
  float acc[4][4] = {};
  for (int k0 = 0; k0 < 64; k0 += BK) {
    float4 av = *(const float4*)(A + (size_t)lr * 64 + k0 + lc);
    float4 bv = *(const float4*)(Bt + (size_t)(bn + lr) * D_MODEL + k0 + lc);
    As[lc + 0][lr] = av.x; As[lc + 1][lr] = av.y;
    As[lc + 2][lr] = av.z; As[lc + 3][lr] = av.w;
    Bs[lc + 0][lr] = bv.x; Bs[lc + 1][lr] = bv.y;
    Bs[lc + 2][lr] = bv.z; Bs[lc + 3][lr] = bv.w;
    __syncthreads();
#pragma unroll
    for (int kk = 0; kk < BK; ++kk) {
      float4 a4 = *(const float4*)&As[kk][ty << 2];
      float4 b4 = *(const float4*)&Bs[kk][tx << 2];
      float ar[4] = {a4.x, a4.y, a4.z, a4.w};
      float br[4] = {b4.x, b4.y, b4.z, b4.w};
#pragma unroll
      for (int i = 0; i < 4; ++i)
#pragma unroll
        for (int j = 0; j < 4; ++j) acc[i][j] += ar[i] * br[j];
    }
    __syncthreads();
  }
#pragma unroll
  for (int i = 0; i < 4; ++i) {
    float* Sr = Sz + (size_t)((ty << 2) + i) * L + bn;
#pragma unroll
    for (int j = 0; j < 4; ++j) Sr[(tx << 2) + j] = 0.125f * acc[i][j];
  }
}

// ---------------- softmax: one block per (z,row) ----------------
template <int LC>
__global__ __launch_bounds__(256) void softmax_kernel(float* __restrict__ S,
                                                      int U) {
  constexpr int NE = LC / 256;
  int rid = blockIdx.x;
  int z = rid / U, r = rid % U;
  float* row = S + (size_t)z * 64 * LC + (size_t)r * LC;
  int t = threadIdx.x;
  float vals[NE];
  float m = -INFINITY;
#pragma unroll
  for (int i = 0; i < NE; ++i) {
    vals[i] = row[t + i * 256];
    m = fmaxf(m, vals[i]);
  }
  __shared__ float red[256];
  red[t] = m;
  __syncthreads();
  for (int s = 128; s > 0; s >>= 1) { if (t < s) red[t] = fmaxf(red[t], red[t + s]); __syncthreads(); }
  m = red[0];
  __syncthreads();
  float sum = 0.f;
#pragma unroll
  for (int i = 0; i < NE; ++i) {
    vals[i] = expf(vals[i] - m);
    sum += vals[i];
  }
  red[t] = sum;
  __syncthreads();
  for (int s = 128; s > 0; s >>= 1) { if (t < s) red[t] += red[t + s]; __syncthreads(); }
  float inv = 1.0f / red[0];
#pragma unroll
  for (int i = 0; i < NE; ++i) row[t + i * 256] = vals[i] * inv;
}

static void run_softmax(float* S, int L, int U, hipStream_t stream) {
  int blocks = 32 * U;
  if (L == 2048)      softmax_kernel<2048><<<blocks, 256, 0, stream>>>(S, U);
  else if (L == 1024) softmax_kernel<1024><<<blocks, 256, 0, stream>>>(S, U);
  else                softmax_kernel<512><<<blocks, 256, 0, stream>>>(S, U);
}

// zero the selected ctx rows before split-K PV atomics
__global__ void zero_sel_kernel(const int* __restrict__ Mtop,
                                float* __restrict__ O, int L, int U) {
  int z = blockIdx.x;
  int b = z / NH, h = z % NH;
  int t = threadIdx.x;
  int d = t & 63;
  for (int r = t >> 6; r < U; r += 4) {
    int l = Mtop[z * U + r];
    O[((size_t)(b * L + l)) * D_MODEL + h * DH + d] = 0.f;
  }
}

// O[sel rows] += P(UxL) @ V(Lx64), split-K over 128-chunks of L.
#define PV_LC 128

template <int U>
__global__ __launch_bounds__(256) void pv_kernel(
    const float* __restrict__ P, const float* __restrict__ V,
    const int* __restrict__ Mtop, float* __restrict__ O, int L) {
  __shared__ float Pl[U][PV_LC];
  __shared__ float Vl[PV_LC][DH + 4];
  const int z = blockIdx.y;
  const int b = z / NH, h = z % NH;
  const int c0 = blockIdx.x * PV_LC;
  const int tid = threadIdx.x;
  const float* Pz = P + (size_t)z * 64 * L + c0;
  for (int i4 = tid; i4 < U * (PV_LC / 4); i4 += 256) {
    int r = i4 / (PV_LC / 4);
    int lq = (i4 % (PV_LC / 4)) * 4;
    float4 p4 = *(const float4*)(Pz + (size_t)r * L + lq);
    Pl[r][lq + 0] = p4.x; Pl[r][lq + 1] = p4.y;
    Pl[r][lq + 2] = p4.z; Pl[r][lq + 3] = p4.w;
  }
  const float* Vb = V + ((size_t)b * L + c0) * D_MODEL + h * DH;
  for (int i4 = tid; i4 < PV_LC * (DH / 4); i4 += 256) {
    int l = i4 >> 4;
    int d4 = (i4 & 15) * 4;
    float4 v4 = *(const float4*)(Vb + (size_t)l * D_MODEL + d4);
    Vl[l][d4 + 0] = v4.x; Vl[l][d4 + 1] = v4.y;
    Vl[l][d4 + 2] = v4.z; Vl[l][d4 + 3] = v4.w;
  }
  __syncthreads();
  const int wave = tid >> 6, lane = tid & 63;
  constexpr int NJ = (U + 3) / 4;
  float acc[NJ] = {};
  for (int l = 0; l < PV_LC; ++l) {
    float vv = Vl[l][lane];
#pragma unroll
    for (int j = 0; j < NJ; ++j) {
      int r = wave + 4 * j;
      if (r < U) acc[j] += Pl[r][l] * vv;
    }
  }
#pragma unroll
  for (int j = 0; j < NJ; ++j) {
    int r = wave + 4 * j;
    if (r < U) {
      int ml = Mtop[z * U + r];
      atomicAdd(&O[((size_t)(b * L + ml)) * D_MODEL + h * DH + lane], acc[j]);
    }
  }
}

static void run_pv(const float* P, const float* V, const int* Mtop, float* O,
                   int L, int U, hipStream_t stream) {
  dim3 gg(L / PV_LC, 32);
  if (U == 40)      pv_kernel<40><<<gg, 256, 0, stream>>>(P, V, Mtop, O, L);
  else if (U == 35) pv_kernel<35><<<gg, 256, 0, stream>>>(P, V, Mtop, O, L);
  else              pv_kernel<64><<<gg, 256, 0, stream>>>(P, V, Mtop, O, L);
}

// ---------------- im2col (circular, K=3) -> bf16 --------------------------
__global__ void im2col_kernel(const float* __restrict__ X,
                              unsigned short* __restrict__ Y, int B, int L) {
  int i = blockIdx.x * 256 + threadIdx.x;
  int total = B * L * 1536;
  if (i >= total) return;
  int ck = i % 1536;
  int l = (i / 1536) % L;
  int b = i / (1536 * L);
  int c = ck / 3, k = ck % 3;
  int lm = l + k - 1;
  if (lm < 0) lm += L;
  else if (lm >= L) lm -= L;
  Y[i] = f2bf(X[((size_t)(b * L + lm)) * D_MODEL + c]);
}

// ---------------- maxpool k=3 s=2, one -inf pad each side -----------------
__global__ void maxpool_kernel(const float* __restrict__ Y,
                               float* __restrict__ X, int B, int L) {
  int Lo = L / 2;
  int i = blockIdx.x * 256 + threadIdx.x;
  int total = B * Lo * D_MODEL;
  if (i >= total) return;
  int d = i % D_MODEL;
  int lp = (i / D_MODEL) % Lo;
  int b = i / (D_MODEL * Lo);
  int l0 = 2 * lp - 1;
  float m = -INFINITY;
#pragma unroll
  for (int k = 0; k < 3; ++k) {
    int l = l0 + k;
    if (l >= 0 && l < L) m = fmaxf(m, Y[((size_t)(b * L + l)) * D_MODEL + d]);
  }
  X[i] = m;
}

// ==========================================================================
extern "C" void kernel_launch(void* const* d_in, const int* in_sizes, int n_in,
                              void* d_out, int out_size, void* d_ws,
                              size_t ws_size, hipStream_t stream) {
  const float* x_enc  = (const float*)d_in[0];
  const float* emb_w  = (const float*)d_in[1];
  const float* Wq     = (const float*)d_in[2];
  const float* bq     = (const float*)d_in[3];
  const float* Wk     = (const float*)d_in[4];
  const float* bk     = (const float*)d_in[5];
  const float* Wv     = (const float*)d_in[6];
  const float* bv     = (const float*)d_in[7];
  const float* Wo     = (const float*)d_in[8];
  const float* bo     = (const float*)d_in[9];
  const float* ln1_g  = (const float*)d_in[10];
  const float* ln1_b  = (const float*)d_in[11];
  const float* ff_w1  = (const float*)d_in[12];
  const float* ff_b1  = (const float*)d_in[13];
  const float* ff_w2  = (const float*)d_in[14];
  const float* ff_b2  = (const float*)d_in[15];
  const float* ln2_g  = (const float*)d_in[16];
  const float* ln2_b  = (const float*)d_in[17];
  const float* cv_w   = (const float*)d_in[18];
  const float* cv_b   = (const float*)d_in[19];
  const float* bn_g   = (const float*)d_in[20];
  const float* bn_b   = (const float*)d_in[21];
  const float* norm_g = (const float*)d_in[22];
  const float* norm_b = (const float*)d_in[23];

  const int B = 4, L0 = 2048, EL = 3;
  const size_t SZ = (size_t)B * 2048 * 512;
  float* ws   = (float*)d_ws;
  float* xbuf = ws;
  float* ebuf = ws + SZ;   // pre-LN temp; QKs; Sbuf; ab16(V)
  float* qbuf = ws + 2 * SZ;
  float* kbuf = ws + 3 * SZ;
  float* vbuf = ws + 4 * SZ;
  float* obuf = ws + 5 * SZ;
  float* sm   = ws + 6 * SZ;
  int*   d_idx   = (int*)sm;
  float* d_M     = sm + 81920;
  int*   d_Mtop  = (int*)(sm + 81920 + 65536);
  float* d_vmean = sm + 81920 + 65536 + 1280;
  float* qred    = sm;    // reuses idx+M region (dead post-topk)
  float* QKs     = ebuf;
  float* Sbuf    = ebuf;

  const float inv_s = 1.0f / sqrtf(1.0f + 1e-5f);
  auto cast = [&](const float* s, unsigned short* d, int n) {
    cast_bf16_kernel<<<ceil_div(n / 4, 256), 256, 0, stream>>>(s, d, n);
  };

  embed_kernel<<<ceil_div(B * L0 * D_MODEL, 256), 256, 0, stream>>>(
      x_enc, emb_w, xbuf, B, L0);

  int L = L0;
  for (int i = 0; i < EL; ++i) {
    const int M_ = B * L;
    int c = 5 * (int)ceil(log((double)L));
    int U = c < L ? c : L;
    const float* Wq_i = Wq + (size_t)i * 512 * 512;
    const float* Wk_i = Wk + (size_t)i * 512 * 512;
    const float* Wv_i = Wv + (size_t)i * 512 * 512;
    const float* Wo_i = Wo + (size_t)i * 512 * 512;
    const float* w1_i = ff_w1 + (size_t)i * 512 * 512;
    const float* w2_i = ff_w2 + (size_t)i * 512 * 512;

    // Q, K stay fp32 (feed the discontinuous top-k path exactly)
    run_gemm<0>(xbuf, Wq_i, bq + i * 512, nullptr, nullptr, nullptr, qbuf,
                M_, 512, 512, 0.f, stream);
    run_gemm<0>(xbuf, Wk_i, bk + i * 512, nullptr, nullptr, nullptr, kbuf,
                M_, 512, 512, 0.f, stream);

    // V in bf16 MFMA: ab16 @ ebuf (free), wb16 @ obuf (free), C=vbuf
    {
      unsigned short* ab16 = (unsigned short*)ebuf;
      unsigned short* wb16 = (unsigned short*)obuf;
      cast(xbuf, ab16, M_ * 512);
      cast(Wv_i, wb16, 512 * 512);
      run_bgemm<0>(ab16, wb16, bv + i * 512, nullptr, nullptr, nullptr, vbuf,
                   M_, 512, 512, 0.f, stream);
    }

    uint32_t lk0, lk1, k20, k21;
    threefry2x32(0u, 42u, 0u, (uint32_t)i, &lk0, &lk1);
    threefry2x32(lk0, lk1, 0u, 1u, &k20, &k21);
    idx_kernel<<<ceil_div(L * U, 256), 256, 0, stream>>>(d_idx, L, U, k20, k21);

    sparse_qk_kernel<<<B * L, 256, 0, stream>>>(qbuf, kbuf, d_idx, QKs, B, L, U);
    sparse_reduce_kernel<<<ceil_div(B * NH * L * 64, 256), 256, 0, stream>>>(
        QKs, d_M, B * NH * L, L, U);
    topk_kernel<<<B * NH, 256, 0, stream>>>(d_M, d_Mtop, L, U);
    vmean_kernel<<<B * NH, 256, 0, stream>>>(vbuf, d_vmean, B, L);
    fill_ctx_kernel<<<ceil_div(B * L * D_MODEL, 256), 256, 0, stream>>>(
        d_vmean, obuf, B, L);

    pack_qred_kernel<<<B * NH, 256, 0, stream>>>(qbuf, d_Mtop, qred, L, U);
    scores_gemm_kernel<<<dim3(L / 64, B * NH), 256, 0, stream>>>(qred, kbuf,
                                                                 Sbuf, L);
    run_softmax(Sbuf, L, U, stream);
    zero_sel_kernel<<<B * NH, 256, 0, stream>>>(d_Mtop, obuf, L, U);
    run_pv(Sbuf, vbuf, d_Mtop, obuf, L, U, stream);

    // O-proj bf16: ab16 @ qbuf (Q dead), wb16 @ kbuf (K dead), C=ebuf
    unsigned short* ab16 = (unsigned short*)qbuf;
    unsigned short* wb16 = (unsigned short*)kbuf;
    cast(obuf, ab16, M_ * 512);
    cast(Wo_i, wb16, 512 * 512);
    run_bgemm<2>(ab16, wb16, bo + i * 512, xbuf, nullptr, nullptr, ebuf,
                 M_, 512, 512, 0.f, stream);
    ln_kernel<<<M_, 256, 0, stream>>>(ebuf, ln1_g + i * 512, ln1_b + i * 512, xbuf);

    // FF1 bf16 (gelu fused), C=obuf
    cast(xbuf, ab16, M_ * 512);
    cast(w1_i, wb16, 512 * 512);
    run_bgemm<1>(ab16, wb16, ff_b1 + i * 512, nullptr, nullptr, nullptr, obuf,
                 M_, 512, 512, 0.f, stream);
    // FF2 bf16 (+residual), C=ebuf
    cast(obuf, ab16, M_ * 512);
    cast(w2_i, wb16, 512 * 512);
    run_bgemm<2>(ab16, wb16, ff_b2 + i * 512, xbuf, nullptr, nullptr, ebuf,
                 M_, 512, 512, 0.f, stream);
    ln_kernel<<<M_, 256, 0, stream>>>(ebuf, ln2_g + i * 512, ln2_b + i * 512, xbuf);

    if (i < EL - 1) {
      // conv distill bf16: im2col -> imb16 @ qbuf(+kbuf), weights @ vbuf
      unsigned short* imb16 = (unsigned short*)qbuf;
      unsigned short* wb16c = (unsigned short*)vbuf;
      im2col_kernel<<<ceil_div(B * L * 1536, 256), 256, 0, stream>>>(xbuf, imb16, B, L);
      cast(cv_w + (size_t)i * 512 * 1536, wb16c, 512 * 1536);
      run_bgemm<3>(imb16, wb16c, cv_b + i * 512, nullptr, bn_g + i * 512,
                   bn_b + i * 512, ebuf, M_, 512, 1536, inv_s, stream);
      maxpool_kernel<<<ceil_div(B * (L / 2) * D_MODEL, 256), 256, 0, stream>>>(
          ebuf, xbuf, B, L);
      L /= 2;
    }
  }

  ln_kernel<<<B * L, 256, 0, stream>>>(xbuf, norm_g, norm_b, (float*)d_out);
}

// Round 9
// 1274.008 us; speedup vs baseline: 2.5447x; 1.1600x over previous
//
#include <hip/hip_runtime.h>
#include <cmath>
#include <cstdint>

#define D_MODEL 512
#define NH 8
#define DH 64

static inline int ceil_div(int a, int b) { return (a + b - 1) / b; }

typedef __attribute__((ext_vector_type(8))) short short8;
typedef __attribute__((ext_vector_type(4))) float floatx4;

// fp32 -> bf16 (RNE)
__device__ __forceinline__ unsigned short f2bf(float f) {
  uint32_t u = __float_as_uint(f);
  uint32_t r = (u + 0x7fffu + ((u >> 16) & 1u)) >> 16;
  return (unsigned short)r;
}

// ---------------- threefry2x32 (JAX-exact) ----------------
#define TF_ROTL(x, r) (((x) << (r)) | ((x) >> (32 - (r))))

__host__ __device__ inline void threefry2x32(uint32_t k0, uint32_t k1,
                                             uint32_t x0, uint32_t x1,
                                             uint32_t* o0, uint32_t* o1) {
  uint32_t ks2 = k0 ^ k1 ^ 0x1BD11BDAu;
  x0 += k0; x1 += k1;
#define TF_R4(a, b, c, d)                                    \
  x0 += x1; x1 = TF_ROTL(x1, a); x1 ^= x0;                   \
  x0 += x1; x1 = TF_ROTL(x1, b); x1 ^= x0;                   \
  x0 += x1; x1 = TF_ROTL(x1, c); x1 ^= x0;                   \
  x0 += x1; x1 = TF_ROTL(x1, d); x1 ^= x0;
  TF_R4(13, 15, 26, 6);  x0 += k1;  x1 += ks2 + 1u;
  TF_R4(17, 29, 16, 24); x0 += ks2; x1 += k0 + 2u;
  TF_R4(13, 15, 26, 6);  x0 += k0;  x1 += k1 + 3u;
  TF_R4(17, 29, 16, 24); x0 += k1;  x1 += ks2 + 4u;
  TF_R4(13, 15, 26, 6);  x0 += ks2; x1 += k0 + 5u;
#undef TF_R4
  *o0 = x0; *o1 = x1;
}

__global__ void idx_kernel(int* __restrict__ idx, int L, int U,
                           uint32_t k0, uint32_t k1) {
  int n = blockIdx.x * 256 + threadIdx.x;
  if (n >= L * U) return;
  uint32_t o0, o1;
  threefry2x32(k0, k1, 0u, (uint32_t)n, &o0, &o1);
  idx[n] = (int)((o0 ^ o1) & (uint32_t)(L - 1));
}

// ---------------- fp32 -> bf16 cast, 4 elems/thread ----------------
__global__ __launch_bounds__(256) void cast_bf16_kernel(
    const float* __restrict__ src, unsigned short* __restrict__ dst, int n) {
  int i = (blockIdx.x * 256 + threadIdx.x) * 4;
  if (i >= n) return;
  float4 v = *(const float4*)(src + i);
  ushort4 o;
  o.x = f2bf(v.x); o.y = f2bf(v.y); o.z = f2bf(v.z); o.w = f2bf(v.w);
  *(ushort4*)(dst + i) = o;
}

// ---------------- embedding: circular conv (C=2,K=3) + pos encoding -------
__global__ __launch_bounds__(256) void embed_kernel(
    const float* __restrict__ x_enc, const float* __restrict__ emb_w,
    float* __restrict__ x, int B, int L) {
  int i = blockIdx.x * 256 + threadIdx.x;
  int total = B * L * D_MODEL;
  if (i >= total) return;
  int d = i % D_MODEL;
  int l = (i / D_MODEL) % L;
  int b = i / (D_MODEL * L);
  int lm = (l == 0) ? (L - 1) : (l - 1);
  int lp = (l == L - 1) ? 0 : (l + 1);
  const float* w = emb_w + d * 6;
  const float* xb = x_enc + (size_t)b * L * 2;
  float acc = 0.f;
  acc += xb[lm * 2 + 0] * w[0] + xb[l * 2 + 0] * w[1] + xb[lp * 2 + 0] * w[2];
  acc += xb[lm * 2 + 1] * w[3] + xb[l * 2 + 1] * w[4] + xb[lp * 2 + 1] * w[5];
  int j = d >> 1;
  const float coef = -0.017988946039015985f;  // -ln(10000)/512
  float div = expf((float)(2 * j) * coef);
  float ang = (float)l * div;
  float pe = (d & 1) ? cosf(ang) : sinf(ang);
  x[i] = acc + pe;
}

// ---------------- layer norm over D=512 ----------------
__global__ __launch_bounds__(256) void ln_kernel(
    const float* __restrict__ in, const float* __restrict__ g,
    const float* __restrict__ b, float* __restrict__ out) {
  int row = blockIdx.x;
  int t = threadIdx.x;
  const float* xr = in + (size_t)row * D_MODEL;
  float v0 = xr[t], v1 = xr[t + 256];
  __shared__ float red[256];
  red[t] = v0 + v1;
  __syncthreads();
  for (int s = 128; s > 0; s >>= 1) { if (t < s) red[t] += red[t + s]; __syncthreads(); }
  float mean = red[0] * (1.0f / 512.0f);
  __syncthreads();
  float d0 = v0 - mean, d1 = v1 - mean;
  red[t] = d0 * d0 + d1 * d1;
  __syncthreads();
  for (int s = 128; s > 0; s >>= 1) { if (t < s) red[t] += red[t + s]; __syncthreads(); }
  float var = red[0] * (1.0f / 512.0f);
  float rstd = 1.0f / sqrtf(var + 1e-5f);
  float* outr = out + (size_t)row * D_MODEL;
  outr[t]       = d0 * rstd * g[t]       + b[t];
  outr[t + 256] = d1 * rstd * g[t + 256] + b[t + 256];
}

// MODE 0: +bias   1: gelu(+bias)   2: +bias +R   3: elu((+bias)*scl*g + bb)
__device__ __forceinline__ float epilogue_apply(int MODE, float v, float r,
                                                float g, float bb, float scl) {
  if (MODE == 1) {
    v = 0.5f * v * (1.0f + erff(v * 0.7071067811865475f));
  } else if (MODE == 2) {
    v += r;
  } else if (MODE == 3) {
    v = v * scl * g + bb;
    v = (v > 0.f) ? v : expm1f(v);
  }
  return v;
}

// ---------------- fp32 tiled GEMM 64x64, 4x4/thread ----------
#define BM 64
#define BN 64
#define BK 16
#define PADR 4

template <int MODE>
__global__ __launch_bounds__(256) void gemm_kernel(
    const float* __restrict__ A, const float* __restrict__ Bt,
    const float* __restrict__ bias, const float* __restrict__ R,
    const float* __restrict__ gvec, const float* __restrict__ bvec,
    float* __restrict__ C, int M, int N, int K, float scl) {
  __shared__ float As[BK][BM + PADR];
  __shared__ float Bs[BK][BN + PADR];
  const int bm = blockIdx.y * BM;
  const int bn = blockIdx.x * BN;
  const int tid = threadIdx.x;
  const int tx = tid & 15, ty = tid >> 4;
  const int lr = tid >> 2;
  const int lc = (tid & 3) << 2;
  const float* Aptr = A + (size_t)(bm + lr) * K + lc;
  const float* Bptr = Bt + (size_t)(bn + lr) * K + lc;
  float acc[4][4] = {};
  for (int k0 = 0; k0 < K; k0 += BK) {
    float4 av = *(const float4*)(Aptr + k0);
    float4 bv = *(const float4*)(Bptr + k0);
    As[lc + 0][lr] = av.x; As[lc + 1][lr] = av.y;
    As[lc + 2][lr] = av.z; As[lc + 3][lr] = av.w;
    Bs[lc + 0][lr] = bv.x; Bs[lc + 1][lr] = bv.y;
    Bs[lc + 2][lr] = bv.z; Bs[lc + 3][lr] = bv.w;
    __syncthreads();
#pragma unroll
    for (int kk = 0; kk < BK; ++kk) {
      float4 a4 = *(const float4*)&As[kk][ty << 2];
      float4 b4 = *(const float4*)&Bs[kk][tx << 2];
      float ar[4] = {a4.x, a4.y, a4.z, a4.w};
      float br[4] = {b4.x, b4.y, b4.z, b4.w};
#pragma unroll
      for (int i = 0; i < 4; ++i)
#pragma unroll
        for (int j = 0; j < 4; ++j) acc[i][j] += ar[i] * br[j];
    }
    __syncthreads();
  }
#pragma unroll
  for (int i = 0; i < 4; ++i) {
    int row = bm + (ty << 2) + i;
    float* Cr = C + (size_t)row * N;
    const float* Rr = (MODE == 2) ? (R + (size_t)row * N) : nullptr;
#pragma unroll
    for (int j = 0; j < 4; ++j) {
      int col = bn + (tx << 2) + j;
      float v = acc[i][j] + bias[col];
      v = epilogue_apply(MODE, v, (MODE == 2) ? Rr[col] : 0.f,
                         (MODE == 3) ? gvec[col] : 0.f,
                         (MODE == 3) ? bvec[col] : 0.f, scl);
      Cr[col] = v;
    }
  }
}

// ---------------- fp32 GEMM 128x64 tile, 8x4/thread (M>=8192 only) --------
template <int MODE>
__global__ __launch_bounds__(256) void gemm128_kernel(
    const float* __restrict__ A, const float* __restrict__ Bt,
    const float* __restrict__ bias, const float* __restrict__ R,
    const float* __restrict__ gvec, const float* __restrict__ bvec,
    float* __restrict__ C, int M, int N, int K, float scl) {
  __shared__ float As[BK][128 + PADR];
  __shared__ float Bs[BK][64 + PADR];
  const int bm = blockIdx.y * 128;
  const int bn = blockIdx.x * 64;
  const int tid = threadIdx.x;
  const int tx = tid & 15, ty = tid >> 4;
  const int arow = tid >> 1;
  const int acol = (tid & 1) * 8;
  const int brow = tid >> 2;
  const int bcol = (tid & 3) * 4;
  const float* Aptr = A + (size_t)(bm + arow) * K + acol;
  const float* Bptr = Bt + (size_t)(bn + brow) * K + bcol;
  float acc[8][4] = {};
  for (int k0 = 0; k0 < K; k0 += BK) {
    float4 av0 = *(const float4*)(Aptr + k0);
    float4 av1 = *(const float4*)(Aptr + k0 + 4);
    float4 bv = *(const float4*)(Bptr + k0);
    As[acol + 0][arow] = av0.x; As[acol + 1][arow] = av0.y;
    As[acol + 2][arow] = av0.z; As[acol + 3][arow] = av0.w;
    As[acol + 4][arow] = av1.x; As[acol + 5][arow] = av1.y;
    As[acol + 6][arow] = av1.z; As[acol + 7][arow] = av1.w;
    Bs[bcol + 0][brow] = bv.x; Bs[bcol + 1][brow] = bv.y;
    Bs[bcol + 2][brow] = bv.z; Bs[bcol + 3][brow] = bv.w;
    __syncthreads();
#pragma unroll
    for (int kk = 0; kk < BK; ++kk) {
      float4 a0 = *(const float4*)&As[kk][ty << 3];
      float4 a1 = *(const float4*)&As[kk][(ty << 3) + 4];
      float4 b4 = *(const float4*)&Bs[kk][tx << 2];
      float ar[8] = {a0.x, a0.y, a0.z, a0.w, a1.x, a1.y, a1.z, a1.w};
      float br[4] = {b4.x, b4.y, b4.z, b4.w};
#pragma unroll
      for (int i = 0; i < 8; ++i)
#pragma unroll
        for (int j = 0; j < 4; ++j) acc[i][j] += ar[i] * br[j];
    }
    __syncthreads();
  }
#pragma unroll
  for (int i = 0; i < 8; ++i) {
    int row = bm + (ty << 3) + i;
    float* Cr = C + (size_t)row * N;
    const float* Rr = (MODE == 2) ? (R + (size_t)row * N) : nullptr;
#pragma unroll
    for (int j = 0; j < 4; ++j) {
      int col = bn + (tx << 2) + j;
      float v = acc[i][j] + bias[col];
      v = epilogue_apply(MODE, v, (MODE == 2) ? Rr[col] : 0.f,
                         (MODE == 3) ? gvec[col] : 0.f,
                         (MODE == 3) ? bvec[col] : 0.f, scl);
      Cr[col] = v;
    }
  }
}

template <int MODE>
static void run_gemm(const float* A, const float* Bt, const float* bias,
                     const float* R, const float* g, const float* bb, float* C,
                     int M, int N, int K, float scl, hipStream_t stream) {
  if (M >= 8192) {
    dim3 gg(N / 64, M / 128);
    gemm128_kernel<MODE><<<gg, 256, 0, stream>>>(A, Bt, bias, R, g, bb, C, M, N, K, scl);
  } else {
    dim3 gg(N / BN, M / BM);
    gemm_kernel<MODE><<<gg, 256, 0, stream>>>(A, Bt, bias, R, g, bb, C, M, N, K, scl);
  }
}

// ---------------- bf16 MFMA GEMM 64x64, BK=32, 4 waves (32x32 each) -------
template <int MODE>
__global__ __launch_bounds__(256) void bgemm_kernel(
    const unsigned short* __restrict__ A, const unsigned short* __restrict__ Bt,
    const float* __restrict__ bias, const float* __restrict__ R,
    const float* __restrict__ gvec, const float* __restrict__ bvec,
    float* __restrict__ C, int M, int N, int K, float scl) {
  __shared__ unsigned short Al[64][40];
  __shared__ unsigned short Bl[64][40];
  const int bm = blockIdx.y * 64, bn = blockIdx.x * 64;
  const int tid = threadIdx.x;
  const int wave = tid >> 6, lane = tid & 63;
  const int wm = (wave >> 1) * 32, wn = (wave & 1) * 32;
  const int quad = lane >> 4, l16 = lane & 15;
  const int sr = tid >> 2;
  const int sc = (tid & 3) * 8;
  const unsigned short* Ag = A + (size_t)(bm + sr) * K + sc;
  const unsigned short* Bg = Bt + (size_t)(bn + sr) * K + sc;
  floatx4 zero = {0.f, 0.f, 0.f, 0.f};
  floatx4 acc00 = zero, acc01 = zero, acc10 = zero, acc11 = zero;
  for (int k0 = 0; k0 < K; k0 += 32) {
    short8 a8 = *(const short8*)(Ag + k0);
    short8 b8 = *(const short8*)(Bg + k0);
    *(short8*)&Al[sr][sc] = a8;
    *(short8*)&Bl[sr][sc] = b8;
    __syncthreads();
    short8 af0 = *(const short8*)&Al[wm + l16][quad * 8];
    short8 af1 = *(const short8*)&Al[wm + 16 + l16][quad * 8];
    short8 bf0 = *(const short8*)&Bl[wn + l16][quad * 8];
    short8 bf1 = *(const short8*)&Bl[wn + 16 + l16][quad * 8];
    acc00 = __builtin_amdgcn_mfma_f32_16x16x32_bf16(af0, bf0, acc00, 0, 0, 0);
    acc01 = __builtin_amdgcn_mfma_f32_16x16x32_bf16(af0, bf1, acc01, 0, 0, 0);
    acc10 = __builtin_amdgcn_mfma_f32_16x16x32_bf16(af1, bf0, acc10, 0, 0, 0);
    acc11 = __builtin_amdgcn_mfma_f32_16x16x32_bf16(af1, bf1, acc11, 0, 0, 0);
    __syncthreads();
  }
  floatx4 accs[2][2] = {{acc00, acc01}, {acc10, acc11}};
#pragma unroll
  for (int i = 0; i < 2; ++i) {
#pragma unroll
    for (int j = 0; j < 2; ++j) {
      int col = bn + wn + j * 16 + l16;
#pragma unroll
      for (int p = 0; p < 4; ++p) {
        int row = bm + wm + i * 16 + quad * 4 + p;
        float v = accs[i][j][p] + bias[col];
        v = epilogue_apply(MODE, v, (MODE == 2) ? R[(size_t)row * N + col] : 0.f,
                           (MODE == 3) ? gvec[col] : 0.f,
                           (MODE == 3) ? bvec[col] : 0.f, scl);
        C[(size_t)row * N + col] = v;
      }
    }
  }
}

template <int MODE>
static void run_bgemm(const unsigned short* A, const unsigned short* Bt,
                      const float* bias, const float* R, const float* g,
                      const float* bb, float* C, int M, int N, int K,
                      float scl, hipStream_t stream) {
  dim3 gg(N / 64, M / 64);
  bgemm_kernel<MODE><<<gg, 256, 0, stream>>>(A, Bt, bias, R, g, bb, C, M, N, K, scl);
}

// ---------------- sparse QK: one BLOCK per (b,l), all heads at once -------
__global__ __launch_bounds__(256) void sparse_qk_kernel(
    const float* __restrict__ Q, const float* __restrict__ Km,
    const int* __restrict__ idx, float* __restrict__ QKs, int B, int L,
    int U) {
  int bl = blockIdx.x;  // b*L + l
  int b = bl / L, l = bl - b * L;
  int tid = threadIdx.x;
  int wave = tid >> 6, lane = tid & 63;
  int h = lane >> 3;
  const float4* qr = (const float4*)(Q + (size_t)bl * D_MODEL + lane * 8);
  float4 q0 = qr[0], q1 = qr[1];
  const int* idxl = idx + l * U;
  for (int u = wave; u < U; u += 4) {
    int ki = idxl[u];
    const float4* kr =
        (const float4*)(Km + ((size_t)b * L + ki) * D_MODEL + lane * 8);
    float4 k0 = kr[0], k1 = kr[1];
    float p = q0.x * k0.x + q0.y * k0.y + q0.z * k0.z + q0.w * k0.w +
              q1.x * k1.x + q1.y * k1.y + q1.z * k1.z + q1.w * k1.w;
    p += __shfl_xor(p, 1);
    p += __shfl_xor(p, 2);
    p += __shfl_xor(p, 4);
    if ((lane & 7) == 0)
      QKs[(((size_t)(b * NH + h)) * L + l) * U + u] = p;
  }
}

// M[bh*L+l] = max_u(QKs) - sum_u(QKs)/L ; one wave per query, ONE butterfly
__global__ __launch_bounds__(256) void sparse_reduce_kernel(
    const float* __restrict__ QKs, float* __restrict__ Mout, int total,
    int L, int U) {
  int wid = (blockIdx.x * 256 + threadIdx.x) >> 6;
  int lane = threadIdx.x & 63;
  if (wid >= total) return;
  float v = (lane < U) ? QKs[(size_t)wid * U + lane] : -INFINITY;
  float m = v;
#pragma unroll
  for (int k = 32; k; k >>= 1) m = fmaxf(m, __shfl_xor(m, k));
  float sv = (lane < U) ? v : 0.f;
#pragma unroll
  for (int k = 32; k; k >>= 1) sv += __shfl_xor(sv, k);
  if (lane == 0) Mout[wid] = m - sv / (float)L;
}

// ---------------- top-k (stable: ties -> lower index), u <= 40 ------------
__global__ __launch_bounds__(256) void topk_kernel(
    const float* __restrict__ Mv, int* __restrict__ Mtop, int L, int u) {
  __shared__ float sv[2048];
  __shared__ float rv[256];
  __shared__ int ri[256];
  int bh = blockIdx.x;
  int t = threadIdx.x;
  for (int l = t; l < L; l += 256) sv[l] = Mv[(size_t)bh * L + l];
  __syncthreads();
  for (int it = 0; it < u; ++it) {
    float bv = -INFINITY;
    int bi = 0x7fffffff;
    for (int l = t; l < L; l += 256) {
      float v = sv[l];
      if (v > bv || (v == bv && l < bi)) { bv = v; bi = l; }
    }
    rv[t] = bv; ri[t] = bi;
    __syncthreads();
    for (int s = 128; s > 0; s >>= 1) {
      if (t < s) {
        float v2 = rv[t + s]; int i2 = ri[t + s];
        if (v2 > rv[t] || (v2 == rv[t] && i2 < ri[t])) { rv[t] = v2; ri[t] = i2; }
      }
      __syncthreads();
    }
    if (t == 0) { Mtop[bh * u + it] = ri[0]; sv[ri[0]] = -INFINITY; }
    __syncthreads();
  }
}

// ---------------- mean of V over L: split-L partial + atomic --------------
// R8's version: 32 blocks, 1.4% occupancy, 123us. Now: zero then 256 blocks
// (64 chunks x B), fully-coalesced 512-wide row reads (all 8 heads at once),
// one atomicAdd per column per block. vmean[b*512+col] == [(b*NH+h)*64+e].
__global__ void vmean_zero_kernel(float* __restrict__ vmean) {
  vmean[blockIdx.x * 256 + threadIdx.x] = 0.f;
}

__global__ __launch_bounds__(256) void vmean_partial_kernel(
    const float* __restrict__ V, float* __restrict__ vmean, int L) {
  int b = blockIdx.y;
  int chunk = blockIdx.x;           // 64 chunks
  int rows = L >> 6;
  int t = threadIdx.x;
  const float* base = V + ((size_t)b * L + (size_t)chunk * rows) * D_MODEL;
  float s0 = 0.f, s1 = 0.f;
  for (int r = 0; r < rows; ++r) {
    s0 += base[(size_t)r * D_MODEL + t];
    s1 += base[(size_t)r * D_MODEL + t + 256];
  }
  float invL = 1.0f / (float)L;
  atomicAdd(&vmean[b * D_MODEL + t], s0 * invL);
  atomicAdd(&vmean[b * D_MODEL + t + 256], s1 * invL);
}

__global__ void fill_ctx_kernel(const float* __restrict__ vmean,
                                float* __restrict__ O, int B, int L) {
  int i = blockIdx.x * 256 + threadIdx.x;
  int total = B * L * D_MODEL;
  if (i >= total) return;
  int dcol = i % D_MODEL;
  int b = i / (D_MODEL * L);
  O[i] = vmean[b * D_MODEL + dcol];
}

// ============== attention as batched GEMM pipeline ==============
__global__ void pack_qred_kernel(const float* __restrict__ Q,
                                 const int* __restrict__ Mtop,
                                 float* __restrict__ qred, int L, int U) {
  int z = blockIdx.x;  // bh
  int b = z / NH, h = z % NH;
  int t = threadIdx.x;
  int d = t & 63;
  for (int r = t >> 6; r < 64; r += 4) {
    float v = 0.f;
    if (r < U) {
      int l = Mtop[z * U + r];
      v = Q[((size_t)(b * L + l)) * D_MODEL + h * DH + d];
    }
    qred[((size_t)z * 64 + r) * 64 + d] = v;
  }
}

// S[z][64][L] = 0.125 * Qred[z](64x64) @ K_z^T ; K_z rows stride 512
__global__ __launch_bounds__(256) void scores_gemm_kernel(
    const float* __restrict__ qred, const float* __restrict__ Km,
    float* __restrict__ S, int L) {
  __shared__ float As[BK][64 + PADR];
  __shared__ float Bs[BK][64 + PADR];
  const int z = blockIdx.y;
  const int b = z / NH, h = z % NH;
  const float* A = qred + (size_t)z * 64 * 64;
  const float* Bt = Km + (size_t)b * L * D_MODEL + h * DH;  // ldb = 512
  float* Sz = S + (size_t)z * 64 * L;
  const int bn = blockIdx.x * 64;
  const int tid = threadIdx.x;
  const int tx = tid & 15, ty = tid >> 4;
  const int lr = tid >> 2;
  const int lc = (tid & 3) << 2;
  float acc[4][4] = {};
  for (int k0 = 0; k0 < 64; k0 += BK) {
    float4 av = *(const float4*)(A + (size_t)lr * 64 + k0 + lc);
    float4 bv = *(const float4*)(Bt + (size_t)(bn + lr) * D_MODEL + k0 + lc);
    As[lc + 0][lr] = av.x; As[lc + 1][lr] = av.y;
    As[lc + 2][lr] = av.z; As[lc + 3][lr] = av.w;
    Bs[lc + 0][lr] = bv.x; Bs[lc + 1][lr] = bv.y;
    Bs[lc + 2][lr] = bv.z; Bs[lc + 3][lr] = bv.w;
    __syncthreads();
#pragma unroll
    for (int kk = 0; kk < BK; ++kk) {
      float4 a4 = *(const float4*)&As[kk][ty << 2];
      float4 b4 = *(const float4*)&Bs[kk][tx << 2];
      float ar[4] = {a4.x, a4.y, a4.z, a4.w};
      float br[4] = {b4.x, b4.y, b4.z, b4.w};
#pragma unroll
      for (int i = 0; i < 4; ++i)
#pragma unroll
        for (int j = 0; j < 4; ++j) acc[i][j] += ar[i] * br[j];
    }
    __syncthreads();
  }
#pragma unroll
  for (int i = 0; i < 4; ++i) {
    float* Sr = Sz + (size_t)((ty << 2) + i) * L + bn;
#pragma unroll
    for (int j = 0; j < 4; ++j) Sr[(tx << 2) + j] = 0.125f * acc[i][j];
  }
}

// ---------------- softmax: one block per (z,row) ----------------
template <int LC>
__global__ __launch_bounds__(256) void softmax_kernel(float* __restrict__ S,
                                                      int U) {
  constexpr int NE = LC / 256;
  int rid = blockIdx.x;
  int z = rid / U, r = rid % U;
  float* row = S + (size_t)z * 64 * LC + (size_t)r * LC;
  int t = threadIdx.x;
  float vals[NE];
  float m = -INFINITY;
#pragma unroll
  for (int i = 0; i < NE; ++i) {
    vals[i] = row[t + i * 256];
    m = fmaxf(m, vals[i]);
  }
  __shared__ float red[256];
  red[t] = m;
  __syncthreads();
  for (int s = 128; s > 0; s >>= 1) { if (t < s) red[t] = fmaxf(red[t], red[t + s]); __syncthreads(); }
  m = red[0];
  __syncthreads();
  float sum = 0.f;
#pragma unroll
  for (int i = 0; i < NE; ++i) {
    vals[i] = expf(vals[i] - m);
    sum += vals[i];
  }
  red[t] = sum;
  __syncthreads();
  for (int s = 128; s > 0; s >>= 1) { if (t < s) red[t] += red[t + s]; __syncthreads(); }
  float inv = 1.0f / red[0];
#pragma unroll
  for (int i = 0; i < NE; ++i) row[t + i * 256] = vals[i] * inv;
}

static void run_softmax(float* S, int L, int U, hipStream_t stream) {
  int blocks = 32 * U;
  if (L == 2048)      softmax_kernel<2048><<<blocks, 256, 0, stream>>>(S, U);
  else if (L == 1024) softmax_kernel<1024><<<blocks, 256, 0, stream>>>(S, U);
  else                softmax_kernel<512><<<blocks, 256, 0, stream>>>(S, U);
}

// zero the selected ctx rows before split-K PV atomics
__global__ void zero_sel_kernel(const int* __restrict__ Mtop,
                                float* __restrict__ O, int L, int U) {
  int z = blockIdx.x;
  int b = z / NH, h = z % NH;
  int t = threadIdx.x;
  int d = t & 63;
  for (int r = t >> 6; r < U; r += 4) {
    int l = Mtop[z * U + r];
    O[((size_t)(b * L + l)) * D_MODEL + h * DH + d] = 0.f;
  }
}

// O[sel rows] += P(UxL) @ V(Lx64), split-K over 128-chunks of L.
#define PV_LC 128

template <int U>
__global__ __launch_bounds__(256) void pv_kernel(
    const float* __restrict__ P, const float* __restrict__ V,
    const int* __restrict__ Mtop, float* __restrict__ O, int L) {
  __shared__ float Pl[U][PV_LC];
  __shared__ float Vl[PV_LC][DH + 4];
  const int z = blockIdx.y;
  const int b = z / NH, h = z % NH;
  const int c0 = blockIdx.x * PV_LC;
  const int tid = threadIdx.x;
  const float* Pz = P + (size_t)z * 64 * L + c0;
  for (int i4 = tid; i4 < U * (PV_LC / 4); i4 += 256) {
    int r = i4 / (PV_LC / 4);
    int lq = (i4 % (PV_LC / 4)) * 4;
    float4 p4 = *(const float4*)(Pz + (size_t)r * L + lq);
    Pl[r][lq + 0] = p4.x; Pl[r][lq + 1] = p4.y;
    Pl[r][lq + 2] = p4.z; Pl[r][lq + 3] = p4.w;
  }
  const float* Vb = V + ((size_t)b * L + c0) * D_MODEL + h * DH;
  for (int i4 = tid; i4 < PV_LC * (DH / 4); i4 += 256) {
    int l = i4 >> 4;
    int d4 = (i4 & 15) * 4;
    float4 v4 = *(const float4*)(Vb + (size_t)l * D_MODEL + d4);
    Vl[l][d4 + 0] = v4.x; Vl[l][d4 + 1] = v4.y;
    Vl[l][d4 + 2] = v4.z; Vl[l][d4 + 3] = v4.w;
  }
  __syncthreads();
  const int wave = tid >> 6, lane = tid & 63;
  constexpr int NJ = (U + 3) / 4;
  float acc[NJ] = {};
  for (int l = 0; l < PV_LC; ++l) {
    float vv = Vl[l][lane];
#pragma unroll
    for (int j = 0; j < NJ; ++j) {
      int r = wave + 4 * j;
      if (r < U) acc[j] += Pl[r][l] * vv;
    }
  }
#pragma unroll
  for (int j = 0; j < NJ; ++j) {
    int r = wave + 4 * j;
    if (r < U) {
      int ml = Mtop[z * U + r];
      atomicAdd(&O[((size_t)(b * L + ml)) * D_MODEL + h * DH + lane], acc[j]);
    }
  }
}

static void run_pv(const float* P, const float* V, const int* Mtop, float* O,
                   int L, int U, hipStream_t stream) {
  dim3 gg(L / PV_LC, 32);
  if (U == 40)      pv_kernel<40><<<gg, 256, 0, stream>>>(P, V, Mtop, O, L);
  else if (U == 35) pv_kernel<35><<<gg, 256, 0, stream>>>(P, V, Mtop, O, L);
  else              pv_kernel<64><<<gg, 256, 0, stream>>>(P, V, Mtop, O, L);
}

// ---------------- im2col (circular, K=3) -> bf16 --------------------------
__global__ void im2col_kernel(const float* __restrict__ X,
                              unsigned short* __restrict__ Y, int B, int L) {
  int i = blockIdx.x * 256 + threadIdx.x;
  int total = B * L * 1536;
  if (i >= total) return;
  int ck = i % 1536;
  int l = (i / 1536) % L;
  int b = i / (1536 * L);
  int c = ck / 3, k = ck % 3;
  int lm = l + k - 1;
  if (lm < 0) lm += L;
  else if (lm >= L) lm -= L;
  Y[i] = f2bf(X[((size_t)(b * L + lm)) * D_MODEL + c]);
}

// ---------------- maxpool k=3 s=2, one -inf pad each side -----------------
__global__ void maxpool_kernel(const float* __restrict__ Y,
                               float* __restrict__ X, int B, int L) {
  int Lo = L / 2;
  int i = blockIdx.x * 256 + threadIdx.x;
  int total = B * Lo * D_MODEL;
  if (i >= total) return;
  int d = i % D_MODEL;
  int lp = (i / D_MODEL) % Lo;
  int b = i / (D_MODEL * Lo);
  int l0 = 2 * lp - 1;
  float m = -INFINITY;
#pragma unroll
  for (int k = 0; k < 3; ++k) {
    int l = l0 + k;
    if (l >= 0 && l < L) m = fmaxf(m, Y[((size_t)(b * L + l)) * D_MODEL + d]);
  }
  X[i] = m;
}

// ==========================================================================
extern "C" void kernel_launch(void* const* d_in, const int* in_sizes, int n_in,
                              void* d_out, int out_size, void* d_ws,
                              size_t ws_size, hipStream_t stream) {
  const float* x_enc  = (const float*)d_in[0];
  const float* emb_w  = (const float*)d_in[1];
  const float* Wq     = (const float*)d_in[2];
  const float* bq     = (const float*)d_in[3];
  const float* Wk     = (const float*)d_in[4];
  const float* bk     = (const float*)d_in[5];
  const float* Wv     = (const float*)d_in[6];
  const float* bv     = (const float*)d_in[7];
  const float* Wo     = (const float*)d_in[8];
  const float* bo     = (const float*)d_in[9];
  const float* ln1_g  = (const float*)d_in[10];
  const float* ln1_b  = (const float*)d_in[11];
  const float* ff_w1  = (const float*)d_in[12];
  const float* ff_b1  = (const float*)d_in[13];
  const float* ff_w2  = (const float*)d_in[14];
  const float* ff_b2  = (const float*)d_in[15];
  const float* ln2_g  = (const float*)d_in[16];
  const float* ln2_b  = (const float*)d_in[17];
  const float* cv_w   = (const float*)d_in[18];
  const float* cv_b   = (const float*)d_in[19];
  const float* bn_g   = (const float*)d_in[20];
  const float* bn_b   = (const float*)d_in[21];
  const float* norm_g = (const float*)d_in[22];
  const float* norm_b = (const float*)d_in[23];

  const int B = 4, L0 = 2048, EL = 3;
  const size_t SZ = (size_t)B * 2048 * 512;
  float* ws   = (float*)d_ws;
  float* xbuf = ws;
  float* ebuf = ws + SZ;   // pre-LN temp; QKs; Sbuf; ab16(V)
  float* qbuf = ws + 2 * SZ;
  float* kbuf = ws + 3 * SZ;
  float* vbuf = ws + 4 * SZ;
  float* obuf = ws + 5 * SZ;
  float* sm   = ws + 6 * SZ;
  int*   d_idx   = (int*)sm;
  float* d_M     = sm + 81920;
  int*   d_Mtop  = (int*)(sm + 81920 + 65536);
  float* d_vmean = sm + 81920 + 65536 + 1280;
  float* qred    = sm;    // reuses idx+M region (dead post-topk)
  float* QKs     = ebuf;
  float* Sbuf    = ebuf;

  const float inv_s = 1.0f / sqrtf(1.0f + 1e-5f);
  auto cast = [&](const float* s, unsigned short* d, int n) {
    cast_bf16_kernel<<<ceil_div(n / 4, 256), 256, 0, stream>>>(s, d, n);
  };

  embed_kernel<<<ceil_div(B * L0 * D_MODEL, 256), 256, 0, stream>>>(
      x_enc, emb_w, xbuf, B, L0);

  int L = L0;
  for (int i = 0; i < EL; ++i) {
    const int M_ = B * L;
    int c = 5 * (int)ceil(log((double)L));
    int U = c < L ? c : L;
    const float* Wq_i = Wq + (size_t)i * 512 * 512;
    const float* Wk_i = Wk + (size_t)i * 512 * 512;
    const float* Wv_i = Wv + (size_t)i * 512 * 512;
    const float* Wo_i = Wo + (size_t)i * 512 * 512;
    const float* w1_i = ff_w1 + (size_t)i * 512 * 512;
    const float* w2_i = ff_w2 + (size_t)i * 512 * 512;

    // Q, K stay fp32 (feed the discontinuous top-k path exactly)
    run_gemm<0>(xbuf, Wq_i, bq + i * 512, nullptr, nullptr, nullptr, qbuf,
                M_, 512, 512, 0.f, stream);
    run_gemm<0>(xbuf, Wk_i, bk + i * 512, nullptr, nullptr, nullptr, kbuf,
                M_, 512, 512, 0.f, stream);

    // V in bf16 MFMA: ab16 @ ebuf (free), wb16 @ obuf (free), C=vbuf
    {
      unsigned short* ab16 = (unsigned short*)ebuf;
      unsigned short* wb16 = (unsigned short*)obuf;
      cast(xbuf, ab16, M_ * 512);
      cast(Wv_i, wb16, 512 * 512);
      run_bgemm<0>(ab16, wb16, bv + i * 512, nullptr, nullptr, nullptr, vbuf,
                   M_, 512, 512, 0.f, stream);
    }

    uint32_t lk0, lk1, k20, k21;
    threefry2x32(0u, 42u, 0u, (uint32_t)i, &lk0, &lk1);
    threefry2x32(lk0, lk1, 0u, 1u, &k20, &k21);
    idx_kernel<<<ceil_div(L * U, 256), 256, 0, stream>>>(d_idx, L, U, k20, k21);

    sparse_qk_kernel<<<B * L, 256, 0, stream>>>(qbuf, kbuf, d_idx, QKs, B, L, U);
    sparse_reduce_kernel<<<ceil_div(B * NH * L * 64, 256), 256, 0, stream>>>(
        QKs, d_M, B * NH * L, L, U);
    topk_kernel<<<B * NH, 256, 0, stream>>>(d_M, d_Mtop, L, U);
    vmean_zero_kernel<<<8, 256, 0, stream>>>(d_vmean);
    vmean_partial_kernel<<<dim3(64, B), 256, 0, stream>>>(vbuf, d_vmean, L);
    fill_ctx_kernel<<<ceil_div(B * L * D_MODEL, 256), 256, 0, stream>>>(
        d_vmean, obuf, B, L);

    pack_qred_kernel<<<B * NH, 256, 0, stream>>>(qbuf, d_Mtop, qred, L, U);
    scores_gemm_kernel<<<dim3(L / 64, B * NH), 256, 0, stream>>>(qred, kbuf,
                                                                 Sbuf, L);
    run_softmax(Sbuf, L, U, stream);
    zero_sel_kernel<<<B * NH, 256, 0, stream>>>(d_Mtop, obuf, L, U);
    run_pv(Sbuf, vbuf, d_Mtop, obuf, L, U, stream);

    // O-proj bf16: ab16 @ qbuf (Q dead), wb16 @ kbuf (K dead), C=ebuf
    unsigned short* ab16 = (unsigned short*)qbuf;
    unsigned short* wb16 = (unsigned short*)kbuf;
    cast(obuf, ab16, M_ * 512);
    cast(Wo_i, wb16, 512 * 512);
    run_bgemm<2>(ab16, wb16, bo + i * 512, xbuf, nullptr, nullptr, ebuf,
                 M_, 512, 512, 0.f, stream);
    ln_kernel<<<M_, 256, 0, stream>>>(ebuf, ln1_g + i * 512, ln1_b + i * 512, xbuf);

    // FF1 bf16 (gelu fused), C=obuf
    cast(xbuf, ab16, M_ * 512);
    cast(w1_i, wb16, 512 * 512);
    run_bgemm<1>(ab16, wb16, ff_b1 + i * 512, nullptr, nullptr, nullptr, obuf,
                 M_, 512, 512, 0.f, stream);
    // FF2 bf16 (+residual), C=ebuf
    cast(obuf, ab16, M_ * 512);
    cast(w2_i, wb16, 512 * 512);
    run_bgemm<2>(ab16, wb16, ff_b2 + i * 512, xbuf, nullptr, nullptr, ebuf,
                 M_, 512, 512, 0.f, stream);
    ln_kernel<<<M_, 256, 0, stream>>>(ebuf, ln2_g + i * 512, ln2_b + i * 512, xbuf);

    if (i < EL - 1) {
      // conv distill bf16: im2col -> imb16 @ qbuf(+kbuf), weights @ vbuf
      unsigned short* imb16 = (unsigned short*)qbuf;
      unsigned short* wb16c = (unsigned short*)vbuf;
      im2col_kernel<<<ceil_div(B * L * 1536, 256), 256, 0, stream>>>(xbuf, imb16, B, L);
      cast(cv_w + (size_t)i * 512 * 1536, wb16c, 512 * 1536);
      run_bgemm<3>(imb16, wb16c, cv_b + i * 512, nullptr, bn_g + i * 512,
                   bn_b + i * 512, ebuf, M_, 512, 1536, inv_s, stream);
      maxpool_kernel<<<ceil_div(B * (L / 2) * D_MODEL, 256), 256, 0, stream>>>(
          ebuf, xbuf, B, L);
      L /= 2;
    }
  }

  ln_kernel<<<B * L, 256, 0, stream>>>(xbuf, norm_g, norm_b, (float*)d_out);
}

// Round 10
// 1218.691 us; speedup vs baseline: 2.6602x; 1.0454x over previous
//
#include <hip/hip_runtime.h>
#include <cmath>
#include <cstdint>

#define D_MODEL 512
#define NH 8
#define DH 64

static inline int ceil_div(int a, int b) { return (a + b - 1) / b; }

typedef __attribute__((ext_vector_type(8))) short short8;
typedef __attribute__((ext_vector_type(4))) float floatx4;

// fp32 -> bf16 (RNE)
__device__ __forceinline__ unsigned short f2bf(float f) {
  uint32_t u = __float_as_uint(f);
  uint32_t r = (u + 0x7fffu + ((u >> 16) & 1u)) >> 16;
  return (unsigned short)r;
}

// ---------------- threefry2x32 (JAX-exact) ----------------
#define TF_ROTL(x, r) (((x) << (r)) | ((x) >> (32 - (r))))

__host__ __device__ inline void threefry2x32(uint32_t k0, uint32_t k1,
                                             uint32_t x0, uint32_t x1,
                                             uint32_t* o0, uint32_t* o1) {
  uint32_t ks2 = k0 ^ k1 ^ 0x1BD11BDAu;
  x0 += k0; x1 += k1;
#define TF_R4(a, b, c, d)                                    \
  x0 += x1; x1 = TF_ROTL(x1, a); x1 ^= x0;                   \
  x0 += x1; x1 = TF_ROTL(x1, b); x1 ^= x0;                   \
  x0 += x1; x1 = TF_ROTL(x1, c); x1 ^= x0;                   \
  x0 += x1; x1 = TF_ROTL(x1, d); x1 ^= x0;
  TF_R4(13, 15, 26, 6);  x0 += k1;  x1 += ks2 + 1u;
  TF_R4(17, 29, 16, 24); x0 += ks2; x1 += k0 + 2u;
  TF_R4(13, 15, 26, 6);  x0 += k0;  x1 += k1 + 3u;
  TF_R4(17, 29, 16, 24); x0 += k1;  x1 += ks2 + 4u;
  TF_R4(13, 15, 26, 6);  x0 += ks2; x1 += k0 + 5u;
#undef TF_R4
  *o0 = x0; *o1 = x1;
}

__global__ void idx_kernel(int* __restrict__ idx, int L, int U,
                           uint32_t k0, uint32_t k1) {
  int n = blockIdx.x * 256 + threadIdx.x;
  if (n >= L * U) return;
  uint32_t o0, o1;
  threefry2x32(k0, k1, 0u, (uint32_t)n, &o0, &o1);
  idx[n] = (int)((o0 ^ o1) & (uint32_t)(L - 1));
}

// ---------------- fp32 -> bf16 cast, 4 elems/thread ----------------
__global__ __launch_bounds__(256) void cast_bf16_kernel(
    const float* __restrict__ src, unsigned short* __restrict__ dst, int n) {
  int i = (blockIdx.x * 256 + threadIdx.x) * 4;
  if (i >= n) return;
  float4 v = *(const float4*)(src + i);
  ushort4 o;
  o.x = f2bf(v.x); o.y = f2bf(v.y); o.z = f2bf(v.z); o.w = f2bf(v.w);
  *(ushort4*)(dst + i) = o;
}

// ---------------- embedding: circular conv (C=2,K=3) + pos encoding -------
__global__ __launch_bounds__(256) void embed_kernel(
    const float* __restrict__ x_enc, const float* __restrict__ emb_w,
    float* __restrict__ x, int B, int L) {
  int i = blockIdx.x * 256 + threadIdx.x;
  int total = B * L * D_MODEL;
  if (i >= total) return;
  int d = i % D_MODEL;
  int l = (i / D_MODEL) % L;
  int b = i / (D_MODEL * L);
  int lm = (l == 0) ? (L - 1) : (l - 1);
  int lp = (l == L - 1) ? 0 : (l + 1);
  const float* w = emb_w + d * 6;
  const float* xb = x_enc + (size_t)b * L * 2;
  float acc = 0.f;
  acc += xb[lm * 2 + 0] * w[0] + xb[l * 2 + 0] * w[1] + xb[lp * 2 + 0] * w[2];
  acc += xb[lm * 2 + 1] * w[3] + xb[l * 2 + 1] * w[4] + xb[lp * 2 + 1] * w[5];
  int j = d >> 1;
  const float coef = -0.017988946039015985f;  // -ln(10000)/512
  float div = expf((float)(2 * j) * coef);
  float ang = (float)l * div;
  float pe = (d & 1) ? cosf(ang) : sinf(ang);
  x[i] = acc + pe;
}

// ---------------- layer norm over D=512 ----------------
__global__ __launch_bounds__(256) void ln_kernel(
    const float* __restrict__ in, const float* __restrict__ g,
    const float* __restrict__ b, float* __restrict__ out) {
  int row = blockIdx.x;
  int t = threadIdx.x;
  const float* xr = in + (size_t)row * D_MODEL;
  float v0 = xr[t], v1 = xr[t + 256];
  __shared__ float red[256];
  red[t] = v0 + v1;
  __syncthreads();
  for (int s = 128; s > 0; s >>= 1) { if (t < s) red[t] += red[t + s]; __syncthreads(); }
  float mean = red[0] * (1.0f / 512.0f);
  __syncthreads();
  float d0 = v0 - mean, d1 = v1 - mean;
  red[t] = d0 * d0 + d1 * d1;
  __syncthreads();
  for (int s = 128; s > 0; s >>= 1) { if (t < s) red[t] += red[t + s]; __syncthreads(); }
  float var = red[0] * (1.0f / 512.0f);
  float rstd = 1.0f / sqrtf(var + 1e-5f);
  float* outr = out + (size_t)row * D_MODEL;
  outr[t]       = d0 * rstd * g[t]       + b[t];
  outr[t + 256] = d1 * rstd * g[t + 256] + b[t + 256];
}

// MODE 0: +bias   1: gelu(+bias)   2: +bias +R   3: elu((+bias)*scl*g + bb)
__device__ __forceinline__ float epilogue_apply(int MODE, float v, float r,
                                                float g, float bb, float scl) {
  if (MODE == 1) {
    v = 0.5f * v * (1.0f + erff(v * 0.7071067811865475f));
  } else if (MODE == 2) {
    v += r;
  } else if (MODE == 3) {
    v = v * scl * g + bb;
    v = (v > 0.f) ? v : expm1f(v);
  }
  return v;
}

// ---------------- fp32 tiled GEMM 64x64, 4x4/thread ----------
#define BM 64
#define BN 64
#define BK 16
#define PADR 4

template <int MODE>
__global__ __launch_bounds__(256) void gemm_kernel(
    const float* __restrict__ A, const float* __restrict__ Bt,
    const float* __restrict__ bias, const float* __restrict__ R,
    const float* __restrict__ gvec, const float* __restrict__ bvec,
    float* __restrict__ C, int M, int N, int K, float scl) {
  __shared__ float As[BK][BM + PADR];
  __shared__ float Bs[BK][BN + PADR];
  const int bm = blockIdx.y * BM;
  const int bn = blockIdx.x * BN;
  const int tid = threadIdx.x;
  const int tx = tid & 15, ty = tid >> 4;
  const int lr = tid >> 2;
  const int lc = (tid & 3) << 2;
  const float* Aptr = A + (size_t)(bm + lr) * K + lc;
  const float* Bptr = Bt + (size_t)(bn + lr) * K + lc;
  float acc[4][4] = {};
  for (int k0 = 0; k0 < K; k0 += BK) {
    float4 av = *(const float4*)(Aptr + k0);
    float4 bv = *(const float4*)(Bptr + k0);
    As[lc + 0][lr] = av.x; As[lc + 1][lr] = av.y;
    As[lc + 2][lr] = av.z; As[lc + 3][lr] = av.w;
    Bs[lc + 0][lr] = bv.x; Bs[lc + 1][lr] = bv.y;
    Bs[lc + 2][lr] = bv.z; Bs[lc + 3][lr] = bv.w;
    __syncthreads();
#pragma unroll
    for (int kk = 0; kk < BK; ++kk) {
      float4 a4 = *(const float4*)&As[kk][ty << 2];
      float4 b4 = *(const float4*)&Bs[kk][tx << 2];
      float ar[4] = {a4.x, a4.y, a4.z, a4.w};
      float br[4] = {b4.x, b4.y, b4.z, b4.w};
#pragma unroll
      for (int i = 0; i < 4; ++i)
#pragma unroll
        for (int j = 0; j < 4; ++j) acc[i][j] += ar[i] * br[j];
    }
    __syncthreads();
  }
#pragma unroll
  for (int i = 0; i < 4; ++i) {
    int row = bm + (ty << 2) + i;
    float* Cr = C + (size_t)row * N;
    const float* Rr = (MODE == 2) ? (R + (size_t)row * N) : nullptr;
#pragma unroll
    for (int j = 0; j < 4; ++j) {
      int col = bn + (tx << 2) + j;
      float v = acc[i][j] + bias[col];
      v = epilogue_apply(MODE, v, (MODE == 2) ? Rr[col] : 0.f,
                         (MODE == 3) ? gvec[col] : 0.f,
                         (MODE == 3) ? bvec[col] : 0.f, scl);
      Cr[col] = v;
    }
  }
}

// ---------------- fp32 GEMM 128x64 tile, 8x4/thread (M>=8192 only) --------
template <int MODE>
__global__ __launch_bounds__(256) void gemm128_kernel(
    const float* __restrict__ A, const float* __restrict__ Bt,
    const float* __restrict__ bias, const float* __restrict__ R,
    const float* __restrict__ gvec, const float* __restrict__ bvec,
    float* __restrict__ C, int M, int N, int K, float scl) {
  __shared__ float As[BK][128 + PADR];
  __shared__ float Bs[BK][64 + PADR];
  const int bm = blockIdx.y * 128;
  const int bn = blockIdx.x * 64;
  const int tid = threadIdx.x;
  const int tx = tid & 15, ty = tid >> 4;
  const int arow = tid >> 1;
  const int acol = (tid & 1) * 8;
  const int brow = tid >> 2;
  const int bcol = (tid & 3) * 4;
  const float* Aptr = A + (size_t)(bm + arow) * K + acol;
  const float* Bptr = Bt + (size_t)(bn + brow) * K + bcol;
  float acc[8][4] = {};
  for (int k0 = 0; k0 < K; k0 += BK) {
    float4 av0 = *(const float4*)(Aptr + k0);
    float4 av1 = *(const float4*)(Aptr + k0 + 4);
    float4 bv = *(const float4*)(Bptr + k0);
    As[acol + 0][arow] = av0.x; As[acol + 1][arow] = av0.y;
    As[acol + 2][arow] = av0.z; As[acol + 3][arow] = av0.w;
    As[acol + 4][arow] = av1.x; As[acol + 5][arow] = av1.y;
    As[acol + 6][arow] = av1.z; As[acol + 7][arow] = av1.w;
    Bs[bcol + 0][brow] = bv.x; Bs[bcol + 1][brow] = bv.y;
    Bs[bcol + 2][brow] = bv.z; Bs[bcol + 3][brow] = bv.w;
    __syncthreads();
#pragma unroll
    for (int kk = 0; kk < BK; ++kk) {
      float4 a0 = *(const float4*)&As[kk][ty << 3];
      float4 a1 = *(const float4*)&As[kk][(ty << 3) + 4];
      float4 b4 = *(const float4*)&Bs[kk][tx << 2];
      float ar[8] = {a0.x, a0.y, a0.z, a0.w, a1.x, a1.y, a1.z, a1.w};
      float br[4] = {b4.x, b4.y, b4.z, b4.w};
#pragma unroll
      for (int i = 0; i < 8; ++i)
#pragma unroll
        for (int j = 0; j < 4; ++j) acc[i][j] += ar[i] * br[j];
    }
    __syncthreads();
  }
#pragma unroll
  for (int i = 0; i < 8; ++i) {
    int row = bm + (ty << 3) + i;
    float* Cr = C + (size_t)row * N;
    const float* Rr = (MODE == 2) ? (R + (size_t)row * N) : nullptr;
#pragma unroll
    for (int j = 0; j < 4; ++j) {
      int col = bn + (tx << 2) + j;
      float v = acc[i][j] + bias[col];
      v = epilogue_apply(MODE, v, (MODE == 2) ? Rr[col] : 0.f,
                         (MODE == 3) ? gvec[col] : 0.f,
                         (MODE == 3) ? bvec[col] : 0.f, scl);
      Cr[col] = v;
    }
  }
}

template <int MODE>
static void run_gemm(const float* A, const float* Bt, const float* bias,
                     const float* R, const float* g, const float* bb, float* C,
                     int M, int N, int K, float scl, hipStream_t stream) {
  if (M >= 8192) {
    dim3 gg(N / 64, M / 128);
    gemm128_kernel<MODE><<<gg, 256, 0, stream>>>(A, Bt, bias, R, g, bb, C, M, N, K, scl);
  } else {
    dim3 gg(N / BN, M / BM);
    gemm_kernel<MODE><<<gg, 256, 0, stream>>>(A, Bt, bias, R, g, bb, C, M, N, K, scl);
  }
}

// ---------------- bf16 MFMA GEMM 64x64, BK=32, 4 waves (32x32 each) -------
template <int MODE>
__global__ __launch_bounds__(256) void bgemm_kernel(
    const unsigned short* __restrict__ A, const unsigned short* __restrict__ Bt,
    const float* __restrict__ bias, const float* __restrict__ R,
    const float* __restrict__ gvec, const float* __restrict__ bvec,
    float* __restrict__ C, int M, int N, int K, float scl) {
  __shared__ unsigned short Al[64][40];
  __shared__ unsigned short Bl[64][40];
  const int bm = blockIdx.y * 64, bn = blockIdx.x * 64;
  const int tid = threadIdx.x;
  const int wave = tid >> 6, lane = tid & 63;
  const int wm = (wave >> 1) * 32, wn = (wave & 1) * 32;
  const int quad = lane >> 4, l16 = lane & 15;
  const int sr = tid >> 2;
  const int sc = (tid & 3) * 8;
  const unsigned short* Ag = A + (size_t)(bm + sr) * K + sc;
  const unsigned short* Bg = Bt + (size_t)(bn + sr) * K + sc;
  floatx4 zero = {0.f, 0.f, 0.f, 0.f};
  floatx4 acc00 = zero, acc01 = zero, acc10 = zero, acc11 = zero;
  for (int k0 = 0; k0 < K; k0 += 32) {
    short8 a8 = *(const short8*)(Ag + k0);
    short8 b8 = *(const short8*)(Bg + k0);
    *(short8*)&Al[sr][sc] = a8;
    *(short8*)&Bl[sr][sc] = b8;
    __syncthreads();
    short8 af0 = *(const short8*)&Al[wm + l16][quad * 8];
    short8 af1 = *(const short8*)&Al[wm + 16 + l16][quad * 8];
    short8 bf0 = *(const short8*)&Bl[wn + l16][quad * 8];
    short8 bf1 = *(const short8*)&Bl[wn + 16 + l16][quad * 8];
    acc00 = __builtin_amdgcn_mfma_f32_16x16x32_bf16(af0, bf0, acc00, 0, 0, 0);
    acc01 = __builtin_amdgcn_mfma_f32_16x16x32_bf16(af0, bf1, acc01, 0, 0, 0);
    acc10 = __builtin_amdgcn_mfma_f32_16x16x32_bf16(af1, bf0, acc10, 0, 0, 0);
    acc11 = __builtin_amdgcn_mfma_f32_16x16x32_bf16(af1, bf1, acc11, 0, 0, 0);
    __syncthreads();
  }
  floatx4 accs[2][2] = {{acc00, acc01}, {acc10, acc11}};
#pragma unroll
  for (int i = 0; i < 2; ++i) {
#pragma unroll
    for (int j = 0; j < 2; ++j) {
      int col = bn + wn + j * 16 + l16;
#pragma unroll
      for (int p = 0; p < 4; ++p) {
        int row = bm + wm + i * 16 + quad * 4 + p;
        float v = accs[i][j][p] + bias[col];
        v = epilogue_apply(MODE, v, (MODE == 2) ? R[(size_t)row * N + col] : 0.f,
                           (MODE == 3) ? gvec[col] : 0.f,
                           (MODE == 3) ? bvec[col] : 0.f, scl);
        C[(size_t)row * N + col] = v;
      }
    }
  }
}

template <int MODE>
static void run_bgemm(const unsigned short* A, const unsigned short* Bt,
                      const float* bias, const float* R, const float* g,
                      const float* bb, float* C, int M, int N, int K,
                      float scl, hipStream_t stream) {
  dim3 gg(N / 64, M / 64);
  bgemm_kernel<MODE><<<gg, 256, 0, stream>>>(A, Bt, bias, R, g, bb, C, M, N, K, scl);
}

// ---------------- sparse QK: one BLOCK per (b,l), all heads at once -------
__global__ __launch_bounds__(256) void sparse_qk_kernel(
    const float* __restrict__ Q, const float* __restrict__ Km,
    const int* __restrict__ idx, float* __restrict__ QKs, int B, int L,
    int U) {
  int bl = blockIdx.x;  // b*L + l
  int b = bl / L, l = bl - b * L;
  int tid = threadIdx.x;
  int wave = tid >> 6, lane = tid & 63;
  int h = lane >> 3;
  const float4* qr = (const float4*)(Q + (size_t)bl * D_MODEL + lane * 8);
  float4 q0 = qr[0], q1 = qr[1];
  const int* idxl = idx + l * U;
  for (int u = wave; u < U; u += 4) {
    int ki = idxl[u];
    const float4* kr =
        (const float4*)(Km + ((size_t)b * L + ki) * D_MODEL + lane * 8);
    float4 k0 = kr[0], k1 = kr[1];
    float p = q0.x * k0.x + q0.y * k0.y + q0.z * k0.z + q0.w * k0.w +
              q1.x * k1.x + q1.y * k1.y + q1.z * k1.z + q1.w * k1.w;
    p += __shfl_xor(p, 1);
    p += __shfl_xor(p, 2);
    p += __shfl_xor(p, 4);
    if ((lane & 7) == 0)
      QKs[(((size_t)(b * NH + h)) * L + l) * U + u] = p;
  }
}

// M[bh*L+l] = max_u(QKs) - sum_u(QKs)/L ; one wave per query, ONE butterfly
__global__ __launch_bounds__(256) void sparse_reduce_kernel(
    const float* __restrict__ QKs, float* __restrict__ Mout, int total,
    int L, int U) {
  int wid = (blockIdx.x * 256 + threadIdx.x) >> 6;
  int lane = threadIdx.x & 63;
  if (wid >= total) return;
  float v = (lane < U) ? QKs[(size_t)wid * U + lane] : -INFINITY;
  float m = v;
#pragma unroll
  for (int k = 32; k; k >>= 1) m = fmaxf(m, __shfl_xor(m, k));
  float sv = (lane < U) ? v : 0.f;
#pragma unroll
  for (int k = 32; k; k >>= 1) sv += __shfl_xor(sv, k);
  if (lane == 0) Mout[wid] = m - sv / (float)L;
}

// ---------------- top-k: register-resident iterative selection ------------
// R9's version: 40 iters x (LDS scan + 8-level LDS tree w/ syncthreads) at
// 1 block/CU -> ~3000 exposed-latency cycles/iter (74us). Now: M in
// registers (NE compile-time), wave butterfly on (v,i) pairs (in-register),
// one 4-way LDS merge, 2 barriers/iter. Tie-break (v desc, idx asc) = JAX.
template <int NE>
__global__ __launch_bounds__(256) void topk_kernel(
    const float* __restrict__ Mv, int* __restrict__ Mtop, int u) {
  int bh = blockIdx.x;
  int t = threadIdx.x;
  int wave = t >> 6, lane = t & 63;
  float vals[NE];
  const float* src = Mv + (size_t)bh * (NE * 256);
#pragma unroll
  for (int i = 0; i < NE; ++i) vals[i] = src[t + i * 256];
  __shared__ float wv[4];
  __shared__ int wi[4];
  __shared__ int gi;
  for (int it = 0; it < u; ++it) {
    float bv = -INFINITY;
    int bi = 0x7fffffff;
#pragma unroll
    for (int i = 0; i < NE; ++i) {
      float v = vals[i];
      int ix = t + i * 256;
      if (v > bv || (v == bv && ix < bi)) { bv = v; bi = ix; }
    }
#pragma unroll
    for (int k = 32; k; k >>= 1) {
      float ov = __shfl_xor(bv, k);
      int oi = __shfl_xor(bi, k);
      if (ov > bv || (ov == bv && oi < bi)) { bv = ov; bi = oi; }
    }
    if (lane == 0) { wv[wave] = bv; wi[wave] = bi; }
    __syncthreads();
    if (t == 0) {
      float fv = wv[0];
      int fi = wi[0];
#pragma unroll
      for (int w = 1; w < 4; ++w)
        if (wv[w] > fv || (wv[w] == fv && wi[w] < fi)) { fv = wv[w]; fi = wi[w]; }
      gi = fi;
      Mtop[bh * u + it] = fi;
    }
    __syncthreads();
    int fi = gi;
#pragma unroll
    for (int i = 0; i < NE; ++i)
      if (fi == t + i * 256) vals[i] = -INFINITY;
  }
}

static void run_topk(const float* Mv, int* Mtop, int L, int u,
                     hipStream_t stream) {
  if (L == 2048)      topk_kernel<8><<<32, 256, 0, stream>>>(Mv, Mtop, u);
  else if (L == 1024) topk_kernel<4><<<32, 256, 0, stream>>>(Mv, Mtop, u);
  else                topk_kernel<2><<<32, 256, 0, stream>>>(Mv, Mtop, u);
}

// ---------------- mean of V over L: split-L partial + atomic --------------
__global__ void vmean_zero_kernel(float* __restrict__ vmean) {
  vmean[blockIdx.x * 256 + threadIdx.x] = 0.f;
}

__global__ __launch_bounds__(256) void vmean_partial_kernel(
    const float* __restrict__ V, float* __restrict__ vmean, int L) {
  int b = blockIdx.y;
  int chunk = blockIdx.x;           // 64 chunks
  int rows = L >> 6;
  int t = threadIdx.x;
  const float* base = V + ((size_t)b * L + (size_t)chunk * rows) * D_MODEL;
  float s0 = 0.f, s1 = 0.f;
  for (int r = 0; r < rows; ++r) {
    s0 += base[(size_t)r * D_MODEL + t];
    s1 += base[(size_t)r * D_MODEL + t + 256];
  }
  float invL = 1.0f / (float)L;
  atomicAdd(&vmean[b * D_MODEL + t], s0 * invL);
  atomicAdd(&vmean[b * D_MODEL + t + 256], s1 * invL);
}

__global__ void fill_ctx_kernel(const float* __restrict__ vmean,
                                float* __restrict__ O, int B, int L) {
  int i = blockIdx.x * 256 + threadIdx.x;
  int total = B * L * D_MODEL;
  if (i >= total) return;
  int dcol = i % D_MODEL;
  int b = i / (D_MODEL * L);
  O[i] = vmean[b * D_MODEL + dcol];
}

// ============== attention as batched GEMM pipeline ==============
__global__ void pack_qred_kernel(const float* __restrict__ Q,
                                 const int* __restrict__ Mtop,
                                 float* __restrict__ qred, int L, int U) {
  int z = blockIdx.x;  // bh
  int b = z / NH, h = z % NH;
  int t = threadIdx.x;
  int d = t & 63;
  for (int r = t >> 6; r < 64; r += 4) {
    float v = 0.f;
    if (r < U) {
      int l = Mtop[z * U + r];
      v = Q[((size_t)(b * L + l)) * D_MODEL + h * DH + d];
    }
    qred[((size_t)z * 64 + r) * 64 + d] = v;
  }
}

// S[z][64][L] = 0.125 * Qred[z](64x64) @ K_z^T ; K_z rows stride 512
__global__ __launch_bounds__(256) void scores_gemm_kernel(
    const float* __restrict__ qred, const float* __restrict__ Km,
    float* __restrict__ S, int L) {
  __shared__ float As[BK][64 + PADR];
  __shared__ float Bs[BK][64 + PADR];
  const int z = blockIdx.y;
  const int b = z / NH, h = z % NH;
  const float* A = qred + (size_t)z * 64 * 64;
  const float* Bt = Km + (size_t)b * L * D_MODEL + h * DH;  // ldb = 512
  float* Sz = S + (size_t)z * 64 * L;
  const int bn = blockIdx.x * 64;
  const int tid = threadIdx.x;
  const int tx = tid & 15, ty = tid >> 4;
  const int lr = tid >> 2;
  const int lc = (tid & 3) << 2;
  float acc[4][4] = {};
  for (int k0 = 0; k0 < 64; k0 += BK) {
    float4 av = *(const float4*)(A + (size_t)lr * 64 + k0 + lc);
    float4 bv = *(const float4*)(Bt + (size_t)(bn + lr) * D_MODEL + k0 + lc);
    As[lc + 0][lr] = av.x; As[lc + 1][lr] = av.y;
    As[lc + 2][lr] = av.z; As[lc + 3][lr] = av.w;
    Bs[lc + 0][lr] = bv.x; Bs[lc + 1][lr] = bv.y;
    Bs[lc + 2][lr] = bv.z; Bs[lc + 3][lr] = bv.w;
    __syncthreads();
#pragma unroll
    for (int kk = 0; kk < BK; ++kk) {
      float4 a4 = *(const float4*)&As[kk][ty << 2];
      float4 b4 = *(const float4*)&Bs[kk][tx << 2];
      float ar[4] = {a4.x, a4.y, a4.z, a4.w};
      float br[4] = {b4.x, b4.y, b4.z, b4.w};
#pragma unroll
      for (int i = 0; i < 4; ++i)
#pragma unroll
        for (int j = 0; j < 4; ++j) acc[i][j] += ar[i] * br[j];
    }
    __syncthreads();
  }
#pragma unroll
  for (int i = 0; i < 4; ++i) {
    float* Sr = Sz + (size_t)((ty << 2) + i) * L + bn;
#pragma unroll
    for (int j = 0; j < 4; ++j) Sr[(tx << 2) + j] = 0.125f * acc[i][j];
  }
}

// ---------------- softmax: one block per (z,row) ----------------
template <int LC>
__global__ __launch_bounds__(256) void softmax_kernel(float* __restrict__ S,
                                                      int U) {
  constexpr int NE = LC / 256;
  int rid = blockIdx.x;
  int z = rid / U, r = rid % U;
  float* row = S + (size_t)z * 64 * LC + (size_t)r * LC;
  int t = threadIdx.x;
  float vals[NE];
  float m = -INFINITY;
#pragma unroll
  for (int i = 0; i < NE; ++i) {
    vals[i] = row[t + i * 256];
    m = fmaxf(m, vals[i]);
  }
  __shared__ float red[256];
  red[t] = m;
  __syncthreads();
  for (int s = 128; s > 0; s >>= 1) { if (t < s) red[t] = fmaxf(red[t], red[t + s]); __syncthreads(); }
  m = red[0];
  __syncthreads();
  float sum = 0.f;
#pragma unroll
  for (int i = 0; i < NE; ++i) {
    vals[i] = expf(vals[i] - m);
    sum += vals[i];
  }
  red[t] = sum;
  __syncthreads();
  for (int s = 128; s > 0; s >>= 1) { if (t < s) red[t] += red[t + s]; __syncthreads(); }
  float inv = 1.0f / red[0];
#pragma unroll
  for (int i = 0; i < NE; ++i) row[t + i * 256] = vals[i] * inv;
}

static void run_softmax(float* S, int L, int U, hipStream_t stream) {
  int blocks = 32 * U;
  if (L == 2048)      softmax_kernel<2048><<<blocks, 256, 0, stream>>>(S, U);
  else if (L == 1024) softmax_kernel<1024><<<blocks, 256, 0, stream>>>(S, U);
  else                softmax_kernel<512><<<blocks, 256, 0, stream>>>(S, U);
}

// zero the selected ctx rows before split-K PV atomics
__global__ void zero_sel_kernel(const int* __restrict__ Mtop,
                                float* __restrict__ O, int L, int U) {
  int z = blockIdx.x;
  int b = z / NH, h = z % NH;
  int t = threadIdx.x;
  int d = t & 63;
  for (int r = t >> 6; r < U; r += 4) {
    int l = Mtop[z * U + r];
    O[((size_t)(b * L + l)) * D_MODEL + h * DH + d] = 0.f;
  }
}

// O[sel rows] += P(UxL) @ V(Lx64), split-K over 128-chunks of L.
#define PV_LC 128

template <int U>
__global__ __launch_bounds__(256) void pv_kernel(
    const float* __restrict__ P, const float* __restrict__ V,
    const int* __restrict__ Mtop, float* __restrict__ O, int L) {
  __shared__ float Pl[U][PV_LC];
  __shared__ float Vl[PV_LC][DH + 4];
  const int z = blockIdx.y;
  const int b = z / NH, h = z % NH;
  const int c0 = blockIdx.x * PV_LC;
  const int tid = threadIdx.x;
  const float* Pz = P + (size_t)z * 64 * L + c0;
  for (int i4 = tid; i4 < U * (PV_LC / 4); i4 += 256) {
    int r = i4 / (PV_LC / 4);
    int lq = (i4 % (PV_LC / 4)) * 4;
    float4 p4 = *(const float4*)(Pz + (size_t)r * L + lq);
    Pl[r][lq + 0] = p4.x; Pl[r][lq + 1] = p4.y;
    Pl[r][lq + 2] = p4.z; Pl[r][lq + 3] = p4.w;
  }
  const float* Vb = V + ((size_t)b * L + c0) * D_MODEL + h * DH;
  for (int i4 = tid; i4 < PV_LC * (DH / 4); i4 += 256) {
    int l = i4 >> 4;
    int d4 = (i4 & 15) * 4;
    float4 v4 = *(const float4*)(Vb + (size_t)l * D_MODEL + d4);
    Vl[l][d4 + 0] = v4.x; Vl[l][d4 + 1] = v4.y;
    Vl[l][d4 + 2] = v4.z; Vl[l][d4 + 3] = v4.w;
  }
  __syncthreads();
  const int wave = tid >> 6, lane = tid & 63;
  constexpr int NJ = (U + 3) / 4;
  float acc[NJ] = {};
  for (int l = 0; l < PV_LC; ++l) {
    float vv = Vl[l][lane];
#pragma unroll
    for (int j = 0; j < NJ; ++j) {
      int r = wave + 4 * j;
      if (r < U) acc[j] += Pl[r][l] * vv;
    }
  }
#pragma unroll
  for (int j = 0; j < NJ; ++j) {
    int r = wave + 4 * j;
    if (r < U) {
      int ml = Mtop[z * U + r];
      atomicAdd(&O[((size_t)(b * L + ml)) * D_MODEL + h * DH + lane], acc[j]);
    }
  }
}

static void run_pv(const float* P, const float* V, const int* Mtop, float* O,
                   int L, int U, hipStream_t stream) {
  dim3 gg(L / PV_LC, 32);
  if (U == 40)      pv_kernel<40><<<gg, 256, 0, stream>>>(P, V, Mtop, O, L);
  else if (U == 35) pv_kernel<35><<<gg, 256, 0, stream>>>(P, V, Mtop, O, L);
  else              pv_kernel<64><<<gg, 256, 0, stream>>>(P, V, Mtop, O, L);
}

// ---------------- im2col (circular, K=3) -> bf16 --------------------------
__global__ void im2col_kernel(const float* __restrict__ X,
                              unsigned short* __restrict__ Y, int B, int L) {
  int i = blockIdx.x * 256 + threadIdx.x;
  int total = B * L * 1536;
  if (i >= total) return;
  int ck = i % 1536;
  int l = (i / 1536) % L;
  int b = i / (1536 * L);
  int c = ck / 3, k = ck % 3;
  int lm = l + k - 1;
  if (lm < 0) lm += L;
  else if (lm >= L) lm -= L;
  Y[i] = f2bf(X[((size_t)(b * L + lm)) * D_MODEL + c]);
}

// ---------------- maxpool k=3 s=2, one -inf pad each side -----------------
__global__ void maxpool_kernel(const float* __restrict__ Y,
                               float* __restrict__ X, int B, int L) {
  int Lo = L / 2;
  int i = blockIdx.x * 256 + threadIdx.x;
  int total = B * Lo * D_MODEL;
  if (i >= total) return;
  int d = i % D_MODEL;
  int lp = (i / D_MODEL) % Lo;
  int b = i / (D_MODEL * Lo);
  int l0 = 2 * lp - 1;
  float m = -INFINITY;
#pragma unroll
  for (int k = 0; k < 3; ++k) {
    int l = l0 + k;
    if (l >= 0 && l < L) m = fmaxf(m, Y[((size_t)(b * L + l)) * D_MODEL + d]);
  }
  X[i] = m;
}

// ==========================================================================
extern "C" void kernel_launch(void* const* d_in, const int* in_sizes, int n_in,
                              void* d_out, int out_size, void* d_ws,
                              size_t ws_size, hipStream_t stream) {
  const float* x_enc  = (const float*)d_in[0];
  const float* emb_w  = (const float*)d_in[1];
  const float* Wq     = (const float*)d_in[2];
  const float* bq     = (const float*)d_in[3];
  const float* Wk     = (const float*)d_in[4];
  const float* bk     = (const float*)d_in[5];
  const float* Wv     = (const float*)d_in[6];
  const float* bv     = (const float*)d_in[7];
  const float* Wo     = (const float*)d_in[8];
  const float* bo     = (const float*)d_in[9];
  const float* ln1_g  = (const float*)d_in[10];
  const float* ln1_b  = (const float*)d_in[11];
  const float* ff_w1  = (const float*)d_in[12];
  const float* ff_b1  = (const float*)d_in[13];
  const float* ff_w2  = (const float*)d_in[14];
  const float* ff_b2  = (const float*)d_in[15];
  const float* ln2_g  = (const float*)d_in[16];
  const float* ln2_b  = (const float*)d_in[17];
  const float* cv_w   = (const float*)d_in[18];
  const float* cv_b   = (const float*)d_in[19];
  const float* bn_g   = (const float*)d_in[20];
  const float* bn_b   = (const float*)d_in[21];
  const float* norm_g = (const float*)d_in[22];
  const float* norm_b = (const float*)d_in[23];

  const int B = 4, L0 = 2048, EL = 3;
  const size_t SZ = (size_t)B * 2048 * 512;
  float* ws   = (float*)d_ws;
  float* xbuf = ws;
  float* ebuf = ws + SZ;   // pre-LN temp; QKs; Sbuf; ab16(V)
  float* qbuf = ws + 2 * SZ;
  float* kbuf = ws + 3 * SZ;
  float* vbuf = ws + 4 * SZ;
  float* obuf = ws + 5 * SZ;
  float* sm   = ws + 6 * SZ;
  int*   d_idx   = (int*)sm;
  float* d_M     = sm + 81920;
  int*   d_Mtop  = (int*)(sm + 81920 + 65536);
  float* d_vmean = sm + 81920 + 65536 + 1280;
  float* qred    = sm;    // reuses idx+M region (dead post-topk)
  float* QKs     = ebuf;
  float* Sbuf    = ebuf;

  const float inv_s = 1.0f / sqrtf(1.0f + 1e-5f);
  auto cast = [&](const float* s, unsigned short* d, int n) {
    cast_bf16_kernel<<<ceil_div(n / 4, 256), 256, 0, stream>>>(s, d, n);
  };

  embed_kernel<<<ceil_div(B * L0 * D_MODEL, 256), 256, 0, stream>>>(
      x_enc, emb_w, xbuf, B, L0);

  int L = L0;
  for (int i = 0; i < EL; ++i) {
    const int M_ = B * L;
    int c = 5 * (int)ceil(log((double)L));
    int U = c < L ? c : L;
    const float* Wq_i = Wq + (size_t)i * 512 * 512;
    const float* Wk_i = Wk + (size_t)i * 512 * 512;
    const float* Wv_i = Wv + (size_t)i * 512 * 512;
    const float* Wo_i = Wo + (size_t)i * 512 * 512;
    const float* w1_i = ff_w1 + (size_t)i * 512 * 512;
    const float* w2_i = ff_w2 + (size_t)i * 512 * 512;

    // Q, K stay fp32 (feed the discontinuous top-k path exactly)
    run_gemm<0>(xbuf, Wq_i, bq + i * 512, nullptr, nullptr, nullptr, qbuf,
                M_, 512, 512, 0.f, stream);
    run_gemm<0>(xbuf, Wk_i, bk + i * 512, nullptr, nullptr, nullptr, kbuf,
                M_, 512, 512, 0.f, stream);

    // V in bf16 MFMA: ab16 @ ebuf (free), wb16 @ obuf (free), C=vbuf
    {
      unsigned short* ab16 = (unsigned short*)ebuf;
      unsigned short* wb16 = (unsigned short*)obuf;
      cast(xbuf, ab16, M_ * 512);
      cast(Wv_i, wb16, 512 * 512);
      run_bgemm<0>(ab16, wb16, bv + i * 512, nullptr, nullptr, nullptr, vbuf,
                   M_, 512, 512, 0.f, stream);
    }

    uint32_t lk0, lk1, k20, k21;
    threefry2x32(0u, 42u, 0u, (uint32_t)i, &lk0, &lk1);
    threefry2x32(lk0, lk1, 0u, 1u, &k20, &k21);
    idx_kernel<<<ceil_div(L * U, 256), 256, 0, stream>>>(d_idx, L, U, k20, k21);

    sparse_qk_kernel<<<B * L, 256, 0, stream>>>(qbuf, kbuf, d_idx, QKs, B, L, U);
    sparse_reduce_kernel<<<ceil_div(B * NH * L * 64, 256), 256, 0, stream>>>(
        QKs, d_M, B * NH * L, L, U);
    run_topk(d_M, d_Mtop, L, U, stream);
    vmean_zero_kernel<<<8, 256, 0, stream>>>(d_vmean);
    vmean_partial_kernel<<<dim3(64, B), 256, 0, stream>>>(vbuf, d_vmean, L);
    fill_ctx_kernel<<<ceil_div(B * L * D_MODEL, 256), 256, 0, stream>>>(
        d_vmean, obuf, B, L);

    pack_qred_kernel<<<B * NH, 256, 0, stream>>>(qbuf, d_Mtop, qred, L, U);
    scores_gemm_kernel<<<dim3(L / 64, B * NH), 256, 0, stream>>>(qred, kbuf,
                                                                 Sbuf, L);
    run_softmax(Sbuf, L, U, stream);
    zero_sel_kernel<<<B * NH, 256, 0, stream>>>(d_Mtop, obuf, L, U);
    run_pv(Sbuf, vbuf, d_Mtop, obuf, L, U, stream);

    // O-proj bf16: ab16 @ qbuf (Q dead), wb16 @ kbuf (K dead), C=ebuf
    unsigned short* ab16 = (unsigned short*)qbuf;
    unsigned short* wb16 = (unsigned short*)kbuf;
    cast(obuf, ab16, M_ * 512);
    cast(Wo_i, wb16, 512 * 512);
    run_bgemm<2>(ab16, wb16, bo + i * 512, xbuf, nullptr, nullptr, ebuf,
                 M_, 512, 512, 0.f, stream);
    ln_kernel<<<M_, 256, 0, stream>>>(ebuf, ln1_g + i * 512, ln1_b + i * 512, xbuf);

    // FF1 bf16 (gelu fused), C=obuf
    cast(xbuf, ab16, M_ * 512);
    cast(w1_i, wb16, 512 * 512);
    run_bgemm<1>(ab16, wb16, ff_b1 + i * 512, nullptr, nullptr, nullptr, obuf,
                 M_, 512, 512, 0.f, stream);
    // FF2 bf16 (+residual), C=ebuf
    cast(obuf, ab16, M_ * 512);
    cast(w2_i, wb16, 512 * 512);
    run_bgemm<2>(ab16, wb16, ff_b2 + i * 512, xbuf, nullptr, nullptr, ebuf,
                 M_, 512, 512, 0.f, stream);
    ln_kernel<<<M_, 256, 0, stream>>>(ebuf, ln2_g + i * 512, ln2_b + i * 512, xbuf);

    if (i < EL - 1) {
      // conv distill bf16: im2col -> imb16 @ qbuf(+kbuf), weights @ vbuf
      unsigned short* imb16 = (unsigned short*)qbuf;
      unsigned short* wb16c = (unsigned short*)vbuf;
      im2col_kernel<<<ceil_div(B * L * 1536, 256), 256, 0, stream>>>(xbuf, imb16, B, L);
      cast(cv_w + (size_t)i * 512 * 1536, wb16c, 512 * 1536);
      run_bgemm<3>(imb16, wb16c, cv_b + i * 512, nullptr, bn_g + i * 512,
                   bn_b + i * 512, ebuf, M_, 512, 1536, inv_s, stream);
      maxpool_kernel<<<ceil_div(B * (L / 2) * D_MODEL, 256), 256, 0, stream>>>(
          ebuf, xbuf, B, L);
      L /= 2;
    }
  }

  ln_kernel<<<B * L, 256, 0, stream>>>(xbuf, norm_g, norm_b, (float*)d_out);
}

// Round 11
// 1070.732 us; speedup vs baseline: 3.0278x; 1.1382x over previous
//
#include <hip/hip_runtime.h>
#include <cmath>
#include <cstdint>

#define D_MODEL 512
#define NH 8
#define DH 64

static inline int ceil_div(int a, int b) { return (a + b - 1) / b; }

typedef __attribute__((ext_vector_type(8))) short short8;
typedef __attribute__((ext_vector_type(4))) float floatx4;

// fp32 -> bf16 (RNE)
__device__ __forceinline__ unsigned short f2bf(float f) {
  uint32_t u = __float_as_uint(f);
  uint32_t r = (u + 0x7fffu + ((u >> 16) & 1u)) >> 16;
  return (unsigned short)r;
}

// ---------------- threefry2x32 (JAX-exact) ----------------
#define TF_ROTL(x, r) (((x) << (r)) | ((x) >> (32 - (r))))

__host__ __device__ inline void threefry2x32(uint32_t k0, uint32_t k1,
                                             uint32_t x0, uint32_t x1,
                                             uint32_t* o0, uint32_t* o1) {
  uint32_t ks2 = k0 ^ k1 ^ 0x1BD11BDAu;
  x0 += k0; x1 += k1;
#define TF_R4(a, b, c, d)                                    \
  x0 += x1; x1 = TF_ROTL(x1, a); x1 ^= x0;                   \
  x0 += x1; x1 = TF_ROTL(x1, b); x1 ^= x0;                   \
  x0 += x1; x1 = TF_ROTL(x1, c); x1 ^= x0;                   \
  x0 += x1; x1 = TF_ROTL(x1, d); x1 ^= x0;
  TF_R4(13, 15, 26, 6);  x0 += k1;  x1 += ks2 + 1u;
  TF_R4(17, 29, 16, 24); x0 += ks2; x1 += k0 + 2u;
  TF_R4(13, 15, 26, 6);  x0 += k0;  x1 += k1 + 3u;
  TF_R4(17, 29, 16, 24); x0 += k1;  x1 += ks2 + 4u;
  TF_R4(13, 15, 26, 6);  x0 += ks2; x1 += k0 + 5u;
#undef TF_R4
  *o0 = x0; *o1 = x1;
}

__global__ void idx_kernel(int* __restrict__ idx, int L, int U,
                           uint32_t k0, uint32_t k1) {
  int n = blockIdx.x * 256 + threadIdx.x;
  if (n >= L * U) return;
  uint32_t o0, o1;
  threefry2x32(k0, k1, 0u, (uint32_t)n, &o0, &o1);
  idx[n] = (int)((o0 ^ o1) & (uint32_t)(L - 1));
}

// ---------------- fp32 -> bf16 cast, 4 elems/thread ----------------
__global__ __launch_bounds__(256) void cast_bf16_kernel(
    const float* __restrict__ src, unsigned short* __restrict__ dst, int n) {
  int i = (blockIdx.x * 256 + threadIdx.x) * 4;
  if (i >= n) return;
  float4 v = *(const float4*)(src + i);
  ushort4 o;
  o.x = f2bf(v.x); o.y = f2bf(v.y); o.z = f2bf(v.z); o.w = f2bf(v.w);
  *(ushort4*)(dst + i) = o;
}

// ---------------- embedding: circular conv (C=2,K=3) + pos encoding -------
__global__ __launch_bounds__(256) void embed_kernel(
    const float* __restrict__ x_enc, const float* __restrict__ emb_w,
    float* __restrict__ x, int B, int L) {
  int i = blockIdx.x * 256 + threadIdx.x;
  int total = B * L * D_MODEL;
  if (i >= total) return;
  int d = i % D_MODEL;
  int l = (i / D_MODEL) % L;
  int b = i / (D_MODEL * L);
  int lm = (l == 0) ? (L - 1) : (l - 1);
  int lp = (l == L - 1) ? 0 : (l + 1);
  const float* w = emb_w + d * 6;
  const float* xb = x_enc + (size_t)b * L * 2;
  float acc = 0.f;
  acc += xb[lm * 2 + 0] * w[0] + xb[l * 2 + 0] * w[1] + xb[lp * 2 + 0] * w[2];
  acc += xb[lm * 2 + 1] * w[3] + xb[l * 2 + 1] * w[4] + xb[lp * 2 + 1] * w[5];
  int j = d >> 1;
  const float coef = -0.017988946039015985f;  // -ln(10000)/512
  float div = expf((float)(2 * j) * coef);
  float ang = (float)l * div;
  float pe = (d & 1) ? cosf(ang) : sinf(ang);
  x[i] = acc + pe;
}

// ---------------- layer norm over D=512 ----------------
__global__ __launch_bounds__(256) void ln_kernel(
    const float* __restrict__ in, const float* __restrict__ g,
    const float* __restrict__ b, float* __restrict__ out) {
  int row = blockIdx.x;
  int t = threadIdx.x;
  const float* xr = in + (size_t)row * D_MODEL;
  float v0 = xr[t], v1 = xr[t + 256];
  __shared__ float red[256];
  red[t] = v0 + v1;
  __syncthreads();
  for (int s = 128; s > 0; s >>= 1) { if (t < s) red[t] += red[t + s]; __syncthreads(); }
  float mean = red[0] * (1.0f / 512.0f);
  __syncthreads();
  float d0 = v0 - mean, d1 = v1 - mean;
  red[t] = d0 * d0 + d1 * d1;
  __syncthreads();
  for (int s = 128; s > 0; s >>= 1) { if (t < s) red[t] += red[t + s]; __syncthreads(); }
  float var = red[0] * (1.0f / 512.0f);
  float rstd = 1.0f / sqrtf(var + 1e-5f);
  float* outr = out + (size_t)row * D_MODEL;
  outr[t]       = d0 * rstd * g[t]       + b[t];
  outr[t + 256] = d1 * rstd * g[t + 256] + b[t + 256];
}

// MODE 0: +bias   1: gelu(+bias)   2: +bias +R   3: elu((+bias)*scl*g + bb)
__device__ __forceinline__ float epilogue_apply(int MODE, float v, float r,
                                                float g, float bb, float scl) {
  if (MODE == 1) {
    v = 0.5f * v * (1.0f + erff(v * 0.7071067811865475f));
  } else if (MODE == 2) {
    v += r;
  } else if (MODE == 3) {
    v = v * scl * g + bb;
    v = (v > 0.f) ? v : expm1f(v);
  }
  return v;
}

// ---------------- fp32 tiled GEMM 64x64, 4x4/thread (unused fallback) -----
#define BM 64
#define BN 64
#define BK 16
#define PADR 4

template <int MODE>
__global__ __launch_bounds__(256) void gemm_kernel(
    const float* __restrict__ A, const float* __restrict__ Bt,
    const float* __restrict__ bias, const float* __restrict__ R,
    const float* __restrict__ gvec, const float* __restrict__ bvec,
    float* __restrict__ C, int M, int N, int K, float scl) {
  __shared__ float As[BK][BM + PADR];
  __shared__ float Bs[BK][BN + PADR];
  const int bm = blockIdx.y * BM;
  const int bn = blockIdx.x * BN;
  const int tid = threadIdx.x;
  const int tx = tid & 15, ty = tid >> 4;
  const int lr = tid >> 2;
  const int lc = (tid & 3) << 2;
  const float* Aptr = A + (size_t)(bm + lr) * K + lc;
  const float* Bptr = Bt + (size_t)(bn + lr) * K + lc;
  float acc[4][4] = {};
  for (int k0 = 0; k0 < K; k0 += BK) {
    float4 av = *(const float4*)(Aptr + k0);
    float4 bv = *(const float4*)(Bptr + k0);
    As[lc + 0][lr] = av.x; As[lc + 1][lr] = av.y;
    As[lc + 2][lr] = av.z; As[lc + 3][lr] = av.w;
    Bs[lc + 0][lr] = bv.x; Bs[lc + 1][lr] = bv.y;
    Bs[lc + 2][lr] = bv.z; Bs[lc + 3][lr] = bv.w;
    __syncthreads();
#pragma unroll
    for (int kk = 0; kk < BK; ++kk) {
      float4 a4 = *(const float4*)&As[kk][ty << 2];
      float4 b4 = *(const float4*)&Bs[kk][tx << 2];
      float ar[4] = {a4.x, a4.y, a4.z, a4.w};
      float br[4] = {b4.x, b4.y, b4.z, b4.w};
#pragma unroll
      for (int i = 0; i < 4; ++i)
#pragma unroll
        for (int j = 0; j < 4; ++j) acc[i][j] += ar[i] * br[j];
    }
    __syncthreads();
  }
#pragma unroll
  for (int i = 0; i < 4; ++i) {
    int row = bm + (ty << 2) + i;
    float* Cr = C + (size_t)row * N;
    const float* Rr = (MODE == 2) ? (R + (size_t)row * N) : nullptr;
#pragma unroll
    for (int j = 0; j < 4; ++j) {
      int col = bn + (tx << 2) + j;
      float v = acc[i][j] + bias[col];
      v = epilogue_apply(MODE, v, (MODE == 2) ? Rr[col] : 0.f,
                         (MODE == 3) ? gvec[col] : 0.f,
                         (MODE == 3) ? bvec[col] : 0.f, scl);
      Cr[col] = v;
    }
  }
}

// ---------------- bf16 MFMA GEMM 64x64, BK=32, 4 waves (32x32 each) -------
template <int MODE>
__global__ __launch_bounds__(256) void bgemm_kernel(
    const unsigned short* __restrict__ A, const unsigned short* __restrict__ Bt,
    const float* __restrict__ bias, const float* __restrict__ R,
    const float* __restrict__ gvec, const float* __restrict__ bvec,
    float* __restrict__ C, int M, int N, int K, float scl) {
  __shared__ unsigned short Al[64][40];
  __shared__ unsigned short Bl[64][40];
  const int bm = blockIdx.y * 64, bn = blockIdx.x * 64;
  const int tid = threadIdx.x;
  const int wave = tid >> 6, lane = tid & 63;
  const int wm = (wave >> 1) * 32, wn = (wave & 1) * 32;
  const int quad = lane >> 4, l16 = lane & 15;
  const int sr = tid >> 2;
  const int sc = (tid & 3) * 8;
  const unsigned short* Ag = A + (size_t)(bm + sr) * K + sc;
  const unsigned short* Bg = Bt + (size_t)(bn + sr) * K + sc;
  floatx4 zero = {0.f, 0.f, 0.f, 0.f};
  floatx4 acc00 = zero, acc01 = zero, acc10 = zero, acc11 = zero;
  for (int k0 = 0; k0 < K; k0 += 32) {
    short8 a8 = *(const short8*)(Ag + k0);
    short8 b8 = *(const short8*)(Bg + k0);
    *(short8*)&Al[sr][sc] = a8;
    *(short8*)&Bl[sr][sc] = b8;
    __syncthreads();
    short8 af0 = *(const short8*)&Al[wm + l16][quad * 8];
    short8 af1 = *(const short8*)&Al[wm + 16 + l16][quad * 8];
    short8 bf0 = *(const short8*)&Bl[wn + l16][quad * 8];
    short8 bf1 = *(const short8*)&Bl[wn + 16 + l16][quad * 8];
    acc00 = __builtin_amdgcn_mfma_f32_16x16x32_bf16(af0, bf0, acc00, 0, 0, 0);
    acc01 = __builtin_amdgcn_mfma_f32_16x16x32_bf16(af0, bf1, acc01, 0, 0, 0);
    acc10 = __builtin_amdgcn_mfma_f32_16x16x32_bf16(af1, bf0, acc10, 0, 0, 0);
    acc11 = __builtin_amdgcn_mfma_f32_16x16x32_bf16(af1, bf1, acc11, 0, 0, 0);
    __syncthreads();
  }
  floatx4 accs[2][2] = {{acc00, acc01}, {acc10, acc11}};
#pragma unroll
  for (int i = 0; i < 2; ++i) {
#pragma unroll
    for (int j = 0; j < 2; ++j) {
      int col = bn + wn + j * 16 + l16;
#pragma unroll
      for (int p = 0; p < 4; ++p) {
        int row = bm + wm + i * 16 + quad * 4 + p;
        float v = accs[i][j][p] + bias[col];
        v = epilogue_apply(MODE, v, (MODE == 2) ? R[(size_t)row * N + col] : 0.f,
                           (MODE == 3) ? gvec[col] : 0.f,
                           (MODE == 3) ? bvec[col] : 0.f, scl);
        C[(size_t)row * N + col] = v;
      }
    }
  }
}

template <int MODE>
static void run_bgemm(const unsigned short* A, const unsigned short* Bt,
                      const float* bias, const float* R, const float* g,
                      const float* bb, float* C, int M, int N, int K,
                      float scl, hipStream_t stream) {
  dim3 gg(N / 64, M / 64);
  bgemm_kernel<MODE><<<gg, 256, 0, stream>>>(A, Bt, bias, R, g, bb, C, M, N, K, scl);
}

// ---------------- sparse QK: one BLOCK per (b,l), all heads at once -------
__global__ __launch_bounds__(256) void sparse_qk_kernel(
    const float* __restrict__ Q, const float* __restrict__ Km,
    const int* __restrict__ idx, float* __restrict__ QKs, int B, int L,
    int U) {
  int bl = blockIdx.x;  // b*L + l
  int b = bl / L, l = bl - b * L;
  int tid = threadIdx.x;
  int wave = tid >> 6, lane = tid & 63;
  int h = lane >> 3;
  const float4* qr = (const float4*)(Q + (size_t)bl * D_MODEL + lane * 8);
  float4 q0 = qr[0], q1 = qr[1];
  const int* idxl = idx + l * U;
  for (int u = wave; u < U; u += 4) {
    int ki = idxl[u];
    const float4* kr =
        (const float4*)(Km + ((size_t)b * L + ki) * D_MODEL + lane * 8);
    float4 k0 = kr[0], k1 = kr[1];
    float p = q0.x * k0.x + q0.y * k0.y + q0.z * k0.z + q0.w * k0.w +
              q1.x * k1.x + q1.y * k1.y + q1.z * k1.z + q1.w * k1.w;
    p += __shfl_xor(p, 1);
    p += __shfl_xor(p, 2);
    p += __shfl_xor(p, 4);
    if ((lane & 7) == 0)
      QKs[(((size_t)(b * NH + h)) * L + l) * U + u] = p;
  }
}

// M[bh*L+l] = max_u(QKs) - sum_u(QKs)/L ; one wave per query, ONE butterfly
__global__ __launch_bounds__(256) void sparse_reduce_kernel(
    const float* __restrict__ QKs, float* __restrict__ Mout, int total,
    int L, int U) {
  int wid = (blockIdx.x * 256 + threadIdx.x) >> 6;
  int lane = threadIdx.x & 63;
  if (wid >= total) return;
  float v = (lane < U) ? QKs[(size_t)wid * U + lane] : -INFINITY;
  float m = v;
#pragma unroll
  for (int k = 32; k; k >>= 1) m = fmaxf(m, __shfl_xor(m, k));
  float sv = (lane < U) ? v : 0.f;
#pragma unroll
  for (int k = 32; k; k >>= 1) sv += __shfl_xor(sv, k);
  if (lane == 0) Mout[wid] = m - sv / (float)L;
}

// ---------------- top-k: register-resident iterative selection ------------
template <int NE>
__global__ __launch_bounds__(256) void topk_kernel(
    const float* __restrict__ Mv, int* __restrict__ Mtop, int u) {
  int bh = blockIdx.x;
  int t = threadIdx.x;
  int wave = t >> 6, lane = t & 63;
  float vals[NE];
  const float* src = Mv + (size_t)bh * (NE * 256);
#pragma unroll
  for (int i = 0; i < NE; ++i) vals[i] = src[t + i * 256];
  __shared__ float wv[4];
  __shared__ int wi[4];
  __shared__ int gi;
  for (int it = 0; it < u; ++it) {
    float bv = -INFINITY;
    int bi = 0x7fffffff;
#pragma unroll
    for (int i = 0; i < NE; ++i) {
      float v = vals[i];
      int ix = t + i * 256;
      if (v > bv || (v == bv && ix < bi)) { bv = v; bi = ix; }
    }
#pragma unroll
    for (int k = 32; k; k >>= 1) {
      float ov = __shfl_xor(bv, k);
      int oi = __shfl_xor(bi, k);
      if (ov > bv || (ov == bv && oi < bi)) { bv = ov; bi = oi; }
    }
    if (lane == 0) { wv[wave] = bv; wi[wave] = bi; }
    __syncthreads();
    if (t == 0) {
      float fv = wv[0];
      int fi = wi[0];
#pragma unroll
      for (int w = 1; w < 4; ++w)
        if (wv[w] > fv || (wv[w] == fv && wi[w] < fi)) { fv = wv[w]; fi = wi[w]; }
      gi = fi;
      Mtop[bh * u + it] = fi;
    }
    __syncthreads();
    int fi = gi;
#pragma unroll
    for (int i = 0; i < NE; ++i)
      if (fi == t + i * 256) vals[i] = -INFINITY;
  }
}

static void run_topk(const float* Mv, int* Mtop, int L, int u,
                     hipStream_t stream) {
  if (L == 2048)      topk_kernel<8><<<32, 256, 0, stream>>>(Mv, Mtop, u);
  else if (L == 1024) topk_kernel<4><<<32, 256, 0, stream>>>(Mv, Mtop, u);
  else                topk_kernel<2><<<32, 256, 0, stream>>>(Mv, Mtop, u);
}

// ---------------- mean of V over L: split-L partial + atomic --------------
__global__ void vmean_zero_kernel(float* __restrict__ vmean) {
  vmean[blockIdx.x * 256 + threadIdx.x] = 0.f;
}

__global__ __launch_bounds__(256) void vmean_partial_kernel(
    const float* __restrict__ V, float* __restrict__ vmean, int L) {
  int b = blockIdx.y;
  int chunk = blockIdx.x;           // 64 chunks
  int rows = L >> 6;
  int t = threadIdx.x;
  const float* base = V + ((size_t)b * L + (size_t)chunk * rows) * D_MODEL;
  float s0 = 0.f, s1 = 0.f;
  for (int r = 0; r < rows; ++r) {
    s0 += base[(size_t)r * D_MODEL + t];
    s1 += base[(size_t)r * D_MODEL + t + 256];
  }
  float invL = 1.0f / (float)L;
  atomicAdd(&vmean[b * D_MODEL + t], s0 * invL);
  atomicAdd(&vmean[b * D_MODEL + t + 256], s1 * invL);
}

__global__ void fill_ctx_kernel(const float* __restrict__ vmean,
                                float* __restrict__ O, int B, int L) {
  int i = blockIdx.x * 256 + threadIdx.x;
  int total = B * L * D_MODEL;
  if (i >= total) return;
  int dcol = i % D_MODEL;
  int b = i / (D_MODEL * L);
  O[i] = vmean[b * D_MODEL + dcol];
}

// ============== attention as batched GEMM pipeline ==============
__global__ void pack_qred_kernel(const float* __restrict__ Q,
                                 const int* __restrict__ Mtop,
                                 float* __restrict__ qred, int L, int U) {
  int z = blockIdx.x;  // bh
  int b = z / NH, h = z % NH;
  int t = threadIdx.x;
  int d = t & 63;
  for (int r = t >> 6; r < 64; r += 4) {
    float v = 0.f;
    if (r < U) {
      int l = Mtop[z * U + r];
      v = Q[((size_t)(b * L + l)) * D_MODEL + h * DH + d];
    }
    qred[((size_t)z * 64 + r) * 64 + d] = v;
  }
}

// S[z][64][L] = 0.125 * Qred[z](64x64) @ K_z^T ; K_z rows stride 512
__global__ __launch_bounds__(256) void scores_gemm_kernel(
    const float* __restrict__ qred, const float* __restrict__ Km,
    float* __restrict__ S, int L) {
  __shared__ float As[BK][64 + PADR];
  __shared__ float Bs[BK][64 + PADR];
  const int z = blockIdx.y;
  const int b = z / NH, h = z % NH;
  const float* A = qred + (size_t)z * 64 * 64;
  const float* Bt = Km + (size_t)b * L * D_MODEL + h * DH;  // ldb = 512
  float* Sz = S + (size_t)z * 64 * L;
  const int bn = blockIdx.x * 64;
  const int tid = threadIdx.x;
  const int tx = tid & 15, ty = tid >> 4;
  const int lr = tid >> 2;
  const int lc = (tid & 3) << 2;
  float acc[4][4] = {};
  for (int k0 = 0; k0 < 64; k0 += BK) {
    float4 av = *(const float4*)(A + (size_t)lr * 64 + k0 + lc);
    float4 bv = *(const float4*)(Bt + (size_t)(bn + lr) * D_MODEL + k0 + lc);
    As[lc + 0][lr] = av.x; As[lc + 1][lr] = av.y;
    As[lc + 2][lr] = av.z; As[lc + 3][lr] = av.w;
    Bs[lc + 0][lr] = bv.x; Bs[lc + 1][lr] = bv.y;
    Bs[lc + 2][lr] = bv.z; Bs[lc + 3][lr] = bv.w;
    __syncthreads();
#pragma unroll
    for (int kk = 0; kk < BK; ++kk) {
      float4 a4 = *(const float4*)&As[kk][ty << 2];
      float4 b4 = *(const float4*)&Bs[kk][tx << 2];
      float ar[4] = {a4.x, a4.y, a4.z, a4.w};
      float br[4] = {b4.x, b4.y, b4.z, b4.w};
#pragma unroll
      for (int i = 0; i < 4; ++i)
#pragma unroll
        for (int j = 0; j < 4; ++j) acc[i][j] += ar[i] * br[j];
    }
    __syncthreads();
  }
#pragma unroll
  for (int i = 0; i < 4; ++i) {
    float* Sr = Sz + (size_t)((ty << 2) + i) * L + bn;
#pragma unroll
    for (int j = 0; j < 4; ++j) Sr[(tx << 2) + j] = 0.125f * acc[i][j];
  }
}

// ---------------- softmax: one block per (z,row) ----------------
template <int LC>
__global__ __launch_bounds__(256) void softmax_kernel(float* __restrict__ S,
                                                      int U) {
  constexpr int NE = LC / 256;
  int rid = blockIdx.x;
  int z = rid / U, r = rid % U;
  float* row = S + (size_t)z * 64 * LC + (size_t)r * LC;
  int t = threadIdx.x;
  float vals[NE];
  float m = -INFINITY;
#pragma unroll
  for (int i = 0; i < NE; ++i) {
    vals[i] = row[t + i * 256];
    m = fmaxf(m, vals[i]);
  }
  __shared__ float red[256];
  red[t] = m;
  __syncthreads();
  for (int s = 128; s > 0; s >>= 1) { if (t < s) red[t] = fmaxf(red[t], red[t + s]); __syncthreads(); }
  m = red[0];
  __syncthreads();
  float sum = 0.f;
#pragma unroll
  for (int i = 0; i < NE; ++i) {
    vals[i] = expf(vals[i] - m);
    sum += vals[i];
  }
  red[t] = sum;
  __syncthreads();
  for (int s = 128; s > 0; s >>= 1) { if (t < s) red[t] += red[t + s]; __syncthreads(); }
  float inv = 1.0f / red[0];
#pragma unroll
  for (int i = 0; i < NE; ++i) row[t + i * 256] = vals[i] * inv;
}

static void run_softmax(float* S, int L, int U, hipStream_t stream) {
  int blocks = 32 * U;
  if (L == 2048)      softmax_kernel<2048><<<blocks, 256, 0, stream>>>(S, U);
  else if (L == 1024) softmax_kernel<1024><<<blocks, 256, 0, stream>>>(S, U);
  else                softmax_kernel<512><<<blocks, 256, 0, stream>>>(S, U);
}

// zero the selected ctx rows before split-K PV atomics
__global__ void zero_sel_kernel(const int* __restrict__ Mtop,
                                float* __restrict__ O, int L, int U) {
  int z = blockIdx.x;
  int b = z / NH, h = z % NH;
  int t = threadIdx.x;
  int d = t & 63;
  for (int r = t >> 6; r < U; r += 4) {
    int l = Mtop[z * U + r];
    O[((size_t)(b * L + l)) * D_MODEL + h * DH + d] = 0.f;
  }
}

// O[sel rows] += P(UxL) @ V(Lx64), split-K over 128-chunks of L.
#define PV_LC 128

template <int U>
__global__ __launch_bounds__(256) void pv_kernel(
    const float* __restrict__ P, const float* __restrict__ V,
    const int* __restrict__ Mtop, float* __restrict__ O, int L) {
  __shared__ float Pl[U][PV_LC];
  __shared__ float Vl[PV_LC][DH + 4];
  const int z = blockIdx.y;
  const int b = z / NH, h = z % NH;
  const int c0 = blockIdx.x * PV_LC;
  const int tid = threadIdx.x;
  const float* Pz = P + (size_t)z * 64 * L + c0;
  for (int i4 = tid; i4 < U * (PV_LC / 4); i4 += 256) {
    int r = i4 / (PV_LC / 4);
    int lq = (i4 % (PV_LC / 4)) * 4;
    float4 p4 = *(const float4*)(Pz + (size_t)r * L + lq);
    Pl[r][lq + 0] = p4.x; Pl[r][lq + 1] = p4.y;
    Pl[r][lq + 2] = p4.z; Pl[r][lq + 3] = p4.w;
  }
  const float* Vb = V + ((size_t)b * L + c0) * D_MODEL + h * DH;
  for (int i4 = tid; i4 < PV_LC * (DH / 4); i4 += 256) {
    int l = i4 >> 4;
    int d4 = (i4 & 15) * 4;
    float4 v4 = *(const float4*)(Vb + (size_t)l * D_MODEL + d4);
    Vl[l][d4 + 0] = v4.x; Vl[l][d4 + 1] = v4.y;
    Vl[l][d4 + 2] = v4.z; Vl[l][d4 + 3] = v4.w;
  }
  __syncthreads();
  const int wave = tid >> 6, lane = tid & 63;
  constexpr int NJ = (U + 3) / 4;
  float acc[NJ] = {};
  for (int l = 0; l < PV_LC; ++l) {
    float vv = Vl[l][lane];
#pragma unroll
    for (int j = 0; j < NJ; ++j) {
      int r = wave + 4 * j;
      if (r < U) acc[j] += Pl[r][l] * vv;
    }
  }
#pragma unroll
  for (int j = 0; j < NJ; ++j) {
    int r = wave + 4 * j;
    if (r < U) {
      int ml = Mtop[z * U + r];
      atomicAdd(&O[((size_t)(b * L + ml)) * D_MODEL + h * DH + lane], acc[j]);
    }
  }
}

static void run_pv(const float* P, const float* V, const int* Mtop, float* O,
                   int L, int U, hipStream_t stream) {
  dim3 gg(L / PV_LC, 32);
  if (U == 40)      pv_kernel<40><<<gg, 256, 0, stream>>>(P, V, Mtop, O, L);
  else if (U == 35) pv_kernel<35><<<gg, 256, 0, stream>>>(P, V, Mtop, O, L);
  else              pv_kernel<64><<<gg, 256, 0, stream>>>(P, V, Mtop, O, L);
}

// ---------------- im2col (circular, K=3) -> bf16 --------------------------
__global__ void im2col_kernel(const float* __restrict__ X,
                              unsigned short* __restrict__ Y, int B, int L) {
  int i = blockIdx.x * 256 + threadIdx.x;
  int total = B * L * 1536;
  if (i >= total) return;
  int ck = i % 1536;
  int l = (i / 1536) % L;
  int b = i / (1536 * L);
  int c = ck / 3, k = ck % 3;
  int lm = l + k - 1;
  if (lm < 0) lm += L;
  else if (lm >= L) lm -= L;
  Y[i] = f2bf(X[((size_t)(b * L + lm)) * D_MODEL + c]);
}

// ---------------- maxpool k=3 s=2, one -inf pad each side -----------------
__global__ void maxpool_kernel(const float* __restrict__ Y,
                               float* __restrict__ X, int B, int L) {
  int Lo = L / 2;
  int i = blockIdx.x * 256 + threadIdx.x;
  int total = B * Lo * D_MODEL;
  if (i >= total) return;
  int d = i % D_MODEL;
  int lp = (i / D_MODEL) % Lo;
  int b = i / (D_MODEL * Lo);
  int l0 = 2 * lp - 1;
  float m = -INFINITY;
#pragma unroll
  for (int k = 0; k < 3; ++k) {
    int l = l0 + k;
    if (l >= 0 && l < L) m = fmaxf(m, Y[((size_t)(b * L + l)) * D_MODEL + d]);
  }
  X[i] = m;
}

// ==========================================================================
extern "C" void kernel_launch(void* const* d_in, const int* in_sizes, int n_in,
                              void* d_out, int out_size, void* d_ws,
                              size_t ws_size, hipStream_t stream) {
  const float* x_enc  = (const float*)d_in[0];
  const float* emb_w  = (const float*)d_in[1];
  const float* Wq     = (const float*)d_in[2];
  const float* bq     = (const float*)d_in[3];
  const float* Wk     = (const float*)d_in[4];
  const float* bk     = (const float*)d_in[5];
  const float* Wv     = (const float*)d_in[6];
  const float* bv     = (const float*)d_in[7];
  const float* Wo     = (const float*)d_in[8];
  const float* bo     = (const float*)d_in[9];
  const float* ln1_g  = (const float*)d_in[10];
  const float* ln1_b  = (const float*)d_in[11];
  const float* ff_w1  = (const float*)d_in[12];
  const float* ff_b1  = (const float*)d_in[13];
  const float* ff_w2  = (const float*)d_in[14];
  const float* ff_b2  = (const float*)d_in[15];
  const float* ln2_g  = (const float*)d_in[16];
  const float* ln2_b  = (const float*)d_in[17];
  const float* cv_w   = (const float*)d_in[18];
  const float* cv_b   = (const float*)d_in[19];
  const float* bn_g   = (const float*)d_in[20];
  const float* bn_b   = (const float*)d_in[21];
  const float* norm_g = (const float*)d_in[22];
  const float* norm_b = (const float*)d_in[23];

  const int B = 4, L0 = 2048, EL = 3;
  const size_t SZ = (size_t)B * 2048 * 512;
  float* ws   = (float*)d_ws;
  float* xbuf = ws;
  float* ebuf = ws + SZ;   // pre-LN temp; ab16(x); QKs; Sbuf
  float* qbuf = ws + 2 * SZ;
  float* kbuf = ws + 3 * SZ;
  float* vbuf = ws + 4 * SZ;
  float* obuf = ws + 5 * SZ;
  float* sm   = ws + 6 * SZ;
  int*   d_idx   = (int*)sm;
  float* d_M     = sm + 81920;
  int*   d_Mtop  = (int*)(sm + 81920 + 65536);
  float* d_vmean = sm + 81920 + 65536 + 1280;
  float* qred    = sm;    // reuses idx+M region (dead post-topk)
  float* QKs     = ebuf;
  float* Sbuf    = ebuf;

  const float inv_s = 1.0f / sqrtf(1.0f + 1e-5f);
  auto cast = [&](const float* s, unsigned short* d, int n) {
    cast_bf16_kernel<<<ceil_div(n / 4, 256), 256, 0, stream>>>(s, d, n);
  };

  embed_kernel<<<ceil_div(B * L0 * D_MODEL, 256), 256, 0, stream>>>(
      x_enc, emb_w, xbuf, B, L0);

  int L = L0;
  for (int i = 0; i < EL; ++i) {
    const int M_ = B * L;
    int c = 5 * (int)ceil(log((double)L));
    int U = c < L ? c : L;
    const float* Wq_i = Wq + (size_t)i * 512 * 512;
    const float* Wk_i = Wk + (size_t)i * 512 * 512;
    const float* Wv_i = Wv + (size_t)i * 512 * 512;
    const float* Wo_i = Wo + (size_t)i * 512 * 512;
    const float* w1_i = ff_w1 + (size_t)i * 512 * 512;
    const float* w2_i = ff_w2 + (size_t)i * 512 * 512;

    // Q, K, V all bf16 MFMA. x cast once (ebuf), three weights into obuf
    // slices. bf16 Q/K noise matches the bf16-path noise already in x
    // (absmax pinned 0.0313 since R6); borderline top-k queries are the
    // near-uniform ones whose attn output ~= vmean, so swaps are cheap.
    {
      unsigned short* ab16 = (unsigned short*)ebuf;
      unsigned short* wq16 = (unsigned short*)obuf;
      unsigned short* wk16 = wq16 + 262144;
      unsigned short* wv16 = wq16 + 524288;
      cast(xbuf, ab16, M_ * 512);
      cast(Wq_i, wq16, 512 * 512);
      cast(Wk_i, wk16, 512 * 512);
      cast(Wv_i, wv16, 512 * 512);
      run_bgemm<0>(ab16, wq16, bq + i * 512, nullptr, nullptr, nullptr, qbuf,
                   M_, 512, 512, 0.f, stream);
      run_bgemm<0>(ab16, wk16, bk + i * 512, nullptr, nullptr, nullptr, kbuf,
                   M_, 512, 512, 0.f, stream);
      run_bgemm<0>(ab16, wv16, bv + i * 512, nullptr, nullptr, nullptr, vbuf,
                   M_, 512, 512, 0.f, stream);
    }

    uint32_t lk0, lk1, k20, k21;
    threefry2x32(0u, 42u, 0u, (uint32_t)i, &lk0, &lk1);
    threefry2x32(lk0, lk1, 0u, 1u, &k20, &k21);
    idx_kernel<<<ceil_div(L * U, 256), 256, 0, stream>>>(d_idx, L, U, k20, k21);

    sparse_qk_kernel<<<B * L, 256, 0, stream>>>(qbuf, kbuf, d_idx, QKs, B, L, U);
    sparse_reduce_kernel<<<ceil_div(B * NH * L * 64, 256), 256, 0, stream>>>(
        QKs, d_M, B * NH * L, L, U);
    run_topk(d_M, d_Mtop, L, U, stream);
    vmean_zero_kernel<<<8, 256, 0, stream>>>(d_vmean);
    vmean_partial_kernel<<<dim3(64, B), 256, 0, stream>>>(vbuf, d_vmean, L);
    fill_ctx_kernel<<<ceil_div(B * L * D_MODEL, 256), 256, 0, stream>>>(
        d_vmean, obuf, B, L);

    pack_qred_kernel<<<B * NH, 256, 0, stream>>>(qbuf, d_Mtop, qred, L, U);
    scores_gemm_kernel<<<dim3(L / 64, B * NH), 256, 0, stream>>>(qred, kbuf,
                                                                 Sbuf, L);
    run_softmax(Sbuf, L, U, stream);
    zero_sel_kernel<<<B * NH, 256, 0, stream>>>(d_Mtop, obuf, L, U);
    run_pv(Sbuf, vbuf, d_Mtop, obuf, L, U, stream);

    // O-proj bf16: ab16 @ qbuf (Q dead), wb16 @ kbuf (K dead), C=ebuf
    unsigned short* ab16 = (unsigned short*)qbuf;
    unsigned short* wb16 = (unsigned short*)kbuf;
    cast(obuf, ab16, M_ * 512);
    cast(Wo_i, wb16, 512 * 512);
    run_bgemm<2>(ab16, wb16, bo + i * 512, xbuf, nullptr, nullptr, ebuf,
                 M_, 512, 512, 0.f, stream);
    ln_kernel<<<M_, 256, 0, stream>>>(ebuf, ln1_g + i * 512, ln1_b + i * 512, xbuf);

    // FF1 bf16 (gelu fused), C=obuf
    cast(xbuf, ab16, M_ * 512);
    cast(w1_i, wb16, 512 * 512);
    run_bgemm<1>(ab16, wb16, ff_b1 + i * 512, nullptr, nullptr, nullptr, obuf,
                 M_, 512, 512, 0.f, stream);
    // FF2 bf16 (+residual), C=ebuf
    cast(obuf, ab16, M_ * 512);
    cast(w2_i, wb16, 512 * 512);
    run_bgemm<2>(ab16, wb16, ff_b2 + i * 512, xbuf, nullptr, nullptr, ebuf,
                 M_, 512, 512, 0.f, stream);
    ln_kernel<<<M_, 256, 0, stream>>>(ebuf, ln2_g + i * 512, ln2_b + i * 512, xbuf);

    if (i < EL - 1) {
      // conv distill bf16: im2col -> imb16 @ qbuf(+kbuf), weights @ vbuf
      unsigned short* imb16 = (unsigned short*)qbuf;
      unsigned short* wb16c = (unsigned short*)vbuf;
      im2col_kernel<<<ceil_div(B * L * 1536, 256), 256, 0, stream>>>(xbuf, imb16, B, L);
      cast(cv_w + (size_t)i * 512 * 1536, wb16c, 512 * 1536);
      run_bgemm<3>(imb16, wb16c, cv_b + i * 512, nullptr, bn_g + i * 512,
                   bn_b + i * 512, ebuf, M_, 512, 1536, inv_s, stream);
      maxpool_kernel<<<ceil_div(B * (L / 2) * D_MODEL, 256), 256, 0, stream>>>(
          ebuf, xbuf, B, L);
      L /= 2;
    }
  }

  ln_kernel<<<B * L, 256, 0, stream>>>(xbuf, norm_g, norm_b, (float*)d_out);
}

// Round 12
// 1000.343 us; speedup vs baseline: 3.2408x; 1.0704x over previous
//
#include <hip/hip_runtime.h>
#include <cmath>
#include <cstdint>

#define D_MODEL 512
#define NH 8
#define DH 64

static inline int ceil_div(int a, int b) { return (a + b - 1) / b; }

typedef __attribute__((ext_vector_type(8))) short short8;
typedef __attribute__((ext_vector_type(4))) float floatx4;

// fp32 -> bf16 (RNE)
__device__ __forceinline__ unsigned short f2bf(float f) {
  uint32_t u = __float_as_uint(f);
  uint32_t r = (u + 0x7fffu + ((u >> 16) & 1u)) >> 16;
  return (unsigned short)r;
}
__device__ __forceinline__ float bf2f(unsigned short s) {
  return __uint_as_float(((uint32_t)s) << 16);
}

// ---------------- threefry2x32 (JAX-exact) ----------------
#define TF_ROTL(x, r) (((x) << (r)) | ((x) >> (32 - (r))))

__host__ __device__ inline void threefry2x32(uint32_t k0, uint32_t k1,
                                             uint32_t x0, uint32_t x1,
                                             uint32_t* o0, uint32_t* o1) {
  uint32_t ks2 = k0 ^ k1 ^ 0x1BD11BDAu;
  x0 += k0; x1 += k1;
#define TF_R4(a, b, c, d)                                    \
  x0 += x1; x1 = TF_ROTL(x1, a); x1 ^= x0;                   \
  x0 += x1; x1 = TF_ROTL(x1, b); x1 ^= x0;                   \
  x0 += x1; x1 = TF_ROTL(x1, c); x1 ^= x0;                   \
  x0 += x1; x1 = TF_ROTL(x1, d); x1 ^= x0;
  TF_R4(13, 15, 26, 6);  x0 += k1;  x1 += ks2 + 1u;
  TF_R4(17, 29, 16, 24); x0 += ks2; x1 += k0 + 2u;
  TF_R4(13, 15, 26, 6);  x0 += k0;  x1 += k1 + 3u;
  TF_R4(17, 29, 16, 24); x0 += k1;  x1 += ks2 + 4u;
  TF_R4(13, 15, 26, 6);  x0 += ks2; x1 += k0 + 5u;
#undef TF_R4
  *o0 = x0; *o1 = x1;
}

__global__ void idx_kernel(int* __restrict__ idx, int L, int U,
                           uint32_t k0, uint32_t k1) {
  int n = blockIdx.x * 256 + threadIdx.x;
  if (n >= L * U) return;
  uint32_t o0, o1;
  threefry2x32(k0, k1, 0u, (uint32_t)n, &o0, &o1);
  idx[n] = (int)((o0 ^ o1) & (uint32_t)(L - 1));
}

// ---------------- fp32 -> bf16 cast, 4 elems/thread ----------------
__global__ __launch_bounds__(256) void cast_bf16_kernel(
    const float* __restrict__ src, unsigned short* __restrict__ dst, int n) {
  int i = (blockIdx.x * 256 + threadIdx.x) * 4;
  if (i >= n) return;
  float4 v = *(const float4*)(src + i);
  ushort4 o;
  o.x = f2bf(v.x); o.y = f2bf(v.y); o.z = f2bf(v.z); o.w = f2bf(v.w);
  *(ushort4*)(dst + i) = o;
}

// ---------------- embedding + pos encoding, dual fp32/bf16 out ------------
__global__ __launch_bounds__(256) void embed_kernel(
    const float* __restrict__ x_enc, const float* __restrict__ emb_w,
    float* __restrict__ x, unsigned short* __restrict__ xb, int B, int L) {
  int i = blockIdx.x * 256 + threadIdx.x;
  int total = B * L * D_MODEL;
  if (i >= total) return;
  int d = i % D_MODEL;
  int l = (i / D_MODEL) % L;
  int b = i / (D_MODEL * L);
  int lm = (l == 0) ? (L - 1) : (l - 1);
  int lp = (l == L - 1) ? 0 : (l + 1);
  const float* w = emb_w + d * 6;
  const float* xb_in = x_enc + (size_t)b * L * 2;
  float acc = 0.f;
  acc += xb_in[lm * 2 + 0] * w[0] + xb_in[l * 2 + 0] * w[1] + xb_in[lp * 2 + 0] * w[2];
  acc += xb_in[lm * 2 + 1] * w[3] + xb_in[l * 2 + 1] * w[4] + xb_in[lp * 2 + 1] * w[5];
  int j = d >> 1;
  const float coef = -0.017988946039015985f;  // -ln(10000)/512
  float div = expf((float)(2 * j) * coef);
  float ang = (float)l * div;
  float pe = (d & 1) ? cosf(ang) : sinf(ang);
  float v = acc + pe;
  x[i] = v;
  xb[i] = f2bf(v);
}

// ---------------- layer norm over D=512 (plain + dual-output) -------------
__global__ __launch_bounds__(256) void ln_kernel(
    const float* __restrict__ in, const float* __restrict__ g,
    const float* __restrict__ b, float* __restrict__ out) {
  int row = blockIdx.x;
  int t = threadIdx.x;
  const float* xr = in + (size_t)row * D_MODEL;
  float v0 = xr[t], v1 = xr[t + 256];
  __shared__ float red[256];
  red[t] = v0 + v1;
  __syncthreads();
  for (int s = 128; s > 0; s >>= 1) { if (t < s) red[t] += red[t + s]; __syncthreads(); }
  float mean = red[0] * (1.0f / 512.0f);
  __syncthreads();
  float d0 = v0 - mean, d1 = v1 - mean;
  red[t] = d0 * d0 + d1 * d1;
  __syncthreads();
  for (int s = 128; s > 0; s >>= 1) { if (t < s) red[t] += red[t + s]; __syncthreads(); }
  float var = red[0] * (1.0f / 512.0f);
  float rstd = 1.0f / sqrtf(var + 1e-5f);
  float* outr = out + (size_t)row * D_MODEL;
  outr[t]       = d0 * rstd * g[t]       + b[t];
  outr[t + 256] = d1 * rstd * g[t + 256] + b[t + 256];
}

__global__ __launch_bounds__(256) void ln_dual_kernel(
    const float* __restrict__ in, const float* __restrict__ g,
    const float* __restrict__ b, float* __restrict__ out,
    unsigned short* __restrict__ out16) {
  int row = blockIdx.x;
  int t = threadIdx.x;
  const float* xr = in + (size_t)row * D_MODEL;
  float v0 = xr[t], v1 = xr[t + 256];
  __shared__ float red[256];
  red[t] = v0 + v1;
  __syncthreads();
  for (int s = 128; s > 0; s >>= 1) { if (t < s) red[t] += red[t + s]; __syncthreads(); }
  float mean = red[0] * (1.0f / 512.0f);
  __syncthreads();
  float d0 = v0 - mean, d1 = v1 - mean;
  red[t] = d0 * d0 + d1 * d1;
  __syncthreads();
  for (int s = 128; s > 0; s >>= 1) { if (t < s) red[t] += red[t + s]; __syncthreads(); }
  float var = red[0] * (1.0f / 512.0f);
  float rstd = 1.0f / sqrtf(var + 1e-5f);
  float* outr = out + (size_t)row * D_MODEL;
  unsigned short* o16 = out16 + (size_t)row * D_MODEL;
  float r0 = d0 * rstd * g[t] + b[t];
  float r1 = d1 * rstd * g[t + 256] + b[t + 256];
  outr[t] = r0;       o16[t] = f2bf(r0);
  outr[t + 256] = r1; o16[t + 256] = f2bf(r1);
}

// MODE 0: +bias   1: gelu(+bias)   2: +bias +R   3: elu((+bias)*scl*g + bb)
__device__ __forceinline__ float epilogue_apply(int MODE, float v, float r,
                                                float g, float bb, float scl) {
  if (MODE == 1) {
    v = 0.5f * v * (1.0f + erff(v * 0.7071067811865475f));
  } else if (MODE == 2) {
    v += r;
  } else if (MODE == 3) {
    v = v * scl * g + bb;
    v = (v > 0.f) ? v : expm1f(v);
  }
  return v;
}

// ---------------- bf16 MFMA GEMM 64x64, BK=32, 4 waves (32x32 each) -------
// OUT bitmask: 1 = fp32 C, 2 = bf16 C16 (dead branches fold at compile time)
template <int MODE, int OUT>
__global__ __launch_bounds__(256) void bgemm_kernel(
    const unsigned short* __restrict__ A, const unsigned short* __restrict__ Bt,
    const float* __restrict__ bias, const float* __restrict__ R,
    const float* __restrict__ gvec, const float* __restrict__ bvec,
    float* __restrict__ C, unsigned short* __restrict__ C16,
    int M, int N, int K, float scl) {
  __shared__ unsigned short Al[64][40];
  __shared__ unsigned short Bl[64][40];
  const int bm = blockIdx.y * 64, bn = blockIdx.x * 64;
  const int tid = threadIdx.x;
  const int wave = tid >> 6, lane = tid & 63;
  const int wm = (wave >> 1) * 32, wn = (wave & 1) * 32;
  const int quad = lane >> 4, l16 = lane & 15;
  const int sr = tid >> 2;
  const int sc = (tid & 3) * 8;
  const unsigned short* Ag = A + (size_t)(bm + sr) * K + sc;
  const unsigned short* Bg = Bt + (size_t)(bn + sr) * K + sc;
  floatx4 zero = {0.f, 0.f, 0.f, 0.f};
  floatx4 acc00 = zero, acc01 = zero, acc10 = zero, acc11 = zero;
  for (int k0 = 0; k0 < K; k0 += 32) {
    short8 a8 = *(const short8*)(Ag + k0);
    short8 b8 = *(const short8*)(Bg + k0);
    *(short8*)&Al[sr][sc] = a8;
    *(short8*)&Bl[sr][sc] = b8;
    __syncthreads();
    short8 af0 = *(const short8*)&Al[wm + l16][quad * 8];
    short8 af1 = *(const short8*)&Al[wm + 16 + l16][quad * 8];
    short8 bf0 = *(const short8*)&Bl[wn + l16][quad * 8];
    short8 bf1 = *(const short8*)&Bl[wn + 16 + l16][quad * 8];
    acc00 = __builtin_amdgcn_mfma_f32_16x16x32_bf16(af0, bf0, acc00, 0, 0, 0);
    acc01 = __builtin_amdgcn_mfma_f32_16x16x32_bf16(af0, bf1, acc01, 0, 0, 0);
    acc10 = __builtin_amdgcn_mfma_f32_16x16x32_bf16(af1, bf0, acc10, 0, 0, 0);
    acc11 = __builtin_amdgcn_mfma_f32_16x16x32_bf16(af1, bf1, acc11, 0, 0, 0);
    __syncthreads();
  }
  floatx4 accs[2][2] = {{acc00, acc01}, {acc10, acc11}};
#pragma unroll
  for (int i = 0; i < 2; ++i) {
#pragma unroll
    for (int j = 0; j < 2; ++j) {
      int col = bn + wn + j * 16 + l16;
#pragma unroll
      for (int p = 0; p < 4; ++p) {
        int row = bm + wm + i * 16 + quad * 4 + p;
        float v = accs[i][j][p] + bias[col];
        v = epilogue_apply(MODE, v, (MODE == 2) ? R[(size_t)row * N + col] : 0.f,
                           (MODE == 3) ? gvec[col] : 0.f,
                           (MODE == 3) ? bvec[col] : 0.f, scl);
        if (OUT & 1) C[(size_t)row * N + col] = v;
        if (OUT & 2) C16[(size_t)row * N + col] = f2bf(v);
      }
    }
  }
}

template <int MODE, int OUT>
static void run_bgemm(const unsigned short* A, const unsigned short* Bt,
                      const float* bias, const float* R, const float* g,
                      const float* bb, float* C, unsigned short* C16,
                      int M, int N, int K, float scl, hipStream_t stream) {
  dim3 gg(N / 64, M / 64);
  bgemm_kernel<MODE, OUT><<<gg, 256, 0, stream>>>(A, Bt, bias, R, g, bb, C,
                                                  C16, M, N, K, scl);
}

// ---------------- sparse QK: one BLOCK per (b,l), bf16 K gathers ----------
// K gather rows are bf16 (16 B/lane, half of R11's 32 B) -> halves the
// ~655 MB logical / ~100 MB HBM gather stream. Q stays fp32 (read once).
__global__ __launch_bounds__(256) void sparse_qk_kernel(
    const float* __restrict__ Q, const unsigned short* __restrict__ K16,
    const int* __restrict__ idx, float* __restrict__ QKs, int B, int L,
    int U) {
  int bl = blockIdx.x;  // b*L + l
  int b = bl / L, l = bl - b * L;
  int tid = threadIdx.x;
  int wave = tid >> 6, lane = tid & 63;
  int h = lane >> 3;
  const float4* qr = (const float4*)(Q + (size_t)bl * D_MODEL + lane * 8);
  float4 q0 = qr[0], q1 = qr[1];
  float qv[8] = {q0.x, q0.y, q0.z, q0.w, q1.x, q1.y, q1.z, q1.w};
  const int* idxl = idx + l * U;
  for (int u = wave; u < U; u += 4) {
    int ki = idxl[u];
    short8 k8 = *(const short8*)(K16 + ((size_t)b * L + ki) * D_MODEL + lane * 8);
    float p = 0.f;
#pragma unroll
    for (int e = 0; e < 8; ++e) p += qv[e] * bf2f((unsigned short)k8[e]);
    p += __shfl_xor(p, 1);
    p += __shfl_xor(p, 2);
    p += __shfl_xor(p, 4);
    if ((lane & 7) == 0)
      QKs[(((size_t)(b * NH + h)) * L + l) * U + u] = p;
  }
}

// M[bh*L+l] = max_u(QKs) - sum_u(QKs)/L ; one wave per query, ONE butterfly
__global__ __launch_bounds__(256) void sparse_reduce_kernel(
    const float* __restrict__ QKs, float* __restrict__ Mout, int total,
    int L, int U) {
  int wid = (blockIdx.x * 256 + threadIdx.x) >> 6;
  int lane = threadIdx.x & 63;
  if (wid >= total) return;
  float v = (lane < U) ? QKs[(size_t)wid * U + lane] : -INFINITY;
  float m = v;
#pragma unroll
  for (int k = 32; k; k >>= 1) m = fmaxf(m, __shfl_xor(m, k));
  float sv = (lane < U) ? v : 0.f;
#pragma unroll
  for (int k = 32; k; k >>= 1) sv += __shfl_xor(sv, k);
  if (lane == 0) Mout[wid] = m - sv / (float)L;
}

// ---------------- top-k: register-resident iterative selection ------------
template <int NE>
__global__ __launch_bounds__(256) void topk_kernel(
    const float* __restrict__ Mv, int* __restrict__ Mtop, int u) {
  int bh = blockIdx.x;
  int t = threadIdx.x;
  int wave = t >> 6, lane = t & 63;
  float vals[NE];
  const float* src = Mv + (size_t)bh * (NE * 256);
#pragma unroll
  for (int i = 0; i < NE; ++i) vals[i] = src[t + i * 256];
  __shared__ float wv[4];
  __shared__ int wi[4];
  __shared__ int gi;
  for (int it = 0; it < u; ++it) {
    float bv = -INFINITY;
    int bi = 0x7fffffff;
#pragma unroll
    for (int i = 0; i < NE; ++i) {
      float v = vals[i];
      int ix = t + i * 256;
      if (v > bv || (v == bv && ix < bi)) { bv = v; bi = ix; }
    }
#pragma unroll
    for (int k = 32; k; k >>= 1) {
      float ov = __shfl_xor(bv, k);
      int oi = __shfl_xor(bi, k);
      if (ov > bv || (ov == bv && oi < bi)) { bv = ov; bi = oi; }
    }
    if (lane == 0) { wv[wave] = bv; wi[wave] = bi; }
    __syncthreads();
    if (t == 0) {
      float fv = wv[0];
      int fi = wi[0];
#pragma unroll
      for (int w = 1; w < 4; ++w)
        if (wv[w] > fv || (wv[w] == fv && wi[w] < fi)) { fv = wv[w]; fi = wi[w]; }
      gi = fi;
      Mtop[bh * u + it] = fi;
    }
    __syncthreads();
    int fi = gi;
#pragma unroll
    for (int i = 0; i < NE; ++i)
      if (fi == t + i * 256) vals[i] = -INFINITY;
  }
}

static void run_topk(const float* Mv, int* Mtop, int L, int u,
                     hipStream_t stream) {
  if (L == 2048)      topk_kernel<8><<<32, 256, 0, stream>>>(Mv, Mtop, u);
  else if (L == 1024) topk_kernel<4><<<32, 256, 0, stream>>>(Mv, Mtop, u);
  else                topk_kernel<2><<<32, 256, 0, stream>>>(Mv, Mtop, u);
}

// ---------------- mean of V over L: split-L partial + atomic --------------
__global__ void vmean_zero_kernel(float* __restrict__ vmean) {
  vmean[blockIdx.x * 256 + threadIdx.x] = 0.f;
}

__global__ __launch_bounds__(256) void vmean_partial_kernel(
    const float* __restrict__ V, float* __restrict__ vmean, int L) {
  int b = blockIdx.y;
  int chunk = blockIdx.x;           // 64 chunks
  int rows = L >> 6;
  int t = threadIdx.x;
  const float* base = V + ((size_t)b * L + (size_t)chunk * rows) * D_MODEL;
  float s0 = 0.f, s1 = 0.f;
  for (int r = 0; r < rows; ++r) {
    s0 += base[(size_t)r * D_MODEL + t];
    s1 += base[(size_t)r * D_MODEL + t + 256];
  }
  float invL = 1.0f / (float)L;
  atomicAdd(&vmean[b * D_MODEL + t], s0 * invL);
  atomicAdd(&vmean[b * D_MODEL + t + 256], s1 * invL);
}

__global__ void fill_ctx_kernel(const float* __restrict__ vmean,
                                float* __restrict__ O, int B, int L) {
  int i = blockIdx.x * 256 + threadIdx.x;
  int total = B * L * D_MODEL;
  if (i >= total) return;
  int dcol = i % D_MODEL;
  int b = i / (D_MODEL * L);
  O[i] = vmean[b * D_MODEL + dcol];
}

// ============== attention as batched GEMM pipeline ==============
__global__ void pack_qred_kernel(const float* __restrict__ Q,
                                 const int* __restrict__ Mtop,
                                 float* __restrict__ qred, int L, int U) {
  int z = blockIdx.x;  // bh
  int b = z / NH, h = z % NH;
  int t = threadIdx.x;
  int d = t & 63;
  for (int r = t >> 6; r < 64; r += 4) {
    float v = 0.f;
    if (r < U) {
      int l = Mtop[z * U + r];
      v = Q[((size_t)(b * L + l)) * D_MODEL + h * DH + d];
    }
    qred[((size_t)z * 64 + r) * 64 + d] = v;
  }
}

#define BK 16
#define PADR 4

// S[z][64][L] = 0.125 * Qred[z](64x64) @ K_z^T ; K_z rows stride 512
__global__ __launch_bounds__(256) void scores_gemm_kernel(
    const float* __restrict__ qred, const float* __restrict__ Km,
    float* __restrict__ S, int L) {
  __shared__ float As[BK][64 + PADR];
  __shared__ float Bs[BK][64 + PADR];
  const int z = blockIdx.y;
  const int b = z / NH, h = z % NH;
  const float* A = qred + (size_t)z * 64 * 64;
  const float* Bt = Km + (size_t)b * L * D_MODEL + h * DH;  // ldb = 512
  float* Sz = S + (size_t)z * 64 * L;
  const int bn = blockIdx.x * 64;
  const int tid = threadIdx.x;
  const int tx = tid & 15, ty = tid >> 4;
  const int lr = tid >> 2;
  const int lc = (tid & 3) << 2;
  float acc[4][4] = {};
  for (int k0 = 0; k0 < 64; k0 += BK) {
    float4 av = *(const float4*)(A + (size_t)lr * 64 + k0 + lc);
    float4 bv = *(const float4*)(Bt + (size_t)(bn + lr) * D_MODEL + k0 + lc);
    As[lc + 0][lr] = av.x; As[lc + 1][lr] = av.y;
    As[lc + 2][lr] = av.z; As[lc + 3][lr] = av.w;
    Bs[lc + 0][lr] = bv.x; Bs[lc + 1][lr] = bv.y;
    Bs[lc + 2][lr] = bv.z; Bs[lc + 3][lr] = bv.w;
    __syncthreads();
#pragma unroll
    for (int kk = 0; kk < BK; ++kk) {
      float4 a4 = *(const float4*)&As[kk][ty << 2];
      float4 b4 = *(const float4*)&Bs[kk][tx << 2];
      float ar[4] = {a4.x, a4.y, a4.z, a4.w};
      float br[4] = {b4.x, b4.y, b4.z, b4.w};
#pragma unroll
      for (int i = 0; i < 4; ++i)
#pragma unroll
        for (int j = 0; j < 4; ++j) acc[i][j] += ar[i] * br[j];
    }
    __syncthreads();
  }
#pragma unroll
  for (int i = 0; i < 4; ++i) {
    float* Sr = Sz + (size_t)((ty << 2) + i) * L + bn;
#pragma unroll
    for (int j = 0; j < 4; ++j) Sr[(tx << 2) + j] = 0.125f * acc[i][j];
  }
}

// ---------------- softmax: one block per (z,row) ----------------
template <int LC>
__global__ __launch_bounds__(256) void softmax_kernel(float* __restrict__ S,
                                                      int U) {
  constexpr int NE = LC / 256;
  int rid = blockIdx.x;
  int z = rid / U, r = rid % U;
  float* row = S + (size_t)z * 64 * LC + (size_t)r * LC;
  int t = threadIdx.x;
  float vals[NE];
  float m = -INFINITY;
#pragma unroll
  for (int i = 0; i < NE; ++i) {
    vals[i] = row[t + i * 256];
    m = fmaxf(m, vals[i]);
  }
  __shared__ float red[256];
  red[t] = m;
  __syncthreads();
  for (int s = 128; s > 0; s >>= 1) { if (t < s) red[t] = fmaxf(red[t], red[t + s]); __syncthreads(); }
  m = red[0];
  __syncthreads();
  float sum = 0.f;
#pragma unroll
  for (int i = 0; i < NE; ++i) {
    vals[i] = expf(vals[i] - m);
    sum += vals[i];
  }
  red[t] = sum;
  __syncthreads();
  for (int s = 128; s > 0; s >>= 1) { if (t < s) red[t] += red[t + s]; __syncthreads(); }
  float inv = 1.0f / red[0];
#pragma unroll
  for (int i = 0; i < NE; ++i) row[t + i * 256] = vals[i] * inv;
}

static void run_softmax(float* S, int L, int U, hipStream_t stream) {
  int blocks = 32 * U;
  if (L == 2048)      softmax_kernel<2048><<<blocks, 256, 0, stream>>>(S, U);
  else if (L == 1024) softmax_kernel<1024><<<blocks, 256, 0, stream>>>(S, U);
  else                softmax_kernel<512><<<blocks, 256, 0, stream>>>(S, U);
}

// zero the selected ctx rows before split-K PV atomics
__global__ void zero_sel_kernel(const int* __restrict__ Mtop,
                                float* __restrict__ O, int L, int U) {
  int z = blockIdx.x;
  int b = z / NH, h = z % NH;
  int t = threadIdx.x;
  int d = t & 63;
  for (int r = t >> 6; r < U; r += 4) {
    int l = Mtop[z * U + r];
    O[((size_t)(b * L + l)) * D_MODEL + h * DH + d] = 0.f;
  }
}

// O[sel rows] += P(UxL) @ V(Lx64), split-K over 128-chunks of L.
#define PV_LC 128

template <int U>
__global__ __launch_bounds__(256) void pv_kernel(
    const float* __restrict__ P, const float* __restrict__ V,
    const int* __restrict__ Mtop, float* __restrict__ O, int L) {
  __shared__ float Pl[U][PV_LC];
  __shared__ float Vl[PV_LC][DH + 4];
  const int z = blockIdx.y;
  const int b = z / NH, h = z % NH;
  const int c0 = blockIdx.x * PV_LC;
  const int tid = threadIdx.x;
  const float* Pz = P + (size_t)z * 64 * L + c0;
  for (int i4 = tid; i4 < U * (PV_LC / 4); i4 += 256) {
    int r = i4 / (PV_LC / 4);
    int lq = (i4 % (PV_LC / 4)) * 4;
    float4 p4 = *(const float4*)(Pz + (size_t)r * L + lq);
    Pl[r][lq + 0] = p4.x; Pl[r][lq + 1] = p4.y;
    Pl[r][lq + 2] = p4.z; Pl[r][lq + 3] = p4.w;
  }
  const float* Vb = V + ((size_t)b * L + c0) * D_MODEL + h * DH;
  for (int i4 = tid; i4 < PV_LC * (DH / 4); i4 += 256) {
    int l = i4 >> 4;
    int d4 = (i4 & 15) * 4;
    float4 v4 = *(const float4*)(Vb + (size_t)l * D_MODEL + d4);
    Vl[l][d4 + 0] = v4.x; Vl[l][d4 + 1] = v4.y;
    Vl[l][d4 + 2] = v4.z; Vl[l][d4 + 3] = v4.w;
  }
  __syncthreads();
  const int wave = tid >> 6, lane = tid & 63;
  constexpr int NJ = (U + 3) / 4;
  float acc[NJ] = {};
  for (int l = 0; l < PV_LC; ++l) {
    float vv = Vl[l][lane];
#pragma unroll
    for (int j = 0; j < NJ; ++j) {
      int r = wave + 4 * j;
      if (r < U) acc[j] += Pl[r][l] * vv;
    }
  }
#pragma unroll
  for (int j = 0; j < NJ; ++j) {
    int r = wave + 4 * j;
    if (r < U) {
      int ml = Mtop[z * U + r];
      atomicAdd(&O[((size_t)(b * L + ml)) * D_MODEL + h * DH + lane], acc[j]);
    }
  }
}

static void run_pv(const float* P, const float* V, const int* Mtop, float* O,
                   int L, int U, hipStream_t stream) {
  dim3 gg(L / PV_LC, 32);
  if (U == 40)      pv_kernel<40><<<gg, 256, 0, stream>>>(P, V, Mtop, O, L);
  else if (U == 35) pv_kernel<35><<<gg, 256, 0, stream>>>(P, V, Mtop, O, L);
  else              pv_kernel<64><<<gg, 256, 0, stream>>>(P, V, Mtop, O, L);
}

// ---------------- im2col (circular, K=3) -> bf16 --------------------------
__global__ void im2col_kernel(const float* __restrict__ X,
                              unsigned short* __restrict__ Y, int B, int L) {
  int i = blockIdx.x * 256 + threadIdx.x;
  int total = B * L * 1536;
  if (i >= total) return;
  int ck = i % 1536;
  int l = (i / 1536) % L;
  int b = i / (1536 * L);
  int c = ck / 3, k = ck % 3;
  int lm = l + k - 1;
  if (lm < 0) lm += L;
  else if (lm >= L) lm -= L;
  Y[i] = f2bf(X[((size_t)(b * L + lm)) * D_MODEL + c]);
}

// ---------------- maxpool k=3 s=2, dual fp32/bf16 out ---------------------
__global__ void maxpool_kernel(const float* __restrict__ Y,
                               float* __restrict__ X,
                               unsigned short* __restrict__ Xb, int B, int L) {
  int Lo = L / 2;
  int i = blockIdx.x * 256 + threadIdx.x;
  int total = B * Lo * D_MODEL;
  if (i >= total) return;
  int d = i % D_MODEL;
  int lp = (i / D_MODEL) % Lo;
  int b = i / (D_MODEL * Lo);
  int l0 = 2 * lp - 1;
  float m = -INFINITY;
#pragma unroll
  for (int k = 0; k < 3; ++k) {
    int l = l0 + k;
    if (l >= 0 && l < L) m = fmaxf(m, Y[((size_t)(b * L + l)) * D_MODEL + d]);
  }
  X[i] = m;
  Xb[i] = f2bf(m);
}

// ==========================================================================
extern "C" void kernel_launch(void* const* d_in, const int* in_sizes, int n_in,
                              void* d_out, int out_size, void* d_ws,
                              size_t ws_size, hipStream_t stream) {
  const float* x_enc  = (const float*)d_in[0];
  const float* emb_w  = (const float*)d_in[1];
  const float* Wq     = (const float*)d_in[2];
  const float* bq     = (const float*)d_in[3];
  const float* Wk     = (const float*)d_in[4];
  const float* bk     = (const float*)d_in[5];
  const float* Wv     = (const float*)d_in[6];
  const float* bv     = (const float*)d_in[7];
  const float* Wo     = (const float*)d_in[8];
  const float* bo     = (const float*)d_in[9];
  const float* ln1_g  = (const float*)d_in[10];
  const float* ln1_b  = (const float*)d_in[11];
  const float* ff_w1  = (const float*)d_in[12];
  const float* ff_b1  = (const float*)d_in[13];
  const float* ff_w2  = (const float*)d_in[14];
  const float* ff_b2  = (const float*)d_in[15];
  const float* ln2_g  = (const float*)d_in[16];
  const float* ln2_b  = (const float*)d_in[17];
  const float* cv_w   = (const float*)d_in[18];
  const float* cv_b   = (const float*)d_in[19];
  const float* bn_g   = (const float*)d_in[20];
  const float* bn_b   = (const float*)d_in[21];
  const float* norm_g = (const float*)d_in[22];
  const float* norm_b = (const float*)d_in[23];

  const int B = 4, L0 = 2048, EL = 3;
  const size_t SZ = (size_t)B * 2048 * 512;
  float* ws   = (float*)d_ws;
  float* xbuf = ws;
  float* ebuf = ws + SZ;   // layer0 xb16; pre-LN temp; QKs; Sbuf
  float* qbuf = ws + 2 * SZ;
  float* kbuf = ws + 3 * SZ;
  float* vbuf = ws + 4 * SZ;
  float* obuf = ws + 5 * SZ;
  float* sm   = ws + 6 * SZ;
  int*   d_idx   = (int*)sm;
  float* d_M     = sm + 81920;
  int*   d_Mtop  = (int*)(sm + 81920 + 65536);
  float* d_vmean = sm + 81920 + 65536 + 1280;
  float* qred    = sm;    // reuses idx+M region (dead post-topk)
  float* QKs     = ebuf;
  float* Sbuf    = ebuf;

  const float inv_s = 1.0f / sqrtf(1.0f + 1e-5f);
  auto cast = [&](const float* s, unsigned short* d, int n) {
    cast_bf16_kernel<<<ceil_div(n / 4, 256), 256, 0, stream>>>(s, d, n);
  };

  // layer-0 x bf16 fused into embed (-> ebuf)
  embed_kernel<<<ceil_div(B * L0 * D_MODEL, 256), 256, 0, stream>>>(
      x_enc, emb_w, xbuf, (unsigned short*)ebuf, B, L0);
  unsigned short* xb16 = (unsigned short*)ebuf;  // current layer's bf16 x

  int L = L0;
  for (int i = 0; i < EL; ++i) {
    const int M_ = B * L;
    int c = 5 * (int)ceil(log((double)L));
    int U = c < L ? c : L;
    const float* Wq_i = Wq + (size_t)i * 512 * 512;
    const float* Wk_i = Wk + (size_t)i * 512 * 512;
    const float* Wv_i = Wv + (size_t)i * 512 * 512;
    const float* Wo_i = Wo + (size_t)i * 512 * 512;
    const float* w1_i = ff_w1 + (size_t)i * 512 * 512;
    const float* w2_i = ff_w2 + (size_t)i * 512 * 512;

    // QKV bf16 MFMA. K dual-writes fp32 kbuf (scores) + bf16 k16 (gathers).
    unsigned short* wq16 = (unsigned short*)obuf;
    unsigned short* wk16 = wq16 + 262144;
    unsigned short* wv16 = wq16 + 524288;
    unsigned short* k16  = wq16 + 1048576;  // obuf bytes [2MB, 2MB+M_*1KB)
    {
      cast(Wq_i, wq16, 512 * 512);
      cast(Wk_i, wk16, 512 * 512);
      cast(Wv_i, wv16, 512 * 512);
      run_bgemm<0, 1>(xb16, wq16, bq + i * 512, nullptr, nullptr, nullptr,
                      qbuf, nullptr, M_, 512, 512, 0.f, stream);
      run_bgemm<0, 3>(xb16, wk16, bk + i * 512, nullptr, nullptr, nullptr,
                      kbuf, k16, M_, 512, 512, 0.f, stream);
      run_bgemm<0, 1>(xb16, wv16, bv + i * 512, nullptr, nullptr, nullptr,
                      vbuf, nullptr, M_, 512, 512, 0.f, stream);
    }

    uint32_t lk0, lk1, k20, k21;
    threefry2x32(0u, 42u, 0u, (uint32_t)i, &lk0, &lk1);
    threefry2x32(lk0, lk1, 0u, 1u, &k20, &k21);
    idx_kernel<<<ceil_div(L * U, 256), 256, 0, stream>>>(d_idx, L, U, k20, k21);

    sparse_qk_kernel<<<B * L, 256, 0, stream>>>(qbuf, k16, d_idx, QKs, B, L, U);
    sparse_reduce_kernel<<<ceil_div(B * NH * L * 64, 256), 256, 0, stream>>>(
        QKs, d_M, B * NH * L, L, U);
    run_topk(d_M, d_Mtop, L, U, stream);
    vmean_zero_kernel<<<8, 256, 0, stream>>>(d_vmean);
    vmean_partial_kernel<<<dim3(64, B), 256, 0, stream>>>(vbuf, d_vmean, L);
    fill_ctx_kernel<<<ceil_div(B * L * D_MODEL, 256), 256, 0, stream>>>(
        d_vmean, obuf, B, L);

    pack_qred_kernel<<<B * NH, 256, 0, stream>>>(qbuf, d_Mtop, qred, L, U);
    scores_gemm_kernel<<<dim3(L / 64, B * NH), 256, 0, stream>>>(qred, kbuf,
                                                                 Sbuf, L);
    run_softmax(Sbuf, L, U, stream);
    zero_sel_kernel<<<B * NH, 256, 0, stream>>>(d_Mtop, obuf, L, U);
    run_pv(Sbuf, vbuf, d_Mtop, obuf, L, U, stream);

    // O-proj: ctx cast -> qbuf shorts (Q dead), Wo -> kbuf shorts (K dead)
    unsigned short* ab16 = (unsigned short*)qbuf;
    unsigned short* wb16 = (unsigned short*)kbuf;
    cast(obuf, ab16, M_ * 512);
    cast(Wo_i, wb16, 512 * 512);
    run_bgemm<2, 1>(ab16, wb16, bo + i * 512, xbuf, nullptr, nullptr, ebuf,
                    nullptr, M_, 512, 512, 0.f, stream);
    // ln1 dual-writes x fp32 + bf16 (FF1 A input) -> qbuf shorts
    ln_dual_kernel<<<M_, 256, 0, stream>>>(ebuf, ln1_g + i * 512,
                                           ln1_b + i * 512, xbuf, ab16);

    // FF1: bf16-only output (consumed solely as FF2's A) -> obuf shorts
    unsigned short* ff1b16 = (unsigned short*)obuf;
    cast(w1_i, wb16, 512 * 512);
    run_bgemm<1, 2>(ab16, wb16, ff_b1 + i * 512, nullptr, nullptr, nullptr,
                    nullptr, ff1b16, M_, 512, 512, 0.f, stream);
    // FF2 (+residual) -> ebuf fp32
    cast(w2_i, wb16, 512 * 512);
    run_bgemm<2, 1>(ff1b16, wb16, ff_b2 + i * 512, xbuf, nullptr, nullptr,
                    ebuf, nullptr, M_, 512, 512, 0.f, stream);
    ln_kernel<<<M_, 256, 0, stream>>>(ebuf, ln2_g + i * 512, ln2_b + i * 512, xbuf);

    if (i < EL - 1) {
      // conv distill: im2col -> qbuf(+kbuf) shorts, weights -> vbuf shorts
      unsigned short* imb16 = (unsigned short*)qbuf;
      unsigned short* wb16c = (unsigned short*)vbuf;
      im2col_kernel<<<ceil_div(B * L * 1536, 256), 256, 0, stream>>>(xbuf, imb16, B, L);
      cast(cv_w + (size_t)i * 512 * 1536, wb16c, 512 * 1536);
      run_bgemm<3, 1>(imb16, wb16c, cv_b + i * 512, nullptr, bn_g + i * 512,
                      bn_b + i * 512, ebuf, nullptr, M_, 512, 1536, inv_s,
                      stream);
      // maxpool dual-writes next-layer x fp32 + bf16 @ vbuf tail (V dead;
      // next layer's V-proj writes only vbuf[0, M_/2*512*4B) -- no overlap)
      xb16 = (unsigned short*)vbuf + 6291456;  // byte offset 12.6MB
      maxpool_kernel<<<ceil_div(B * (L / 2) * D_MODEL, 256), 256, 0, stream>>>(
          ebuf, xbuf, xb16, B, L);
      L /= 2;
    }
  }

  ln_kernel<<<B * L, 256, 0, stream>>>(xbuf, norm_g, norm_b, (float*)d_out);
}

// Round 13
// 970.381 us; speedup vs baseline: 3.3409x; 1.0309x over previous
//
#include <hip/hip_runtime.h>
#include <cmath>
#include <cstdint>

#define D_MODEL 512
#define NH 8
#define DH 64

static inline int ceil_div(int a, int b) { return (a + b - 1) / b; }

typedef __attribute__((ext_vector_type(8))) short short8;
typedef __attribute__((ext_vector_type(4))) float floatx4;

// fp32 -> bf16 (RNE)
__device__ __forceinline__ unsigned short f2bf(float f) {
  uint32_t u = __float_as_uint(f);
  uint32_t r = (u + 0x7fffu + ((u >> 16) & 1u)) >> 16;
  return (unsigned short)r;
}
__device__ __forceinline__ float bf2f(unsigned short s) {
  return __uint_as_float(((uint32_t)s) << 16);
}

// ---------------- threefry2x32 (JAX-exact) ----------------
#define TF_ROTL(x, r) (((x) << (r)) | ((x) >> (32 - (r))))

__host__ __device__ inline void threefry2x32(uint32_t k0, uint32_t k1,
                                             uint32_t x0, uint32_t x1,
                                             uint32_t* o0, uint32_t* o1) {
  uint32_t ks2 = k0 ^ k1 ^ 0x1BD11BDAu;
  x0 += k0; x1 += k1;
#define TF_R4(a, b, c, d)                                    \
  x0 += x1; x1 = TF_ROTL(x1, a); x1 ^= x0;                   \
  x0 += x1; x1 = TF_ROTL(x1, b); x1 ^= x0;                   \
  x0 += x1; x1 = TF_ROTL(x1, c); x1 ^= x0;                   \
  x0 += x1; x1 = TF_ROTL(x1, d); x1 ^= x0;
  TF_R4(13, 15, 26, 6);  x0 += k1;  x1 += ks2 + 1u;
  TF_R4(17, 29, 16, 24); x0 += ks2; x1 += k0 + 2u;
  TF_R4(13, 15, 26, 6);  x0 += k0;  x1 += k1 + 3u;
  TF_R4(17, 29, 16, 24); x0 += k1;  x1 += ks2 + 4u;
  TF_R4(13, 15, 26, 6);  x0 += ks2; x1 += k0 + 5u;
#undef TF_R4
  *o0 = x0; *o1 = x1;
}

__global__ void idx_kernel(int* __restrict__ idx, int L, int U,
                           uint32_t k0, uint32_t k1) {
  int n = blockIdx.x * 256 + threadIdx.x;
  if (n >= L * U) return;
  uint32_t o0, o1;
  threefry2x32(k0, k1, 0u, (uint32_t)n, &o0, &o1);
  idx[n] = (int)((o0 ^ o1) & (uint32_t)(L - 1));
}

// ---------------- fp32 -> bf16 cast, 4 elems/thread ----------------
__global__ __launch_bounds__(256) void cast_bf16_kernel(
    const float* __restrict__ src, unsigned short* __restrict__ dst, int n) {
  int i = (blockIdx.x * 256 + threadIdx.x) * 4;
  if (i >= n) return;
  float4 v = *(const float4*)(src + i);
  ushort4 o;
  o.x = f2bf(v.x); o.y = f2bf(v.y); o.z = f2bf(v.z); o.w = f2bf(v.w);
  *(ushort4*)(dst + i) = o;
}

// ---------------- embedding + pos encoding, dual fp32/bf16 out ------------
__global__ __launch_bounds__(256) void embed_kernel(
    const float* __restrict__ x_enc, const float* __restrict__ emb_w,
    float* __restrict__ x, unsigned short* __restrict__ xb, int B, int L) {
  int i = blockIdx.x * 256 + threadIdx.x;
  int total = B * L * D_MODEL;
  if (i >= total) return;
  int d = i % D_MODEL;
  int l = (i / D_MODEL) % L;
  int b = i / (D_MODEL * L);
  int lm = (l == 0) ? (L - 1) : (l - 1);
  int lp = (l == L - 1) ? 0 : (l + 1);
  const float* w = emb_w + d * 6;
  const float* xb_in = x_enc + (size_t)b * L * 2;
  float acc = 0.f;
  acc += xb_in[lm * 2 + 0] * w[0] + xb_in[l * 2 + 0] * w[1] + xb_in[lp * 2 + 0] * w[2];
  acc += xb_in[lm * 2 + 1] * w[3] + xb_in[l * 2 + 1] * w[4] + xb_in[lp * 2 + 1] * w[5];
  int j = d >> 1;
  const float coef = -0.017988946039015985f;  // -ln(10000)/512
  float div = expf((float)(2 * j) * coef);
  float ang = (float)l * div;
  float pe = (d & 1) ? cosf(ang) : sinf(ang);
  float v = acc + pe;
  x[i] = v;
  xb[i] = f2bf(v);
}

// ---------------- layer norm over D=512 (plain + dual-output) -------------
__global__ __launch_bounds__(256) void ln_kernel(
    const float* __restrict__ in, const float* __restrict__ g,
    const float* __restrict__ b, float* __restrict__ out) {
  int row = blockIdx.x;
  int t = threadIdx.x;
  const float* xr = in + (size_t)row * D_MODEL;
  float v0 = xr[t], v1 = xr[t + 256];
  __shared__ float red[256];
  red[t] = v0 + v1;
  __syncthreads();
  for (int s = 128; s > 0; s >>= 1) { if (t < s) red[t] += red[t + s]; __syncthreads(); }
  float mean = red[0] * (1.0f / 512.0f);
  __syncthreads();
  float d0 = v0 - mean, d1 = v1 - mean;
  red[t] = d0 * d0 + d1 * d1;
  __syncthreads();
  for (int s = 128; s > 0; s >>= 1) { if (t < s) red[t] += red[t + s]; __syncthreads(); }
  float var = red[0] * (1.0f / 512.0f);
  float rstd = 1.0f / sqrtf(var + 1e-5f);
  float* outr = out + (size_t)row * D_MODEL;
  outr[t]       = d0 * rstd * g[t]       + b[t];
  outr[t + 256] = d1 * rstd * g[t + 256] + b[t + 256];
}

__global__ __launch_bounds__(256) void ln_dual_kernel(
    const float* __restrict__ in, const float* __restrict__ g,
    const float* __restrict__ b, float* __restrict__ out,
    unsigned short* __restrict__ out16) {
  int row = blockIdx.x;
  int t = threadIdx.x;
  const float* xr = in + (size_t)row * D_MODEL;
  float v0 = xr[t], v1 = xr[t + 256];
  __shared__ float red[256];
  red[t] = v0 + v1;
  __syncthreads();
  for (int s = 128; s > 0; s >>= 1) { if (t < s) red[t] += red[t + s]; __syncthreads(); }
  float mean = red[0] * (1.0f / 512.0f);
  __syncthreads();
  float d0 = v0 - mean, d1 = v1 - mean;
  red[t] = d0 * d0 + d1 * d1;
  __syncthreads();
  for (int s = 128; s > 0; s >>= 1) { if (t < s) red[t] += red[t + s]; __syncthreads(); }
  float var = red[0] * (1.0f / 512.0f);
  float rstd = 1.0f / sqrtf(var + 1e-5f);
  float* outr = out + (size_t)row * D_MODEL;
  unsigned short* o16 = out16 + (size_t)row * D_MODEL;
  float r0 = d0 * rstd * g[t] + b[t];
  float r1 = d1 * rstd * g[t + 256] + b[t + 256];
  outr[t] = r0;       o16[t] = f2bf(r0);
  outr[t + 256] = r1; o16[t + 256] = f2bf(r1);
}

// MODE 0: +bias   1: gelu(+bias)   2: +bias +R   3: elu((+bias)*scl*g + bb)
__device__ __forceinline__ float epilogue_apply(int MODE, float v, float r,
                                                float g, float bb, float scl) {
  if (MODE == 1) {
    v = 0.5f * v * (1.0f + erff(v * 0.7071067811865475f));
  } else if (MODE == 2) {
    v += r;
  } else if (MODE == 3) {
    v = v * scl * g + bb;
    v = (v > 0.f) ? v : expm1f(v);
  }
  return v;
}

// ---------------- bf16 MFMA GEMM 64x64, BK=32, 4 waves (32x32 each) -------
// OUT bitmask: 1 = fp32 C, 2 = bf16 C16 (dead branches fold at compile time)
template <int MODE, int OUT>
__global__ __launch_bounds__(256) void bgemm_kernel(
    const unsigned short* __restrict__ A, const unsigned short* __restrict__ Bt,
    const float* __restrict__ bias, const float* __restrict__ R,
    const float* __restrict__ gvec, const float* __restrict__ bvec,
    float* __restrict__ C, unsigned short* __restrict__ C16,
    int M, int N, int K, float scl) {
  __shared__ unsigned short Al[64][40];
  __shared__ unsigned short Bl[64][40];
  const int bm = blockIdx.y * 64, bn = blockIdx.x * 64;
  const int tid = threadIdx.x;
  const int wave = tid >> 6, lane = tid & 63;
  const int wm = (wave >> 1) * 32, wn = (wave & 1) * 32;
  const int quad = lane >> 4, l16 = lane & 15;
  const int sr = tid >> 2;
  const int sc = (tid & 3) * 8;
  const unsigned short* Ag = A + (size_t)(bm + sr) * K + sc;
  const unsigned short* Bg = Bt + (size_t)(bn + sr) * K + sc;
  floatx4 zero = {0.f, 0.f, 0.f, 0.f};
  floatx4 acc00 = zero, acc01 = zero, acc10 = zero, acc11 = zero;
  for (int k0 = 0; k0 < K; k0 += 32) {
    short8 a8 = *(const short8*)(Ag + k0);
    short8 b8 = *(const short8*)(Bg + k0);
    *(short8*)&Al[sr][sc] = a8;
    *(short8*)&Bl[sr][sc] = b8;
    __syncthreads();
    short8 af0 = *(const short8*)&Al[wm + l16][quad * 8];
    short8 af1 = *(const short8*)&Al[wm + 16 + l16][quad * 8];
    short8 bf0 = *(const short8*)&Bl[wn + l16][quad * 8];
    short8 bf1 = *(const short8*)&Bl[wn + 16 + l16][quad * 8];
    acc00 = __builtin_amdgcn_mfma_f32_16x16x32_bf16(af0, bf0, acc00, 0, 0, 0);
    acc01 = __builtin_amdgcn_mfma_f32_16x16x32_bf16(af0, bf1, acc01, 0, 0, 0);
    acc10 = __builtin_amdgcn_mfma_f32_16x16x32_bf16(af1, bf0, acc10, 0, 0, 0);
    acc11 = __builtin_amdgcn_mfma_f32_16x16x32_bf16(af1, bf1, acc11, 0, 0, 0);
    __syncthreads();
  }
  floatx4 accs[2][2] = {{acc00, acc01}, {acc10, acc11}};
#pragma unroll
  for (int i = 0; i < 2; ++i) {
#pragma unroll
    for (int j = 0; j < 2; ++j) {
      int col = bn + wn + j * 16 + l16;
#pragma unroll
      for (int p = 0; p < 4; ++p) {
        int row = bm + wm + i * 16 + quad * 4 + p;
        float v = accs[i][j][p] + bias[col];
        v = epilogue_apply(MODE, v, (MODE == 2) ? R[(size_t)row * N + col] : 0.f,
                           (MODE == 3) ? gvec[col] : 0.f,
                           (MODE == 3) ? bvec[col] : 0.f, scl);
        if (OUT & 1) C[(size_t)row * N + col] = v;
        if (OUT & 2) C16[(size_t)row * N + col] = f2bf(v);
      }
    }
  }
}

template <int MODE, int OUT>
static void run_bgemm(const unsigned short* A, const unsigned short* Bt,
                      const float* bias, const float* R, const float* g,
                      const float* bb, float* C, unsigned short* C16,
                      int M, int N, int K, float scl, hipStream_t stream) {
  dim3 gg(N / 64, M / 64);
  bgemm_kernel<MODE, OUT><<<gg, 256, 0, stream>>>(A, Bt, bias, R, g, bb, C,
                                                  C16, M, N, K, scl);
}

// ---------------- sparse QK: one BLOCK per (b,l), bf16 K gathers ----------
__global__ __launch_bounds__(256) void sparse_qk_kernel(
    const float* __restrict__ Q, const unsigned short* __restrict__ K16,
    const int* __restrict__ idx, float* __restrict__ QKs, int B, int L,
    int U) {
  int bl = blockIdx.x;  // b*L + l
  int b = bl / L, l = bl - b * L;
  int tid = threadIdx.x;
  int wave = tid >> 6, lane = tid & 63;
  int h = lane >> 3;
  const float4* qr = (const float4*)(Q + (size_t)bl * D_MODEL + lane * 8);
  float4 q0 = qr[0], q1 = qr[1];
  float qv[8] = {q0.x, q0.y, q0.z, q0.w, q1.x, q1.y, q1.z, q1.w};
  const int* idxl = idx + l * U;
  for (int u = wave; u < U; u += 4) {
    int ki = idxl[u];
    short8 k8 = *(const short8*)(K16 + ((size_t)b * L + ki) * D_MODEL + lane * 8);
    float p = 0.f;
#pragma unroll
    for (int e = 0; e < 8; ++e) p += qv[e] * bf2f((unsigned short)k8[e]);
    p += __shfl_xor(p, 1);
    p += __shfl_xor(p, 2);
    p += __shfl_xor(p, 4);
    if ((lane & 7) == 0)
      QKs[(((size_t)(b * NH + h)) * L + l) * U + u] = p;
  }
}

// M[bh*L+l] = max_u(QKs) - sum_u(QKs)/L ; one wave per query, ONE butterfly
__global__ __launch_bounds__(256) void sparse_reduce_kernel(
    const float* __restrict__ QKs, float* __restrict__ Mout, int total,
    int L, int U) {
  int wid = (blockIdx.x * 256 + threadIdx.x) >> 6;
  int lane = threadIdx.x & 63;
  if (wid >= total) return;
  float v = (lane < U) ? QKs[(size_t)wid * U + lane] : -INFINITY;
  float m = v;
#pragma unroll
  for (int k = 32; k; k >>= 1) m = fmaxf(m, __shfl_xor(m, k));
  float sv = (lane < U) ? v : 0.f;
#pragma unroll
  for (int k = 32; k; k >>= 1) sv += __shfl_xor(sv, k);
  if (lane == 0) Mout[wid] = m - sv / (float)L;
}

// ---------------- top-k: barrier-free per-wave selection + rank merge -----
// R12's version: 40 iters x (2 syncthreads + thread0 serial merge + LDS
// broadcast) at 1 block/CU = ~2900 cyc/iter (52.8us). Now: each wave
// selects top-u of its L/4 slice entirely in registers + wave butterfly
// (winner lands in ALL lanes -> no broadcast, no barriers). ONE barrier,
// then rank-merge of the 4 sorted lists: thread t's candidate rank = own
// pos + 3 binary searches (6 LDS probes each); ranks unique under the
// (v desc, idx asc) total order -> direct scatter (= JAX sorted order).
template <int NE>  // NE = L/256 elems per lane
__global__ __launch_bounds__(256) void topk_kernel(
    const float* __restrict__ Mv, int* __restrict__ Mtop, int u) {
  int bh = blockIdx.x;
  int t = threadIdx.x;
  int wave = t >> 6, lane = t & 63;
  const int base = wave * 64 * NE;
  float vals[NE];
  const float* src = Mv + (size_t)bh * (NE * 256);
#pragma unroll
  for (int i = 0; i < NE; ++i) vals[i] = src[base + i * 64 + lane];
  __shared__ float cv[4][40];
  __shared__ int ci[4][40];
  for (int it = 0; it < u; ++it) {
    float bv = -INFINITY;
    int bi = 0x7fffffff;
#pragma unroll
    for (int i = 0; i < NE; ++i) {
      float v = vals[i];
      int ix = base + i * 64 + lane;
      if (v > bv || (v == bv && ix < bi)) { bv = v; bi = ix; }
    }
#pragma unroll
    for (int k = 32; k; k >>= 1) {
      float ov = __shfl_xor(bv, k);
      int oi = __shfl_xor(bi, k);
      if (ov > bv || (ov == bv && oi < bi)) { bv = ov; bi = oi; }
    }
    if (lane == 0) { cv[wave][it] = bv; ci[wave][it] = bi; }
#pragma unroll
    for (int i = 0; i < NE; ++i)
      if (bi == base + i * 64 + lane) vals[i] = -INFINITY;
  }
  __syncthreads();
  if (t < 4 * u) {
    int w = t / u, p = t - w * u;
    float mv = cv[w][p];
    int mi = ci[w][p];
    int rank = p;
    for (int w2 = 0; w2 < 4; ++w2) {
      if (w2 == w) continue;
      int lo = 0, hi = u;
      while (lo < hi) {
        int mid = (lo + hi) >> 1;
        float v2 = cv[w2][mid];
        int i2 = ci[w2][mid];
        if (v2 > mv || (v2 == mv && i2 < mi)) lo = mid + 1;
        else hi = mid;
      }
      rank += lo;
    }
    if (rank < u) Mtop[bh * u + rank] = mi;
  }
}

static void run_topk(const float* Mv, int* Mtop, int L, int u,
                     hipStream_t stream) {
  if (L == 2048)      topk_kernel<8><<<32, 256, 0, stream>>>(Mv, Mtop, u);
  else if (L == 1024) topk_kernel<4><<<32, 256, 0, stream>>>(Mv, Mtop, u);
  else                topk_kernel<2><<<32, 256, 0, stream>>>(Mv, Mtop, u);
}

// ---------------- mean of V over L: split-L partial + atomic --------------
__global__ void vmean_zero_kernel(float* __restrict__ vmean) {
  vmean[blockIdx.x * 256 + threadIdx.x] = 0.f;
}

__global__ __launch_bounds__(256) void vmean_partial_kernel(
    const float* __restrict__ V, float* __restrict__ vmean, int L) {
  int b = blockIdx.y;
  int chunk = blockIdx.x;           // 64 chunks
  int rows = L >> 6;
  int t = threadIdx.x;
  const float* base = V + ((size_t)b * L + (size_t)chunk * rows) * D_MODEL;
  float s0 = 0.f, s1 = 0.f;
  for (int r = 0; r < rows; ++r) {
    s0 += base[(size_t)r * D_MODEL + t];
    s1 += base[(size_t)r * D_MODEL + t + 256];
  }
  float invL = 1.0f / (float)L;
  atomicAdd(&vmean[b * D_MODEL + t], s0 * invL);
  atomicAdd(&vmean[b * D_MODEL + t + 256], s1 * invL);
}

__global__ void fill_ctx_kernel(const float* __restrict__ vmean,
                                float* __restrict__ O, int B, int L) {
  int i = blockIdx.x * 256 + threadIdx.x;
  int total = B * L * D_MODEL;
  if (i >= total) return;
  int dcol = i % D_MODEL;
  int b = i / (D_MODEL * L);
  O[i] = vmean[b * D_MODEL + dcol];
}

// ============== attention as batched GEMM pipeline ==============
__global__ void pack_qred_kernel(const float* __restrict__ Q,
                                 const int* __restrict__ Mtop,
                                 float* __restrict__ qred, int L, int U) {
  int z = blockIdx.x;  // bh
  int b = z / NH, h = z % NH;
  int t = threadIdx.x;
  int d = t & 63;
  for (int r = t >> 6; r < 64; r += 4) {
    float v = 0.f;
    if (r < U) {
      int l = Mtop[z * U + r];
      v = Q[((size_t)(b * L + l)) * D_MODEL + h * DH + d];
    }
    qred[((size_t)z * 64 + r) * 64 + d] = v;
  }
}

#define BK 16
#define PADR 4

// S[z][64][L] = 0.125 * Qred[z](64x64) @ K_z^T ; K_z rows stride 512
__global__ __launch_bounds__(256) void scores_gemm_kernel(
    const float* __restrict__ qred, const float* __restrict__ Km,
    float* __restrict__ S, int L) {
  __shared__ float As[BK][64 + PADR];
  __shared__ float Bs[BK][64 + PADR];
  const int z = blockIdx.y;
  const int b = z / NH, h = z % NH;
  const float* A = qred + (size_t)z * 64 * 64;
  const float* Bt = Km + (size_t)b * L * D_MODEL + h * DH;  // ldb = 512
  float* Sz = S + (size_t)z * 64 * L;
  const int bn = blockIdx.x * 64;
  const int tid = threadIdx.x;
  const int tx = tid & 15, ty = tid >> 4;
  const int lr = tid >> 2;
  const int lc = (tid & 3) << 2;
  float acc[4][4] = {};
  for (int k0 = 0; k0 < 64; k0 += BK) {
    float4 av = *(const float4*)(A + (size_t)lr * 64 + k0 + lc);
    float4 bv = *(const float4*)(Bt + (size_t)(bn + lr) * D_MODEL + k0 + lc);
    As[lc + 0][lr] = av.x; As[lc + 1][lr] = av.y;
    As[lc + 2][lr] = av.z; As[lc + 3][lr] = av.w;
    Bs[lc + 0][lr] = bv.x; Bs[lc + 1][lr] = bv.y;
    Bs[lc + 2][lr] = bv.z; Bs[lc + 3][lr] = bv.w;
    __syncthreads();
#pragma unroll
    for (int kk = 0; kk < BK; ++kk) {
      float4 a4 = *(const float4*)&As[kk][ty << 2];
      float4 b4 = *(const float4*)&Bs[kk][tx << 2];
      float ar[4] = {a4.x, a4.y, a4.z, a4.w};
      float br[4] = {b4.x, b4.y, b4.z, b4.w};
#pragma unroll
      for (int i = 0; i < 4; ++i)
#pragma unroll
        for (int j = 0; j < 4; ++j) acc[i][j] += ar[i] * br[j];
    }
    __syncthreads();
  }
#pragma unroll
  for (int i = 0; i < 4; ++i) {
    float* Sr = Sz + (size_t)((ty << 2) + i) * L + bn;
#pragma unroll
    for (int j = 0; j < 4; ++j) Sr[(tx << 2) + j] = 0.125f * acc[i][j];
  }
}

// ---------------- softmax: one block per (z,row) ----------------
template <int LC>
__global__ __launch_bounds__(256) void softmax_kernel(float* __restrict__ S,
                                                      int U) {
  constexpr int NE = LC / 256;
  int rid = blockIdx.x;
  int z = rid / U, r = rid % U;
  float* row = S + (size_t)z * 64 * LC + (size_t)r * LC;
  int t = threadIdx.x;
  float vals[NE];
  float m = -INFINITY;
#pragma unroll
  for (int i = 0; i < NE; ++i) {
    vals[i] = row[t + i * 256];
    m = fmaxf(m, vals[i]);
  }
  __shared__ float red[256];
  red[t] = m;
  __syncthreads();
  for (int s = 128; s > 0; s >>= 1) { if (t < s) red[t] = fmaxf(red[t], red[t + s]); __syncthreads(); }
  m = red[0];
  __syncthreads();
  float sum = 0.f;
#pragma unroll
  for (int i = 0; i < NE; ++i) {
    vals[i] = expf(vals[i] - m);
    sum += vals[i];
  }
  red[t] = sum;
  __syncthreads();
  for (int s = 128; s > 0; s >>= 1) { if (t < s) red[t] += red[t + s]; __syncthreads(); }
  float inv = 1.0f / red[0];
#pragma unroll
  for (int i = 0; i < NE; ++i) row[t + i * 256] = vals[i] * inv;
}

static void run_softmax(float* S, int L, int U, hipStream_t stream) {
  int blocks = 32 * U;
  if (L == 2048)      softmax_kernel<2048><<<blocks, 256, 0, stream>>>(S, U);
  else if (L == 1024) softmax_kernel<1024><<<blocks, 256, 0, stream>>>(S, U);
  else                softmax_kernel<512><<<blocks, 256, 0, stream>>>(S, U);
}

// zero the selected ctx rows before split-K PV atomics
__global__ void zero_sel_kernel(const int* __restrict__ Mtop,
                                float* __restrict__ O, int L, int U) {
  int z = blockIdx.x;
  int b = z / NH, h = z % NH;
  int t = threadIdx.x;
  int d = t & 63;
  for (int r = t >> 6; r < U; r += 4) {
    int l = Mtop[z * U + r];
    O[((size_t)(b * L + l)) * D_MODEL + h * DH + d] = 0.f;
  }
}

// O[sel rows] += P(UxL) @ V(Lx64), split-K over 128-chunks of L.
#define PV_LC 128

template <int U>
__global__ __launch_bounds__(256) void pv_kernel(
    const float* __restrict__ P, const float* __restrict__ V,
    const int* __restrict__ Mtop, float* __restrict__ O, int L) {
  __shared__ float Pl[U][PV_LC];
  __shared__ float Vl[PV_LC][DH + 4];
  const int z = blockIdx.y;
  const int b = z / NH, h = z % NH;
  const int c0 = blockIdx.x * PV_LC;
  const int tid = threadIdx.x;
  const float* Pz = P + (size_t)z * 64 * L + c0;
  for (int i4 = tid; i4 < U * (PV_LC / 4); i4 += 256) {
    int r = i4 / (PV_LC / 4);
    int lq = (i4 % (PV_LC / 4)) * 4;
    float4 p4 = *(const float4*)(Pz + (size_t)r * L + lq);
    Pl[r][lq + 0] = p4.x; Pl[r][lq + 1] = p4.y;
    Pl[r][lq + 2] = p4.z; Pl[r][lq + 3] = p4.w;
  }
  const float* Vb = V + ((size_t)b * L + c0) * D_MODEL + h * DH;
  for (int i4 = tid; i4 < PV_LC * (DH / 4); i4 += 256) {
    int l = i4 >> 4;
    int d4 = (i4 & 15) * 4;
    float4 v4 = *(const float4*)(Vb + (size_t)l * D_MODEL + d4);
    Vl[l][d4 + 0] = v4.x; Vl[l][d4 + 1] = v4.y;
    Vl[l][d4 + 2] = v4.z; Vl[l][d4 + 3] = v4.w;
  }
  __syncthreads();
  const int wave = tid >> 6, lane = tid & 63;
  constexpr int NJ = (U + 3) / 4;
  float acc[NJ] = {};
  for (int l = 0; l < PV_LC; ++l) {
    float vv = Vl[l][lane];
#pragma unroll
    for (int j = 0; j < NJ; ++j) {
      int r = wave + 4 * j;
      if (r < U) acc[j] += Pl[r][l] * vv;
    }
  }
#pragma unroll
  for (int j = 0; j < NJ; ++j) {
    int r = wave + 4 * j;
    if (r < U) {
      int ml = Mtop[z * U + r];
      atomicAdd(&O[((size_t)(b * L + ml)) * D_MODEL + h * DH + lane], acc[j]);
    }
  }
}

static void run_pv(const float* P, const float* V, const int* Mtop, float* O,
                   int L, int U, hipStream_t stream) {
  dim3 gg(L / PV_LC, 32);
  if (U == 40)      pv_kernel<40><<<gg, 256, 0, stream>>>(P, V, Mtop, O, L);
  else if (U == 35) pv_kernel<35><<<gg, 256, 0, stream>>>(P, V, Mtop, O, L);
  else              pv_kernel<64><<<gg, 256, 0, stream>>>(P, V, Mtop, O, L);
}

// ---------------- im2col (circular, K=3) -> bf16 --------------------------
__global__ void im2col_kernel(const float* __restrict__ X,
                              unsigned short* __restrict__ Y, int B, int L) {
  int i = blockIdx.x * 256 + threadIdx.x;
  int total = B * L * 1536;
  if (i >= total) return;
  int ck = i % 1536;
  int l = (i / 1536) % L;
  int b = i / (1536 * L);
  int c = ck / 3, k = ck % 3;
  int lm = l + k - 1;
  if (lm < 0) lm += L;
  else if (lm >= L) lm -= L;
  Y[i] = f2bf(X[((size_t)(b * L + lm)) * D_MODEL + c]);
}

// ---------------- maxpool k=3 s=2, dual fp32/bf16 out ---------------------
__global__ void maxpool_kernel(const float* __restrict__ Y,
                               float* __restrict__ X,
                               unsigned short* __restrict__ Xb, int B, int L) {
  int Lo = L / 2;
  int i = blockIdx.x * 256 + threadIdx.x;
  int total = B * Lo * D_MODEL;
  if (i >= total) return;
  int d = i % D_MODEL;
  int lp = (i / D_MODEL) % Lo;
  int b = i / (D_MODEL * Lo);
  int l0 = 2 * lp - 1;
  float m = -INFINITY;
#pragma unroll
  for (int k = 0; k < 3; ++k) {
    int l = l0 + k;
    if (l >= 0 && l < L) m = fmaxf(m, Y[((size_t)(b * L + l)) * D_MODEL + d]);
  }
  X[i] = m;
  Xb[i] = f2bf(m);
}

// ==========================================================================
extern "C" void kernel_launch(void* const* d_in, const int* in_sizes, int n_in,
                              void* d_out, int out_size, void* d_ws,
                              size_t ws_size, hipStream_t stream) {
  const float* x_enc  = (const float*)d_in[0];
  const float* emb_w  = (const float*)d_in[1];
  const float* Wq     = (const float*)d_in[2];
  const float* bq     = (const float*)d_in[3];
  const float* Wk     = (const float*)d_in[4];
  const float* bk     = (const float*)d_in[5];
  const float* Wv     = (const float*)d_in[6];
  const float* bv     = (const float*)d_in[7];
  const float* Wo     = (const float*)d_in[8];
  const float* bo     = (const float*)d_in[9];
  const float* ln1_g  = (const float*)d_in[10];
  const float* ln1_b  = (const float*)d_in[11];
  const float* ff_w1  = (const float*)d_in[12];
  const float* ff_b1  = (const float*)d_in[13];
  const float* ff_w2  = (const float*)d_in[14];
  const float* ff_b2  = (const float*)d_in[15];
  const float* ln2_g  = (const float*)d_in[16];
  const float* ln2_b  = (const float*)d_in[17];
  const float* cv_w   = (const float*)d_in[18];
  const float* cv_b   = (const float*)d_in[19];
  const float* bn_g   = (const float*)d_in[20];
  const float* bn_b   = (const float*)d_in[21];
  const float* norm_g = (const float*)d_in[22];
  const float* norm_b = (const float*)d_in[23];

  const int B = 4, L0 = 2048, EL = 3;
  const size_t SZ = (size_t)B * 2048 * 512;
  float* ws   = (float*)d_ws;
  float* xbuf = ws;
  float* ebuf = ws + SZ;   // layer0 xb16; pre-LN temp; QKs; Sbuf
  float* qbuf = ws + 2 * SZ;
  float* kbuf = ws + 3 * SZ;
  float* vbuf = ws + 4 * SZ;
  float* obuf = ws + 5 * SZ;
  float* sm   = ws + 6 * SZ;
  int*   d_idx   = (int*)sm;
  float* d_M     = sm + 81920;
  int*   d_Mtop  = (int*)(sm + 81920 + 65536);
  float* d_vmean = sm + 81920 + 65536 + 1280;
  float* qred    = sm;    // reuses idx+M region (dead post-topk)
  float* QKs     = ebuf;
  float* Sbuf    = ebuf;

  const float inv_s = 1.0f / sqrtf(1.0f + 1e-5f);
  auto cast = [&](const float* s, unsigned short* d, int n) {
    cast_bf16_kernel<<<ceil_div(n / 4, 256), 256, 0, stream>>>(s, d, n);
  };

  // layer-0 x bf16 fused into embed (-> ebuf)
  embed_kernel<<<ceil_div(B * L0 * D_MODEL, 256), 256, 0, stream>>>(
      x_enc, emb_w, xbuf, (unsigned short*)ebuf, B, L0);
  unsigned short* xb16 = (unsigned short*)ebuf;  // current layer's bf16 x

  int L = L0;
  for (int i = 0; i < EL; ++i) {
    const int M_ = B * L;
    int c = 5 * (int)ceil(log((double)L));
    int U = c < L ? c : L;
    const float* Wq_i = Wq + (size_t)i * 512 * 512;
    const float* Wk_i = Wk + (size_t)i * 512 * 512;
    const float* Wv_i = Wv + (size_t)i * 512 * 512;
    const float* Wo_i = Wo + (size_t)i * 512 * 512;
    const float* w1_i = ff_w1 + (size_t)i * 512 * 512;
    const float* w2_i = ff_w2 + (size_t)i * 512 * 512;

    // QKV bf16 MFMA. K dual-writes fp32 kbuf (scores) + bf16 k16 (gathers).
    unsigned short* wq16 = (unsigned short*)obuf;
    unsigned short* wk16 = wq16 + 262144;
    unsigned short* wv16 = wq16 + 524288;
    unsigned short* k16  = wq16 + 1048576;  // obuf bytes [2MB, 2MB+M_*1KB)
    {
      cast(Wq_i, wq16, 512 * 512);
      cast(Wk_i, wk16, 512 * 512);
      cast(Wv_i, wv16, 512 * 512);
      run_bgemm<0, 1>(xb16, wq16, bq + i * 512, nullptr, nullptr, nullptr,
                      qbuf, nullptr, M_, 512, 512, 0.f, stream);
      run_bgemm<0, 3>(xb16, wk16, bk + i * 512, nullptr, nullptr, nullptr,
                      kbuf, k16, M_, 512, 512, 0.f, stream);
      run_bgemm<0, 1>(xb16, wv16, bv + i * 512, nullptr, nullptr, nullptr,
                      vbuf, nullptr, M_, 512, 512, 0.f, stream);
    }

    uint32_t lk0, lk1, k20, k21;
    threefry2x32(0u, 42u, 0u, (uint32_t)i, &lk0, &lk1);
    threefry2x32(lk0, lk1, 0u, 1u, &k20, &k21);
    idx_kernel<<<ceil_div(L * U, 256), 256, 0, stream>>>(d_idx, L, U, k20, k21);

    sparse_qk_kernel<<<B * L, 256, 0, stream>>>(qbuf, k16, d_idx, QKs, B, L, U);
    sparse_reduce_kernel<<<ceil_div(B * NH * L * 64, 256), 256, 0, stream>>>(
        QKs, d_M, B * NH * L, L, U);
    run_topk(d_M, d_Mtop, L, U, stream);
    vmean_zero_kernel<<<8, 256, 0, stream>>>(d_vmean);
    vmean_partial_kernel<<<dim3(64, B), 256, 0, stream>>>(vbuf, d_vmean, L);
    fill_ctx_kernel<<<ceil_div(B * L * D_MODEL, 256), 256, 0, stream>>>(
        d_vmean, obuf, B, L);

    pack_qred_kernel<<<B * NH, 256, 0, stream>>>(qbuf, d_Mtop, qred, L, U);
    scores_gemm_kernel<<<dim3(L / 64, B * NH), 256, 0, stream>>>(qred, kbuf,
                                                                 Sbuf, L);
    run_softmax(Sbuf, L, U, stream);
    zero_sel_kernel<<<B * NH, 256, 0, stream>>>(d_Mtop, obuf, L, U);
    run_pv(Sbuf, vbuf, d_Mtop, obuf, L, U, stream);

    // O-proj: ctx cast -> qbuf shorts (Q dead), Wo -> kbuf shorts (K dead)
    unsigned short* ab16 = (unsigned short*)qbuf;
    unsigned short* wb16 = (unsigned short*)kbuf;
    cast(obuf, ab16, M_ * 512);
    cast(Wo_i, wb16, 512 * 512);
    run_bgemm<2, 1>(ab16, wb16, bo + i * 512, xbuf, nullptr, nullptr, ebuf,
                    nullptr, M_, 512, 512, 0.f, stream);
    // ln1 dual-writes x fp32 + bf16 (FF1 A input) -> qbuf shorts
    ln_dual_kernel<<<M_, 256, 0, stream>>>(ebuf, ln1_g + i * 512,
                                           ln1_b + i * 512, xbuf, ab16);

    // FF1: bf16-only output (consumed solely as FF2's A) -> obuf shorts
    unsigned short* ff1b16 = (unsigned short*)obuf;
    cast(w1_i, wb16, 512 * 512);
    run_bgemm<1, 2>(ab16, wb16, ff_b1 + i * 512, nullptr, nullptr, nullptr,
                    nullptr, ff1b16, M_, 512, 512, 0.f, stream);
    // FF2 (+residual) -> ebuf fp32
    cast(w2_i, wb16, 512 * 512);
    run_bgemm<2, 1>(ff1b16, wb16, ff_b2 + i * 512, xbuf, nullptr, nullptr,
                    ebuf, nullptr, M_, 512, 512, 0.f, stream);
    ln_kernel<<<M_, 256, 0, stream>>>(ebuf, ln2_g + i * 512, ln2_b + i * 512, xbuf);

    if (i < EL - 1) {
      // conv distill: im2col -> qbuf(+kbuf) shorts, weights -> vbuf shorts
      unsigned short* imb16 = (unsigned short*)qbuf;
      unsigned short* wb16c = (unsigned short*)vbuf;
      im2col_kernel<<<ceil_div(B * L * 1536, 256), 256, 0, stream>>>(xbuf, imb16, B, L);
      cast(cv_w + (size_t)i * 512 * 1536, wb16c, 512 * 1536);
      run_bgemm<3, 1>(imb16, wb16c, cv_b + i * 512, nullptr, bn_g + i * 512,
                      bn_b + i * 512, ebuf, nullptr, M_, 512, 1536, inv_s,
                      stream);
      // maxpool dual-writes next-layer x fp32 + bf16 @ vbuf tail (V dead;
      // next layer's V-proj writes only vbuf[0, M_/2*512*4B) -- no overlap)
      xb16 = (unsigned short*)vbuf + 6291456;  // byte offset 12.6MB
      maxpool_kernel<<<ceil_div(B * (L / 2) * D_MODEL, 256), 256, 0, stream>>>(
          ebuf, xbuf, xb16, B, L);
      L /= 2;
    }
  }

  ln_kernel<<<B * L, 256, 0, stream>>>(xbuf, norm_g, norm_b, (float*)d_out);
}